// Round 1
// 469.469 us; speedup vs baseline: 1.0532x; 1.0532x over previous
//
#include <hip/hip_runtime.h>

#define NFULL 8192
#define BATCH 4

typedef unsigned long long u64;
typedef unsigned int u32;
typedef __attribute__((ext_vector_type(8))) short bf8_t;   // 8 bf16 (4 VGPRs)
typedef __attribute__((ext_vector_type(4))) float f4_t;    // MFMA C/D

__device__ __forceinline__ u32 fbias(float f) {
  u32 u = __float_as_uint(f);
  return (u & 0x80000000u) ? ~u : (u | 0x80000000u);
}
__device__ __forceinline__ float funbias(u32 b) {
  u32 u = (b & 0x80000000u) ? (b & 0x7fffffffu) : ~b;
  return __uint_as_float(u);
}
__device__ __forceinline__ short f2bf(float f) {
  u32 u = __float_as_uint(f);
  u32 r = u + 0x7FFFu + ((u >> 16) & 1u);
  return (short)(r >> 16);
}

// ------------------------------------------------ fused grid build (both) --
__global__ __launch_bounds__(256) void build_grids_kernel(
    const float* __restrict__ pos, float4* __restrict__ sortedA,
    int* __restrict__ csA, float4* __restrict__ sortedB, int* __restrict__ csB) {
  __shared__ int cnt[4096];
  __shared__ int partial[256];
  int which = blockIdx.y, b = blockIdx.x, t = threadIdx.x;
  int NREF = which ? 2048 : 8192;
  int GR = which ? 8 : 16;
  int NC = GR * GR * GR;
  float4* sorted = (which ? sortedB : sortedA) + (size_t)b * NREF;
  int* cs = (which ? csB : csA) + b * (which ? 513 : 4097);
  const float* pb = pos + (size_t)b * NFULL * 3;
  for (int c = t; c < NC; c += 256) cnt[c] = 0;
  __syncthreads();
  for (int p = t; p < NREF; p += 256) {
    float x = pb[p * 3 + 0], y = pb[p * 3 + 1], z = pb[p * 3 + 2];
    int cx = min(max((int)(x * GR), 0), GR - 1);
    int cy = min(max((int)(y * GR), 0), GR - 1);
    int cz = min(max((int)(z * GR), 0), GR - 1);
    atomicAdd(&cnt[(cz * GR + cy) * GR + cx], 1);
  }
  __syncthreads();
  int chunk = (NC + 255) / 256;
  int s = 0;
  for (int i = 0; i < chunk; ++i) {
    int c = t * chunk + i;
    if (c < NC) s += cnt[c];
  }
  partial[t] = s;
  __syncthreads();
  if (t == 0) {
    int run = 0;
    for (int i = 0; i < 256; ++i) { int v = partial[i]; partial[i] = run; run += v; }
  }
  __syncthreads();
  int run = partial[t];
  for (int i = 0; i < chunk; ++i) {
    int c = t * chunk + i;
    if (c < NC) { int v = cnt[c]; cnt[c] = run; run += v; }
  }
  __syncthreads();
  for (int c = t; c < NC; c += 256) cs[c] = cnt[c];
  if (t == 0) cs[NC] = NREF;
  __syncthreads();
  for (int p = t; p < NREF; p += 256) {
    float x = pb[p * 3 + 0], y = pb[p * 3 + 1], z = pb[p * 3 + 2];
    int cx = min(max((int)(x * GR), 0), GR - 1);
    int cy = min(max((int)(y * GR), 0), GR - 1);
    int cz = min(max((int)(z * GR), 0), GR - 1);
    int slot = atomicAdd(&cnt[(cz * GR + cy) * GR + cx], 1);
    sorted[slot] = make_float4(x, y, z, __uint_as_float((u32)p));
  }
}

// --------------------------------------------------- grouped insert core ---
template<int SL>
__device__ __forceinline__ void group_insert(u32 m16, u64 ck, int slot,
                                             u64& val, u64& tau) {
  if (m16) {
    while (m16) {
      int src = __ffs(m16) - 1;
      m16 &= m16 - 1;
      u64 c = __shfl((unsigned long long)ck, src, 16);
      u64 prev = __shfl_up((unsigned long long)val, 1, SL);
      if (slot == 0) prev = 0ull;
      val = (val <= c) ? val : ((prev <= c) ? c : prev);
    }
    tau = __shfl((unsigned long long)val, SL - 1, SL);
  }
}

// ------------------------- shared: scan a contiguous sorted[] range --------
template<int SL>
__device__ __forceinline__ void scan_range(const float4* __restrict__ sb,
    int s, int e, float qx, float qy, float qz, float qq,
    int g, int gl, int slot, u64& val, u64& tau) {
  for (int t0 = s; t0 < e; t0 += 16) {
    int j = t0 + gl;
    u64 ck = ~0ull;
    if (j < e) {
      float4 P = sb[j];
      float rr = P.x * P.x + P.y * P.y + P.z * P.z;
      float d2 = qq + rr - 2.0f * (qx * P.x + qy * P.y + qz * P.z);
      ck = ((u64)fbias(d2) << 32) | (u32)__float_as_uint(P.w);
    }
    u64 full = __ballot(ck < tau);
    u32 m16 = (u32)((full >> (g * 16)) & 0xFFFFull);
    group_insert<SL>(m16, ck, slot, val, tau);
  }
}

// Exactness argument (unchanged core + ring expansion):
//  - After scanning a box B, if the KOUT-th smallest d2 is strictly less than
//    the squared distance from q to the nearest NON-clipped face of B, no
//    point outside B can enter the top-KOUT (clipped faces coincide with the
//    domain boundary; all points lie in [0,1)^3 so nothing is beyond them).
//  - The ring expansion scans exactly the cells of box(R+1) \ box(R) via the
//    cell structure (per-row segments excluding the old x-range), so every
//    point is considered at most once and keys stay unique u64s -> identical
//    tie-breaking to the reference top_k.

// --------------------------------------- kNN grid, FLAT (NROW <= 16) -------
template<int SL, int KOUT, int GR, int R, int NREF>
__global__ __launch_bounds__(256) void knn_grid_flat_kernel(
    const float* __restrict__ pos, const float4* __restrict__ sorted,
    const int* __restrict__ cellStart, int csStride, int Mq,
    int* __restrict__ oidx, float* __restrict__ od2) {
  int b = blockIdx.y;
  int wv = threadIdx.x >> 6, lane = threadIdx.x & 63;
  int g = lane >> 4, gl = lane & 15;
  int q = blockIdx.x * 16 + wv * 4 + g;
  const float* pb = pos + (size_t)b * NFULL * 3;
  const float4* sb = sorted + (size_t)b * NREF;
  const int* cs = cellStart + b * csStride;
  float qx = pb[q * 3 + 0], qy = pb[q * 3 + 1], qz = pb[q * 3 + 2];
  float qq = qx * qx + qy * qy + qz * qz;
  int ix = min(max((int)(qx * GR), 0), GR - 1);
  int iy = min(max((int)(qy * GR), 0), GR - 1);
  int iz = min(max((int)(qz * GR), 0), GR - 1);
  int x0 = max(ix - R, 0), x1 = min(ix + R, GR - 1);
  int y0 = max(iy - R, 0), y1 = min(iy + R, GR - 1);
  int z0 = max(iz - R, 0), z1 = min(iz + R, GR - 1);

  int ny = y1 - y0 + 1;
  int nrow = (z1 - z0 + 1) * ny;  // <= 9 for R=1
  int s_i = 0, len_i = 0;
  if (gl < nrow) {
    int zz = z0 + gl / ny, yy = y0 + gl % ny;
    int c0 = (zz * GR + yy) * GR + x0;
    s_i = cs[c0];
    len_i = cs[c0 + (x1 - x0) + 1] - s_i;
  }
  int p_i = len_i;
#pragma unroll
  for (int st = 1; st < 16; st <<= 1) {
    int o = __shfl_up(p_i, st, 16);
    if (gl >= st) p_i += o;
  }
  int T = __shfl(p_i, 15, 16);
  p_i -= len_i;              // exclusive prefix
  int d_i = s_i - p_i;       // sorted index = v + d_row
  if (gl >= nrow) p_i = 0x7fffffff;

  int slot = gl & (SL - 1);
  u64 val = ~0ull, tau = ~0ull;

  for (int v0 = 0; v0 < T; v0 += 16) {  // T group-uniform
    int v = v0 + gl;
    int r = 0;
#pragma unroll
    for (int st = 8; st >= 1; st >>= 1) {
      int pc = __shfl(p_i, r + st, 16);
      if (v >= pc) r += st;
    }
    int addr = v + __shfl(d_i, r, 16);
    u64 ck = ~0ull;
    if (v < T) {
      float4 P = sb[addr];
      float rr = P.x * P.x + P.y * P.y + P.z * P.z;
      float d2 = qq + rr - 2.0f * (qx * P.x + qy * P.y + qz * P.z);
      ck = ((u64)fbias(d2) << 32) | (u32)__float_as_uint(P.w);
    }
    u64 full = __ballot(ck < tau);
    u32 m16 = (u32)((full >> (g * 16)) & 0xFFFFull);
    group_insert<SL>(m16, ck, slot, val, tau);
  }

  const float h = 1.0f / GR;
  float m = 1e30f;
  if (x0 > 0)      m = fminf(m, qx - x0 * h);
  if (x1 < GR - 1) m = fminf(m, (x1 + 1) * h - qx);
  if (y0 > 0)      m = fminf(m, qy - y0 * h);
  if (y1 < GR - 1) m = fminf(m, (y1 + 1) * h - qy);
  if (z0 > 0)      m = fminf(m, qz - z0 * h);
  if (z1 < GR - 1) m = fminf(m, (z1 + 1) * h - qz);
  float bound = m * m;
  // KOUT-th (not SL-th) smallest is all correctness requires.
  u64 kv = __shfl((unsigned long long)val, KOUT - 1, SL);
  float kth_d2 = funbias((u32)(kv >> 32));
  if (!(kth_d2 < bound)) {  // group-uniform; rare (corner/edge queries)
    // ---- ring expansion: box(R+1) \ box(R) via cell structure ----
    int X0 = max(ix - (R + 1), 0), X1 = min(ix + (R + 1), GR - 1);
    int Y0 = max(iy - (R + 1), 0), Y1 = min(iy + (R + 1), GR - 1);
    int Z0 = max(iz - (R + 1), 0), Z1 = min(iz + (R + 1), GR - 1);
    int NY2 = Y1 - Y0 + 1;
    int nrow2 = (Z1 - Z0 + 1) * NY2;
    for (int rr2 = 0; rr2 < nrow2; ++rr2) {
      int zz = Z0 + rr2 / NY2, yy = Y0 + rr2 % NY2;
      int c0 = (zz * GR + yy) * GR;
      bool mid = (zz >= z0 && zz <= z1 && yy >= y0 && yy <= y1);
      int s1 = cs[c0 + X0];
      int e1 = mid ? cs[c0 + x0] : cs[c0 + X1 + 1];
      scan_range<SL>(sb, s1, e1, qx, qy, qz, qq, g, gl, slot, val, tau);
      if (mid) {
        int s2 = cs[c0 + x1 + 1];
        int e2 = cs[c0 + X1 + 1];
        scan_range<SL>(sb, s2, e2, qx, qy, qz, qq, g, gl, slot, val, tau);
      }
    }
    x0 = X0; x1 = X1; y0 = Y0; y1 = Y1; z0 = Z0; z1 = Z1;
    m = 1e30f;
    if (x0 > 0)      m = fminf(m, qx - x0 * h);
    if (x1 < GR - 1) m = fminf(m, (x1 + 1) * h - qx);
    if (y0 > 0)      m = fminf(m, qy - y0 * h);
    if (y1 < GR - 1) m = fminf(m, (y1 + 1) * h - qy);
    if (z0 > 0)      m = fminf(m, qz - z0 * h);
    if (z1 < GR - 1) m = fminf(m, (z1 + 1) * h - qz);
    bound = m * m;
    kv = __shfl((unsigned long long)val, KOUT - 1, SL);
    kth_d2 = funbias((u32)(kv >> 32));
    if (!(kth_d2 < bound)) {  // essentially unreachable now
      for (int t0 = 0; t0 < NREF; t0 += 16) {
        int j = t0 + gl;
        u64 ck = ~0ull;
        if (j < NREF) {
          float4 P = sb[j];
          int cx = min(max((int)(P.x * GR), 0), GR - 1);
          int cy = min(max((int)(P.y * GR), 0), GR - 1);
          int cz = min(max((int)(P.z * GR), 0), GR - 1);
          bool inbox = (cx >= x0 && cx <= x1 && cy >= y0 && cy <= y1 &&
                        cz >= z0 && cz <= z1);
          if (!inbox) {
            float rr = P.x * P.x + P.y * P.y + P.z * P.z;
            float d2 = qq + rr - 2.0f * (qx * P.x + qy * P.y + qz * P.z);
            ck = ((u64)fbias(d2) << 32) | (u32)__float_as_uint(P.w);
          }
        }
        u64 full = __ballot(ck < tau);
        u32 m16 = (u32)((full >> (g * 16)) & 0xFFFFull);
        group_insert<SL>(m16, ck, slot, val, tau);
      }
    }
  }

  if (gl < KOUT) {
    size_t base = ((size_t)b * Mq + q) * KOUT;
    oidx[base + gl] = (int)(u32)val;
    od2[base + gl] = fmaxf(funbias((u32)(val >> 32)), 0.0f);
  }
}

// --------------------------------------- kNN grid, ROWS (NROW <= 32) -------
template<int SL, int KOUT, int GR, int R, int NREF>
__global__ __launch_bounds__(256) void knn_grid_rows_kernel(
    const float* __restrict__ pos, const float4* __restrict__ sorted,
    const int* __restrict__ cellStart, int csStride, int Mq,
    int* __restrict__ oidx, float* __restrict__ od2) {
  int b = blockIdx.y;
  int wv = threadIdx.x >> 6, lane = threadIdx.x & 63;
  int g = lane >> 4, gl = lane & 15;
  int q = blockIdx.x * 16 + wv * 4 + g;
  const float* pb = pos + (size_t)b * NFULL * 3;
  const float4* sb = sorted + (size_t)b * NREF;
  const int* cs = cellStart + b * csStride;
  float qx = pb[q * 3 + 0], qy = pb[q * 3 + 1], qz = pb[q * 3 + 2];
  float qq = qx * qx + qy * qy + qz * qz;
  int ix = min(max((int)(qx * GR), 0), GR - 1);
  int iy = min(max((int)(qy * GR), 0), GR - 1);
  int iz = min(max((int)(qz * GR), 0), GR - 1);
  int x0 = max(ix - R, 0), x1 = min(ix + R, GR - 1);
  int y0 = max(iy - R, 0), y1 = min(iy + R, GR - 1);
  int z0 = max(iz - R, 0), z1 = min(iz + R, GR - 1);

  int ny = y1 - y0 + 1;
  int nrow = (z1 - z0 + 1) * ny;  // <= 25 for R=2
  int sLo = 0, eLo = 0, sHi = 0, eHi = 0;
  if (gl < nrow) {
    int zz = z0 + gl / ny, yy = y0 + gl % ny;
    int c0 = (zz * GR + yy) * GR + x0;
    sLo = cs[c0]; eLo = cs[c0 + (x1 - x0) + 1];
  }
  {
    int i2 = gl + 16;
    if (i2 < nrow) {
      int zz = z0 + i2 / ny, yy = y0 + i2 % ny;
      int c0 = (zz * GR + yy) * GR + x0;
      sHi = cs[c0]; eHi = cs[c0 + (x1 - x0) + 1];
    }
  }

  int slot = gl & (SL - 1);
  u64 val = ~0ull, tau = ~0ull;

  for (int r = 0; r < nrow; ++r) {  // r group-uniform
    int sa = __shfl(sLo, r & 15, 16);
    int sb2 = __shfl(sHi, r & 15, 16);
    int ea = __shfl(eLo, r & 15, 16);
    int eb = __shfl(eHi, r & 15, 16);
    int s = (r < 16) ? sa : sb2;
    int e = (r < 16) ? ea : eb;
    scan_range<SL>(sb, s, e, qx, qy, qz, qq, g, gl, slot, val, tau);
  }

  const float h = 1.0f / GR;
  float m = 1e30f;
  if (x0 > 0)      m = fminf(m, qx - x0 * h);
  if (x1 < GR - 1) m = fminf(m, (x1 + 1) * h - qx);
  if (y0 > 0)      m = fminf(m, qy - y0 * h);
  if (y1 < GR - 1) m = fminf(m, (y1 + 1) * h - qy);
  if (z0 > 0)      m = fminf(m, qz - z0 * h);
  if (z1 < GR - 1) m = fminf(m, (z1 + 1) * h - qz);
  float bound = m * m;
  u64 kv = __shfl((unsigned long long)val, KOUT - 1, SL);
  float kth_d2 = funbias((u32)(kv >> 32));
  if (!(kth_d2 < bound)) {  // group-uniform; rare (corner/edge queries)
    // ---- ring expansion: box(R+1) \ box(R) via cell structure ----
    int X0 = max(ix - (R + 1), 0), X1 = min(ix + (R + 1), GR - 1);
    int Y0 = max(iy - (R + 1), 0), Y1 = min(iy + (R + 1), GR - 1);
    int Z0 = max(iz - (R + 1), 0), Z1 = min(iz + (R + 1), GR - 1);
    int NY2 = Y1 - Y0 + 1;
    int nrow2 = (Z1 - Z0 + 1) * NY2;
    for (int rr2 = 0; rr2 < nrow2; ++rr2) {
      int zz = Z0 + rr2 / NY2, yy = Y0 + rr2 % NY2;
      int c0 = (zz * GR + yy) * GR;
      bool mid = (zz >= z0 && zz <= z1 && yy >= y0 && yy <= y1);
      int s1 = cs[c0 + X0];
      int e1 = mid ? cs[c0 + x0] : cs[c0 + X1 + 1];
      scan_range<SL>(sb, s1, e1, qx, qy, qz, qq, g, gl, slot, val, tau);
      if (mid) {
        int s2 = cs[c0 + x1 + 1];
        int e2 = cs[c0 + X1 + 1];
        scan_range<SL>(sb, s2, e2, qx, qy, qz, qq, g, gl, slot, val, tau);
      }
    }
    x0 = X0; x1 = X1; y0 = Y0; y1 = Y1; z0 = Z0; z1 = Z1;
    m = 1e30f;
    if (x0 > 0)      m = fminf(m, qx - x0 * h);
    if (x1 < GR - 1) m = fminf(m, (x1 + 1) * h - qx);
    if (y0 > 0)      m = fminf(m, qy - y0 * h);
    if (y1 < GR - 1) m = fminf(m, (y1 + 1) * h - qy);
    if (z0 > 0)      m = fminf(m, qz - z0 * h);
    if (z1 < GR - 1) m = fminf(m, (z1 + 1) * h - qz);
    bound = m * m;
    kv = __shfl((unsigned long long)val, KOUT - 1, SL);
    kth_d2 = funbias((u32)(kv >> 32));
    if (!(kth_d2 < bound)) {  // essentially unreachable now
      for (int t0 = 0; t0 < NREF; t0 += 16) {
        int j = t0 + gl;
        u64 ck = ~0ull;
        if (j < NREF) {
          float4 P = sb[j];
          int cx = min(max((int)(P.x * GR), 0), GR - 1);
          int cy = min(max((int)(P.y * GR), 0), GR - 1);
          int cz = min(max((int)(P.z * GR), 0), GR - 1);
          bool inbox = (cx >= x0 && cx <= x1 && cy >= y0 && cy <= y1 &&
                        cz >= z0 && cz <= z1);
          if (!inbox) {
            float rr = P.x * P.x + P.y * P.y + P.z * P.z;
            float d2 = qq + rr - 2.0f * (qx * P.x + qy * P.y + qz * P.z);
            ck = ((u64)fbias(d2) << 32) | (u32)__float_as_uint(P.w);
          }
        }
        u64 full = __ballot(ck < tau);
        u32 m16 = (u32)((full >> (g * 16)) & 0xFFFFull);
        group_insert<SL>(m16, ck, slot, val, tau);
      }
    }
  }

  if (gl < KOUT) {
    size_t base = ((size_t)b * Mq + q) * KOUT;
    oidx[base + gl] = (int)(u32)val;
    od2[base + gl] = fmaxf(funbias((u32)(val >> 32)), 0.0f);
  }
}

// -------------------------------------------------------- kNN (brute) ------
template<int SL, int KOUT>
__global__ __launch_bounds__(256) void knn_kernel(
    const float* __restrict__ pos, int Nref, int Mq,
    int* __restrict__ oidx, float* __restrict__ od2) {
  int b = blockIdx.y;
  int wv = threadIdx.x >> 6, lane = threadIdx.x & 63;
  int g = lane >> 4, gl = lane & 15;
  int q = blockIdx.x * 16 + wv * 4 + g;
  const float* pb = pos + (size_t)b * NFULL * 3;
  float qx = pb[q * 3 + 0], qy = pb[q * 3 + 1], qz = pb[q * 3 + 2];
  float qq = qx * qx + qy * qy + qz * qz;

  int slot = gl & (SL - 1);
  u64 val = ~0ull, tau = ~0ull;

  for (int t0 = 0; t0 < Nref; t0 += 16) {
    int j = t0 + gl;
    float rx = pb[j * 3 + 0];
    float ry = pb[j * 3 + 1];
    float rz = pb[j * 3 + 2];
    float rr = rx * rx + ry * ry + rz * rz;
    float d2 = qq + rr - 2.0f * (qx * rx + qy * ry + qz * rz);
    u64 ck = ((u64)fbias(d2) << 32) | (u32)j;
    u64 full = __ballot(ck < tau);
    u32 m16 = (u32)((full >> (g * 16)) & 0xFFFFull);
    group_insert<SL>(m16, ck, slot, val, tau);
  }

  if (gl < KOUT) {
    size_t base = ((size_t)b * Mq + q) * KOUT;
    oidx[base + gl] = (int)(u32)val;
    od2[base + gl] = fmaxf(funbias((u32)(val >> 32)), 0.0f);
  }
}

// ----------------------------------- fused weight packing + pos copy -------
__device__ __forceinline__ void pack_tile_rt(const float* __restrict__ W,
                                             short* __restrict__ outp,
                                             int KDIM, int N, int tile, int lane) {
  int NT = N >> 4;
  int kt = tile / NT, nt = tile - kt * NT;
  int n = nt * 16 + (lane & 15);
  int k0 = kt * 32 + (lane >> 4) * 8;
  bf8_t v;
#pragma unroll
  for (int j = 0; j < 8; ++j) {
    int k = k0 + j;
    v[j] = (k < KDIM) ? f2bf(W[(size_t)k * N + n]) : (short)0;
  }
  *(bf8_t*)(outp + ((size_t)tile * 64 + lane) * 8) = v;
}

__global__ __launch_bounds__(64) void pack_copy_all_kernel(
    const float* d0W1, short* d0W1p, const float* d0W2, short* d0W2p,
    const float* d1W1, short* d1W1p, const float* d1W2, short* d1W2p,
    const float* d2W1, short* d2W1p, const float* d2W2, short* d2W2p,
    const float* u2W, short* u2Wp, const float* fW1, short* fW1p,
    const float* fW2, short* fW2p,
    const float* pos, float* posOut) {
  int blk = blockIdx.x, lane = threadIdx.x;
  if      (blk < 8)    pack_tile_rt(d0W1, d0W1p, 6, 128, blk, lane);
  else if (blk < 40)   pack_tile_rt(d0W2, d0W2p, 128, 128, blk - 8, lane);
  else if (blk < 120)  pack_tile_rt(d1W1, d1W1p, 131, 256, blk - 40, lane);
  else if (blk < 248)  pack_tile_rt(d1W2, d1W2p, 256, 256, blk - 120, lane);
  else if (blk < 536)  pack_tile_rt(d2W1, d2W1p, 259, 512, blk - 248, lane);
  else if (blk < 1048) pack_tile_rt(d2W2, d2W2p, 512, 512, blk - 536, lane);
  else if (blk < 1088) pack_tile_rt(u2W, u2Wp, 134, 128, blk - 1048, lane);
  else if (blk < 1120) pack_tile_rt(fW1, fW1p, 128, 128, blk - 1088, lane);
  else if (blk < 1152) pack_tile_rt(fW2, fW2p, 128, 128, blk - 1120, lane);
  else {
    int base = (blk - 1152) * 256;  // 384 blocks x 256 = 98304 = BATCH*NFULL*3
#pragma unroll
    for (int j = 0; j < 4; ++j) {
      int i = base + lane + j * 64;
      posOut[i] = pos[i];
    }
  }
}

// ----------------------------------------------------- down MLP (MFMA) -----
template<int FEAT, int CIN, int CHID, int FPAD, int WPB>
__global__ __launch_bounds__(64 * WPB) void down_mfma_kernel(
    const float* __restrict__ pos, const float* __restrict__ xin,
    const int* __restrict__ idx,
    const short* __restrict__ W1p, const float* __restrict__ b1,
    const short* __restrict__ W2p, const float* __restrict__ b2,
    float* __restrict__ out, int n, int nprev) {
  const int KT1 = FPAD / 32, NT1 = CHID / 16;
  const int KT2 = CHID / 32, NT2 = CHID / 16;
  __shared__ short sFeat[16][FPAD];
  __shared__ short sH1[16][CHID];
  __shared__ int sIdx[16];
  __shared__ float sCtr[3];
  int b = blockIdx.y, q = blockIdx.x;
  int lane = threadIdx.x & 63, wv = threadIdx.x >> 6;
  const float* pb = pos + (size_t)b * NFULL * 3;
  const float* xb = xin + (size_t)b * nprev * CIN;
  if (threadIdx.x < 16) sIdx[threadIdx.x] = idx[((size_t)b * n + q) * 16 + threadIdx.x];
  if (threadIdx.x < 3) sCtr[threadIdx.x] = pb[q * 3 + threadIdx.x];
  __syncthreads();
  for (int e = threadIdx.x; e < 16 * FPAD; e += 64 * WPB) {
    int k = e / FPAD, c = e % FPAD;
    float v = 0.f;
    if (c < 3) v = pb[sIdx[k] * 3 + c] - sCtr[c];
    else if (c < FEAT) v = xb[(size_t)sIdx[k] * CIN + (c - 3)];
    sFeat[k][c] = f2bf(v);
  }
  __syncthreads();

  int col = lane & 15, quad = lane >> 4;
  bf8_t afr[KT1];
#pragma unroll
  for (int kt = 0; kt < KT1; ++kt)
    afr[kt] = *(const bf8_t*)&sFeat[col][kt * 32 + quad * 8];
  const bf8_t* W1t = (const bf8_t*)W1p;
  for (int nt = 2 * wv; nt < NT1; nt += 2 * WPB) {
    float bb0 = b1[nt * 16 + col], bb1 = b1[nt * 16 + 16 + col];
    f4_t acc0 = {bb0, bb0, bb0, bb0}, acc1 = {bb1, bb1, bb1, bb1};
#pragma unroll
    for (int kt = 0; kt < KT1; ++kt) {
      bf8_t bf0 = W1t[(kt * NT1 + nt) * 64 + lane];
      bf8_t bf1 = W1t[(kt * NT1 + nt + 1) * 64 + lane];
      acc0 = __builtin_amdgcn_mfma_f32_16x16x32_bf16(afr[kt], bf0, acc0, 0, 0, 0);
      acc1 = __builtin_amdgcn_mfma_f32_16x16x32_bf16(afr[kt], bf1, acc1, 0, 0, 0);
    }
#pragma unroll
    for (int r = 0; r < 4; ++r) {
      sH1[quad * 4 + r][nt * 16 + col] = f2bf(fmaxf(acc0[r], 0.f));
      sH1[quad * 4 + r][nt * 16 + 16 + col] = f2bf(fmaxf(acc1[r], 0.f));
    }
  }
  __syncthreads();

  bf8_t afr2[KT2];
#pragma unroll
  for (int kt = 0; kt < KT2; ++kt)
    afr2[kt] = *(const bf8_t*)&sH1[col][kt * 32 + quad * 8];
  const bf8_t* W2t = (const bf8_t*)W2p;
  float* ob = out + ((size_t)b * n + q) * CHID;
  for (int nt = 2 * wv; nt < NT2; nt += 2 * WPB) {
    float bb0 = b2[nt * 16 + col], bb1 = b2[nt * 16 + 16 + col];
    f4_t acc0 = {bb0, bb0, bb0, bb0}, acc1 = {bb1, bb1, bb1, bb1};
#pragma unroll
    for (int kt = 0; kt < KT2; ++kt) {
      bf8_t bf0 = W2t[(kt * NT2 + nt) * 64 + lane];
      bf8_t bf1 = W2t[(kt * NT2 + nt + 1) * 64 + lane];
      acc0 = __builtin_amdgcn_mfma_f32_16x16x32_bf16(afr2[kt], bf0, acc0, 0, 0, 0);
      acc1 = __builtin_amdgcn_mfma_f32_16x16x32_bf16(afr2[kt], bf1, acc1, 0, 0, 0);
    }
    float m0 = fmaxf(fmaxf(acc0[0], acc0[1]), fmaxf(acc0[2], acc0[3]));
    float m1 = fmaxf(fmaxf(acc1[0], acc1[1]), fmaxf(acc1[2], acc1[3]));
    m0 = fmaxf(m0, __shfl_xor(m0, 16, 64));
    m0 = fmaxf(m0, __shfl_xor(m0, 32, 64));
    m1 = fmaxf(m1, __shfl_xor(m1, 16, 64));
    m1 = fmaxf(m1, __shfl_xor(m1, 32, 64));
    if (lane < 16) {
      ob[nt * 16 + lane] = m0;
      ob[nt * 16 + 16 + lane] = m1;
    }
  }
}

// --------------------------------------------------------------- up MLP ----
template<int CIN, int CPRV, int COUT, int TP>
__global__ __launch_bounds__(COUT) void up_kernel(
    const float* __restrict__ xc, int ncoarse,
    const int* __restrict__ idx3, const float* __restrict__ d23,
    const float* __restrict__ prv, const float* __restrict__ W,
    const float* __restrict__ bvec, float* __restrict__ out, int m) {
  const int CTOT = CIN + CPRV;
  __shared__ float sCat[TP][CTOT];
  __shared__ float sWt[TP][3];
  __shared__ int   sIt[TP][3];
  int b = blockIdx.y, q0 = blockIdx.x * TP, t = threadIdx.x;
  if (t < TP) {
    size_t base = ((size_t)b * m + q0 + t) * 3;
    float d0 = d23[base + 0], d1 = d23[base + 1], d2v = d23[base + 2];
    float w0 = 1.f / (d0 + 1e-8f), w1 = 1.f / (d1 + 1e-8f), w2 = 1.f / (d2v + 1e-8f);
    float s = w0 + w1 + w2;
    sWt[t][0] = w0 / s; sWt[t][1] = w1 / s; sWt[t][2] = w2 / s;
    sIt[t][0] = idx3[base + 0]; sIt[t][1] = idx3[base + 1]; sIt[t][2] = idx3[base + 2];
  }
  __syncthreads();
  const float* xb = xc + (size_t)b * ncoarse * CIN;
  const float* pvb = prv + ((size_t)b * m + q0) * CPRV;
  for (int e = t; e < TP * CIN; e += COUT) {
    int p = e / CIN, c = e % CIN;
    sCat[p][c] = sWt[p][0] * xb[(size_t)sIt[p][0] * CIN + c]
               + sWt[p][1] * xb[(size_t)sIt[p][1] * CIN + c]
               + sWt[p][2] * xb[(size_t)sIt[p][2] * CIN + c];
  }
  for (int e = t; e < TP * CPRV; e += COUT) {
    int p = e / CPRV, c = e % CPRV;
    sCat[p][CIN + c] = pvb[(size_t)p * CPRV + c];
  }
  __syncthreads();
  float acc[TP];
  float bb = bvec[t];
#pragma unroll
  for (int p = 0; p < TP; ++p) acc[p] = bb;
  for (int c4 = 0; c4 < CTOT / 4; ++c4) {
    int c = 4 * c4;
    float w0 = W[(c + 0) * COUT + t];
    float w1 = W[(c + 1) * COUT + t];
    float w2 = W[(c + 2) * COUT + t];
    float w3 = W[(c + 3) * COUT + t];
#pragma unroll
    for (int p = 0; p < TP; ++p) {
      float4 v = *(const float4*)&sCat[p][c];
      acc[p] = fmaf(v.x, w0, acc[p]);
      acc[p] = fmaf(v.y, w1, acc[p]);
      acc[p] = fmaf(v.z, w2, acc[p]);
      acc[p] = fmaf(v.w, w3, acc[p]);
    }
  }
#pragma unroll
  for (int p = 0; p < TP; ++p)
    out[((size_t)b * m + q0 + p) * COUT + t] = fmaxf(acc[p], 0.f);
}

// ------------------------------------- fused up2 + final MLP (bf16 MFMA) ---
__global__ __launch_bounds__(128) void up2f_mfma_kernel(
    const float* __restrict__ xc,
    const int* __restrict__ idx3, const float* __restrict__ d23,
    const float* __restrict__ x0, const float* __restrict__ pos0,
    const short* __restrict__ u2Wp, const float* __restrict__ u2b,
    const short* __restrict__ fW1p, const float* __restrict__ fb1,
    const short* __restrict__ fW2p, const float* __restrict__ fb2,
    float* __restrict__ out) {
  __shared__ short sA[16][160];
  __shared__ short sB[16][128];
  __shared__ float sWt[16][3];
  __shared__ int   sIt[16][3];
  int b = blockIdx.y, q0 = blockIdx.x * 16, t = threadIdx.x;
  int lane = t & 63, wv = t >> 6;
  if (t < 16) {
    size_t base = ((size_t)b * NFULL + q0 + t) * 3;
    float d0 = d23[base + 0], d1 = d23[base + 1], d2v = d23[base + 2];
    float w0 = 1.f / (d0 + 1e-8f), w1 = 1.f / (d1 + 1e-8f), w2 = 1.f / (d2v + 1e-8f);
    float s = w0 + w1 + w2;
    sWt[t][0] = w0 / s; sWt[t][1] = w1 / s; sWt[t][2] = w2 / s;
    sIt[t][0] = idx3[base + 0]; sIt[t][1] = idx3[base + 1]; sIt[t][2] = idx3[base + 2];
  }
  __syncthreads();
  const float* xb = xc + (size_t)b * 2048 * 128;
#pragma unroll
  for (int p = 0; p < 16; ++p) {
    float v = sWt[p][0] * xb[(size_t)sIt[p][0] * 128 + t]
            + sWt[p][1] * xb[(size_t)sIt[p][1] * 128 + t]
            + sWt[p][2] * xb[(size_t)sIt[p][2] * 128 + t];
    sA[p][t] = f2bf(v);
  }
  for (int e = t; e < 16 * 32; e += 128) {
    int p = e / 32, c = 128 + (e % 32);
    float v = 0.f;
    if (c < 131) v = x0[((size_t)b * NFULL + q0 + p) * 3 + (c - 128)];
    else if (c < 134) v = pos0[((size_t)b * NFULL + q0 + p) * 3 + (c - 131)];
    sA[p][c] = f2bf(v);
  }
  __syncthreads();
  int col = lane & 15, quad = lane >> 4;

  bf8_t a1[5];
#pragma unroll
  for (int kt = 0; kt < 5; ++kt)
    a1[kt] = *(const bf8_t*)&sA[col][kt * 32 + quad * 8];
  const bf8_t* W1t = (const bf8_t*)u2Wp;
  for (int nt = 2 * wv; nt < 8; nt += 4) {
    float bb0 = u2b[nt * 16 + col], bb1 = u2b[nt * 16 + 16 + col];
    f4_t acc0 = {bb0, bb0, bb0, bb0}, acc1 = {bb1, bb1, bb1, bb1};
#pragma unroll
    for (int kt = 0; kt < 5; ++kt) {
      bf8_t bf0 = W1t[(kt * 8 + nt) * 64 + lane];
      bf8_t bf1 = W1t[(kt * 8 + nt + 1) * 64 + lane];
      acc0 = __builtin_amdgcn_mfma_f32_16x16x32_bf16(a1[kt], bf0, acc0, 0, 0, 0);
      acc1 = __builtin_amdgcn_mfma_f32_16x16x32_bf16(a1[kt], bf1, acc1, 0, 0, 0);
    }
#pragma unroll
    for (int r = 0; r < 4; ++r) {
      sB[quad * 4 + r][nt * 16 + col] = f2bf(fmaxf(acc0[r], 0.f));
      sB[quad * 4 + r][nt * 16 + 16 + col] = f2bf(fmaxf(acc1[r], 0.f));
    }
  }
  __syncthreads();

  bf8_t a2[4];
#pragma unroll
  for (int kt = 0; kt < 4; ++kt)
    a2[kt] = *(const bf8_t*)&sB[col][kt * 32 + quad * 8];
  const bf8_t* W2t = (const bf8_t*)fW1p;
  for (int nt = 2 * wv; nt < 8; nt += 4) {
    float bb0 = fb1[nt * 16 + col], bb1 = fb1[nt * 16 + 16 + col];
    f4_t acc0 = {bb0, bb0, bb0, bb0}, acc1 = {bb1, bb1, bb1, bb1};
#pragma unroll
    for (int kt = 0; kt < 4; ++kt) {
      bf8_t bf0 = W2t[(kt * 8 + nt) * 64 + lane];
      bf8_t bf1 = W2t[(kt * 8 + nt + 1) * 64 + lane];
      acc0 = __builtin_amdgcn_mfma_f32_16x16x32_bf16(a2[kt], bf0, acc0, 0, 0, 0);
      acc1 = __builtin_amdgcn_mfma_f32_16x16x32_bf16(a2[kt], bf1, acc1, 0, 0, 0);
    }
#pragma unroll
    for (int r = 0; r < 4; ++r) {
      sA[quad * 4 + r][nt * 16 + col] = f2bf(fmaxf(acc0[r], 0.f));
      sA[quad * 4 + r][nt * 16 + 16 + col] = f2bf(fmaxf(acc1[r], 0.f));
    }
  }
  __syncthreads();

  bf8_t a3[4];
#pragma unroll
  for (int kt = 0; kt < 4; ++kt)
    a3[kt] = *(const bf8_t*)&sA[col][kt * 32 + quad * 8];
  const bf8_t* W3t = (const bf8_t*)fW2p;
  float* ob = out + ((size_t)b * NFULL + q0) * 128;
  for (int nt = 2 * wv; nt < 8; nt += 4) {
    float bb0 = fb2[nt * 16 + col], bb1 = fb2[nt * 16 + 16 + col];
    f4_t acc0 = {bb0, bb0, bb0, bb0}, acc1 = {bb1, bb1, bb1, bb1};
#pragma unroll
    for (int kt = 0; kt < 4; ++kt) {
      bf8_t bf0 = W3t[(kt * 8 + nt) * 64 + lane];
      bf8_t bf1 = W3t[(kt * 8 + nt + 1) * 64 + lane];
      acc0 = __builtin_amdgcn_mfma_f32_16x16x32_bf16(a3[kt], bf0, acc0, 0, 0, 0);
      acc1 = __builtin_amdgcn_mfma_f32_16x16x32_bf16(a3[kt], bf1, acc1, 0, 0, 0);
    }
#pragma unroll
    for (int r = 0; r < 4; ++r) {
      ob[(size_t)(quad * 4 + r) * 128 + nt * 16 + col] = acc0[r];
      ob[(size_t)(quad * 4 + r) * 128 + nt * 16 + 16 + col] = acc1[r];
    }
  }
}

// ------------------------------------------------------------------ launch -
extern "C" void kernel_launch(void* const* d_in, const int* in_sizes, int n_in,
                              void* d_out, int out_size, void* d_ws, size_t ws_size,
                              hipStream_t stream) {
  const float* x    = (const float*)d_in[0];
  const float* pos  = (const float*)d_in[1];
  const float* d0W1 = (const float*)d_in[2];
  const float* d0b1 = (const float*)d_in[3];
  const float* d0W2 = (const float*)d_in[4];
  const float* d0b2 = (const float*)d_in[5];
  const float* d1W1 = (const float*)d_in[6];
  const float* d1b1 = (const float*)d_in[7];
  const float* d1W2 = (const float*)d_in[8];
  const float* d1b2 = (const float*)d_in[9];
  const float* d2W1 = (const float*)d_in[10];
  const float* d2b1 = (const float*)d_in[11];
  const float* d2W2 = (const float*)d_in[12];
  const float* d2b2 = (const float*)d_in[13];
  const float* u0W  = (const float*)d_in[14];
  const float* u0b  = (const float*)d_in[15];
  const float* u1W  = (const float*)d_in[16];
  const float* u1b  = (const float*)d_in[17];
  const float* u2W  = (const float*)d_in[18];
  const float* u2b  = (const float*)d_in[19];
  const float* fW1  = (const float*)d_in[20];
  const float* fb1  = (const float*)d_in[21];
  const float* fW2  = (const float*)d_in[22];
  const float* fb2  = (const float*)d_in[23];

  char* ws = (char*)d_ws;
  float* x1    = (float*)(ws + 0);
  float* x2    = (float*)(ws + 4194304);
  float* x3    = (float*)(ws + 6291456);
  float* up0o  = (float*)(ws + 7340032);
  float* up1o  = (float*)(ws + 9437184);
  int*   idx0  = (int*)  (ws + 13631488);
  int*   idx1  = (int*)  (ws + 14155776);
  int*   idx2  = (int*)  (ws + 14286848);
  float* d2s   = (float*)(ws + 14319616);
  int*   idxu0 = (int*)  (ws + 14843904);
  float* d2u0  = (float*)(ws + 14868480);
  int*   idxu1 = (int*)  (ws + 14893056);
  float* d2u1  = (float*)(ws + 14991360);
  int*   idxu2 = (int*)  (ws + 15089664);
  float* d2u2  = (float*)(ws + 15482880);
  short* d1W1p = (short*)(ws + 15876096);
  short* d1W2p = (short*)(ws + 15958016);
  short* d2W1p = (short*)(ws + 16089088);
  short* d2W2p = (short*)(ws + 16384000);
  short* d0W1p = (short*)(ws + 16908288);
  short* d0W2p = (short*)(ws + 16916480);
  float4* sortedA = (float4*)(ws + 16949248);  // 4*8192*16 = 524288
  int*    csA     = (int*)   (ws + 17473536);  // 4*4097*4  = 65552
  float4* sortedB = (float4*)(ws + 17539136);  // 4*2048*16 = 131072
  int*    csB     = (int*)   (ws + 17670208);  // 4*513*4   = 8208
  short* u2Wp  = (short*)(ws + 17697920);
  short* fW1p  = (short*)(ws + 17738880);
  short* fW2p  = (short*)(ws + 17771648);

  float* out = (float*)d_out;

  // ---- fused packing + pos passthrough; fused grid builds ----
  pack_copy_all_kernel<<<dim3(1536), 64, 0, stream>>>(
      d0W1, d0W1p, d0W2, d0W2p, d1W1, d1W1p, d1W2, d1W2p,
      d2W1, d2W1p, d2W2, d2W2p, u2W, u2Wp, fW1, fW1p, fW2, fW2p,
      pos, out + (size_t)BATCH * NFULL * 128);
  build_grids_kernel<<<dim3(BATCH, 2), 256, 0, stream>>>(pos, sortedA, csA, sortedB, csB);

  // ---- down path ----
  knn_grid_rows_kernel<16, 16, 16, 2, 8192><<<dim3(128, BATCH), 256, 0, stream>>>(
      pos, sortedA, csA, 4097, 2048, idx0, d2s);
  down_mfma_kernel<6, 3, 128, 32, 1><<<dim3(2048, BATCH), 64, 0, stream>>>(
      pos, x, idx0, d0W1p, d0b1, d0W2p, d0b2, x1, 2048, 8192);
  knn_grid_rows_kernel<16, 16, 8, 2, 2048><<<dim3(32, BATCH), 256, 0, stream>>>(
      pos, sortedB, csB, 513, 512, idx1, d2s);
  down_mfma_kernel<131, 128, 256, 160, 1><<<dim3(512, BATCH), 64, 0, stream>>>(
      pos, x1, idx1, d1W1p, d1b1, d1W2p, d1b2, x2, 512, 2048);
  knn_kernel<16, 16><<<dim3(8, BATCH), 256, 0, stream>>>(pos, 512, 128, idx2, d2s);
  down_mfma_kernel<259, 256, 512, 288, 2><<<dim3(128, BATCH), 128, 0, stream>>>(
      pos, x2, idx2, d2W1p, d2b1, d2W2p, d2b2, x3, 128, 512);

  // ---- up path ----
  knn_kernel<4, 3><<<dim3(32, BATCH), 256, 0, stream>>>(pos, 128, 512, idxu0, d2u0);
  up_kernel<512, 256, 256, 8><<<dim3(64, BATCH), 256, 0, stream>>>(
      x3, 128, idxu0, d2u0, x2, u0W, u0b, up0o, 512);
  knn_kernel<4, 3><<<dim3(128, BATCH), 256, 0, stream>>>(pos, 512, 2048, idxu1, d2u1);
  up_kernel<256, 128, 128, 16><<<dim3(128, BATCH), 128, 0, stream>>>(
      up0o, 512, idxu1, d2u1, x1, u1W, u1b, up1o, 2048);
  knn_grid_flat_kernel<4, 3, 8, 1, 2048><<<dim3(512, BATCH), 256, 0, stream>>>(
      pos, sortedB, csB, 513, 8192, idxu2, d2u2);
  up2f_mfma_kernel<<<dim3(512, BATCH), 128, 0, stream>>>(
      up1o, idxu2, d2u2, x, pos, u2Wp, u2b, fW1p, fb1, fW2p, fb2, out);
}

// Round 2
// 423.493 us; speedup vs baseline: 1.1675x; 1.1086x over previous
//
#include <hip/hip_runtime.h>

#define NFULL 8192
#define BATCH 4

typedef unsigned long long u64;
typedef unsigned int u32;
typedef __attribute__((ext_vector_type(8))) short bf8_t;   // 8 bf16 (4 VGPRs)
typedef __attribute__((ext_vector_type(4))) float f4_t;    // MFMA C/D

__device__ __forceinline__ u32 fbias(float f) {
  u32 u = __float_as_uint(f);
  return (u & 0x80000000u) ? ~u : (u | 0x80000000u);
}
__device__ __forceinline__ float funbias(u32 b) {
  u32 u = (b & 0x80000000u) ? (b & 0x7fffffffu) : ~b;
  return __uint_as_float(u);
}
__device__ __forceinline__ short f2bf(float f) {
  u32 u = __float_as_uint(f);
  u32 r = u + 0x7FFFu + ((u >> 16) & 1u);
  return (short)(r >> 16);
}

// ------------------------------------------------ fused grid build (both) --
__global__ __launch_bounds__(256) void build_grids_kernel(
    const float* __restrict__ pos, float4* __restrict__ sortedA,
    int* __restrict__ csA, float4* __restrict__ sortedB, int* __restrict__ csB) {
  __shared__ int cnt[4096];
  __shared__ int partial[256];
  int which = blockIdx.y, b = blockIdx.x, t = threadIdx.x;
  int NREF = which ? 2048 : 8192;
  int GR = which ? 8 : 16;
  int NC = GR * GR * GR;
  float4* sorted = (which ? sortedB : sortedA) + (size_t)b * NREF;
  int* cs = (which ? csB : csA) + b * (which ? 513 : 4097);
  const float* pb = pos + (size_t)b * NFULL * 3;
  for (int c = t; c < NC; c += 256) cnt[c] = 0;
  __syncthreads();
  for (int p = t; p < NREF; p += 256) {
    float x = pb[p * 3 + 0], y = pb[p * 3 + 1], z = pb[p * 3 + 2];
    int cx = min(max((int)(x * GR), 0), GR - 1);
    int cy = min(max((int)(y * GR), 0), GR - 1);
    int cz = min(max((int)(z * GR), 0), GR - 1);
    atomicAdd(&cnt[(cz * GR + cy) * GR + cx], 1);
  }
  __syncthreads();
  int chunk = (NC + 255) / 256;
  int s = 0;
  for (int i = 0; i < chunk; ++i) {
    int c = t * chunk + i;
    if (c < NC) s += cnt[c];
  }
  partial[t] = s;
  __syncthreads();
  if (t == 0) {
    int run = 0;
    for (int i = 0; i < 256; ++i) { int v = partial[i]; partial[i] = run; run += v; }
  }
  __syncthreads();
  int run = partial[t];
  for (int i = 0; i < chunk; ++i) {
    int c = t * chunk + i;
    if (c < NC) { int v = cnt[c]; cnt[c] = run; run += v; }
  }
  __syncthreads();
  for (int c = t; c < NC; c += 256) cs[c] = cnt[c];
  if (t == 0) cs[NC] = NREF;
  __syncthreads();
  for (int p = t; p < NREF; p += 256) {
    float x = pb[p * 3 + 0], y = pb[p * 3 + 1], z = pb[p * 3 + 2];
    int cx = min(max((int)(x * GR), 0), GR - 1);
    int cy = min(max((int)(y * GR), 0), GR - 1);
    int cz = min(max((int)(z * GR), 0), GR - 1);
    int slot = atomicAdd(&cnt[(cz * GR + cy) * GR + cx], 1);
    sorted[slot] = make_float4(x, y, z, __uint_as_float((u32)p));
  }
}

// --------------------------------------------------- grouped insert core ---
template<int SL>
__device__ __forceinline__ void group_insert(u32 m16, u64 ck, int slot,
                                             u64& val, u64& tau) {
  if (m16) {
    while (m16) {
      int src = __ffs(m16) - 1;
      m16 &= m16 - 1;
      u64 c = __shfl((unsigned long long)ck, src, 16);
      u64 prev = __shfl_up((unsigned long long)val, 1, SL);
      if (slot == 0) prev = 0ull;
      val = (val <= c) ? val : ((prev <= c) ? c : prev);
    }
    tau = __shfl((unsigned long long)val, SL - 1, SL);
  }
}

// ------------------------- shared: scan a contiguous sorted[] range --------
template<int SL>
__device__ __forceinline__ void scan_range(const float4* __restrict__ sb,
    int s, int e, float qx, float qy, float qz, float qq,
    int g, int gl, int slot, u64& val, u64& tau) {
  for (int t0 = s; t0 < e; t0 += 16) {
    int j = t0 + gl;
    u64 ck = ~0ull;
    if (j < e) {
      float4 P = sb[j];
      float rr = P.x * P.x + P.y * P.y + P.z * P.z;
      float d2 = qq + rr - 2.0f * (qx * P.x + qy * P.y + qz * P.z);
      ck = ((u64)fbias(d2) << 32) | (u32)__float_as_uint(P.w);
    }
    u64 full = __ballot(ck < tau);
    u32 m16 = (u32)((full >> (g * 16)) & 0xFFFFull);
    group_insert<SL>(m16, ck, slot, val, tau);
  }
}

// Exactness: after scanning box B, if the KOUT-th smallest d2 is strictly
// less than the squared distance to the nearest NON-clipped face of B, no
// outside point can enter the top-KOUT. Ring expansion scans box(R+1)\box(R)
// exactly once per point via per-row segments; unique u64 keys keep the
// tie-breaking identical to the reference top_k.

// --------------------------------------- kNN grid, FLAT (NROW <= 16) -------
template<int SL, int KOUT, int GR, int R, int NREF>
__global__ __launch_bounds__(256) void knn_grid_flat_kernel(
    const float* __restrict__ pos, const float4* __restrict__ sorted,
    const int* __restrict__ cellStart, int csStride, int Mq,
    int* __restrict__ oidx, float* __restrict__ od2) {
  int b = blockIdx.y;
  int wv = threadIdx.x >> 6, lane = threadIdx.x & 63;
  int g = lane >> 4, gl = lane & 15;
  int q = blockIdx.x * 16 + wv * 4 + g;
  const float* pb = pos + (size_t)b * NFULL * 3;
  const float4* sb = sorted + (size_t)b * NREF;
  const int* cs = cellStart + b * csStride;
  float qx = pb[q * 3 + 0], qy = pb[q * 3 + 1], qz = pb[q * 3 + 2];
  float qq = qx * qx + qy * qy + qz * qz;
  int ix = min(max((int)(qx * GR), 0), GR - 1);
  int iy = min(max((int)(qy * GR), 0), GR - 1);
  int iz = min(max((int)(qz * GR), 0), GR - 1);
  int x0 = max(ix - R, 0), x1 = min(ix + R, GR - 1);
  int y0 = max(iy - R, 0), y1 = min(iy + R, GR - 1);
  int z0 = max(iz - R, 0), z1 = min(iz + R, GR - 1);

  int ny = y1 - y0 + 1;
  int nrow = (z1 - z0 + 1) * ny;  // <= 9 for R=1
  int s_i = 0, len_i = 0;
  if (gl < nrow) {
    int zz = z0 + gl / ny, yy = y0 + gl % ny;
    int c0 = (zz * GR + yy) * GR + x0;
    s_i = cs[c0];
    len_i = cs[c0 + (x1 - x0) + 1] - s_i;
  }
  int p_i = len_i;
#pragma unroll
  for (int st = 1; st < 16; st <<= 1) {
    int o = __shfl_up(p_i, st, 16);
    if (gl >= st) p_i += o;
  }
  int T = __shfl(p_i, 15, 16);
  p_i -= len_i;              // exclusive prefix
  int d_i = s_i - p_i;       // sorted index = v + d_row
  if (gl >= nrow) p_i = 0x7fffffff;

  int slot = gl & (SL - 1);
  u64 val = ~0ull, tau = ~0ull;

  for (int v0 = 0; v0 < T; v0 += 16) {  // T group-uniform
    int v = v0 + gl;
    int r = 0;
#pragma unroll
    for (int st = 8; st >= 1; st >>= 1) {
      int pc = __shfl(p_i, r + st, 16);
      if (v >= pc) r += st;
    }
    int addr = v + __shfl(d_i, r, 16);
    u64 ck = ~0ull;
    if (v < T) {
      float4 P = sb[addr];
      float rr = P.x * P.x + P.y * P.y + P.z * P.z;
      float d2 = qq + rr - 2.0f * (qx * P.x + qy * P.y + qz * P.z);
      ck = ((u64)fbias(d2) << 32) | (u32)__float_as_uint(P.w);
    }
    u64 full = __ballot(ck < tau);
    u32 m16 = (u32)((full >> (g * 16)) & 0xFFFFull);
    group_insert<SL>(m16, ck, slot, val, tau);
  }

  const float h = 1.0f / GR;
  float m = 1e30f;
  if (x0 > 0)      m = fminf(m, qx - x0 * h);
  if (x1 < GR - 1) m = fminf(m, (x1 + 1) * h - qx);
  if (y0 > 0)      m = fminf(m, qy - y0 * h);
  if (y1 < GR - 1) m = fminf(m, (y1 + 1) * h - qy);
  if (z0 > 0)      m = fminf(m, qz - z0 * h);
  if (z1 < GR - 1) m = fminf(m, (z1 + 1) * h - qz);
  float bound = m * m;
  u64 kv = __shfl((unsigned long long)val, KOUT - 1, SL);
  float kth_d2 = funbias((u32)(kv >> 32));
  if (!(kth_d2 < bound)) {  // group-uniform; rare (corner/edge queries)
    // ---- ring expansion: box(R+1) \ box(R) via cell structure ----
    int X0 = max(ix - (R + 1), 0), X1 = min(ix + (R + 1), GR - 1);
    int Y0 = max(iy - (R + 1), 0), Y1 = min(iy + (R + 1), GR - 1);
    int Z0 = max(iz - (R + 1), 0), Z1 = min(iz + (R + 1), GR - 1);
    int NY2 = Y1 - Y0 + 1;
    int nrow2 = (Z1 - Z0 + 1) * NY2;
    for (int rr2 = 0; rr2 < nrow2; ++rr2) {
      int zz = Z0 + rr2 / NY2, yy = Y0 + rr2 % NY2;
      int c0 = (zz * GR + yy) * GR;
      bool mid = (zz >= z0 && zz <= z1 && yy >= y0 && yy <= y1);
      int s1 = cs[c0 + X0];
      int e1 = mid ? cs[c0 + x0] : cs[c0 + X1 + 1];
      scan_range<SL>(sb, s1, e1, qx, qy, qz, qq, g, gl, slot, val, tau);
      if (mid) {
        int s2 = cs[c0 + x1 + 1];
        int e2 = cs[c0 + X1 + 1];
        scan_range<SL>(sb, s2, e2, qx, qy, qz, qq, g, gl, slot, val, tau);
      }
    }
    x0 = X0; x1 = X1; y0 = Y0; y1 = Y1; z0 = Z0; z1 = Z1;
    m = 1e30f;
    if (x0 > 0)      m = fminf(m, qx - x0 * h);
    if (x1 < GR - 1) m = fminf(m, (x1 + 1) * h - qx);
    if (y0 > 0)      m = fminf(m, qy - y0 * h);
    if (y1 < GR - 1) m = fminf(m, (y1 + 1) * h - qy);
    if (z0 > 0)      m = fminf(m, qz - z0 * h);
    if (z1 < GR - 1) m = fminf(m, (z1 + 1) * h - qz);
    bound = m * m;
    kv = __shfl((unsigned long long)val, KOUT - 1, SL);
    kth_d2 = funbias((u32)(kv >> 32));
    if (!(kth_d2 < bound)) {  // essentially unreachable now
      for (int t0 = 0; t0 < NREF; t0 += 16) {
        int j = t0 + gl;
        u64 ck = ~0ull;
        if (j < NREF) {
          float4 P = sb[j];
          int cx = min(max((int)(P.x * GR), 0), GR - 1);
          int cy = min(max((int)(P.y * GR), 0), GR - 1);
          int cz = min(max((int)(P.z * GR), 0), GR - 1);
          bool inbox = (cx >= x0 && cx <= x1 && cy >= y0 && cy <= y1 &&
                        cz >= z0 && cz <= z1);
          if (!inbox) {
            float rr = P.x * P.x + P.y * P.y + P.z * P.z;
            float d2 = qq + rr - 2.0f * (qx * P.x + qy * P.y + qz * P.z);
            ck = ((u64)fbias(d2) << 32) | (u32)__float_as_uint(P.w);
          }
        }
        u64 full = __ballot(ck < tau);
        u32 m16 = (u32)((full >> (g * 16)) & 0xFFFFull);
        group_insert<SL>(m16, ck, slot, val, tau);
      }
    }
  }

  if (gl < KOUT) {
    size_t base = ((size_t)b * Mq + q) * KOUT;
    oidx[base + gl] = (int)(u32)val;
    od2[base + gl] = fmaxf(funbias((u32)(val >> 32)), 0.0f);
  }
}

// --------------------------------------- kNN grid, ROWS (NROW <= 32) -------
template<int SL, int KOUT, int GR, int R, int NREF>
__global__ __launch_bounds__(256) void knn_grid_rows_kernel(
    const float* __restrict__ pos, const float4* __restrict__ sorted,
    const int* __restrict__ cellStart, int csStride, int Mq,
    int* __restrict__ oidx, float* __restrict__ od2) {
  int b = blockIdx.y;
  int wv = threadIdx.x >> 6, lane = threadIdx.x & 63;
  int g = lane >> 4, gl = lane & 15;
  int q = blockIdx.x * 16 + wv * 4 + g;
  const float* pb = pos + (size_t)b * NFULL * 3;
  const float4* sb = sorted + (size_t)b * NREF;
  const int* cs = cellStart + b * csStride;
  float qx = pb[q * 3 + 0], qy = pb[q * 3 + 1], qz = pb[q * 3 + 2];
  float qq = qx * qx + qy * qy + qz * qz;
  int ix = min(max((int)(qx * GR), 0), GR - 1);
  int iy = min(max((int)(qy * GR), 0), GR - 1);
  int iz = min(max((int)(qz * GR), 0), GR - 1);
  int x0 = max(ix - R, 0), x1 = min(ix + R, GR - 1);
  int y0 = max(iy - R, 0), y1 = min(iy + R, GR - 1);
  int z0 = max(iz - R, 0), z1 = min(iz + R, GR - 1);

  int ny = y1 - y0 + 1;
  int nrow = (z1 - z0 + 1) * ny;  // <= 25 for R=2
  int sLo = 0, eLo = 0, sHi = 0, eHi = 0;
  if (gl < nrow) {
    int zz = z0 + gl / ny, yy = y0 + gl % ny;
    int c0 = (zz * GR + yy) * GR + x0;
    sLo = cs[c0]; eLo = cs[c0 + (x1 - x0) + 1];
  }
  {
    int i2 = gl + 16;
    if (i2 < nrow) {
      int zz = z0 + i2 / ny, yy = y0 + i2 % ny;
      int c0 = (zz * GR + yy) * GR + x0;
      sHi = cs[c0]; eHi = cs[c0 + (x1 - x0) + 1];
    }
  }

  int slot = gl & (SL - 1);
  u64 val = ~0ull, tau = ~0ull;

  for (int r = 0; r < nrow; ++r) {  // r group-uniform
    int sa = __shfl(sLo, r & 15, 16);
    int sb2 = __shfl(sHi, r & 15, 16);
    int ea = __shfl(eLo, r & 15, 16);
    int eb = __shfl(eHi, r & 15, 16);
    int s = (r < 16) ? sa : sb2;
    int e = (r < 16) ? ea : eb;
    scan_range<SL>(sb, s, e, qx, qy, qz, qq, g, gl, slot, val, tau);
  }

  const float h = 1.0f / GR;
  float m = 1e30f;
  if (x0 > 0)      m = fminf(m, qx - x0 * h);
  if (x1 < GR - 1) m = fminf(m, (x1 + 1) * h - qx);
  if (y0 > 0)      m = fminf(m, qy - y0 * h);
  if (y1 < GR - 1) m = fminf(m, (y1 + 1) * h - qy);
  if (z0 > 0)      m = fminf(m, qz - z0 * h);
  if (z1 < GR - 1) m = fminf(m, (z1 + 1) * h - qz);
  float bound = m * m;
  u64 kv = __shfl((unsigned long long)val, KOUT - 1, SL);
  float kth_d2 = funbias((u32)(kv >> 32));
  if (!(kth_d2 < bound)) {  // group-uniform; rare (corner/edge queries)
    int X0 = max(ix - (R + 1), 0), X1 = min(ix + (R + 1), GR - 1);
    int Y0 = max(iy - (R + 1), 0), Y1 = min(iy + (R + 1), GR - 1);
    int Z0 = max(iz - (R + 1), 0), Z1 = min(iz + (R + 1), GR - 1);
    int NY2 = Y1 - Y0 + 1;
    int nrow2 = (Z1 - Z0 + 1) * NY2;
    for (int rr2 = 0; rr2 < nrow2; ++rr2) {
      int zz = Z0 + rr2 / NY2, yy = Y0 + rr2 % NY2;
      int c0 = (zz * GR + yy) * GR;
      bool mid = (zz >= z0 && zz <= z1 && yy >= y0 && yy <= y1);
      int s1 = cs[c0 + X0];
      int e1 = mid ? cs[c0 + x0] : cs[c0 + X1 + 1];
      scan_range<SL>(sb, s1, e1, qx, qy, qz, qq, g, gl, slot, val, tau);
      if (mid) {
        int s2 = cs[c0 + x1 + 1];
        int e2 = cs[c0 + X1 + 1];
        scan_range<SL>(sb, s2, e2, qx, qy, qz, qq, g, gl, slot, val, tau);
      }
    }
    x0 = X0; x1 = X1; y0 = Y0; y1 = Y1; z0 = Z0; z1 = Z1;
    m = 1e30f;
    if (x0 > 0)      m = fminf(m, qx - x0 * h);
    if (x1 < GR - 1) m = fminf(m, (x1 + 1) * h - qx);
    if (y0 > 0)      m = fminf(m, qy - y0 * h);
    if (y1 < GR - 1) m = fminf(m, (y1 + 1) * h - qy);
    if (z0 > 0)      m = fminf(m, qz - z0 * h);
    if (z1 < GR - 1) m = fminf(m, (z1 + 1) * h - qz);
    bound = m * m;
    kv = __shfl((unsigned long long)val, KOUT - 1, SL);
    kth_d2 = funbias((u32)(kv >> 32));
    if (!(kth_d2 < bound)) {  // essentially unreachable now
      for (int t0 = 0; t0 < NREF; t0 += 16) {
        int j = t0 + gl;
        u64 ck = ~0ull;
        if (j < NREF) {
          float4 P = sb[j];
          int cx = min(max((int)(P.x * GR), 0), GR - 1);
          int cy = min(max((int)(P.y * GR), 0), GR - 1);
          int cz = min(max((int)(P.z * GR), 0), GR - 1);
          bool inbox = (cx >= x0 && cx <= x1 && cy >= y0 && cy <= y1 &&
                        cz >= z0 && cz <= z1);
          if (!inbox) {
            float rr = P.x * P.x + P.y * P.y + P.z * P.z;
            float d2 = qq + rr - 2.0f * (qx * P.x + qy * P.y + qz * P.z);
            ck = ((u64)fbias(d2) << 32) | (u32)__float_as_uint(P.w);
          }
        }
        u64 full = __ballot(ck < tau);
        u32 m16 = (u32)((full >> (g * 16)) & 0xFFFFull);
        group_insert<SL>(m16, ck, slot, val, tau);
      }
    }
  }

  if (gl < KOUT) {
    size_t base = ((size_t)b * Mq + q) * KOUT;
    oidx[base + gl] = (int)(u32)val;
    od2[base + gl] = fmaxf(funbias((u32)(val >> 32)), 0.0f);
  }
}

// -------------------------------------------------------- kNN (brute) ------
template<int SL, int KOUT>
__global__ __launch_bounds__(256) void knn_kernel(
    const float* __restrict__ pos, int Nref, int Mq,
    int* __restrict__ oidx, float* __restrict__ od2) {
  int b = blockIdx.y;
  int wv = threadIdx.x >> 6, lane = threadIdx.x & 63;
  int g = lane >> 4, gl = lane & 15;
  int q = blockIdx.x * 16 + wv * 4 + g;
  const float* pb = pos + (size_t)b * NFULL * 3;
  float qx = pb[q * 3 + 0], qy = pb[q * 3 + 1], qz = pb[q * 3 + 2];
  float qq = qx * qx + qy * qy + qz * qz;

  int slot = gl & (SL - 1);
  u64 val = ~0ull, tau = ~0ull;

  for (int t0 = 0; t0 < Nref; t0 += 16) {
    int j = t0 + gl;
    float rx = pb[j * 3 + 0];
    float ry = pb[j * 3 + 1];
    float rz = pb[j * 3 + 2];
    float rr = rx * rx + ry * ry + rz * rz;
    float d2 = qq + rr - 2.0f * (qx * rx + qy * ry + qz * rz);
    u64 ck = ((u64)fbias(d2) << 32) | (u32)j;
    u64 full = __ballot(ck < tau);
    u32 m16 = (u32)((full >> (g * 16)) & 0xFFFFull);
    group_insert<SL>(m16, ck, slot, val, tau);
  }

  if (gl < KOUT) {
    size_t base = ((size_t)b * Mq + q) * KOUT;
    oidx[base + gl] = (int)(u32)val;
    od2[base + gl] = fmaxf(funbias((u32)(val >> 32)), 0.0f);
  }
}

// ----------------------------------- fused weight packing + pos copy -------
__device__ __forceinline__ void pack_tile_rt(const float* __restrict__ W,
                                             short* __restrict__ outp,
                                             int KDIM, int N, int tile, int lane) {
  int NT = N >> 4;
  int kt = tile / NT, nt = tile - kt * NT;
  int n = nt * 16 + (lane & 15);
  int k0 = kt * 32 + (lane >> 4) * 8;
  bf8_t v;
#pragma unroll
  for (int j = 0; j < 8; ++j) {
    int k = k0 + j;
    v[j] = (k < KDIM) ? f2bf(W[(size_t)k * N + n]) : (short)0;
  }
  *(bf8_t*)(outp + ((size_t)tile * 64 + lane) * 8) = v;
}

__global__ __launch_bounds__(64) void pack_copy_all_kernel(
    const float* d0W1, short* d0W1p, const float* d0W2, short* d0W2p,
    const float* d1W1, short* d1W1p, const float* d1W2, short* d1W2p,
    const float* d2W1, short* d2W1p, const float* d2W2, short* d2W2p,
    const float* u2W, short* u2Wp, const float* fW1, short* fW1p,
    const float* fW2, short* fW2p,
    const float* u0W, short* u0Wp, const float* u1W, short* u1Wp,
    const float* pos, float* posOut) {
  int blk = blockIdx.x, lane = threadIdx.x;
  if      (blk < 8)    pack_tile_rt(d0W1, d0W1p, 6, 128, blk, lane);
  else if (blk < 40)   pack_tile_rt(d0W2, d0W2p, 128, 128, blk - 8, lane);
  else if (blk < 120)  pack_tile_rt(d1W1, d1W1p, 131, 256, blk - 40, lane);
  else if (blk < 248)  pack_tile_rt(d1W2, d1W2p, 256, 256, blk - 120, lane);
  else if (blk < 536)  pack_tile_rt(d2W1, d2W1p, 259, 512, blk - 248, lane);
  else if (blk < 1048) pack_tile_rt(d2W2, d2W2p, 512, 512, blk - 536, lane);
  else if (blk < 1088) pack_tile_rt(u2W, u2Wp, 134, 128, blk - 1048, lane);
  else if (blk < 1120) pack_tile_rt(fW1, fW1p, 128, 128, blk - 1088, lane);
  else if (blk < 1152) pack_tile_rt(fW2, fW2p, 128, 128, blk - 1120, lane);
  else if (blk < 1536) pack_tile_rt(u0W, u0Wp, 768, 256, blk - 1152, lane);
  else if (blk < 1632) pack_tile_rt(u1W, u1Wp, 384, 128, blk - 1536, lane);
  else {
    int base = (blk - 1632) * 256;  // 384 blocks x 256 = 98304 = BATCH*NFULL*3
#pragma unroll
    for (int j = 0; j < 4; ++j) {
      int i = base + lane + j * 64;
      posOut[i] = pos[i];
    }
  }
}

// ----------------------------------------------------- down MLP (MFMA) -----
template<int FEAT, int CIN, int CHID, int FPAD, int WPB>
__global__ __launch_bounds__(64 * WPB) void down_mfma_kernel(
    const float* __restrict__ pos, const float* __restrict__ xin,
    const int* __restrict__ idx,
    const short* __restrict__ W1p, const float* __restrict__ b1,
    const short* __restrict__ W2p, const float* __restrict__ b2,
    float* __restrict__ out, int n, int nprev) {
  const int KT1 = FPAD / 32, NT1 = CHID / 16;
  const int KT2 = CHID / 32, NT2 = CHID / 16;
  __shared__ short sFeat[16][FPAD];
  __shared__ short sH1[16][CHID];
  __shared__ int sIdx[16];
  __shared__ float sCtr[3];
  int b = blockIdx.y, q = blockIdx.x;
  int lane = threadIdx.x & 63, wv = threadIdx.x >> 6;
  const float* pb = pos + (size_t)b * NFULL * 3;
  const float* xb = xin + (size_t)b * nprev * CIN;
  if (threadIdx.x < 16) sIdx[threadIdx.x] = idx[((size_t)b * n + q) * 16 + threadIdx.x];
  if (threadIdx.x < 3) sCtr[threadIdx.x] = pb[q * 3 + threadIdx.x];
  __syncthreads();
  for (int e = threadIdx.x; e < 16 * FPAD; e += 64 * WPB) {
    int k = e / FPAD, c = e % FPAD;
    float v = 0.f;
    if (c < 3) v = pb[sIdx[k] * 3 + c] - sCtr[c];
    else if (c < FEAT) v = xb[(size_t)sIdx[k] * CIN + (c - 3)];
    sFeat[k][c] = f2bf(v);
  }
  __syncthreads();

  int col = lane & 15, quad = lane >> 4;
  bf8_t afr[KT1];
#pragma unroll
  for (int kt = 0; kt < KT1; ++kt)
    afr[kt] = *(const bf8_t*)&sFeat[col][kt * 32 + quad * 8];
  const bf8_t* W1t = (const bf8_t*)W1p;
  for (int nt = 2 * wv; nt < NT1; nt += 2 * WPB) {
    float bb0 = b1[nt * 16 + col], bb1 = b1[nt * 16 + 16 + col];
    f4_t acc0 = {bb0, bb0, bb0, bb0}, acc1 = {bb1, bb1, bb1, bb1};
#pragma unroll
    for (int kt = 0; kt < KT1; ++kt) {
      bf8_t bf0 = W1t[(kt * NT1 + nt) * 64 + lane];
      bf8_t bf1 = W1t[(kt * NT1 + nt + 1) * 64 + lane];
      acc0 = __builtin_amdgcn_mfma_f32_16x16x32_bf16(afr[kt], bf0, acc0, 0, 0, 0);
      acc1 = __builtin_amdgcn_mfma_f32_16x16x32_bf16(afr[kt], bf1, acc1, 0, 0, 0);
    }
#pragma unroll
    for (int r = 0; r < 4; ++r) {
      sH1[quad * 4 + r][nt * 16 + col] = f2bf(fmaxf(acc0[r], 0.f));
      sH1[quad * 4 + r][nt * 16 + 16 + col] = f2bf(fmaxf(acc1[r], 0.f));
    }
  }
  __syncthreads();

  bf8_t afr2[KT2];
#pragma unroll
  for (int kt = 0; kt < KT2; ++kt)
    afr2[kt] = *(const bf8_t*)&sH1[col][kt * 32 + quad * 8];
  const bf8_t* W2t = (const bf8_t*)W2p;
  float* ob = out + ((size_t)b * n + q) * CHID;
  for (int nt = 2 * wv; nt < NT2; nt += 2 * WPB) {
    float bb0 = b2[nt * 16 + col], bb1 = b2[nt * 16 + 16 + col];
    f4_t acc0 = {bb0, bb0, bb0, bb0}, acc1 = {bb1, bb1, bb1, bb1};
#pragma unroll
    for (int kt = 0; kt < KT2; ++kt) {
      bf8_t bf0 = W2t[(kt * NT2 + nt) * 64 + lane];
      bf8_t bf1 = W2t[(kt * NT2 + nt + 1) * 64 + lane];
      acc0 = __builtin_amdgcn_mfma_f32_16x16x32_bf16(afr2[kt], bf0, acc0, 0, 0, 0);
      acc1 = __builtin_amdgcn_mfma_f32_16x16x32_bf16(afr2[kt], bf1, acc1, 0, 0, 0);
    }
    float m0 = fmaxf(fmaxf(acc0[0], acc0[1]), fmaxf(acc0[2], acc0[3]));
    float m1 = fmaxf(fmaxf(acc1[0], acc1[1]), fmaxf(acc1[2], acc1[3]));
    m0 = fmaxf(m0, __shfl_xor(m0, 16, 64));
    m0 = fmaxf(m0, __shfl_xor(m0, 32, 64));
    m1 = fmaxf(m1, __shfl_xor(m1, 16, 64));
    m1 = fmaxf(m1, __shfl_xor(m1, 32, 64));
    if (lane < 16) {
      ob[nt * 16 + lane] = m0;
      ob[nt * 16 + 16 + lane] = m1;
    }
  }
}

// -------------------------------------------- up MLP (bf16 MFMA version) ---
// 16 queries per block: gather+interp into a bf16 LDS tile, then
// [16 x CTOT] x [CTOT x COUT] via 16x16x32 bf16 MFMA against packed weights.
template<int CIN, int CPRV, int COUT, int WPB>
__global__ __launch_bounds__(64 * WPB) void up_mfma_kernel(
    const float* __restrict__ xc, int ncoarse,
    const int* __restrict__ idx3, const float* __restrict__ d23,
    const float* __restrict__ prv, const short* __restrict__ Wp,
    const float* __restrict__ bvec, float* __restrict__ out, int m) {
  const int CTOT = CIN + CPRV;
  const int KT = CTOT / 32, NT = COUT / 16;
  __shared__ short sA[16][CTOT];
  __shared__ float sWt[16][3];
  __shared__ int   sIt[16][3];
  int b = blockIdx.y, q0 = blockIdx.x * 16, t = threadIdx.x;
  int lane = t & 63, wv = t >> 6;
  if (t < 16) {
    size_t base = ((size_t)b * m + q0 + t) * 3;
    float d0 = d23[base + 0], d1 = d23[base + 1], d2v = d23[base + 2];
    float w0 = 1.f / (d0 + 1e-8f), w1 = 1.f / (d1 + 1e-8f), w2 = 1.f / (d2v + 1e-8f);
    float s = w0 + w1 + w2;
    sWt[t][0] = w0 / s; sWt[t][1] = w1 / s; sWt[t][2] = w2 / s;
    sIt[t][0] = idx3[base + 0]; sIt[t][1] = idx3[base + 1]; sIt[t][2] = idx3[base + 2];
  }
  __syncthreads();
  const float* xb = xc + (size_t)b * ncoarse * CIN;
  const float* pvb = prv + ((size_t)b * m + q0) * CPRV;
  for (int e = t; e < 16 * CIN; e += 64 * WPB) {
    int p = e / CIN, c = e % CIN;
    float v = sWt[p][0] * xb[(size_t)sIt[p][0] * CIN + c]
            + sWt[p][1] * xb[(size_t)sIt[p][1] * CIN + c]
            + sWt[p][2] * xb[(size_t)sIt[p][2] * CIN + c];
    sA[p][c] = f2bf(v);
  }
  for (int e = t; e < 16 * CPRV; e += 64 * WPB) {
    int p = e / CPRV, c = e % CPRV;
    sA[p][CIN + c] = f2bf(pvb[(size_t)p * CPRV + c]);
  }
  __syncthreads();
  int col = lane & 15, quad = lane >> 4;
  const bf8_t* Wt = (const bf8_t*)Wp;
  float* ob = out + ((size_t)b * m + q0) * COUT;
  for (int nt = 2 * wv; nt < NT; nt += 2 * WPB) {
    float bb0 = bvec[nt * 16 + col], bb1 = bvec[nt * 16 + 16 + col];
    f4_t acc0 = {bb0, bb0, bb0, bb0}, acc1 = {bb1, bb1, bb1, bb1};
#pragma unroll
    for (int kt = 0; kt < KT; ++kt) {
      bf8_t a = *(const bf8_t*)&sA[col][kt * 32 + quad * 8];
      bf8_t bf0 = Wt[(kt * NT + nt) * 64 + lane];
      bf8_t bf1 = Wt[(kt * NT + nt + 1) * 64 + lane];
      acc0 = __builtin_amdgcn_mfma_f32_16x16x32_bf16(a, bf0, acc0, 0, 0, 0);
      acc1 = __builtin_amdgcn_mfma_f32_16x16x32_bf16(a, bf1, acc1, 0, 0, 0);
    }
#pragma unroll
    for (int r = 0; r < 4; ++r) {
      ob[(size_t)(quad * 4 + r) * COUT + nt * 16 + col] = fmaxf(acc0[r], 0.f);
      ob[(size_t)(quad * 4 + r) * COUT + nt * 16 + 16 + col] = fmaxf(acc1[r], 0.f);
    }
  }
}

// ------------------------------------- fused up2 + final MLP (bf16 MFMA) ---
__global__ __launch_bounds__(128) void up2f_mfma_kernel(
    const float* __restrict__ xc,
    const int* __restrict__ idx3, const float* __restrict__ d23,
    const float* __restrict__ x0, const float* __restrict__ pos0,
    const short* __restrict__ u2Wp, const float* __restrict__ u2b,
    const short* __restrict__ fW1p, const float* __restrict__ fb1,
    const short* __restrict__ fW2p, const float* __restrict__ fb2,
    float* __restrict__ out) {
  __shared__ short sA[16][160];
  __shared__ short sB[16][128];
  __shared__ float sWt[16][3];
  __shared__ int   sIt[16][3];
  int b = blockIdx.y, q0 = blockIdx.x * 16, t = threadIdx.x;
  int lane = t & 63, wv = t >> 6;
  if (t < 16) {
    size_t base = ((size_t)b * NFULL + q0 + t) * 3;
    float d0 = d23[base + 0], d1 = d23[base + 1], d2v = d23[base + 2];
    float w0 = 1.f / (d0 + 1e-8f), w1 = 1.f / (d1 + 1e-8f), w2 = 1.f / (d2v + 1e-8f);
    float s = w0 + w1 + w2;
    sWt[t][0] = w0 / s; sWt[t][1] = w1 / s; sWt[t][2] = w2 / s;
    sIt[t][0] = idx3[base + 0]; sIt[t][1] = idx3[base + 1]; sIt[t][2] = idx3[base + 2];
  }
  __syncthreads();
  const float* xb = xc + (size_t)b * 2048 * 128;
#pragma unroll
  for (int p = 0; p < 16; ++p) {
    float v = sWt[p][0] * xb[(size_t)sIt[p][0] * 128 + t]
            + sWt[p][1] * xb[(size_t)sIt[p][1] * 128 + t]
            + sWt[p][2] * xb[(size_t)sIt[p][2] * 128 + t];
    sA[p][t] = f2bf(v);
  }
  for (int e = t; e < 16 * 32; e += 128) {
    int p = e / 32, c = 128 + (e % 32);
    float v = 0.f;
    if (c < 131) v = x0[((size_t)b * NFULL + q0 + p) * 3 + (c - 128)];
    else if (c < 134) v = pos0[((size_t)b * NFULL + q0 + p) * 3 + (c - 131)];
    sA[p][c] = f2bf(v);
  }
  __syncthreads();
  int col = lane & 15, quad = lane >> 4;

  bf8_t a1[5];
#pragma unroll
  for (int kt = 0; kt < 5; ++kt)
    a1[kt] = *(const bf8_t*)&sA[col][kt * 32 + quad * 8];
  const bf8_t* W1t = (const bf8_t*)u2Wp;
  for (int nt = 2 * wv; nt < 8; nt += 4) {
    float bb0 = u2b[nt * 16 + col], bb1 = u2b[nt * 16 + 16 + col];
    f4_t acc0 = {bb0, bb0, bb0, bb0}, acc1 = {bb1, bb1, bb1, bb1};
#pragma unroll
    for (int kt = 0; kt < 5; ++kt) {
      bf8_t bf0 = W1t[(kt * 8 + nt) * 64 + lane];
      bf8_t bf1 = W1t[(kt * 8 + nt + 1) * 64 + lane];
      acc0 = __builtin_amdgcn_mfma_f32_16x16x32_bf16(a1[kt], bf0, acc0, 0, 0, 0);
      acc1 = __builtin_amdgcn_mfma_f32_16x16x32_bf16(a1[kt], bf1, acc1, 0, 0, 0);
    }
#pragma unroll
    for (int r = 0; r < 4; ++r) {
      sB[quad * 4 + r][nt * 16 + col] = f2bf(fmaxf(acc0[r], 0.f));
      sB[quad * 4 + r][nt * 16 + 16 + col] = f2bf(fmaxf(acc1[r], 0.f));
    }
  }
  __syncthreads();

  bf8_t a2[4];
#pragma unroll
  for (int kt = 0; kt < 4; ++kt)
    a2[kt] = *(const bf8_t*)&sB[col][kt * 32 + quad * 8];
  const bf8_t* W2t = (const bf8_t*)fW1p;
  for (int nt = 2 * wv; nt < 8; nt += 4) {
    float bb0 = fb1[nt * 16 + col], bb1 = fb1[nt * 16 + 16 + col];
    f4_t acc0 = {bb0, bb0, bb0, bb0}, acc1 = {bb1, bb1, bb1, bb1};
#pragma unroll
    for (int kt = 0; kt < 4; ++kt) {
      bf8_t bf0 = W2t[(kt * 8 + nt) * 64 + lane];
      bf8_t bf1 = W2t[(kt * 8 + nt + 1) * 64 + lane];
      acc0 = __builtin_amdgcn_mfma_f32_16x16x32_bf16(a2[kt], bf0, acc0, 0, 0, 0);
      acc1 = __builtin_amdgcn_mfma_f32_16x16x32_bf16(a2[kt], bf1, acc1, 0, 0, 0);
    }
#pragma unroll
    for (int r = 0; r < 4; ++r) {
      sA[quad * 4 + r][nt * 16 + col] = f2bf(fmaxf(acc0[r], 0.f));
      sA[quad * 4 + r][nt * 16 + 16 + col] = f2bf(fmaxf(acc1[r], 0.f));
    }
  }
  __syncthreads();

  bf8_t a3[4];
#pragma unroll
  for (int kt = 0; kt < 4; ++kt)
    a3[kt] = *(const bf8_t*)&sA[col][kt * 32 + quad * 8];
  const bf8_t* W3t = (const bf8_t*)fW2p;
  float* ob = out + ((size_t)b * NFULL + q0) * 128;
  for (int nt = 2 * wv; nt < 8; nt += 4) {
    float bb0 = fb2[nt * 16 + col], bb1 = fb2[nt * 16 + 16 + col];
    f4_t acc0 = {bb0, bb0, bb0, bb0}, acc1 = {bb1, bb1, bb1, bb1};
#pragma unroll
    for (int kt = 0; kt < 4; ++kt) {
      bf8_t bf0 = W3t[(kt * 8 + nt) * 64 + lane];
      bf8_t bf1 = W3t[(kt * 8 + nt + 1) * 64 + lane];
      acc0 = __builtin_amdgcn_mfma_f32_16x16x32_bf16(a3[kt], bf0, acc0, 0, 0, 0);
      acc1 = __builtin_amdgcn_mfma_f32_16x16x32_bf16(a3[kt], bf1, acc1, 0, 0, 0);
    }
#pragma unroll
    for (int r = 0; r < 4; ++r) {
      ob[(size_t)(quad * 4 + r) * 128 + nt * 16 + col] = acc0[r];
      ob[(size_t)(quad * 4 + r) * 128 + nt * 16 + 16 + col] = acc1[r];
    }
  }
}

// ------------------------------------------------------------------ launch -
extern "C" void kernel_launch(void* const* d_in, const int* in_sizes, int n_in,
                              void* d_out, int out_size, void* d_ws, size_t ws_size,
                              hipStream_t stream) {
  const float* x    = (const float*)d_in[0];
  const float* pos  = (const float*)d_in[1];
  const float* d0W1 = (const float*)d_in[2];
  const float* d0b1 = (const float*)d_in[3];
  const float* d0W2 = (const float*)d_in[4];
  const float* d0b2 = (const float*)d_in[5];
  const float* d1W1 = (const float*)d_in[6];
  const float* d1b1 = (const float*)d_in[7];
  const float* d1W2 = (const float*)d_in[8];
  const float* d1b2 = (const float*)d_in[9];
  const float* d2W1 = (const float*)d_in[10];
  const float* d2b1 = (const float*)d_in[11];
  const float* d2W2 = (const float*)d_in[12];
  const float* d2b2 = (const float*)d_in[13];
  const float* u0W  = (const float*)d_in[14];
  const float* u0b  = (const float*)d_in[15];
  const float* u1W  = (const float*)d_in[16];
  const float* u1b  = (const float*)d_in[17];
  const float* u2W  = (const float*)d_in[18];
  const float* u2b  = (const float*)d_in[19];
  const float* fW1  = (const float*)d_in[20];
  const float* fb1  = (const float*)d_in[21];
  const float* fW2  = (const float*)d_in[22];
  const float* fb2  = (const float*)d_in[23];

  char* ws = (char*)d_ws;
  float* x1    = (float*)(ws + 0);
  float* x2    = (float*)(ws + 4194304);
  float* x3    = (float*)(ws + 6291456);
  float* up0o  = (float*)(ws + 7340032);
  float* up1o  = (float*)(ws + 9437184);
  int*   idx0  = (int*)  (ws + 13631488);
  int*   idx1  = (int*)  (ws + 14155776);
  int*   idx2  = (int*)  (ws + 14286848);
  float* d2s   = (float*)(ws + 14319616);
  int*   idxu0 = (int*)  (ws + 14843904);
  float* d2u0  = (float*)(ws + 14868480);
  int*   idxu1 = (int*)  (ws + 14893056);
  float* d2u1  = (float*)(ws + 14991360);
  int*   idxu2 = (int*)  (ws + 15089664);
  float* d2u2  = (float*)(ws + 15482880);
  short* d1W1p = (short*)(ws + 15876096);
  short* d1W2p = (short*)(ws + 15958016);
  short* d2W1p = (short*)(ws + 16089088);
  short* d2W2p = (short*)(ws + 16384000);
  short* d0W1p = (short*)(ws + 16908288);
  short* d0W2p = (short*)(ws + 16916480);
  float4* sortedA = (float4*)(ws + 16949248);  // 4*8192*16 = 524288
  int*    csA     = (int*)   (ws + 17473536);  // 4*4097*4  = 65552
  float4* sortedB = (float4*)(ws + 17539136);  // 4*2048*16 = 131072
  int*    csB     = (int*)   (ws + 17670208);  // 4*513*4   = 8208
  short* u2Wp  = (short*)(ws + 17697920);
  short* fW1p  = (short*)(ws + 17738880);
  short* fW2p  = (short*)(ws + 17771648);

  float* out = (float*)d_out;
  // Packed u0W/u1W live in the d_out main region: it is dead until the final
  // up2f_mfma_kernel writes it, and both are fully consumed before that.
  short* u0Wp = (short*)out;                       // 768*256*2 = 393216 B
  short* u1Wp = (short*)(out + 98304);             // 384*128*2 =  98304 B

  // ---- fused packing + pos passthrough; fused grid builds ----
  pack_copy_all_kernel<<<dim3(2016), 64, 0, stream>>>(
      d0W1, d0W1p, d0W2, d0W2p, d1W1, d1W1p, d1W2, d1W2p,
      d2W1, d2W1p, d2W2, d2W2p, u2W, u2Wp, fW1, fW1p, fW2, fW2p,
      u0W, u0Wp, u1W, u1Wp,
      pos, out + (size_t)BATCH * NFULL * 128);
  build_grids_kernel<<<dim3(BATCH, 2), 256, 0, stream>>>(pos, sortedA, csA, sortedB, csB);

  // ---- down path ----
  knn_grid_rows_kernel<16, 16, 16, 2, 8192><<<dim3(128, BATCH), 256, 0, stream>>>(
      pos, sortedA, csA, 4097, 2048, idx0, d2s);
  down_mfma_kernel<6, 3, 128, 32, 1><<<dim3(2048, BATCH), 64, 0, stream>>>(
      pos, x, idx0, d0W1p, d0b1, d0W2p, d0b2, x1, 2048, 8192);
  knn_grid_rows_kernel<16, 16, 8, 2, 2048><<<dim3(32, BATCH), 256, 0, stream>>>(
      pos, sortedB, csB, 513, 512, idx1, d2s);
  down_mfma_kernel<131, 128, 256, 160, 1><<<dim3(512, BATCH), 64, 0, stream>>>(
      pos, x1, idx1, d1W1p, d1b1, d1W2p, d1b2, x2, 512, 2048);
  knn_kernel<16, 16><<<dim3(8, BATCH), 256, 0, stream>>>(pos, 512, 128, idx2, d2s);
  down_mfma_kernel<259, 256, 512, 288, 2><<<dim3(128, BATCH), 128, 0, stream>>>(
      pos, x2, idx2, d2W1p, d2b1, d2W2p, d2b2, x3, 128, 512);

  // ---- up path ----
  knn_kernel<4, 3><<<dim3(32, BATCH), 256, 0, stream>>>(pos, 128, 512, idxu0, d2u0);
  up_mfma_kernel<512, 256, 256, 4><<<dim3(32, BATCH), 256, 0, stream>>>(
      x3, 128, idxu0, d2u0, x2, u0Wp, u0b, up0o, 512);
  knn_kernel<4, 3><<<dim3(128, BATCH), 256, 0, stream>>>(pos, 512, 2048, idxu1, d2u1);
  up_mfma_kernel<256, 128, 128, 2><<<dim3(128, BATCH), 128, 0, stream>>>(
      up0o, 512, idxu1, d2u1, x1, u1Wp, u1b, up1o, 2048);
  knn_grid_flat_kernel<4, 3, 8, 1, 2048><<<dim3(512, BATCH), 256, 0, stream>>>(
      pos, sortedB, csB, 513, 8192, idxu2, d2u2);
  up2f_mfma_kernel<<<dim3(512, BATCH), 128, 0, stream>>>(
      up1o, idxu2, d2u2, x, pos, u2Wp, u2b, fW1p, fb1, fW2p, fb2, out);
}

// Round 3
// 376.157 us; speedup vs baseline: 1.3144x; 1.1258x over previous
//
#include <hip/hip_runtime.h>

#define NFULL 8192
#define BATCH 4

typedef unsigned long long u64;
typedef unsigned int u32;
typedef __attribute__((ext_vector_type(8))) short bf8_t;   // 8 bf16 (4 VGPRs)
typedef __attribute__((ext_vector_type(4))) float f4_t;    // MFMA C/D

__device__ __forceinline__ u32 fbias(float f) {
  u32 u = __float_as_uint(f);
  return (u & 0x80000000u) ? ~u : (u | 0x80000000u);
}
__device__ __forceinline__ float funbias(u32 b) {
  u32 u = (b & 0x80000000u) ? (b & 0x7fffffffu) : ~b;
  return __uint_as_float(u);
}
__device__ __forceinline__ short f2bf(float f) {
  u32 u = __float_as_uint(f);
  u32 r = u + 0x7FFFu + ((u >> 16) & 1u);
  return (short)(r >> 16);
}

// ------------------------------------------------ fused grid build (both) --
__global__ __launch_bounds__(256) void build_grids_kernel(
    const float* __restrict__ pos, float4* __restrict__ sortedA,
    int* __restrict__ csA, float4* __restrict__ sortedB, int* __restrict__ csB) {
  __shared__ int cnt[4096];
  __shared__ int partial[256];
  int which = blockIdx.y, b = blockIdx.x, t = threadIdx.x;
  int NREF = which ? 2048 : 8192;
  int GR = which ? 8 : 16;
  int NC = GR * GR * GR;
  float4* sorted = (which ? sortedB : sortedA) + (size_t)b * NREF;
  int* cs = (which ? csB : csA) + b * (which ? 513 : 4097);
  const float* pb = pos + (size_t)b * NFULL * 3;
  for (int c = t; c < NC; c += 256) cnt[c] = 0;
  __syncthreads();
  for (int p = t; p < NREF; p += 256) {
    float x = pb[p * 3 + 0], y = pb[p * 3 + 1], z = pb[p * 3 + 2];
    int cx = min(max((int)(x * GR), 0), GR - 1);
    int cy = min(max((int)(y * GR), 0), GR - 1);
    int cz = min(max((int)(z * GR), 0), GR - 1);
    atomicAdd(&cnt[(cz * GR + cy) * GR + cx], 1);
  }
  __syncthreads();
  int chunk = (NC + 255) / 256;
  int s = 0;
  for (int i = 0; i < chunk; ++i) {
    int c = t * chunk + i;
    if (c < NC) s += cnt[c];
  }
  partial[t] = s;
  __syncthreads();
  if (t == 0) {
    int run = 0;
    for (int i = 0; i < 256; ++i) { int v = partial[i]; partial[i] = run; run += v; }
  }
  __syncthreads();
  int run = partial[t];
  for (int i = 0; i < chunk; ++i) {
    int c = t * chunk + i;
    if (c < NC) { int v = cnt[c]; cnt[c] = run; run += v; }
  }
  __syncthreads();
  for (int c = t; c < NC; c += 256) cs[c] = cnt[c];
  if (t == 0) cs[NC] = NREF;
  __syncthreads();
  for (int p = t; p < NREF; p += 256) {
    float x = pb[p * 3 + 0], y = pb[p * 3 + 1], z = pb[p * 3 + 2];
    int cx = min(max((int)(x * GR), 0), GR - 1);
    int cy = min(max((int)(y * GR), 0), GR - 1);
    int cz = min(max((int)(z * GR), 0), GR - 1);
    int slot = atomicAdd(&cnt[(cz * GR + cy) * GR + cx], 1);
    sorted[slot] = make_float4(x, y, z, __uint_as_float((u32)p));
  }
}

// --------------------------------------------------- grouped insert core ---
template<int SL>
__device__ __forceinline__ void group_insert(u32 m16, u64 ck, int slot,
                                             u64& val, u64& tau) {
  if (m16) {
    while (m16) {
      int src = __ffs(m16) - 1;
      m16 &= m16 - 1;
      u64 c = __shfl((unsigned long long)ck, src, 16);
      u64 prev = __shfl_up((unsigned long long)val, 1, SL);
      if (slot == 0) prev = 0ull;
      val = (val <= c) ? val : ((prev <= c) ? c : prev);
    }
    tau = __shfl((unsigned long long)val, SL - 1, SL);
  }
}

// ------------------------- shared: scan a contiguous sorted[] range --------
template<int SL>
__device__ __forceinline__ void scan_range(const float4* __restrict__ sb,
    int s, int e, float qx, float qy, float qz, float qq,
    int g, int gl, int slot, u64& val, u64& tau) {
  for (int t0 = s; t0 < e; t0 += 16) {
    int j = t0 + gl;
    u64 ck = ~0ull;
    if (j < e) {
      float4 P = sb[j];
      float rr = P.x * P.x + P.y * P.y + P.z * P.z;
      float d2 = qq + rr - 2.0f * (qx * P.x + qy * P.y + qz * P.z);
      ck = ((u64)fbias(d2) << 32) | (u32)__float_as_uint(P.w);
    }
    u64 full = __ballot(ck < tau);
    u32 m16 = (u32)((full >> (g * 16)) & 0xFFFFull);
    group_insert<SL>(m16, ck, slot, val, tau);
  }
}

// Exactness: after scanning box B, if the KOUT-th smallest d2 is strictly
// less than the squared distance to the nearest NON-clipped face of B, no
// outside point can enter the top-KOUT. Ring expansion scans box(R+1)\box(R)
// exactly once per point via per-row segments; unique u64 keys keep the
// tie-breaking identical to the reference top_k.

// --------------------------------------- kNN grid, FLAT (NROW <= 16) -------
template<int SL, int KOUT, int GR, int R, int NREF>
__global__ __launch_bounds__(256) void knn_grid_flat_kernel(
    const float* __restrict__ pos, const float4* __restrict__ sorted,
    const int* __restrict__ cellStart, int csStride, int Mq,
    int* __restrict__ oidx, float* __restrict__ od2) {
  int b = blockIdx.y;
  int wv = threadIdx.x >> 6, lane = threadIdx.x & 63;
  int g = lane >> 4, gl = lane & 15;
  int q = blockIdx.x * 16 + wv * 4 + g;
  const float* pb = pos + (size_t)b * NFULL * 3;
  const float4* sb = sorted + (size_t)b * NREF;
  const int* cs = cellStart + b * csStride;
  float qx = pb[q * 3 + 0], qy = pb[q * 3 + 1], qz = pb[q * 3 + 2];
  float qq = qx * qx + qy * qy + qz * qz;
  int ix = min(max((int)(qx * GR), 0), GR - 1);
  int iy = min(max((int)(qy * GR), 0), GR - 1);
  int iz = min(max((int)(qz * GR), 0), GR - 1);
  int x0 = max(ix - R, 0), x1 = min(ix + R, GR - 1);
  int y0 = max(iy - R, 0), y1 = min(iy + R, GR - 1);
  int z0 = max(iz - R, 0), z1 = min(iz + R, GR - 1);

  int ny = y1 - y0 + 1;
  int nrow = (z1 - z0 + 1) * ny;  // <= 9 for R=1
  int s_i = 0, len_i = 0;
  if (gl < nrow) {
    int zz = z0 + gl / ny, yy = y0 + gl % ny;
    int c0 = (zz * GR + yy) * GR + x0;
    s_i = cs[c0];
    len_i = cs[c0 + (x1 - x0) + 1] - s_i;
  }
  int p_i = len_i;
#pragma unroll
  for (int st = 1; st < 16; st <<= 1) {
    int o = __shfl_up(p_i, st, 16);
    if (gl >= st) p_i += o;
  }
  int T = __shfl(p_i, 15, 16);
  p_i -= len_i;              // exclusive prefix
  int d_i = s_i - p_i;       // sorted index = v + d_row
  if (gl >= nrow) p_i = 0x7fffffff;

  int slot = gl & (SL - 1);
  u64 val = ~0ull, tau = ~0ull;

  for (int v0 = 0; v0 < T; v0 += 16) {  // T group-uniform
    int v = v0 + gl;
    int r = 0;
#pragma unroll
    for (int st = 8; st >= 1; st >>= 1) {
      int pc = __shfl(p_i, r + st, 16);
      if (v >= pc) r += st;
    }
    int addr = v + __shfl(d_i, r, 16);
    u64 ck = ~0ull;
    if (v < T) {
      float4 P = sb[addr];
      float rr = P.x * P.x + P.y * P.y + P.z * P.z;
      float d2 = qq + rr - 2.0f * (qx * P.x + qy * P.y + qz * P.z);
      ck = ((u64)fbias(d2) << 32) | (u32)__float_as_uint(P.w);
    }
    u64 full = __ballot(ck < tau);
    u32 m16 = (u32)((full >> (g * 16)) & 0xFFFFull);
    group_insert<SL>(m16, ck, slot, val, tau);
  }

  const float h = 1.0f / GR;
  float m = 1e30f;
  if (x0 > 0)      m = fminf(m, qx - x0 * h);
  if (x1 < GR - 1) m = fminf(m, (x1 + 1) * h - qx);
  if (y0 > 0)      m = fminf(m, qy - y0 * h);
  if (y1 < GR - 1) m = fminf(m, (y1 + 1) * h - qy);
  if (z0 > 0)      m = fminf(m, qz - z0 * h);
  if (z1 < GR - 1) m = fminf(m, (z1 + 1) * h - qz);
  float bound = m * m;
  u64 kv = __shfl((unsigned long long)val, KOUT - 1, SL);
  float kth_d2 = funbias((u32)(kv >> 32));
  if (!(kth_d2 < bound)) {  // group-uniform; rare (corner/edge queries)
    // ---- ring expansion: box(R+1) \ box(R) via cell structure ----
    int X0 = max(ix - (R + 1), 0), X1 = min(ix + (R + 1), GR - 1);
    int Y0 = max(iy - (R + 1), 0), Y1 = min(iy + (R + 1), GR - 1);
    int Z0 = max(iz - (R + 1), 0), Z1 = min(iz + (R + 1), GR - 1);
    int NY2 = Y1 - Y0 + 1;
    int nrow2 = (Z1 - Z0 + 1) * NY2;
    for (int rr2 = 0; rr2 < nrow2; ++rr2) {
      int zz = Z0 + rr2 / NY2, yy = Y0 + rr2 % NY2;
      int c0 = (zz * GR + yy) * GR;
      bool mid = (zz >= z0 && zz <= z1 && yy >= y0 && yy <= y1);
      int s1 = cs[c0 + X0];
      int e1 = mid ? cs[c0 + x0] : cs[c0 + X1 + 1];
      scan_range<SL>(sb, s1, e1, qx, qy, qz, qq, g, gl, slot, val, tau);
      if (mid) {
        int s2 = cs[c0 + x1 + 1];
        int e2 = cs[c0 + X1 + 1];
        scan_range<SL>(sb, s2, e2, qx, qy, qz, qq, g, gl, slot, val, tau);
      }
    }
    x0 = X0; x1 = X1; y0 = Y0; y1 = Y1; z0 = Z0; z1 = Z1;
    m = 1e30f;
    if (x0 > 0)      m = fminf(m, qx - x0 * h);
    if (x1 < GR - 1) m = fminf(m, (x1 + 1) * h - qx);
    if (y0 > 0)      m = fminf(m, qy - y0 * h);
    if (y1 < GR - 1) m = fminf(m, (y1 + 1) * h - qy);
    if (z0 > 0)      m = fminf(m, qz - z0 * h);
    if (z1 < GR - 1) m = fminf(m, (z1 + 1) * h - qz);
    bound = m * m;
    kv = __shfl((unsigned long long)val, KOUT - 1, SL);
    kth_d2 = funbias((u32)(kv >> 32));
    if (!(kth_d2 < bound)) {  // essentially unreachable now
      for (int t0 = 0; t0 < NREF; t0 += 16) {
        int j = t0 + gl;
        u64 ck = ~0ull;
        if (j < NREF) {
          float4 P = sb[j];
          int cx = min(max((int)(P.x * GR), 0), GR - 1);
          int cy = min(max((int)(P.y * GR), 0), GR - 1);
          int cz = min(max((int)(P.z * GR), 0), GR - 1);
          bool inbox = (cx >= x0 && cx <= x1 && cy >= y0 && cy <= y1 &&
                        cz >= z0 && cz <= z1);
          if (!inbox) {
            float rr = P.x * P.x + P.y * P.y + P.z * P.z;
            float d2 = qq + rr - 2.0f * (qx * P.x + qy * P.y + qz * P.z);
            ck = ((u64)fbias(d2) << 32) | (u32)__float_as_uint(P.w);
          }
        }
        u64 full = __ballot(ck < tau);
        u32 m16 = (u32)((full >> (g * 16)) & 0xFFFFull);
        group_insert<SL>(m16, ck, slot, val, tau);
      }
    }
  }

  if (gl < KOUT) {
    size_t base = ((size_t)b * Mq + q) * KOUT;
    oidx[base + gl] = (int)(u32)val;
    od2[base + gl] = fmaxf(funbias((u32)(val >> 32)), 0.0f);
  }
}

// --------------------------------------- kNN grid, ROWS (NROW <= 32) -------
template<int SL, int KOUT, int GR, int R, int NREF>
__global__ __launch_bounds__(256) void knn_grid_rows_kernel(
    const float* __restrict__ pos, const float4* __restrict__ sorted,
    const int* __restrict__ cellStart, int csStride, int Mq,
    int* __restrict__ oidx, float* __restrict__ od2) {
  int b = blockIdx.y;
  int wv = threadIdx.x >> 6, lane = threadIdx.x & 63;
  int g = lane >> 4, gl = lane & 15;
  int q = blockIdx.x * 16 + wv * 4 + g;
  const float* pb = pos + (size_t)b * NFULL * 3;
  const float4* sb = sorted + (size_t)b * NREF;
  const int* cs = cellStart + b * csStride;
  float qx = pb[q * 3 + 0], qy = pb[q * 3 + 1], qz = pb[q * 3 + 2];
  float qq = qx * qx + qy * qy + qz * qz;
  int ix = min(max((int)(qx * GR), 0), GR - 1);
  int iy = min(max((int)(qy * GR), 0), GR - 1);
  int iz = min(max((int)(qz * GR), 0), GR - 1);
  int x0 = max(ix - R, 0), x1 = min(ix + R, GR - 1);
  int y0 = max(iy - R, 0), y1 = min(iy + R, GR - 1);
  int z0 = max(iz - R, 0), z1 = min(iz + R, GR - 1);

  int ny = y1 - y0 + 1;
  int nrow = (z1 - z0 + 1) * ny;  // <= 25 for R=2
  int sLo = 0, eLo = 0, sHi = 0, eHi = 0;
  if (gl < nrow) {
    int zz = z0 + gl / ny, yy = y0 + gl % ny;
    int c0 = (zz * GR + yy) * GR + x0;
    sLo = cs[c0]; eLo = cs[c0 + (x1 - x0) + 1];
  }
  {
    int i2 = gl + 16;
    if (i2 < nrow) {
      int zz = z0 + i2 / ny, yy = y0 + i2 % ny;
      int c0 = (zz * GR + yy) * GR + x0;
      sHi = cs[c0]; eHi = cs[c0 + (x1 - x0) + 1];
    }
  }

  int slot = gl & (SL - 1);
  u64 val = ~0ull, tau = ~0ull;

  for (int r = 0; r < nrow; ++r) {  // r group-uniform
    int sa = __shfl(sLo, r & 15, 16);
    int sb2 = __shfl(sHi, r & 15, 16);
    int ea = __shfl(eLo, r & 15, 16);
    int eb = __shfl(eHi, r & 15, 16);
    int s = (r < 16) ? sa : sb2;
    int e = (r < 16) ? ea : eb;
    scan_range<SL>(sb, s, e, qx, qy, qz, qq, g, gl, slot, val, tau);
  }

  const float h = 1.0f / GR;
  float m = 1e30f;
  if (x0 > 0)      m = fminf(m, qx - x0 * h);
  if (x1 < GR - 1) m = fminf(m, (x1 + 1) * h - qx);
  if (y0 > 0)      m = fminf(m, qy - y0 * h);
  if (y1 < GR - 1) m = fminf(m, (y1 + 1) * h - qy);
  if (z0 > 0)      m = fminf(m, qz - z0 * h);
  if (z1 < GR - 1) m = fminf(m, (z1 + 1) * h - qz);
  float bound = m * m;
  u64 kv = __shfl((unsigned long long)val, KOUT - 1, SL);
  float kth_d2 = funbias((u32)(kv >> 32));
  if (!(kth_d2 < bound)) {  // group-uniform; rare (corner/edge queries)
    int X0 = max(ix - (R + 1), 0), X1 = min(ix + (R + 1), GR - 1);
    int Y0 = max(iy - (R + 1), 0), Y1 = min(iy + (R + 1), GR - 1);
    int Z0 = max(iz - (R + 1), 0), Z1 = min(iz + (R + 1), GR - 1);
    int NY2 = Y1 - Y0 + 1;
    int nrow2 = (Z1 - Z0 + 1) * NY2;
    for (int rr2 = 0; rr2 < nrow2; ++rr2) {
      int zz = Z0 + rr2 / NY2, yy = Y0 + rr2 % NY2;
      int c0 = (zz * GR + yy) * GR;
      bool mid = (zz >= z0 && zz <= z1 && yy >= y0 && yy <= y1);
      int s1 = cs[c0 + X0];
      int e1 = mid ? cs[c0 + x0] : cs[c0 + X1 + 1];
      scan_range<SL>(sb, s1, e1, qx, qy, qz, qq, g, gl, slot, val, tau);
      if (mid) {
        int s2 = cs[c0 + x1 + 1];
        int e2 = cs[c0 + X1 + 1];
        scan_range<SL>(sb, s2, e2, qx, qy, qz, qq, g, gl, slot, val, tau);
      }
    }
    x0 = X0; x1 = X1; y0 = Y0; y1 = Y1; z0 = Z0; z1 = Z1;
    m = 1e30f;
    if (x0 > 0)      m = fminf(m, qx - x0 * h);
    if (x1 < GR - 1) m = fminf(m, (x1 + 1) * h - qx);
    if (y0 > 0)      m = fminf(m, qy - y0 * h);
    if (y1 < GR - 1) m = fminf(m, (y1 + 1) * h - qy);
    if (z0 > 0)      m = fminf(m, qz - z0 * h);
    if (z1 < GR - 1) m = fminf(m, (z1 + 1) * h - qz);
    bound = m * m;
    kv = __shfl((unsigned long long)val, KOUT - 1, SL);
    kth_d2 = funbias((u32)(kv >> 32));
    if (!(kth_d2 < bound)) {  // essentially unreachable now
      for (int t0 = 0; t0 < NREF; t0 += 16) {
        int j = t0 + gl;
        u64 ck = ~0ull;
        if (j < NREF) {
          float4 P = sb[j];
          int cx = min(max((int)(P.x * GR), 0), GR - 1);
          int cy = min(max((int)(P.y * GR), 0), GR - 1);
          int cz = min(max((int)(P.z * GR), 0), GR - 1);
          bool inbox = (cx >= x0 && cx <= x1 && cy >= y0 && cy <= y1 &&
                        cz >= z0 && cz <= z1);
          if (!inbox) {
            float rr = P.x * P.x + P.y * P.y + P.z * P.z;
            float d2 = qq + rr - 2.0f * (qx * P.x + qy * P.y + qz * P.z);
            ck = ((u64)fbias(d2) << 32) | (u32)__float_as_uint(P.w);
          }
        }
        u64 full = __ballot(ck < tau);
        u32 m16 = (u32)((full >> (g * 16)) & 0xFFFFull);
        group_insert<SL>(m16, ck, slot, val, tau);
      }
    }
  }

  if (gl < KOUT) {
    size_t base = ((size_t)b * Mq + q) * KOUT;
    oidx[base + gl] = (int)(u32)val;
    od2[base + gl] = fmaxf(funbias((u32)(val >> 32)), 0.0f);
  }
}

// -------------------------------------------------------- kNN (brute) ------
template<int SL, int KOUT>
__global__ __launch_bounds__(256) void knn_kernel(
    const float* __restrict__ pos, int Nref, int Mq,
    int* __restrict__ oidx, float* __restrict__ od2) {
  int b = blockIdx.y;
  int wv = threadIdx.x >> 6, lane = threadIdx.x & 63;
  int g = lane >> 4, gl = lane & 15;
  int q = blockIdx.x * 16 + wv * 4 + g;
  const float* pb = pos + (size_t)b * NFULL * 3;
  float qx = pb[q * 3 + 0], qy = pb[q * 3 + 1], qz = pb[q * 3 + 2];
  float qq = qx * qx + qy * qy + qz * qz;

  int slot = gl & (SL - 1);
  u64 val = ~0ull, tau = ~0ull;

  for (int t0 = 0; t0 < Nref; t0 += 16) {
    int j = t0 + gl;
    float rx = pb[j * 3 + 0];
    float ry = pb[j * 3 + 1];
    float rz = pb[j * 3 + 2];
    float rr = rx * rx + ry * ry + rz * rz;
    float d2 = qq + rr - 2.0f * (qx * rx + qy * ry + qz * rz);
    u64 ck = ((u64)fbias(d2) << 32) | (u32)j;
    u64 full = __ballot(ck < tau);
    u32 m16 = (u32)((full >> (g * 16)) & 0xFFFFull);
    group_insert<SL>(m16, ck, slot, val, tau);
  }

  if (gl < KOUT) {
    size_t base = ((size_t)b * Mq + q) * KOUT;
    oidx[base + gl] = (int)(u32)val;
    od2[base + gl] = fmaxf(funbias((u32)(val >> 32)), 0.0f);
  }
}

// ----------------------------------- fused weight packing + pos copy -------
__device__ __forceinline__ void pack_tile_rt(const float* __restrict__ W,
                                             short* __restrict__ outp,
                                             int KDIM, int N, int tile, int lane) {
  int NT = N >> 4;
  int kt = tile / NT, nt = tile - kt * NT;
  int n = nt * 16 + (lane & 15);
  int k0 = kt * 32 + (lane >> 4) * 8;
  bf8_t v;
#pragma unroll
  for (int j = 0; j < 8; ++j) {
    int k = k0 + j;
    v[j] = (k < KDIM) ? f2bf(W[(size_t)k * N + n]) : (short)0;
  }
  *(bf8_t*)(outp + ((size_t)tile * 64 + lane) * 8) = v;
}

__global__ __launch_bounds__(64) void pack_copy_all_kernel(
    const float* d0W1, short* d0W1p, const float* d0W2, short* d0W2p,
    const float* d1W1, short* d1W1p, const float* d1W2, short* d1W2p,
    const float* d2W1, short* d2W1p, const float* d2W2, short* d2W2p,
    const float* u2W, short* u2Wp, const float* fW1, short* fW1p,
    const float* fW2, short* fW2p,
    const float* u0W, short* u0Wp, const float* u1W, short* u1Wp,
    const float* pos, float* posOut) {
  int blk = blockIdx.x, lane = threadIdx.x;
  if      (blk < 8)    pack_tile_rt(d0W1, d0W1p, 6, 128, blk, lane);
  else if (blk < 40)   pack_tile_rt(d0W2, d0W2p, 128, 128, blk - 8, lane);
  else if (blk < 120)  pack_tile_rt(d1W1, d1W1p, 131, 256, blk - 40, lane);
  else if (blk < 248)  pack_tile_rt(d1W2, d1W2p, 256, 256, blk - 120, lane);
  else if (blk < 536)  pack_tile_rt(d2W1, d2W1p, 259, 512, blk - 248, lane);
  else if (blk < 1048) pack_tile_rt(d2W2, d2W2p, 512, 512, blk - 536, lane);
  else if (blk < 1088) pack_tile_rt(u2W, u2Wp, 134, 128, blk - 1048, lane);
  else if (blk < 1120) pack_tile_rt(fW1, fW1p, 128, 128, blk - 1088, lane);
  else if (blk < 1152) pack_tile_rt(fW2, fW2p, 128, 128, blk - 1120, lane);
  else if (blk < 1536) pack_tile_rt(u0W, u0Wp, 768, 256, blk - 1152, lane);
  else if (blk < 1632) pack_tile_rt(u1W, u1Wp, 384, 128, blk - 1536, lane);
  else {
    int base = (blk - 1632) * 256;  // 384 blocks x 256 = 98304 = BATCH*NFULL*3
#pragma unroll
    for (int j = 0; j < 4; ++j) {
      int i = base + lane + j * 64;
      posOut[i] = pos[i];
    }
  }
}

// ----------------------------------------------------- down MLP (MFMA) -----
// QB queries per block; weight tiles loaded ONCE per K-step and reused across
// all QB query A-fragments (acc[QB][2], fully unrolled -> registers).
// LDS rows padded +8 shorts: stride % 128 dwords != 0 kills the 16-way
// ds_read_b128 bank conflict (was SQ_LDS_BANK_CONFLICT=627K).
template<int FEAT, int CIN, int CHID, int FPAD, int QB, int WAVES>
__global__ __launch_bounds__(64 * WAVES) void down_mfma_kernel(
    const float* __restrict__ pos, const float* __restrict__ xin,
    const int* __restrict__ idx,
    const short* __restrict__ W1p, const float* __restrict__ b1,
    const short* __restrict__ W2p, const float* __restrict__ b2,
    float* __restrict__ out, int n, int nprev) {
  const int KT1 = FPAD / 32, NT1 = CHID / 16;
  const int KT2 = CHID / 32, NT2 = CHID / 16;
  __shared__ short sFeat[QB][16][FPAD + 8];
  __shared__ short sH1[QB][16][CHID + 8];
  __shared__ int sIdx[QB][16];
  __shared__ float sCtr[QB][3];
  int b = blockIdx.y, q0 = blockIdx.x * QB;
  int t = threadIdx.x;
  int lane = t & 63, wv = t >> 6;
  const float* pb = pos + (size_t)b * NFULL * 3;
  const float* xb = xin + (size_t)b * nprev * CIN;
  if (t < QB * 16)
    sIdx[t >> 4][t & 15] = idx[((size_t)b * n + q0 + (t >> 4)) * 16 + (t & 15)];
  if (t < QB * 3) sCtr[t / 3][t % 3] = pb[(q0 + t / 3) * 3 + (t % 3)];
  __syncthreads();
  for (int e = t; e < QB * 16 * FPAD; e += 64 * WAVES) {
    int k = e / FPAD, c = e - k * FPAD;
    int qq = k >> 4, kk = k & 15;
    float v = 0.f;
    if (c < 3) v = pb[sIdx[qq][kk] * 3 + c] - sCtr[qq][c];
    else if (c < FEAT) v = xb[(size_t)sIdx[qq][kk] * CIN + (c - 3)];
    sFeat[qq][kk][c] = f2bf(v);
  }
  __syncthreads();

  int col = lane & 15, quad = lane >> 4;
  const bf8_t* W1t = (const bf8_t*)W1p;
  for (int nt = 2 * wv; nt < NT1; nt += 2 * WAVES) {
    f4_t acc[QB][2];
    float bb0 = b1[nt * 16 + col], bb1 = b1[nt * 16 + 16 + col];
#pragma unroll
    for (int q = 0; q < QB; ++q) {
      acc[q][0] = {bb0, bb0, bb0, bb0};
      acc[q][1] = {bb1, bb1, bb1, bb1};
    }
#pragma unroll
    for (int kt = 0; kt < KT1; ++kt) {
      bf8_t bf0 = W1t[(kt * NT1 + nt) * 64 + lane];
      bf8_t bf1 = W1t[(kt * NT1 + nt + 1) * 64 + lane];
#pragma unroll
      for (int q = 0; q < QB; ++q) {
        bf8_t a = *(const bf8_t*)&sFeat[q][col][kt * 32 + quad * 8];
        acc[q][0] = __builtin_amdgcn_mfma_f32_16x16x32_bf16(a, bf0, acc[q][0], 0, 0, 0);
        acc[q][1] = __builtin_amdgcn_mfma_f32_16x16x32_bf16(a, bf1, acc[q][1], 0, 0, 0);
      }
    }
#pragma unroll
    for (int q = 0; q < QB; ++q)
#pragma unroll
      for (int r = 0; r < 4; ++r) {
        sH1[q][quad * 4 + r][nt * 16 + col] = f2bf(fmaxf(acc[q][0][r], 0.f));
        sH1[q][quad * 4 + r][nt * 16 + 16 + col] = f2bf(fmaxf(acc[q][1][r], 0.f));
      }
  }
  __syncthreads();

  const bf8_t* W2t = (const bf8_t*)W2p;
  for (int nt = 2 * wv; nt < NT2; nt += 2 * WAVES) {
    f4_t acc[QB][2];
    float bb0 = b2[nt * 16 + col], bb1 = b2[nt * 16 + 16 + col];
#pragma unroll
    for (int q = 0; q < QB; ++q) {
      acc[q][0] = {bb0, bb0, bb0, bb0};
      acc[q][1] = {bb1, bb1, bb1, bb1};
    }
#pragma unroll
    for (int kt = 0; kt < KT2; ++kt) {
      bf8_t bf0 = W2t[(kt * NT2 + nt) * 64 + lane];
      bf8_t bf1 = W2t[(kt * NT2 + nt + 1) * 64 + lane];
#pragma unroll
      for (int q = 0; q < QB; ++q) {
        bf8_t a = *(const bf8_t*)&sH1[q][col][kt * 32 + quad * 8];
        acc[q][0] = __builtin_amdgcn_mfma_f32_16x16x32_bf16(a, bf0, acc[q][0], 0, 0, 0);
        acc[q][1] = __builtin_amdgcn_mfma_f32_16x16x32_bf16(a, bf1, acc[q][1], 0, 0, 0);
      }
    }
#pragma unroll
    for (int q = 0; q < QB; ++q) {
      float m0 = fmaxf(fmaxf(acc[q][0][0], acc[q][0][1]), fmaxf(acc[q][0][2], acc[q][0][3]));
      float m1 = fmaxf(fmaxf(acc[q][1][0], acc[q][1][1]), fmaxf(acc[q][1][2], acc[q][1][3]));
      m0 = fmaxf(m0, __shfl_xor(m0, 16, 64));
      m0 = fmaxf(m0, __shfl_xor(m0, 32, 64));
      m1 = fmaxf(m1, __shfl_xor(m1, 16, 64));
      m1 = fmaxf(m1, __shfl_xor(m1, 32, 64));
      if (lane < 16) {
        float* ob = out + ((size_t)b * n + q0 + q) * CHID;
        ob[nt * 16 + lane] = m0;
        ob[nt * 16 + 16 + lane] = m1;
      }
    }
  }
}

// -------------------------------------------- up MLP (bf16 MFMA version) ---
template<int CIN, int CPRV, int COUT, int WPB>
__global__ __launch_bounds__(64 * WPB) void up_mfma_kernel(
    const float* __restrict__ xc, int ncoarse,
    const int* __restrict__ idx3, const float* __restrict__ d23,
    const float* __restrict__ prv, const short* __restrict__ Wp,
    const float* __restrict__ bvec, float* __restrict__ out, int m) {
  const int CTOT = CIN + CPRV;
  const int KT = CTOT / 32, NT = COUT / 16;
  __shared__ short sA[16][CTOT + 8];
  __shared__ float sWt[16][3];
  __shared__ int   sIt[16][3];
  int b = blockIdx.y, q0 = blockIdx.x * 16, t = threadIdx.x;
  int lane = t & 63, wv = t >> 6;
  if (t < 16) {
    size_t base = ((size_t)b * m + q0 + t) * 3;
    float d0 = d23[base + 0], d1 = d23[base + 1], d2v = d23[base + 2];
    float w0 = 1.f / (d0 + 1e-8f), w1 = 1.f / (d1 + 1e-8f), w2 = 1.f / (d2v + 1e-8f);
    float s = w0 + w1 + w2;
    sWt[t][0] = w0 / s; sWt[t][1] = w1 / s; sWt[t][2] = w2 / s;
    sIt[t][0] = idx3[base + 0]; sIt[t][1] = idx3[base + 1]; sIt[t][2] = idx3[base + 2];
  }
  __syncthreads();
  const float* xb = xc + (size_t)b * ncoarse * CIN;
  const float* pvb = prv + ((size_t)b * m + q0) * CPRV;
  for (int e = t; e < 16 * CIN; e += 64 * WPB) {
    int p = e / CIN, c = e % CIN;
    float v = sWt[p][0] * xb[(size_t)sIt[p][0] * CIN + c]
            + sWt[p][1] * xb[(size_t)sIt[p][1] * CIN + c]
            + sWt[p][2] * xb[(size_t)sIt[p][2] * CIN + c];
    sA[p][c] = f2bf(v);
  }
  for (int e = t; e < 16 * CPRV; e += 64 * WPB) {
    int p = e / CPRV, c = e % CPRV;
    sA[p][CIN + c] = f2bf(pvb[(size_t)p * CPRV + c]);
  }
  __syncthreads();
  int col = lane & 15, quad = lane >> 4;
  const bf8_t* Wt = (const bf8_t*)Wp;
  float* ob = out + ((size_t)b * m + q0) * COUT;
  for (int nt = 2 * wv; nt < NT; nt += 2 * WPB) {
    float bb0 = bvec[nt * 16 + col], bb1 = bvec[nt * 16 + 16 + col];
    f4_t acc0 = {bb0, bb0, bb0, bb0}, acc1 = {bb1, bb1, bb1, bb1};
#pragma unroll
    for (int kt = 0; kt < KT; ++kt) {
      bf8_t a = *(const bf8_t*)&sA[col][kt * 32 + quad * 8];
      bf8_t bf0 = Wt[(kt * NT + nt) * 64 + lane];
      bf8_t bf1 = Wt[(kt * NT + nt + 1) * 64 + lane];
      acc0 = __builtin_amdgcn_mfma_f32_16x16x32_bf16(a, bf0, acc0, 0, 0, 0);
      acc1 = __builtin_amdgcn_mfma_f32_16x16x32_bf16(a, bf1, acc1, 0, 0, 0);
    }
#pragma unroll
    for (int r = 0; r < 4; ++r) {
      ob[(size_t)(quad * 4 + r) * COUT + nt * 16 + col] = fmaxf(acc0[r], 0.f);
      ob[(size_t)(quad * 4 + r) * COUT + nt * 16 + 16 + col] = fmaxf(acc1[r], 0.f);
    }
  }
}

// ------------------------------------- fused up2 + final MLP (bf16 MFMA) ---
__global__ __launch_bounds__(128) void up2f_mfma_kernel(
    const float* __restrict__ xc,
    const int* __restrict__ idx3, const float* __restrict__ d23,
    const float* __restrict__ x0, const float* __restrict__ pos0,
    const short* __restrict__ u2Wp, const float* __restrict__ u2b,
    const short* __restrict__ fW1p, const float* __restrict__ fb1,
    const short* __restrict__ fW2p, const float* __restrict__ fb2,
    float* __restrict__ out) {
  __shared__ short sA[16][168];
  __shared__ short sB[16][136];
  __shared__ float sWt[16][3];
  __shared__ int   sIt[16][3];
  int b = blockIdx.y, q0 = blockIdx.x * 16, t = threadIdx.x;
  int lane = t & 63, wv = t >> 6;
  if (t < 16) {
    size_t base = ((size_t)b * NFULL + q0 + t) * 3;
    float d0 = d23[base + 0], d1 = d23[base + 1], d2v = d23[base + 2];
    float w0 = 1.f / (d0 + 1e-8f), w1 = 1.f / (d1 + 1e-8f), w2 = 1.f / (d2v + 1e-8f);
    float s = w0 + w1 + w2;
    sWt[t][0] = w0 / s; sWt[t][1] = w1 / s; sWt[t][2] = w2 / s;
    sIt[t][0] = idx3[base + 0]; sIt[t][1] = idx3[base + 1]; sIt[t][2] = idx3[base + 2];
  }
  __syncthreads();
  const float* xb = xc + (size_t)b * 2048 * 128;
#pragma unroll
  for (int p = 0; p < 16; ++p) {
    float v = sWt[p][0] * xb[(size_t)sIt[p][0] * 128 + t]
            + sWt[p][1] * xb[(size_t)sIt[p][1] * 128 + t]
            + sWt[p][2] * xb[(size_t)sIt[p][2] * 128 + t];
    sA[p][t] = f2bf(v);
  }
  for (int e = t; e < 16 * 32; e += 128) {
    int p = e / 32, c = 128 + (e % 32);
    float v = 0.f;
    if (c < 131) v = x0[((size_t)b * NFULL + q0 + p) * 3 + (c - 128)];
    else if (c < 134) v = pos0[((size_t)b * NFULL + q0 + p) * 3 + (c - 131)];
    sA[p][c] = f2bf(v);
  }
  __syncthreads();
  int col = lane & 15, quad = lane >> 4;

  bf8_t a1[5];
#pragma unroll
  for (int kt = 0; kt < 5; ++kt)
    a1[kt] = *(const bf8_t*)&sA[col][kt * 32 + quad * 8];
  const bf8_t* W1t = (const bf8_t*)u2Wp;
  for (int nt = 2 * wv; nt < 8; nt += 4) {
    float bb0 = u2b[nt * 16 + col], bb1 = u2b[nt * 16 + 16 + col];
    f4_t acc0 = {bb0, bb0, bb0, bb0}, acc1 = {bb1, bb1, bb1, bb1};
#pragma unroll
    for (int kt = 0; kt < 5; ++kt) {
      bf8_t bf0 = W1t[(kt * 8 + nt) * 64 + lane];
      bf8_t bf1 = W1t[(kt * 8 + nt + 1) * 64 + lane];
      acc0 = __builtin_amdgcn_mfma_f32_16x16x32_bf16(a1[kt], bf0, acc0, 0, 0, 0);
      acc1 = __builtin_amdgcn_mfma_f32_16x16x32_bf16(a1[kt], bf1, acc1, 0, 0, 0);
    }
#pragma unroll
    for (int r = 0; r < 4; ++r) {
      sB[quad * 4 + r][nt * 16 + col] = f2bf(fmaxf(acc0[r], 0.f));
      sB[quad * 4 + r][nt * 16 + 16 + col] = f2bf(fmaxf(acc1[r], 0.f));
    }
  }
  __syncthreads();

  bf8_t a2[4];
#pragma unroll
  for (int kt = 0; kt < 4; ++kt)
    a2[kt] = *(const bf8_t*)&sB[col][kt * 32 + quad * 8];
  const bf8_t* W2t = (const bf8_t*)fW1p;
  for (int nt = 2 * wv; nt < 8; nt += 4) {
    float bb0 = fb1[nt * 16 + col], bb1 = fb1[nt * 16 + 16 + col];
    f4_t acc0 = {bb0, bb0, bb0, bb0}, acc1 = {bb1, bb1, bb1, bb1};
#pragma unroll
    for (int kt = 0; kt < 4; ++kt) {
      bf8_t bf0 = W2t[(kt * 8 + nt) * 64 + lane];
      bf8_t bf1 = W2t[(kt * 8 + nt + 1) * 64 + lane];
      acc0 = __builtin_amdgcn_mfma_f32_16x16x32_bf16(a2[kt], bf0, acc0, 0, 0, 0);
      acc1 = __builtin_amdgcn_mfma_f32_16x16x32_bf16(a2[kt], bf1, acc1, 0, 0, 0);
    }
#pragma unroll
    for (int r = 0; r < 4; ++r) {
      sA[quad * 4 + r][nt * 16 + col] = f2bf(fmaxf(acc0[r], 0.f));
      sA[quad * 4 + r][nt * 16 + 16 + col] = f2bf(fmaxf(acc1[r], 0.f));
    }
  }
  __syncthreads();

  bf8_t a3[4];
#pragma unroll
  for (int kt = 0; kt < 4; ++kt)
    a3[kt] = *(const bf8_t*)&sA[col][kt * 32 + quad * 8];
  const bf8_t* W3t = (const bf8_t*)fW2p;
  float* ob = out + ((size_t)b * NFULL + q0) * 128;
  for (int nt = 2 * wv; nt < 8; nt += 4) {
    float bb0 = fb2[nt * 16 + col], bb1 = fb2[nt * 16 + 16 + col];
    f4_t acc0 = {bb0, bb0, bb0, bb0}, acc1 = {bb1, bb1, bb1, bb1};
#pragma unroll
    for (int kt = 0; kt < 4; ++kt) {
      bf8_t bf0 = W3t[(kt * 8 + nt) * 64 + lane];
      bf8_t bf1 = W3t[(kt * 8 + nt + 1) * 64 + lane];
      acc0 = __builtin_amdgcn_mfma_f32_16x16x32_bf16(a3[kt], bf0, acc0, 0, 0, 0);
      acc1 = __builtin_amdgcn_mfma_f32_16x16x32_bf16(a3[kt], bf1, acc1, 0, 0, 0);
    }
#pragma unroll
    for (int r = 0; r < 4; ++r) {
      ob[(size_t)(quad * 4 + r) * 128 + nt * 16 + col] = acc0[r];
      ob[(size_t)(quad * 4 + r) * 128 + nt * 16 + 16 + col] = acc1[r];
    }
  }
}

// ------------------------------------------------------------------ launch -
extern "C" void kernel_launch(void* const* d_in, const int* in_sizes, int n_in,
                              void* d_out, int out_size, void* d_ws, size_t ws_size,
                              hipStream_t stream) {
  const float* x    = (const float*)d_in[0];
  const float* pos  = (const float*)d_in[1];
  const float* d0W1 = (const float*)d_in[2];
  const float* d0b1 = (const float*)d_in[3];
  const float* d0W2 = (const float*)d_in[4];
  const float* d0b2 = (const float*)d_in[5];
  const float* d1W1 = (const float*)d_in[6];
  const float* d1b1 = (const float*)d_in[7];
  const float* d1W2 = (const float*)d_in[8];
  const float* d1b2 = (const float*)d_in[9];
  const float* d2W1 = (const float*)d_in[10];
  const float* d2b1 = (const float*)d_in[11];
  const float* d2W2 = (const float*)d_in[12];
  const float* d2b2 = (const float*)d_in[13];
  const float* u0W  = (const float*)d_in[14];
  const float* u0b  = (const float*)d_in[15];
  const float* u1W  = (const float*)d_in[16];
  const float* u1b  = (const float*)d_in[17];
  const float* u2W  = (const float*)d_in[18];
  const float* u2b  = (const float*)d_in[19];
  const float* fW1  = (const float*)d_in[20];
  const float* fb1  = (const float*)d_in[21];
  const float* fW2  = (const float*)d_in[22];
  const float* fb2  = (const float*)d_in[23];

  char* ws = (char*)d_ws;
  float* x1    = (float*)(ws + 0);
  float* x2    = (float*)(ws + 4194304);
  float* x3    = (float*)(ws + 6291456);
  float* up0o  = (float*)(ws + 7340032);
  float* up1o  = (float*)(ws + 9437184);
  int*   idx0  = (int*)  (ws + 13631488);
  int*   idx1  = (int*)  (ws + 14155776);
  int*   idx2  = (int*)  (ws + 14286848);
  float* d2s   = (float*)(ws + 14319616);
  int*   idxu0 = (int*)  (ws + 14843904);
  float* d2u0  = (float*)(ws + 14868480);
  int*   idxu1 = (int*)  (ws + 14893056);
  float* d2u1  = (float*)(ws + 14991360);
  int*   idxu2 = (int*)  (ws + 15089664);
  float* d2u2  = (float*)(ws + 15482880);
  short* d1W1p = (short*)(ws + 15876096);
  short* d1W2p = (short*)(ws + 15958016);
  short* d2W1p = (short*)(ws + 16089088);
  short* d2W2p = (short*)(ws + 16384000);
  short* d0W1p = (short*)(ws + 16908288);
  short* d0W2p = (short*)(ws + 16916480);
  float4* sortedA = (float4*)(ws + 16949248);  // 4*8192*16 = 524288
  int*    csA     = (int*)   (ws + 17473536);  // 4*4097*4  = 65552
  float4* sortedB = (float4*)(ws + 17539136);  // 4*2048*16 = 131072
  int*    csB     = (int*)   (ws + 17670208);  // 4*513*4   = 8208
  short* u2Wp  = (short*)(ws + 17697920);
  short* fW1p  = (short*)(ws + 17738880);
  short* fW2p  = (short*)(ws + 17771648);

  float* out = (float*)d_out;
  // Packed u0W/u1W live in the d_out main region: it is dead until the final
  // up2f_mfma_kernel writes it, and both are fully consumed before that.
  short* u0Wp = (short*)out;                       // 768*256*2 = 393216 B
  short* u1Wp = (short*)(out + 98304);             // 384*128*2 =  98304 B

  // ---- fused packing + pos passthrough; fused grid builds ----
  pack_copy_all_kernel<<<dim3(2016), 64, 0, stream>>>(
      d0W1, d0W1p, d0W2, d0W2p, d1W1, d1W1p, d1W2, d1W2p,
      d2W1, d2W1p, d2W2, d2W2p, u2W, u2Wp, fW1, fW1p, fW2, fW2p,
      u0W, u0Wp, u1W, u1Wp,
      pos, out + (size_t)BATCH * NFULL * 128);
  build_grids_kernel<<<dim3(BATCH, 2), 256, 0, stream>>>(pos, sortedA, csA, sortedB, csB);

  // ---- down path ----
  knn_grid_rows_kernel<16, 16, 16, 2, 8192><<<dim3(128, BATCH), 256, 0, stream>>>(
      pos, sortedA, csA, 4097, 2048, idx0, d2s);
  down_mfma_kernel<6, 3, 128, 32, 4, 4><<<dim3(512, BATCH), 256, 0, stream>>>(
      pos, x, idx0, d0W1p, d0b1, d0W2p, d0b2, x1, 2048, 8192);
  knn_grid_rows_kernel<16, 16, 8, 2, 2048><<<dim3(32, BATCH), 256, 0, stream>>>(
      pos, sortedB, csB, 513, 512, idx1, d2s);
  down_mfma_kernel<131, 128, 256, 160, 4, 8><<<dim3(128, BATCH), 512, 0, stream>>>(
      pos, x1, idx1, d1W1p, d1b1, d1W2p, d1b2, x2, 512, 2048);
  knn_kernel<16, 16><<<dim3(8, BATCH), 256, 0, stream>>>(pos, 512, 128, idx2, d2s);
  down_mfma_kernel<259, 256, 512, 288, 2, 8><<<dim3(64, BATCH), 512, 0, stream>>>(
      pos, x2, idx2, d2W1p, d2b1, d2W2p, d2b2, x3, 128, 512);

  // ---- up path ----
  knn_kernel<4, 3><<<dim3(32, BATCH), 256, 0, stream>>>(pos, 128, 512, idxu0, d2u0);
  up_mfma_kernel<512, 256, 256, 4><<<dim3(32, BATCH), 256, 0, stream>>>(
      x3, 128, idxu0, d2u0, x2, u0Wp, u0b, up0o, 512);
  knn_kernel<4, 3><<<dim3(128, BATCH), 256, 0, stream>>>(pos, 512, 2048, idxu1, d2u1);
  up_mfma_kernel<256, 128, 128, 2><<<dim3(128, BATCH), 128, 0, stream>>>(
      up0o, 512, idxu1, d2u1, x1, u1Wp, u1b, up1o, 2048);
  knn_grid_flat_kernel<4, 3, 8, 1, 2048><<<dim3(512, BATCH), 256, 0, stream>>>(
      pos, sortedB, csB, 513, 8192, idxu2, d2u2);
  up2f_mfma_kernel<<<dim3(512, BATCH), 128, 0, stream>>>(
      up1o, idxu2, d2u2, x, pos, u2Wp, u2b, fW1p, fb1, fW2p, fb2, out);
}

// Round 4
// 322.679 us; speedup vs baseline: 1.5323x; 1.1657x over previous
//
#include <hip/hip_runtime.h>

#define NFULL 8192
#define BATCH 4

typedef unsigned long long u64;
typedef unsigned int u32;
typedef __attribute__((ext_vector_type(8))) short bf8_t;   // 8 bf16 (4 VGPRs)
typedef __attribute__((ext_vector_type(4))) float f4_t;    // MFMA C/D

__device__ __forceinline__ u32 fbias(float f) {
  u32 u = __float_as_uint(f);
  return (u & 0x80000000u) ? ~u : (u | 0x80000000u);
}
__device__ __forceinline__ float funbias(u32 b) {
  u32 u = (b & 0x80000000u) ? (b & 0x7fffffffu) : ~b;
  return __uint_as_float(u);
}
__device__ __forceinline__ short f2bf(float f) {
  u32 u = __float_as_uint(f);
  u32 r = u + 0x7FFFu + ((u >> 16) & 1u);
  return (short)(r >> 16);
}

// ------------------------------------------------ fused grid build (both) --
__global__ __launch_bounds__(256) void build_grids_kernel(
    const float* __restrict__ pos, float4* __restrict__ sortedA,
    int* __restrict__ csA, float4* __restrict__ sortedB, int* __restrict__ csB) {
  __shared__ int cnt[4096];
  __shared__ int partial[256];
  int which = blockIdx.y, b = blockIdx.x, t = threadIdx.x;
  int NREF = which ? 2048 : 8192;
  int GR = which ? 8 : 16;
  int NC = GR * GR * GR;
  float4* sorted = (which ? sortedB : sortedA) + (size_t)b * NREF;
  int* cs = (which ? csB : csA) + b * (which ? 513 : 4097);
  const float* pb = pos + (size_t)b * NFULL * 3;
  for (int c = t; c < NC; c += 256) cnt[c] = 0;
  __syncthreads();
  for (int p = t; p < NREF; p += 256) {
    float x = pb[p * 3 + 0], y = pb[p * 3 + 1], z = pb[p * 3 + 2];
    int cx = min(max((int)(x * GR), 0), GR - 1);
    int cy = min(max((int)(y * GR), 0), GR - 1);
    int cz = min(max((int)(z * GR), 0), GR - 1);
    atomicAdd(&cnt[(cz * GR + cy) * GR + cx], 1);
  }
  __syncthreads();
  int chunk = (NC + 255) / 256;
  int s = 0;
  for (int i = 0; i < chunk; ++i) {
    int c = t * chunk + i;
    if (c < NC) s += cnt[c];
  }
  partial[t] = s;
  __syncthreads();
  if (t == 0) {
    int run = 0;
    for (int i = 0; i < 256; ++i) { int v = partial[i]; partial[i] = run; run += v; }
  }
  __syncthreads();
  int run = partial[t];
  for (int i = 0; i < chunk; ++i) {
    int c = t * chunk + i;
    if (c < NC) { int v = cnt[c]; cnt[c] = run; run += v; }
  }
  __syncthreads();
  for (int c = t; c < NC; c += 256) cs[c] = cnt[c];
  if (t == 0) cs[NC] = NREF;
  __syncthreads();
  for (int p = t; p < NREF; p += 256) {
    float x = pb[p * 3 + 0], y = pb[p * 3 + 1], z = pb[p * 3 + 2];
    int cx = min(max((int)(x * GR), 0), GR - 1);
    int cy = min(max((int)(y * GR), 0), GR - 1);
    int cz = min(max((int)(z * GR), 0), GR - 1);
    int slot = atomicAdd(&cnt[(cz * GR + cy) * GR + cx], 1);
    sorted[slot] = make_float4(x, y, z, __uint_as_float((u32)p));
  }
}

// --------------------------------------------------- grouped insert core ---
template<int SL>
__device__ __forceinline__ void group_insert(u32 m16, u64 ck, int slot,
                                             u64& val, u64& tau) {
  if (m16) {
    while (m16) {
      int src = __ffs(m16) - 1;
      m16 &= m16 - 1;
      u64 c = __shfl((unsigned long long)ck, src, 16);
      u64 prev = __shfl_up((unsigned long long)val, 1, SL);
      if (slot == 0) prev = 0ull;
      val = (val <= c) ? val : ((prev <= c) ? c : prev);
    }
    tau = __shfl((unsigned long long)val, SL - 1, SL);
  }
}

// ------------------------- shared: scan a contiguous sorted[] range --------
template<int SL>
__device__ __forceinline__ void scan_range(const float4* __restrict__ sb,
    int s, int e, float qx, float qy, float qz, float qq,
    int g, int gl, int slot, u64& val, u64& tau) {
  for (int t0 = s; t0 < e; t0 += 16) {
    int j = t0 + gl;
    u64 ck = ~0ull;
    if (j < e) {
      float4 P = sb[j];
      float rr = P.x * P.x + P.y * P.y + P.z * P.z;
      float d2 = qq + rr - 2.0f * (qx * P.x + qy * P.y + qz * P.z);
      ck = ((u64)fbias(d2) << 32) | (u32)__float_as_uint(P.w);
    }
    u64 full = __ballot(ck < tau);
    u32 m16 = (u32)((full >> (g * 16)) & 0xFFFFull);
    group_insert<SL>(m16, ck, slot, val, tau);
  }
}

// Exactness: after scanning box B, if the KOUT-th smallest d2 is strictly
// less than the squared distance to the nearest NON-clipped face of B, no
// outside point can enter the top-KOUT. Ring expansion scans box(R+1)\box(R)
// exactly once per point via per-row segments; unique u64 keys keep the
// tie-breaking identical to the reference top_k.

// --------------------------------------- kNN grid, FLAT (NROW <= 16) -------
template<int SL, int KOUT, int GR, int R, int NREF>
__device__ void knn_grid_flat_dev(int vbx,
    const float* __restrict__ pos, const float4* __restrict__ sorted,
    const int* __restrict__ cellStart, int csStride, int Mq,
    int* __restrict__ oidx, float* __restrict__ od2) {
  int b = blockIdx.y;
  int wv = threadIdx.x >> 6, lane = threadIdx.x & 63;
  int g = lane >> 4, gl = lane & 15;
  int q = vbx * 16 + wv * 4 + g;
  const float* pb = pos + (size_t)b * NFULL * 3;
  const float4* sb = sorted + (size_t)b * NREF;
  const int* cs = cellStart + b * csStride;
  float qx = pb[q * 3 + 0], qy = pb[q * 3 + 1], qz = pb[q * 3 + 2];
  float qq = qx * qx + qy * qy + qz * qz;
  int ix = min(max((int)(qx * GR), 0), GR - 1);
  int iy = min(max((int)(qy * GR), 0), GR - 1);
  int iz = min(max((int)(qz * GR), 0), GR - 1);
  int x0 = max(ix - R, 0), x1 = min(ix + R, GR - 1);
  int y0 = max(iy - R, 0), y1 = min(iy + R, GR - 1);
  int z0 = max(iz - R, 0), z1 = min(iz + R, GR - 1);

  int ny = y1 - y0 + 1;
  int nrow = (z1 - z0 + 1) * ny;  // <= 9 for R=1
  int s_i = 0, len_i = 0;
  if (gl < nrow) {
    int zz = z0 + gl / ny, yy = y0 + gl % ny;
    int c0 = (zz * GR + yy) * GR + x0;
    s_i = cs[c0];
    len_i = cs[c0 + (x1 - x0) + 1] - s_i;
  }
  int p_i = len_i;
#pragma unroll
  for (int st = 1; st < 16; st <<= 1) {
    int o = __shfl_up(p_i, st, 16);
    if (gl >= st) p_i += o;
  }
  int T = __shfl(p_i, 15, 16);
  p_i -= len_i;              // exclusive prefix
  int d_i = s_i - p_i;       // sorted index = v + d_row
  if (gl >= nrow) p_i = 0x7fffffff;

  int slot = gl & (SL - 1);
  u64 val = ~0ull, tau = ~0ull;

  for (int v0 = 0; v0 < T; v0 += 16) {  // T group-uniform
    int v = v0 + gl;
    int r = 0;
#pragma unroll
    for (int st = 8; st >= 1; st >>= 1) {
      int pc = __shfl(p_i, r + st, 16);
      if (v >= pc) r += st;
    }
    int addr = v + __shfl(d_i, r, 16);
    u64 ck = ~0ull;
    if (v < T) {
      float4 P = sb[addr];
      float rr = P.x * P.x + P.y * P.y + P.z * P.z;
      float d2 = qq + rr - 2.0f * (qx * P.x + qy * P.y + qz * P.z);
      ck = ((u64)fbias(d2) << 32) | (u32)__float_as_uint(P.w);
    }
    u64 full = __ballot(ck < tau);
    u32 m16 = (u32)((full >> (g * 16)) & 0xFFFFull);
    group_insert<SL>(m16, ck, slot, val, tau);
  }

  const float h = 1.0f / GR;
  float m = 1e30f;
  if (x0 > 0)      m = fminf(m, qx - x0 * h);
  if (x1 < GR - 1) m = fminf(m, (x1 + 1) * h - qx);
  if (y0 > 0)      m = fminf(m, qy - y0 * h);
  if (y1 < GR - 1) m = fminf(m, (y1 + 1) * h - qy);
  if (z0 > 0)      m = fminf(m, qz - z0 * h);
  if (z1 < GR - 1) m = fminf(m, (z1 + 1) * h - qz);
  float bound = m * m;
  u64 kv = __shfl((unsigned long long)val, KOUT - 1, SL);
  float kth_d2 = funbias((u32)(kv >> 32));
  if (!(kth_d2 < bound)) {  // group-uniform; rare (corner/edge queries)
    // ---- ring expansion: box(R+1) \ box(R) via cell structure ----
    int X0 = max(ix - (R + 1), 0), X1 = min(ix + (R + 1), GR - 1);
    int Y0 = max(iy - (R + 1), 0), Y1 = min(iy + (R + 1), GR - 1);
    int Z0 = max(iz - (R + 1), 0), Z1 = min(iz + (R + 1), GR - 1);
    int NY2 = Y1 - Y0 + 1;
    int nrow2 = (Z1 - Z0 + 1) * NY2;
    for (int rr2 = 0; rr2 < nrow2; ++rr2) {
      int zz = Z0 + rr2 / NY2, yy = Y0 + rr2 % NY2;
      int c0 = (zz * GR + yy) * GR;
      bool mid = (zz >= z0 && zz <= z1 && yy >= y0 && yy <= y1);
      int s1 = cs[c0 + X0];
      int e1 = mid ? cs[c0 + x0] : cs[c0 + X1 + 1];
      scan_range<SL>(sb, s1, e1, qx, qy, qz, qq, g, gl, slot, val, tau);
      if (mid) {
        int s2 = cs[c0 + x1 + 1];
        int e2 = cs[c0 + X1 + 1];
        scan_range<SL>(sb, s2, e2, qx, qy, qz, qq, g, gl, slot, val, tau);
      }
    }
    x0 = X0; x1 = X1; y0 = Y0; y1 = Y1; z0 = Z0; z1 = Z1;
    m = 1e30f;
    if (x0 > 0)      m = fminf(m, qx - x0 * h);
    if (x1 < GR - 1) m = fminf(m, (x1 + 1) * h - qx);
    if (y0 > 0)      m = fminf(m, qy - y0 * h);
    if (y1 < GR - 1) m = fminf(m, (y1 + 1) * h - qy);
    if (z0 > 0)      m = fminf(m, qz - z0 * h);
    if (z1 < GR - 1) m = fminf(m, (z1 + 1) * h - qz);
    bound = m * m;
    kv = __shfl((unsigned long long)val, KOUT - 1, SL);
    kth_d2 = funbias((u32)(kv >> 32));
    if (!(kth_d2 < bound)) {  // essentially unreachable now
      for (int t0 = 0; t0 < NREF; t0 += 16) {
        int j = t0 + gl;
        u64 ck = ~0ull;
        if (j < NREF) {
          float4 P = sb[j];
          int cx = min(max((int)(P.x * GR), 0), GR - 1);
          int cy = min(max((int)(P.y * GR), 0), GR - 1);
          int cz = min(max((int)(P.z * GR), 0), GR - 1);
          bool inbox = (cx >= x0 && cx <= x1 && cy >= y0 && cy <= y1 &&
                        cz >= z0 && cz <= z1);
          if (!inbox) {
            float rr = P.x * P.x + P.y * P.y + P.z * P.z;
            float d2 = qq + rr - 2.0f * (qx * P.x + qy * P.y + qz * P.z);
            ck = ((u64)fbias(d2) << 32) | (u32)__float_as_uint(P.w);
          }
        }
        u64 full = __ballot(ck < tau);
        u32 m16 = (u32)((full >> (g * 16)) & 0xFFFFull);
        group_insert<SL>(m16, ck, slot, val, tau);
      }
    }
  }

  if (gl < KOUT) {
    size_t base = ((size_t)b * Mq + q) * KOUT;
    oidx[base + gl] = (int)(u32)val;
    od2[base + gl] = fmaxf(funbias((u32)(val >> 32)), 0.0f);
  }
}

// --------------------------------------- kNN grid, ROWS (NROW <= 32) -------
template<int SL, int KOUT, int GR, int R, int NREF>
__device__ void knn_grid_rows_dev(int vbx,
    const float* __restrict__ pos, const float4* __restrict__ sorted,
    const int* __restrict__ cellStart, int csStride, int Mq,
    int* __restrict__ oidx, float* __restrict__ od2) {
  int b = blockIdx.y;
  int wv = threadIdx.x >> 6, lane = threadIdx.x & 63;
  int g = lane >> 4, gl = lane & 15;
  int q = vbx * 16 + wv * 4 + g;
  const float* pb = pos + (size_t)b * NFULL * 3;
  const float4* sb = sorted + (size_t)b * NREF;
  const int* cs = cellStart + b * csStride;
  float qx = pb[q * 3 + 0], qy = pb[q * 3 + 1], qz = pb[q * 3 + 2];
  float qq = qx * qx + qy * qy + qz * qz;
  int ix = min(max((int)(qx * GR), 0), GR - 1);
  int iy = min(max((int)(qy * GR), 0), GR - 1);
  int iz = min(max((int)(qz * GR), 0), GR - 1);
  int x0 = max(ix - R, 0), x1 = min(ix + R, GR - 1);
  int y0 = max(iy - R, 0), y1 = min(iy + R, GR - 1);
  int z0 = max(iz - R, 0), z1 = min(iz + R, GR - 1);

  int ny = y1 - y0 + 1;
  int nrow = (z1 - z0 + 1) * ny;  // <= 25 for R=2
  int sLo = 0, eLo = 0, sHi = 0, eHi = 0;
  if (gl < nrow) {
    int zz = z0 + gl / ny, yy = y0 + gl % ny;
    int c0 = (zz * GR + yy) * GR + x0;
    sLo = cs[c0]; eLo = cs[c0 + (x1 - x0) + 1];
  }
  {
    int i2 = gl + 16;
    if (i2 < nrow) {
      int zz = z0 + i2 / ny, yy = y0 + i2 % ny;
      int c0 = (zz * GR + yy) * GR + x0;
      sHi = cs[c0]; eHi = cs[c0 + (x1 - x0) + 1];
    }
  }

  int slot = gl & (SL - 1);
  u64 val = ~0ull, tau = ~0ull;

  for (int r = 0; r < nrow; ++r) {  // r group-uniform
    int sa = __shfl(sLo, r & 15, 16);
    int sb2 = __shfl(sHi, r & 15, 16);
    int ea = __shfl(eLo, r & 15, 16);
    int eb = __shfl(eHi, r & 15, 16);
    int s = (r < 16) ? sa : sb2;
    int e = (r < 16) ? ea : eb;
    scan_range<SL>(sb, s, e, qx, qy, qz, qq, g, gl, slot, val, tau);
  }

  const float h = 1.0f / GR;
  float m = 1e30f;
  if (x0 > 0)      m = fminf(m, qx - x0 * h);
  if (x1 < GR - 1) m = fminf(m, (x1 + 1) * h - qx);
  if (y0 > 0)      m = fminf(m, qy - y0 * h);
  if (y1 < GR - 1) m = fminf(m, (y1 + 1) * h - qy);
  if (z0 > 0)      m = fminf(m, qz - z0 * h);
  if (z1 < GR - 1) m = fminf(m, (z1 + 1) * h - qz);
  float bound = m * m;
  u64 kv = __shfl((unsigned long long)val, KOUT - 1, SL);
  float kth_d2 = funbias((u32)(kv >> 32));
  if (!(kth_d2 < bound)) {  // group-uniform; rare (corner/edge queries)
    int X0 = max(ix - (R + 1), 0), X1 = min(ix + (R + 1), GR - 1);
    int Y0 = max(iy - (R + 1), 0), Y1 = min(iy + (R + 1), GR - 1);
    int Z0 = max(iz - (R + 1), 0), Z1 = min(iz + (R + 1), GR - 1);
    int NY2 = Y1 - Y0 + 1;
    int nrow2 = (Z1 - Z0 + 1) * NY2;
    for (int rr2 = 0; rr2 < nrow2; ++rr2) {
      int zz = Z0 + rr2 / NY2, yy = Y0 + rr2 % NY2;
      int c0 = (zz * GR + yy) * GR;
      bool mid = (zz >= z0 && zz <= z1 && yy >= y0 && yy <= y1);
      int s1 = cs[c0 + X0];
      int e1 = mid ? cs[c0 + x0] : cs[c0 + X1 + 1];
      scan_range<SL>(sb, s1, e1, qx, qy, qz, qq, g, gl, slot, val, tau);
      if (mid) {
        int s2 = cs[c0 + x1 + 1];
        int e2 = cs[c0 + X1 + 1];
        scan_range<SL>(sb, s2, e2, qx, qy, qz, qq, g, gl, slot, val, tau);
      }
    }
    x0 = X0; x1 = X1; y0 = Y0; y1 = Y1; z0 = Z0; z1 = Z1;
    m = 1e30f;
    if (x0 > 0)      m = fminf(m, qx - x0 * h);
    if (x1 < GR - 1) m = fminf(m, (x1 + 1) * h - qx);
    if (y0 > 0)      m = fminf(m, qy - y0 * h);
    if (y1 < GR - 1) m = fminf(m, (y1 + 1) * h - qy);
    if (z0 > 0)      m = fminf(m, qz - z0 * h);
    if (z1 < GR - 1) m = fminf(m, (z1 + 1) * h - qz);
    bound = m * m;
    kv = __shfl((unsigned long long)val, KOUT - 1, SL);
    kth_d2 = funbias((u32)(kv >> 32));
    if (!(kth_d2 < bound)) {  // essentially unreachable now
      for (int t0 = 0; t0 < NREF; t0 += 16) {
        int j = t0 + gl;
        u64 ck = ~0ull;
        if (j < NREF) {
          float4 P = sb[j];
          int cx = min(max((int)(P.x * GR), 0), GR - 1);
          int cy = min(max((int)(P.y * GR), 0), GR - 1);
          int cz = min(max((int)(P.z * GR), 0), GR - 1);
          bool inbox = (cx >= x0 && cx <= x1 && cy >= y0 && cy <= y1 &&
                        cz >= z0 && cz <= z1);
          if (!inbox) {
            float rr = P.x * P.x + P.y * P.y + P.z * P.z;
            float d2 = qq + rr - 2.0f * (qx * P.x + qy * P.y + qz * P.z);
            ck = ((u64)fbias(d2) << 32) | (u32)__float_as_uint(P.w);
          }
        }
        u64 full = __ballot(ck < tau);
        u32 m16 = (u32)((full >> (g * 16)) & 0xFFFFull);
        group_insert<SL>(m16, ck, slot, val, tau);
      }
    }
  }

  if (gl < KOUT) {
    size_t base = ((size_t)b * Mq + q) * KOUT;
    oidx[base + gl] = (int)(u32)val;
    od2[base + gl] = fmaxf(funbias((u32)(val >> 32)), 0.0f);
  }
}

// -------------------------------------------------------- kNN (brute) ------
template<int SL, int KOUT>
__device__ void knn_brute_dev(int vbx,
    const float* __restrict__ pos, int Nref, int Mq,
    int* __restrict__ oidx, float* __restrict__ od2) {
  int b = blockIdx.y;
  int wv = threadIdx.x >> 6, lane = threadIdx.x & 63;
  int g = lane >> 4, gl = lane & 15;
  int q = vbx * 16 + wv * 4 + g;
  const float* pb = pos + (size_t)b * NFULL * 3;
  float qx = pb[q * 3 + 0], qy = pb[q * 3 + 1], qz = pb[q * 3 + 2];
  float qq = qx * qx + qy * qy + qz * qz;

  int slot = gl & (SL - 1);
  u64 val = ~0ull, tau = ~0ull;

  for (int t0 = 0; t0 < Nref; t0 += 16) {
    int j = t0 + gl;
    float rx = pb[j * 3 + 0];
    float ry = pb[j * 3 + 1];
    float rz = pb[j * 3 + 2];
    float rr = rx * rx + ry * ry + rz * rz;
    float d2 = qq + rr - 2.0f * (qx * rx + qy * ry + qz * rz);
    u64 ck = ((u64)fbias(d2) << 32) | (u32)j;
    u64 full = __ballot(ck < tau);
    u32 m16 = (u32)((full >> (g * 16)) & 0xFFFFull);
    group_insert<SL>(m16, ck, slot, val, tau);
  }

  if (gl < KOUT) {
    size_t base = ((size_t)b * Mq + q) * KOUT;
    oidx[base + gl] = (int)(u32)val;
    od2[base + gl] = fmaxf(funbias((u32)(val >> 32)), 0.0f);
  }
}

// ----------------------------- fused: ALL SIX kNN queries in one dispatch --
// All depend only on pos + grids; fusing overlaps their low-occupancy tails.
// Block ranges ordered longest-pole-first.
__global__ __launch_bounds__(256) void knn_all_kernel(
    const float* __restrict__ pos,
    const float4* __restrict__ sortedA, const int* __restrict__ csA,
    const float4* __restrict__ sortedB, const int* __restrict__ csB,
    int* __restrict__ idx0,  float* __restrict__ d2s,
    int* __restrict__ idx1,  float* __restrict__ d2s1,
    int* __restrict__ idx2,  float* __restrict__ d2s2,
    int* __restrict__ idxu0, float* __restrict__ d2u0,
    int* __restrict__ idxu1, float* __restrict__ d2u1,
    int* __restrict__ idxu2, float* __restrict__ d2u2) {
  int bx = blockIdx.x;
  if (bx < 128)        // idx0: 2048 q over 8192 pts, K=16
    knn_grid_rows_dev<16, 16, 16, 2, 8192>(bx, pos, sortedA, csA, 4097, 2048, idx0, d2s);
  else if (bx < 640)   // idxu2: 8192 q over 2048 pts, K=3
    knn_grid_flat_dev<4, 3, 8, 1, 2048>(bx - 128, pos, sortedB, csB, 513, 8192, idxu2, d2u2);
  else if (bx < 768)   // idxu1: 2048 q over 512 pts (brute), K=3
    knn_brute_dev<4, 3>(bx - 640, pos, 512, 2048, idxu1, d2u1);
  else if (bx < 800)   // idx1: 512 q over 2048 pts, K=16
    knn_grid_rows_dev<16, 16, 8, 2, 2048>(bx - 768, pos, sortedB, csB, 513, 512, idx1, d2s1);
  else if (bx < 832)   // idxu0: 512 q over 128 pts (brute), K=3
    knn_brute_dev<4, 3>(bx - 800, pos, 128, 512, idxu0, d2u0);
  else                 // idx2: 128 q over 512 pts (brute), K=16
    knn_brute_dev<16, 16>(bx - 832, pos, 512, 128, idx2, d2s2);
}

// ----------------------------------- fused weight packing + pos copy -------
__device__ __forceinline__ void pack_tile_rt(const float* __restrict__ W,
                                             short* __restrict__ outp,
                                             int KDIM, int N, int tile, int lane) {
  int NT = N >> 4;
  int kt = tile / NT, nt = tile - kt * NT;
  int n = nt * 16 + (lane & 15);
  int k0 = kt * 32 + (lane >> 4) * 8;
  bf8_t v;
#pragma unroll
  for (int j = 0; j < 8; ++j) {
    int k = k0 + j;
    v[j] = (k < KDIM) ? f2bf(W[(size_t)k * N + n]) : (short)0;
  }
  *(bf8_t*)(outp + ((size_t)tile * 64 + lane) * 8) = v;
}

__global__ __launch_bounds__(64) void pack_copy_all_kernel(
    const float* d0W1, short* d0W1p, const float* d0W2, short* d0W2p,
    const float* d1W1, short* d1W1p, const float* d1W2, short* d1W2p,
    const float* d2W1, short* d2W1p, const float* d2W2, short* d2W2p,
    const float* u2W, short* u2Wp, const float* fW1, short* fW1p,
    const float* fW2, short* fW2p,
    const float* u0W, short* u0Wp, const float* u1W, short* u1Wp,
    const float* pos, float* posOut) {
  int blk = blockIdx.x, lane = threadIdx.x;
  if      (blk < 8)    pack_tile_rt(d0W1, d0W1p, 6, 128, blk, lane);
  else if (blk < 40)   pack_tile_rt(d0W2, d0W2p, 128, 128, blk - 8, lane);
  else if (blk < 120)  pack_tile_rt(d1W1, d1W1p, 131, 256, blk - 40, lane);
  else if (blk < 248)  pack_tile_rt(d1W2, d1W2p, 256, 256, blk - 120, lane);
  else if (blk < 536)  pack_tile_rt(d2W1, d2W1p, 259, 512, blk - 248, lane);
  else if (blk < 1048) pack_tile_rt(d2W2, d2W2p, 512, 512, blk - 536, lane);
  else if (blk < 1088) pack_tile_rt(u2W, u2Wp, 134, 128, blk - 1048, lane);
  else if (blk < 1120) pack_tile_rt(fW1, fW1p, 128, 128, blk - 1088, lane);
  else if (blk < 1152) pack_tile_rt(fW2, fW2p, 128, 128, blk - 1120, lane);
  else if (blk < 1536) pack_tile_rt(u0W, u0Wp, 768, 256, blk - 1152, lane);
  else if (blk < 1632) pack_tile_rt(u1W, u1Wp, 384, 128, blk - 1536, lane);
  else {
    int base = (blk - 1632) * 256;  // 384 blocks x 256 = 98304 = BATCH*NFULL*3
#pragma unroll
    for (int j = 0; j < 4; ++j) {
      int i = base + lane + j * 64;
      posOut[i] = pos[i];
    }
  }
}

// ----------------------------------------------------- down MLP (MFMA) -----
// QB queries per block; weight tiles loaded ONCE per K-step and reused across
// all QB query A-fragments. LDS rows padded +8 shorts (bank-conflict fix).
template<int FEAT, int CIN, int CHID, int FPAD, int QB, int WAVES>
__global__ __launch_bounds__(64 * WAVES) void down_mfma_kernel(
    const float* __restrict__ pos, const float* __restrict__ xin,
    const int* __restrict__ idx,
    const short* __restrict__ W1p, const float* __restrict__ b1,
    const short* __restrict__ W2p, const float* __restrict__ b2,
    float* __restrict__ out, int n, int nprev) {
  const int KT1 = FPAD / 32, NT1 = CHID / 16;
  const int KT2 = CHID / 32, NT2 = CHID / 16;
  __shared__ short sFeat[QB][16][FPAD + 8];
  __shared__ short sH1[QB][16][CHID + 8];
  __shared__ int sIdx[QB][16];
  __shared__ float sCtr[QB][3];
  int b = blockIdx.y, q0 = blockIdx.x * QB;
  int t = threadIdx.x;
  int lane = t & 63, wv = t >> 6;
  const float* pb = pos + (size_t)b * NFULL * 3;
  const float* xb = xin + (size_t)b * nprev * CIN;
  if (t < QB * 16)
    sIdx[t >> 4][t & 15] = idx[((size_t)b * n + q0 + (t >> 4)) * 16 + (t & 15)];
  if (t < QB * 3) sCtr[t / 3][t % 3] = pb[(q0 + t / 3) * 3 + (t % 3)];
  __syncthreads();
  for (int e = t; e < QB * 16 * FPAD; e += 64 * WAVES) {
    int k = e / FPAD, c = e - k * FPAD;
    int qq = k >> 4, kk = k & 15;
    float v = 0.f;
    if (c < 3) v = pb[sIdx[qq][kk] * 3 + c] - sCtr[qq][c];
    else if (c < FEAT) v = xb[(size_t)sIdx[qq][kk] * CIN + (c - 3)];
    sFeat[qq][kk][c] = f2bf(v);
  }
  __syncthreads();

  int col = lane & 15, quad = lane >> 4;
  const bf8_t* W1t = (const bf8_t*)W1p;
  for (int nt = 2 * wv; nt < NT1; nt += 2 * WAVES) {
    f4_t acc[QB][2];
    float bb0 = b1[nt * 16 + col], bb1 = b1[nt * 16 + 16 + col];
#pragma unroll
    for (int q = 0; q < QB; ++q) {
      acc[q][0] = {bb0, bb0, bb0, bb0};
      acc[q][1] = {bb1, bb1, bb1, bb1};
    }
#pragma unroll
    for (int kt = 0; kt < KT1; ++kt) {
      bf8_t bf0 = W1t[(kt * NT1 + nt) * 64 + lane];
      bf8_t bf1 = W1t[(kt * NT1 + nt + 1) * 64 + lane];
#pragma unroll
      for (int q = 0; q < QB; ++q) {
        bf8_t a = *(const bf8_t*)&sFeat[q][col][kt * 32 + quad * 8];
        acc[q][0] = __builtin_amdgcn_mfma_f32_16x16x32_bf16(a, bf0, acc[q][0], 0, 0, 0);
        acc[q][1] = __builtin_amdgcn_mfma_f32_16x16x32_bf16(a, bf1, acc[q][1], 0, 0, 0);
      }
    }
#pragma unroll
    for (int q = 0; q < QB; ++q)
#pragma unroll
      for (int r = 0; r < 4; ++r) {
        sH1[q][quad * 4 + r][nt * 16 + col] = f2bf(fmaxf(acc[q][0][r], 0.f));
        sH1[q][quad * 4 + r][nt * 16 + 16 + col] = f2bf(fmaxf(acc[q][1][r], 0.f));
      }
  }
  __syncthreads();

  const bf8_t* W2t = (const bf8_t*)W2p;
  for (int nt = 2 * wv; nt < NT2; nt += 2 * WAVES) {
    f4_t acc[QB][2];
    float bb0 = b2[nt * 16 + col], bb1 = b2[nt * 16 + 16 + col];
#pragma unroll
    for (int q = 0; q < QB; ++q) {
      acc[q][0] = {bb0, bb0, bb0, bb0};
      acc[q][1] = {bb1, bb1, bb1, bb1};
    }
#pragma unroll
    for (int kt = 0; kt < KT2; ++kt) {
      bf8_t bf0 = W2t[(kt * NT2 + nt) * 64 + lane];
      bf8_t bf1 = W2t[(kt * NT2 + nt + 1) * 64 + lane];
#pragma unroll
      for (int q = 0; q < QB; ++q) {
        bf8_t a = *(const bf8_t*)&sH1[q][col][kt * 32 + quad * 8];
        acc[q][0] = __builtin_amdgcn_mfma_f32_16x16x32_bf16(a, bf0, acc[q][0], 0, 0, 0);
        acc[q][1] = __builtin_amdgcn_mfma_f32_16x16x32_bf16(a, bf1, acc[q][1], 0, 0, 0);
      }
    }
#pragma unroll
    for (int q = 0; q < QB; ++q) {
      float m0 = fmaxf(fmaxf(acc[q][0][0], acc[q][0][1]), fmaxf(acc[q][0][2], acc[q][0][3]));
      float m1 = fmaxf(fmaxf(acc[q][1][0], acc[q][1][1]), fmaxf(acc[q][1][2], acc[q][1][3]));
      m0 = fmaxf(m0, __shfl_xor(m0, 16, 64));
      m0 = fmaxf(m0, __shfl_xor(m0, 32, 64));
      m1 = fmaxf(m1, __shfl_xor(m1, 16, 64));
      m1 = fmaxf(m1, __shfl_xor(m1, 32, 64));
      if (lane < 16) {
        float* ob = out + ((size_t)b * n + q0 + q) * CHID;
        ob[nt * 16 + lane] = m0;
        ob[nt * 16 + 16 + lane] = m1;
      }
    }
  }
}

// -------------------------------------------- up MLP (bf16 MFMA version) ---
template<int CIN, int CPRV, int COUT, int WPB>
__global__ __launch_bounds__(64 * WPB) void up_mfma_kernel(
    const float* __restrict__ xc, int ncoarse,
    const int* __restrict__ idx3, const float* __restrict__ d23,
    const float* __restrict__ prv, const short* __restrict__ Wp,
    const float* __restrict__ bvec, float* __restrict__ out, int m) {
  const int CTOT = CIN + CPRV;
  const int KT = CTOT / 32, NT = COUT / 16;
  __shared__ short sA[16][CTOT + 8];
  __shared__ float sWt[16][3];
  __shared__ int   sIt[16][3];
  int b = blockIdx.y, q0 = blockIdx.x * 16, t = threadIdx.x;
  int lane = t & 63, wv = t >> 6;
  if (t < 16) {
    size_t base = ((size_t)b * m + q0 + t) * 3;
    float d0 = d23[base + 0], d1 = d23[base + 1], d2v = d23[base + 2];
    float w0 = 1.f / (d0 + 1e-8f), w1 = 1.f / (d1 + 1e-8f), w2 = 1.f / (d2v + 1e-8f);
    float s = w0 + w1 + w2;
    sWt[t][0] = w0 / s; sWt[t][1] = w1 / s; sWt[t][2] = w2 / s;
    sIt[t][0] = idx3[base + 0]; sIt[t][1] = idx3[base + 1]; sIt[t][2] = idx3[base + 2];
  }
  __syncthreads();
  const float* xb = xc + (size_t)b * ncoarse * CIN;
  const float* pvb = prv + ((size_t)b * m + q0) * CPRV;
  for (int e = t; e < 16 * CIN; e += 64 * WPB) {
    int p = e / CIN, c = e % CIN;
    float v = sWt[p][0] * xb[(size_t)sIt[p][0] * CIN + c]
            + sWt[p][1] * xb[(size_t)sIt[p][1] * CIN + c]
            + sWt[p][2] * xb[(size_t)sIt[p][2] * CIN + c];
    sA[p][c] = f2bf(v);
  }
  for (int e = t; e < 16 * CPRV; e += 64 * WPB) {
    int p = e / CPRV, c = e % CPRV;
    sA[p][CIN + c] = f2bf(pvb[(size_t)p * CPRV + c]);
  }
  __syncthreads();
  int col = lane & 15, quad = lane >> 4;
  const bf8_t* Wt = (const bf8_t*)Wp;
  float* ob = out + ((size_t)b * m + q0) * COUT;
  for (int nt = 2 * wv; nt < NT; nt += 2 * WPB) {
    float bb0 = bvec[nt * 16 + col], bb1 = bvec[nt * 16 + 16 + col];
    f4_t acc0 = {bb0, bb0, bb0, bb0}, acc1 = {bb1, bb1, bb1, bb1};
#pragma unroll
    for (int kt = 0; kt < KT; ++kt) {
      bf8_t a = *(const bf8_t*)&sA[col][kt * 32 + quad * 8];
      bf8_t bf0 = Wt[(kt * NT + nt) * 64 + lane];
      bf8_t bf1 = Wt[(kt * NT + nt + 1) * 64 + lane];
      acc0 = __builtin_amdgcn_mfma_f32_16x16x32_bf16(a, bf0, acc0, 0, 0, 0);
      acc1 = __builtin_amdgcn_mfma_f32_16x16x32_bf16(a, bf1, acc1, 0, 0, 0);
    }
#pragma unroll
    for (int r = 0; r < 4; ++r) {
      ob[(size_t)(quad * 4 + r) * COUT + nt * 16 + col] = fmaxf(acc0[r], 0.f);
      ob[(size_t)(quad * 4 + r) * COUT + nt * 16 + 16 + col] = fmaxf(acc1[r], 0.f);
    }
  }
}

// ------------------------------------- fused up2 + final MLP (bf16 MFMA) ---
__global__ __launch_bounds__(128) void up2f_mfma_kernel(
    const float* __restrict__ xc,
    const int* __restrict__ idx3, const float* __restrict__ d23,
    const float* __restrict__ x0, const float* __restrict__ pos0,
    const short* __restrict__ u2Wp, const float* __restrict__ u2b,
    const short* __restrict__ fW1p, const float* __restrict__ fb1,
    const short* __restrict__ fW2p, const float* __restrict__ fb2,
    float* __restrict__ out) {
  __shared__ short sA[16][168];
  __shared__ short sB[16][136];
  __shared__ float sWt[16][3];
  __shared__ int   sIt[16][3];
  int b = blockIdx.y, q0 = blockIdx.x * 16, t = threadIdx.x;
  int lane = t & 63, wv = t >> 6;
  if (t < 16) {
    size_t base = ((size_t)b * NFULL + q0 + t) * 3;
    float d0 = d23[base + 0], d1 = d23[base + 1], d2v = d23[base + 2];
    float w0 = 1.f / (d0 + 1e-8f), w1 = 1.f / (d1 + 1e-8f), w2 = 1.f / (d2v + 1e-8f);
    float s = w0 + w1 + w2;
    sWt[t][0] = w0 / s; sWt[t][1] = w1 / s; sWt[t][2] = w2 / s;
    sIt[t][0] = idx3[base + 0]; sIt[t][1] = idx3[base + 1]; sIt[t][2] = idx3[base + 2];
  }
  __syncthreads();
  const float* xb = xc + (size_t)b * 2048 * 128;
#pragma unroll
  for (int p = 0; p < 16; ++p) {
    float v = sWt[p][0] * xb[(size_t)sIt[p][0] * 128 + t]
            + sWt[p][1] * xb[(size_t)sIt[p][1] * 128 + t]
            + sWt[p][2] * xb[(size_t)sIt[p][2] * 128 + t];
    sA[p][t] = f2bf(v);
  }
  for (int e = t; e < 16 * 32; e += 128) {
    int p = e / 32, c = 128 + (e % 32);
    float v = 0.f;
    if (c < 131) v = x0[((size_t)b * NFULL + q0 + p) * 3 + (c - 128)];
    else if (c < 134) v = pos0[((size_t)b * NFULL + q0 + p) * 3 + (c - 131)];
    sA[p][c] = f2bf(v);
  }
  __syncthreads();
  int col = lane & 15, quad = lane >> 4;

  bf8_t a1[5];
#pragma unroll
  for (int kt = 0; kt < 5; ++kt)
    a1[kt] = *(const bf8_t*)&sA[col][kt * 32 + quad * 8];
  const bf8_t* W1t = (const bf8_t*)u2Wp;
  for (int nt = 2 * wv; nt < 8; nt += 4) {
    float bb0 = u2b[nt * 16 + col], bb1 = u2b[nt * 16 + 16 + col];
    f4_t acc0 = {bb0, bb0, bb0, bb0}, acc1 = {bb1, bb1, bb1, bb1};
#pragma unroll
    for (int kt = 0; kt < 5; ++kt) {
      bf8_t bf0 = W1t[(kt * 8 + nt) * 64 + lane];
      bf8_t bf1 = W1t[(kt * 8 + nt + 1) * 64 + lane];
      acc0 = __builtin_amdgcn_mfma_f32_16x16x32_bf16(a1[kt], bf0, acc0, 0, 0, 0);
      acc1 = __builtin_amdgcn_mfma_f32_16x16x32_bf16(a1[kt], bf1, acc1, 0, 0, 0);
    }
#pragma unroll
    for (int r = 0; r < 4; ++r) {
      sB[quad * 4 + r][nt * 16 + col] = f2bf(fmaxf(acc0[r], 0.f));
      sB[quad * 4 + r][nt * 16 + 16 + col] = f2bf(fmaxf(acc1[r], 0.f));
    }
  }
  __syncthreads();

  bf8_t a2[4];
#pragma unroll
  for (int kt = 0; kt < 4; ++kt)
    a2[kt] = *(const bf8_t*)&sB[col][kt * 32 + quad * 8];
  const bf8_t* W2t = (const bf8_t*)fW1p;
  for (int nt = 2 * wv; nt < 8; nt += 4) {
    float bb0 = fb1[nt * 16 + col], bb1 = fb1[nt * 16 + 16 + col];
    f4_t acc0 = {bb0, bb0, bb0, bb0}, acc1 = {bb1, bb1, bb1, bb1};
#pragma unroll
    for (int kt = 0; kt < 4; ++kt) {
      bf8_t bf0 = W2t[(kt * 8 + nt) * 64 + lane];
      bf8_t bf1 = W2t[(kt * 8 + nt + 1) * 64 + lane];
      acc0 = __builtin_amdgcn_mfma_f32_16x16x32_bf16(a2[kt], bf0, acc0, 0, 0, 0);
      acc1 = __builtin_amdgcn_mfma_f32_16x16x32_bf16(a2[kt], bf1, acc1, 0, 0, 0);
    }
#pragma unroll
    for (int r = 0; r < 4; ++r) {
      sA[quad * 4 + r][nt * 16 + col] = f2bf(fmaxf(acc0[r], 0.f));
      sA[quad * 4 + r][nt * 16 + 16 + col] = f2bf(fmaxf(acc1[r], 0.f));
    }
  }
  __syncthreads();

  bf8_t a3[4];
#pragma unroll
  for (int kt = 0; kt < 4; ++kt)
    a3[kt] = *(const bf8_t*)&sA[col][kt * 32 + quad * 8];
  const bf8_t* W3t = (const bf8_t*)fW2p;
  float* ob = out + ((size_t)b * NFULL + q0) * 128;
  for (int nt = 2 * wv; nt < 8; nt += 4) {
    float bb0 = fb2[nt * 16 + col], bb1 = fb2[nt * 16 + 16 + col];
    f4_t acc0 = {bb0, bb0, bb0, bb0}, acc1 = {bb1, bb1, bb1, bb1};
#pragma unroll
    for (int kt = 0; kt < 4; ++kt) {
      bf8_t bf0 = W3t[(kt * 8 + nt) * 64 + lane];
      bf8_t bf1 = W3t[(kt * 8 + nt + 1) * 64 + lane];
      acc0 = __builtin_amdgcn_mfma_f32_16x16x32_bf16(a3[kt], bf0, acc0, 0, 0, 0);
      acc1 = __builtin_amdgcn_mfma_f32_16x16x32_bf16(a3[kt], bf1, acc1, 0, 0, 0);
    }
#pragma unroll
    for (int r = 0; r < 4; ++r) {
      ob[(size_t)(quad * 4 + r) * 128 + nt * 16 + col] = acc0[r];
      ob[(size_t)(quad * 4 + r) * 128 + nt * 16 + 16 + col] = acc1[r];
    }
  }
}

// ------------------------------------------------------------------ launch -
extern "C" void kernel_launch(void* const* d_in, const int* in_sizes, int n_in,
                              void* d_out, int out_size, void* d_ws, size_t ws_size,
                              hipStream_t stream) {
  const float* x    = (const float*)d_in[0];
  const float* pos  = (const float*)d_in[1];
  const float* d0W1 = (const float*)d_in[2];
  const float* d0b1 = (const float*)d_in[3];
  const float* d0W2 = (const float*)d_in[4];
  const float* d0b2 = (const float*)d_in[5];
  const float* d1W1 = (const float*)d_in[6];
  const float* d1b1 = (const float*)d_in[7];
  const float* d1W2 = (const float*)d_in[8];
  const float* d1b2 = (const float*)d_in[9];
  const float* d2W1 = (const float*)d_in[10];
  const float* d2b1 = (const float*)d_in[11];
  const float* d2W2 = (const float*)d_in[12];
  const float* d2b2 = (const float*)d_in[13];
  const float* u0W  = (const float*)d_in[14];
  const float* u0b  = (const float*)d_in[15];
  const float* u1W  = (const float*)d_in[16];
  const float* u1b  = (const float*)d_in[17];
  const float* u2W  = (const float*)d_in[18];
  const float* u2b  = (const float*)d_in[19];
  const float* fW1  = (const float*)d_in[20];
  const float* fb1  = (const float*)d_in[21];
  const float* fW2  = (const float*)d_in[22];
  const float* fb2  = (const float*)d_in[23];

  char* ws = (char*)d_ws;
  float* x1    = (float*)(ws + 0);
  float* x2    = (float*)(ws + 4194304);
  float* x3    = (float*)(ws + 6291456);
  float* up0o  = (float*)(ws + 7340032);
  float* up1o  = (float*)(ws + 9437184);
  int*   idx0  = (int*)  (ws + 13631488);
  int*   idx1  = (int*)  (ws + 14155776);
  int*   idx2  = (int*)  (ws + 14286848);
  float* d2s   = (float*)(ws + 14319616);
  int*   idxu0 = (int*)  (ws + 14843904);
  float* d2u0  = (float*)(ws + 14868480);
  int*   idxu1 = (int*)  (ws + 14893056);
  float* d2u1  = (float*)(ws + 14991360);
  int*   idxu2 = (int*)  (ws + 15089664);
  float* d2u2  = (float*)(ws + 15482880);
  short* d1W1p = (short*)(ws + 15876096);
  short* d1W2p = (short*)(ws + 15958016);
  short* d2W1p = (short*)(ws + 16089088);
  short* d2W2p = (short*)(ws + 16384000);
  short* d0W1p = (short*)(ws + 16908288);
  short* d0W2p = (short*)(ws + 16916480);
  float4* sortedA = (float4*)(ws + 16949248);  // 4*8192*16 = 524288
  int*    csA     = (int*)   (ws + 17473536);  // 4*4097*4  = 65552
  float4* sortedB = (float4*)(ws + 17539136);  // 4*2048*16 = 131072
  int*    csB     = (int*)   (ws + 17670208);  // 4*513*4   = 8208
  short* u2Wp  = (short*)(ws + 17697920);
  short* fW1p  = (short*)(ws + 17738880);
  short* fW2p  = (short*)(ws + 17771648);
  float* d2s1  = (float*)(ws + 17804416);      // 4*512*16*4 = 131072
  float* d2s2  = (float*)(ws + 17935488);      // 4*128*16*4 =  32768

  float* out = (float*)d_out;
  // Packed u0W/u1W live in the d_out main region: it is dead until the final
  // up2f_mfma_kernel writes it, and both are fully consumed before that.
  short* u0Wp = (short*)out;                       // 768*256*2 = 393216 B
  short* u1Wp = (short*)(out + 98304);             // 384*128*2 =  98304 B

  // ---- fused packing + pos passthrough; fused grid builds ----
  pack_copy_all_kernel<<<dim3(2016), 64, 0, stream>>>(
      d0W1, d0W1p, d0W2, d0W2p, d1W1, d1W1p, d1W2, d1W2p,
      d2W1, d2W1p, d2W2, d2W2p, u2W, u2Wp, fW1, fW1p, fW2, fW2p,
      u0W, u0Wp, u1W, u1Wp,
      pos, out + (size_t)BATCH * NFULL * 128);
  build_grids_kernel<<<dim3(BATCH, 2), 256, 0, stream>>>(pos, sortedA, csA, sortedB, csB);

  // ---- ALL kNN queries in one dispatch (deps: pos + grids only) ----
  knn_all_kernel<<<dim3(840, BATCH), 256, 0, stream>>>(
      pos, sortedA, csA, sortedB, csB,
      idx0, d2s, idx1, d2s1, idx2, d2s2,
      idxu0, d2u0, idxu1, d2u1, idxu2, d2u2);

  // ---- down path ----
  down_mfma_kernel<6, 3, 128, 32, 4, 4><<<dim3(512, BATCH), 256, 0, stream>>>(
      pos, x, idx0, d0W1p, d0b1, d0W2p, d0b2, x1, 2048, 8192);
  down_mfma_kernel<131, 128, 256, 160, 4, 8><<<dim3(128, BATCH), 512, 0, stream>>>(
      pos, x1, idx1, d1W1p, d1b1, d1W2p, d1b2, x2, 512, 2048);
  down_mfma_kernel<259, 256, 512, 288, 2, 8><<<dim3(64, BATCH), 512, 0, stream>>>(
      pos, x2, idx2, d2W1p, d2b1, d2W2p, d2b2, x3, 128, 512);

  // ---- up path ----
  up_mfma_kernel<512, 256, 256, 4><<<dim3(32, BATCH), 256, 0, stream>>>(
      x3, 128, idxu0, d2u0, x2, u0Wp, u0b, up0o, 512);
  up_mfma_kernel<256, 128, 128, 2><<<dim3(128, BATCH), 128, 0, stream>>>(
      up0o, 512, idxu1, d2u1, x1, u1Wp, u1b, up1o, 2048);
  up2f_mfma_kernel<<<dim3(512, BATCH), 128, 0, stream>>>(
      up1o, idxu2, d2u2, x, pos, u2Wp, u2b, fW1p, fb1, fW2p, fb2, out);
}

// Round 5
// 312.317 us; speedup vs baseline: 1.5831x; 1.0332x over previous
//
#include <hip/hip_runtime.h>

#define NFULL 8192
#define BATCH 4

typedef unsigned long long u64;
typedef unsigned int u32;
typedef __attribute__((ext_vector_type(8))) short bf8_t;   // 8 bf16 (4 VGPRs)
typedef __attribute__((ext_vector_type(4))) float f4_t;    // MFMA C/D

__device__ __forceinline__ u32 fbias(float f) {
  u32 u = __float_as_uint(f);
  return (u & 0x80000000u) ? ~u : (u | 0x80000000u);
}
__device__ __forceinline__ float funbias(u32 b) {
  u32 u = (b & 0x80000000u) ? (b & 0x7fffffffu) : ~b;
  return __uint_as_float(u);
}
__device__ __forceinline__ short f2bf(float f) {
  u32 u = __float_as_uint(f);
  u32 r = u + 0x7FFFu + ((u >> 16) & 1u);
  return (short)(r >> 16);
}

// ------------------------------------------- fused grid build (all three) --
// y=0: GR=16 over pos[:8192]; y=1: GR=8 over pos[:2048]; y=2: GR=8 over
// pos[:512]. All h = 2^-k -> margin arithmetic exact in fp32.
__global__ __launch_bounds__(256) void build_grids_kernel(
    const float* __restrict__ pos, float4* __restrict__ sortedA,
    int* __restrict__ csA, float4* __restrict__ sortedB, int* __restrict__ csB,
    float4* __restrict__ sortedC, int* __restrict__ csC) {
  __shared__ int cnt[4096];
  __shared__ int partial[256];
  int which = blockIdx.y, b = blockIdx.x, t = threadIdx.x;
  int NREF = (which == 0) ? 8192 : (which == 1) ? 2048 : 512;
  int GR = (which == 0) ? 16 : 8;
  int NC = GR * GR * GR;
  float4* sorted = ((which == 0) ? sortedA : (which == 1) ? sortedB : sortedC)
                   + (size_t)b * NREF;
  int* cs = ((which == 0) ? csA + b * 4097 : (which == 1) ? csB + b * 513
                                           : csC + b * 513);
  const float* pb = pos + (size_t)b * NFULL * 3;
  for (int c = t; c < NC; c += 256) cnt[c] = 0;
  __syncthreads();
  for (int p = t; p < NREF; p += 256) {
    float x = pb[p * 3 + 0], y = pb[p * 3 + 1], z = pb[p * 3 + 2];
    int cx = min(max((int)(x * GR), 0), GR - 1);
    int cy = min(max((int)(y * GR), 0), GR - 1);
    int cz = min(max((int)(z * GR), 0), GR - 1);
    atomicAdd(&cnt[(cz * GR + cy) * GR + cx], 1);
  }
  __syncthreads();
  int chunk = (NC + 255) / 256;
  int s = 0;
  for (int i = 0; i < chunk; ++i) {
    int c = t * chunk + i;
    if (c < NC) s += cnt[c];
  }
  partial[t] = s;
  __syncthreads();
  if (t == 0) {
    int run = 0;
    for (int i = 0; i < 256; ++i) { int v = partial[i]; partial[i] = run; run += v; }
  }
  __syncthreads();
  int run = partial[t];
  for (int i = 0; i < chunk; ++i) {
    int c = t * chunk + i;
    if (c < NC) { int v = cnt[c]; cnt[c] = run; run += v; }
  }
  __syncthreads();
  for (int c = t; c < NC; c += 256) cs[c] = cnt[c];
  if (t == 0) cs[NC] = NREF;
  __syncthreads();
  for (int p = t; p < NREF; p += 256) {
    float x = pb[p * 3 + 0], y = pb[p * 3 + 1], z = pb[p * 3 + 2];
    int cx = min(max((int)(x * GR), 0), GR - 1);
    int cy = min(max((int)(y * GR), 0), GR - 1);
    int cz = min(max((int)(z * GR), 0), GR - 1);
    int slot = atomicAdd(&cnt[(cz * GR + cy) * GR + cx], 1);
    sorted[slot] = make_float4(x, y, z, __uint_as_float((u32)p));
  }
}

// --------------------------------------------------- grouped insert core ---
template<int SL>
__device__ __forceinline__ void group_insert(u32 m16, u64 ck, int slot,
                                             u64& val, u64& tau) {
  if (m16) {
    while (m16) {
      int src = __ffs(m16) - 1;
      m16 &= m16 - 1;
      u64 c = __shfl((unsigned long long)ck, src, 16);
      u64 prev = __shfl_up((unsigned long long)val, 1, SL);
      if (slot == 0) prev = 0ull;
      val = (val <= c) ? val : ((prev <= c) ? c : prev);
    }
    tau = __shfl((unsigned long long)val, SL - 1, SL);
  }
}

// ------------------------- shared: scan a contiguous sorted[] range --------
template<int SL>
__device__ __forceinline__ void scan_range(const float4* __restrict__ sb,
    int s, int e, float qx, float qy, float qz, float qq,
    int g, int gl, int slot, u64& val, u64& tau) {
  for (int t0 = s; t0 < e; t0 += 16) {
    int j = t0 + gl;
    u64 ck = ~0ull;
    if (j < e) {
      float4 P = sb[j];
      float rr = P.x * P.x + P.y * P.y + P.z * P.z;
      float d2 = qq + rr - 2.0f * (qx * P.x + qy * P.y + qz * P.z);
      ck = ((u64)fbias(d2) << 32) | (u32)__float_as_uint(P.w);
    }
    u64 full = __ballot(ck < tau);
    u32 m16 = (u32)((full >> (g * 16)) & 0xFFFFull);
    group_insert<SL>(m16, ck, slot, val, tau);
  }
}

// Exactness: after scanning box B, if the KOUT-th smallest d2 is strictly
// less than the squared distance to the nearest NON-clipped face of B, no
// outside point can enter the top-KOUT. Ring expansion scans box(R+1)\box(R)
// exactly once per point via per-row segments; unique u64 keys keep the
// tie-breaking identical to the reference top_k.

// -------- shared tail: margin check + ring expansion + full fallback -------
template<int SL, int KOUT, int GR, int R, int NREF>
__device__ __forceinline__ void knn_tail(
    const float4* __restrict__ sb, const int* __restrict__ cs,
    float qx, float qy, float qz, float qq,
    int ix, int iy, int iz, int x0, int x1, int y0, int y1, int z0, int z1,
    int g, int gl, int slot, u64& val, u64& tau) {
  const float h = 1.0f / GR;
  float m = 1e30f;
  if (x0 > 0)      m = fminf(m, qx - x0 * h);
  if (x1 < GR - 1) m = fminf(m, (x1 + 1) * h - qx);
  if (y0 > 0)      m = fminf(m, qy - y0 * h);
  if (y1 < GR - 1) m = fminf(m, (y1 + 1) * h - qy);
  if (z0 > 0)      m = fminf(m, qz - z0 * h);
  if (z1 < GR - 1) m = fminf(m, (z1 + 1) * h - qz);
  float bound = m * m;
  u64 kv = __shfl((unsigned long long)val, KOUT - 1, SL);
  float kth_d2 = funbias((u32)(kv >> 32));
  if (!(kth_d2 < bound)) {  // group-uniform; rare (corner/edge queries)
    // ---- ring expansion: box(R+1) \ box(R) via cell structure ----
    int X0 = max(ix - (R + 1), 0), X1 = min(ix + (R + 1), GR - 1);
    int Y0 = max(iy - (R + 1), 0), Y1 = min(iy + (R + 1), GR - 1);
    int Z0 = max(iz - (R + 1), 0), Z1 = min(iz + (R + 1), GR - 1);
    int NY2 = Y1 - Y0 + 1;
    int nrow2 = (Z1 - Z0 + 1) * NY2;
    for (int rr2 = 0; rr2 < nrow2; ++rr2) {
      int zz = Z0 + rr2 / NY2, yy = Y0 + rr2 % NY2;
      int c0 = (zz * GR + yy) * GR;
      bool mid = (zz >= z0 && zz <= z1 && yy >= y0 && yy <= y1);
      int s1 = cs[c0 + X0];
      int e1 = mid ? cs[c0 + x0] : cs[c0 + X1 + 1];
      scan_range<SL>(sb, s1, e1, qx, qy, qz, qq, g, gl, slot, val, tau);
      if (mid) {
        int s2 = cs[c0 + x1 + 1];
        int e2 = cs[c0 + X1 + 1];
        scan_range<SL>(sb, s2, e2, qx, qy, qz, qq, g, gl, slot, val, tau);
      }
    }
    x0 = X0; x1 = X1; y0 = Y0; y1 = Y1; z0 = Z0; z1 = Z1;
    m = 1e30f;
    if (x0 > 0)      m = fminf(m, qx - x0 * h);
    if (x1 < GR - 1) m = fminf(m, (x1 + 1) * h - qx);
    if (y0 > 0)      m = fminf(m, qy - y0 * h);
    if (y1 < GR - 1) m = fminf(m, (y1 + 1) * h - qy);
    if (z0 > 0)      m = fminf(m, qz - z0 * h);
    if (z1 < GR - 1) m = fminf(m, (z1 + 1) * h - qz);
    bound = m * m;
    kv = __shfl((unsigned long long)val, KOUT - 1, SL);
    kth_d2 = funbias((u32)(kv >> 32));
    if (!(kth_d2 < bound)) {  // essentially unreachable
      for (int t0 = 0; t0 < NREF; t0 += 16) {
        int j = t0 + gl;
        u64 ck = ~0ull;
        if (j < NREF) {
          float4 P = sb[j];
          int cx = min(max((int)(P.x * GR), 0), GR - 1);
          int cy = min(max((int)(P.y * GR), 0), GR - 1);
          int cz = min(max((int)(P.z * GR), 0), GR - 1);
          bool inbox = (cx >= x0 && cx <= x1 && cy >= y0 && cy <= y1 &&
                        cz >= z0 && cz <= z1);
          if (!inbox) {
            float rr = P.x * P.x + P.y * P.y + P.z * P.z;
            float d2 = qq + rr - 2.0f * (qx * P.x + qy * P.y + qz * P.z);
            ck = ((u64)fbias(d2) << 32) | (u32)__float_as_uint(P.w);
          }
        }
        u64 full = __ballot(ck < tau);
        u32 m16 = (u32)((full >> (g * 16)) & 0xFFFFull);
        group_insert<SL>(m16, ck, slot, val, tau);
      }
    }
  }
}

// --------------------------------------- kNN grid, FLAT (NROW <= 16) -------
template<int SL, int KOUT, int GR, int R, int NREF>
__device__ void knn_grid_flat_dev(int vbx,
    const float* __restrict__ pos, const float4* __restrict__ sorted,
    const int* __restrict__ cellStart, int csStride, int Mq,
    int* __restrict__ oidx, float* __restrict__ od2) {
  int b = blockIdx.y;
  int wv = threadIdx.x >> 6, lane = threadIdx.x & 63;
  int g = lane >> 4, gl = lane & 15;
  int q = vbx * 16 + wv * 4 + g;
  const float* pb = pos + (size_t)b * NFULL * 3;
  const float4* sb = sorted + (size_t)b * NREF;
  const int* cs = cellStart + b * csStride;
  float qx = pb[q * 3 + 0], qy = pb[q * 3 + 1], qz = pb[q * 3 + 2];
  float qq = qx * qx + qy * qy + qz * qz;
  int ix = min(max((int)(qx * GR), 0), GR - 1);
  int iy = min(max((int)(qy * GR), 0), GR - 1);
  int iz = min(max((int)(qz * GR), 0), GR - 1);
  int x0 = max(ix - R, 0), x1 = min(ix + R, GR - 1);
  int y0 = max(iy - R, 0), y1 = min(iy + R, GR - 1);
  int z0 = max(iz - R, 0), z1 = min(iz + R, GR - 1);

  int ny = y1 - y0 + 1;
  int nrow = (z1 - z0 + 1) * ny;  // <= 9 for R=1
  int s_i = 0, len_i = 0;
  if (gl < nrow) {
    int zz = z0 + gl / ny, yy = y0 + gl % ny;
    int c0 = (zz * GR + yy) * GR + x0;
    s_i = cs[c0];
    len_i = cs[c0 + (x1 - x0) + 1] - s_i;
  }
  int p_i = len_i;
#pragma unroll
  for (int st = 1; st < 16; st <<= 1) {
    int o = __shfl_up(p_i, st, 16);
    if (gl >= st) p_i += o;
  }
  int T = __shfl(p_i, 15, 16);
  p_i -= len_i;              // exclusive prefix
  int d_i = s_i - p_i;       // sorted index = v + d_row
  if (gl >= nrow) p_i = 0x7fffffff;

  int slot = gl & (SL - 1);
  u64 val = ~0ull, tau = ~0ull;

  for (int v0 = 0; v0 < T; v0 += 16) {  // T group-uniform
    int v = v0 + gl;
    int r = 0;
#pragma unroll
    for (int st = 8; st >= 1; st >>= 1) {
      int pc = __shfl(p_i, r + st, 16);
      if (v >= pc) r += st;
    }
    int addr = v + __shfl(d_i, r, 16);
    u64 ck = ~0ull;
    if (v < T) {
      float4 P = sb[addr];
      float rr = P.x * P.x + P.y * P.y + P.z * P.z;
      float d2 = qq + rr - 2.0f * (qx * P.x + qy * P.y + qz * P.z);
      ck = ((u64)fbias(d2) << 32) | (u32)__float_as_uint(P.w);
    }
    u64 full = __ballot(ck < tau);
    u32 m16 = (u32)((full >> (g * 16)) & 0xFFFFull);
    group_insert<SL>(m16, ck, slot, val, tau);
  }

  knn_tail<SL, KOUT, GR, R, NREF>(sb, cs, qx, qy, qz, qq,
      ix, iy, iz, x0, x1, y0, y1, z0, z1, g, gl, slot, val, tau);

  if (gl < KOUT) {
    size_t base = ((size_t)b * Mq + q) * KOUT;
    oidx[base + gl] = (int)(u32)val;
    if (od2) od2[base + gl] = fmaxf(funbias((u32)(val >> 32)), 0.0f);
  }
}

// --------------------------------------- kNN grid, FLAT32 (NROW <= 32) -----
// Flattened virtual-candidate scan for boxes up to 32 rows: prefix over 32
// row lengths held in 2 regs/lane; 5-step lo/hi binary search per candidate.
template<int SL, int KOUT, int GR, int R, int NREF>
__device__ void knn_grid_flat32_dev(int vbx,
    const float* __restrict__ pos, const float4* __restrict__ sorted,
    const int* __restrict__ cellStart, int csStride, int Mq,
    int* __restrict__ oidx, float* __restrict__ od2) {
  int b = blockIdx.y;
  int wv = threadIdx.x >> 6, lane = threadIdx.x & 63;
  int g = lane >> 4, gl = lane & 15;
  int q = vbx * 16 + wv * 4 + g;
  const float* pb = pos + (size_t)b * NFULL * 3;
  const float4* sb = sorted + (size_t)b * NREF;
  const int* cs = cellStart + b * csStride;
  float qx = pb[q * 3 + 0], qy = pb[q * 3 + 1], qz = pb[q * 3 + 2];
  float qq = qx * qx + qy * qy + qz * qz;
  int ix = min(max((int)(qx * GR), 0), GR - 1);
  int iy = min(max((int)(qy * GR), 0), GR - 1);
  int iz = min(max((int)(qz * GR), 0), GR - 1);
  int x0 = max(ix - R, 0), x1 = min(ix + R, GR - 1);
  int y0 = max(iy - R, 0), y1 = min(iy + R, GR - 1);
  int z0 = max(iz - R, 0), z1 = min(iz + R, GR - 1);

  int ny = y1 - y0 + 1;
  int nrow = (z1 - z0 + 1) * ny;  // <= 25 for R=2
  int sLo = 0, lenLo = 0, sHi = 0, lenHi = 0;
  if (gl < nrow) {
    int zz = z0 + gl / ny, yy = y0 + gl % ny;
    int c0 = (zz * GR + yy) * GR + x0;
    sLo = cs[c0]; lenLo = cs[c0 + (x1 - x0) + 1] - sLo;
  }
  {
    int i2 = gl + 16;
    if (i2 < nrow) {
      int zz = z0 + i2 / ny, yy = y0 + i2 % ny;
      int c0 = (zz * GR + yy) * GR + x0;
      sHi = cs[c0]; lenHi = cs[c0 + (x1 - x0) + 1] - sHi;
    }
  }
  int pLo = lenLo, pHi = lenHi;
#pragma unroll
  for (int st = 1; st < 16; st <<= 1) {
    int o = __shfl_up(pLo, st, 16);
    if (gl >= st) pLo += o;
    int o2 = __shfl_up(pHi, st, 16);
    if (gl >= st) pHi += o2;
  }
  int tot16 = __shfl(pLo, 15, 16);
  pHi += tot16;
  int T = __shfl(pHi, 15, 16);
  pLo -= lenLo; pHi -= lenHi;      // exclusive prefixes
  int dLo = sLo - pLo, dHi = sHi - pHi;
  if (gl >= nrow) pLo = 0x7fffffff;
  if (gl + 16 >= nrow) pHi = 0x7fffffff;

  int slot = gl & (SL - 1);
  u64 val = ~0ull, tau = ~0ull;

  for (int v0 = 0; v0 < T; v0 += 16) {  // T group-uniform
    int v = v0 + gl;
    int r = 0;
#pragma unroll
    for (int st = 16; st >= 1; st >>= 1) {
      int j = r + st;                      // j <= 31
      int pcL = __shfl(pLo, j & 15, 16);
      int pcH = __shfl(pHi, j & 15, 16);
      int pc = (j < 16) ? pcL : pcH;
      if (v >= pc) r = j;
    }
    int dL = __shfl(dLo, r & 15, 16);
    int dH = __shfl(dHi, r & 15, 16);
    int addr = v + ((r < 16) ? dL : dH);
    u64 ck = ~0ull;
    if (v < T) {
      float4 P = sb[addr];
      float rr = P.x * P.x + P.y * P.y + P.z * P.z;
      float d2 = qq + rr - 2.0f * (qx * P.x + qy * P.y + qz * P.z);
      ck = ((u64)fbias(d2) << 32) | (u32)__float_as_uint(P.w);
    }
    u64 full = __ballot(ck < tau);
    u32 m16 = (u32)((full >> (g * 16)) & 0xFFFFull);
    group_insert<SL>(m16, ck, slot, val, tau);
  }

  knn_tail<SL, KOUT, GR, R, NREF>(sb, cs, qx, qy, qz, qq,
      ix, iy, iz, x0, x1, y0, y1, z0, z1, g, gl, slot, val, tau);

  if (gl < KOUT) {
    size_t base = ((size_t)b * Mq + q) * KOUT;
    oidx[base + gl] = (int)(u32)val;
    if (od2) od2[base + gl] = fmaxf(funbias((u32)(val >> 32)), 0.0f);
  }
}

// -------------------------------------------------------- kNN (brute) ------
template<int SL, int KOUT>
__device__ void knn_brute_dev(int vbx,
    const float* __restrict__ pos, int Nref, int Mq,
    int* __restrict__ oidx, float* __restrict__ od2) {
  int b = blockIdx.y;
  int wv = threadIdx.x >> 6, lane = threadIdx.x & 63;
  int g = lane >> 4, gl = lane & 15;
  int q = vbx * 16 + wv * 4 + g;
  const float* pb = pos + (size_t)b * NFULL * 3;
  float qx = pb[q * 3 + 0], qy = pb[q * 3 + 1], qz = pb[q * 3 + 2];
  float qq = qx * qx + qy * qy + qz * qz;

  int slot = gl & (SL - 1);
  u64 val = ~0ull, tau = ~0ull;

  for (int t0 = 0; t0 < Nref; t0 += 16) {
    int j = t0 + gl;
    float rx = pb[j * 3 + 0];
    float ry = pb[j * 3 + 1];
    float rz = pb[j * 3 + 2];
    float rr = rx * rx + ry * ry + rz * rz;
    float d2 = qq + rr - 2.0f * (qx * rx + qy * ry + qz * rz);
    u64 ck = ((u64)fbias(d2) << 32) | (u32)j;
    u64 full = __ballot(ck < tau);
    u32 m16 = (u32)((full >> (g * 16)) & 0xFFFFull);
    group_insert<SL>(m16, ck, slot, val, tau);
  }

  if (gl < KOUT) {
    size_t base = ((size_t)b * Mq + q) * KOUT;
    oidx[base + gl] = (int)(u32)val;
    if (od2) od2[base + gl] = fmaxf(funbias((u32)(val >> 32)), 0.0f);
  }
}

// ----------------------------- fused: ALL SIX kNN queries in one dispatch --
// Ranges ordered heaviest-per-block first to minimize the scheduling tail.
__global__ __launch_bounds__(256) void knn_all_kernel(
    const float* __restrict__ pos,
    const float4* __restrict__ sortedA, const int* __restrict__ csA,
    const float4* __restrict__ sortedB, const int* __restrict__ csB,
    const float4* __restrict__ sortedC, const int* __restrict__ csC,
    int* __restrict__ idx0, int* __restrict__ idx1, int* __restrict__ idx2,
    int* __restrict__ idxu0, float* __restrict__ d2u0,
    int* __restrict__ idxu1, float* __restrict__ d2u1,
    int* __restrict__ idxu2, float* __restrict__ d2u2) {
  int bx = blockIdx.x;
  if (bx < 8)          // idx2: 128 q over 512 pts (brute), K=16 — heaviest
    knn_brute_dev<16, 16>(bx, pos, 512, 128, idx2, nullptr);
  else if (bx < 40)    // idx1: 512 q over 2048 pts, K=16 (flat32, ~500 pts)
    knn_grid_flat32_dev<16, 16, 8, 2, 2048>(bx - 8, pos, sortedB, csB, 513, 512, idx1, nullptr);
  else if (bx < 168)   // idx0: 2048 q over 8192 pts, K=16 (flat32, ~250 pts)
    knn_grid_flat32_dev<16, 16, 16, 2, 8192>(bx - 40, pos, sortedA, csA, 4097, 2048, idx0, nullptr);
  else if (bx < 296)   // idxu1: 2048 q over 512 pts, K=3 (gridC, ~125 pts)
    knn_grid_flat32_dev<4, 3, 8, 2, 512>(bx - 168, pos, sortedC, csC, 513, 2048, idxu1, d2u1);
  else if (bx < 808)   // idxu2: 8192 q over 2048 pts, K=3 (flat, ~108 pts)
    knn_grid_flat_dev<4, 3, 8, 1, 2048>(bx - 296, pos, sortedB, csB, 513, 8192, idxu2, d2u2);
  else                 // idxu0: 512 q over 128 pts (brute), K=3
    knn_brute_dev<4, 3>(bx - 808, pos, 128, 512, idxu0, d2u0);
}

// ----------------------------------- fused weight packing + pos copy -------
__device__ __forceinline__ void pack_tile_rt(const float* __restrict__ W,
                                             short* __restrict__ outp,
                                             int KDIM, int N, int tile, int lane) {
  int NT = N >> 4;
  int kt = tile / NT, nt = tile - kt * NT;
  int n = nt * 16 + (lane & 15);
  int k0 = kt * 32 + (lane >> 4) * 8;
  bf8_t v;
#pragma unroll
  for (int j = 0; j < 8; ++j) {
    int k = k0 + j;
    v[j] = (k < KDIM) ? f2bf(W[(size_t)k * N + n]) : (short)0;
  }
  *(bf8_t*)(outp + ((size_t)tile * 64 + lane) * 8) = v;
}

__global__ __launch_bounds__(64) void pack_copy_all_kernel(
    const float* d0W1, short* d0W1p, const float* d0W2, short* d0W2p,
    const float* d1W1, short* d1W1p, const float* d1W2, short* d1W2p,
    const float* d2W1, short* d2W1p, const float* d2W2, short* d2W2p,
    const float* u2W, short* u2Wp, const float* fW1, short* fW1p,
    const float* fW2, short* fW2p,
    const float* u0W, short* u0Wp, const float* u1W, short* u1Wp,
    const float* pos, float* posOut) {
  int blk = blockIdx.x, lane = threadIdx.x;
  if      (blk < 8)    pack_tile_rt(d0W1, d0W1p, 6, 128, blk, lane);
  else if (blk < 40)   pack_tile_rt(d0W2, d0W2p, 128, 128, blk - 8, lane);
  else if (blk < 120)  pack_tile_rt(d1W1, d1W1p, 131, 256, blk - 40, lane);
  else if (blk < 248)  pack_tile_rt(d1W2, d1W2p, 256, 256, blk - 120, lane);
  else if (blk < 536)  pack_tile_rt(d2W1, d2W1p, 259, 512, blk - 248, lane);
  else if (blk < 1048) pack_tile_rt(d2W2, d2W2p, 512, 512, blk - 536, lane);
  else if (blk < 1088) pack_tile_rt(u2W, u2Wp, 134, 128, blk - 1048, lane);
  else if (blk < 1120) pack_tile_rt(fW1, fW1p, 128, 128, blk - 1088, lane);
  else if (blk < 1152) pack_tile_rt(fW2, fW2p, 128, 128, blk - 1120, lane);
  else if (blk < 1536) pack_tile_rt(u0W, u0Wp, 768, 256, blk - 1152, lane);
  else if (blk < 1632) pack_tile_rt(u1W, u1Wp, 384, 128, blk - 1536, lane);
  else {
    int base = (blk - 1632) * 256;  // 384 blocks x 256 = 98304 = BATCH*NFULL*3
#pragma unroll
    for (int j = 0; j < 4; ++j) {
      int i = base + lane + j * 64;
      posOut[i] = pos[i];
    }
  }
}

// ----------------------------------------------------- down MLP (MFMA) -----
// QB queries per block; weight tiles loaded ONCE per K-step and reused across
// all QB query A-fragments. LDS rows padded +8 shorts (bank-conflict fix).
template<int FEAT, int CIN, int CHID, int FPAD, int QB, int WAVES>
__global__ __launch_bounds__(64 * WAVES) void down_mfma_kernel(
    const float* __restrict__ pos, const float* __restrict__ xin,
    const int* __restrict__ idx,
    const short* __restrict__ W1p, const float* __restrict__ b1,
    const short* __restrict__ W2p, const float* __restrict__ b2,
    float* __restrict__ out, int n, int nprev) {
  const int KT1 = FPAD / 32, NT1 = CHID / 16;
  const int KT2 = CHID / 32, NT2 = CHID / 16;
  __shared__ short sFeat[QB][16][FPAD + 8];
  __shared__ short sH1[QB][16][CHID + 8];
  __shared__ int sIdx[QB][16];
  __shared__ float sCtr[QB][3];
  int b = blockIdx.y, q0 = blockIdx.x * QB;
  int t = threadIdx.x;
  int lane = t & 63, wv = t >> 6;
  const float* pb = pos + (size_t)b * NFULL * 3;
  const float* xb = xin + (size_t)b * nprev * CIN;
  if (t < QB * 16)
    sIdx[t >> 4][t & 15] = idx[((size_t)b * n + q0 + (t >> 4)) * 16 + (t & 15)];
  if (t < QB * 3) sCtr[t / 3][t % 3] = pb[(q0 + t / 3) * 3 + (t % 3)];
  __syncthreads();
  for (int e = t; e < QB * 16 * FPAD; e += 64 * WAVES) {
    int k = e / FPAD, c = e - k * FPAD;
    int qq = k >> 4, kk = k & 15;
    float v = 0.f;
    if (c < 3) v = pb[sIdx[qq][kk] * 3 + c] - sCtr[qq][c];
    else if (c < FEAT) v = xb[(size_t)sIdx[qq][kk] * CIN + (c - 3)];
    sFeat[qq][kk][c] = f2bf(v);
  }
  __syncthreads();

  int col = lane & 15, quad = lane >> 4;
  const bf8_t* W1t = (const bf8_t*)W1p;
  for (int nt = 2 * wv; nt < NT1; nt += 2 * WAVES) {
    f4_t acc[QB][2];
    float bb0 = b1[nt * 16 + col], bb1 = b1[nt * 16 + 16 + col];
#pragma unroll
    for (int q = 0; q < QB; ++q) {
      acc[q][0] = {bb0, bb0, bb0, bb0};
      acc[q][1] = {bb1, bb1, bb1, bb1};
    }
#pragma unroll
    for (int kt = 0; kt < KT1; ++kt) {
      bf8_t bf0 = W1t[(kt * NT1 + nt) * 64 + lane];
      bf8_t bf1 = W1t[(kt * NT1 + nt + 1) * 64 + lane];
#pragma unroll
      for (int q = 0; q < QB; ++q) {
        bf8_t a = *(const bf8_t*)&sFeat[q][col][kt * 32 + quad * 8];
        acc[q][0] = __builtin_amdgcn_mfma_f32_16x16x32_bf16(a, bf0, acc[q][0], 0, 0, 0);
        acc[q][1] = __builtin_amdgcn_mfma_f32_16x16x32_bf16(a, bf1, acc[q][1], 0, 0, 0);
      }
    }
#pragma unroll
    for (int q = 0; q < QB; ++q)
#pragma unroll
      for (int r = 0; r < 4; ++r) {
        sH1[q][quad * 4 + r][nt * 16 + col] = f2bf(fmaxf(acc[q][0][r], 0.f));
        sH1[q][quad * 4 + r][nt * 16 + 16 + col] = f2bf(fmaxf(acc[q][1][r], 0.f));
      }
  }
  __syncthreads();

  const bf8_t* W2t = (const bf8_t*)W2p;
  for (int nt = 2 * wv; nt < NT2; nt += 2 * WAVES) {
    f4_t acc[QB][2];
    float bb0 = b2[nt * 16 + col], bb1 = b2[nt * 16 + 16 + col];
#pragma unroll
    for (int q = 0; q < QB; ++q) {
      acc[q][0] = {bb0, bb0, bb0, bb0};
      acc[q][1] = {bb1, bb1, bb1, bb1};
    }
#pragma unroll
    for (int kt = 0; kt < KT2; ++kt) {
      bf8_t bf0 = W2t[(kt * NT2 + nt) * 64 + lane];
      bf8_t bf1 = W2t[(kt * NT2 + nt + 1) * 64 + lane];
#pragma unroll
      for (int q = 0; q < QB; ++q) {
        bf8_t a = *(const bf8_t*)&sH1[q][col][kt * 32 + quad * 8];
        acc[q][0] = __builtin_amdgcn_mfma_f32_16x16x32_bf16(a, bf0, acc[q][0], 0, 0, 0);
        acc[q][1] = __builtin_amdgcn_mfma_f32_16x16x32_bf16(a, bf1, acc[q][1], 0, 0, 0);
      }
    }
#pragma unroll
    for (int q = 0; q < QB; ++q) {
      float m0 = fmaxf(fmaxf(acc[q][0][0], acc[q][0][1]), fmaxf(acc[q][0][2], acc[q][0][3]));
      float m1 = fmaxf(fmaxf(acc[q][1][0], acc[q][1][1]), fmaxf(acc[q][1][2], acc[q][1][3]));
      m0 = fmaxf(m0, __shfl_xor(m0, 16, 64));
      m0 = fmaxf(m0, __shfl_xor(m0, 32, 64));
      m1 = fmaxf(m1, __shfl_xor(m1, 16, 64));
      m1 = fmaxf(m1, __shfl_xor(m1, 32, 64));
      if (lane < 16) {
        float* ob = out + ((size_t)b * n + q0 + q) * CHID;
        ob[nt * 16 + lane] = m0;
        ob[nt * 16 + 16 + lane] = m1;
      }
    }
  }
}

// -------------------------------------------- up MLP (bf16 MFMA version) ---
template<int CIN, int CPRV, int COUT, int WPB>
__global__ __launch_bounds__(64 * WPB) void up_mfma_kernel(
    const float* __restrict__ xc, int ncoarse,
    const int* __restrict__ idx3, const float* __restrict__ d23,
    const float* __restrict__ prv, const short* __restrict__ Wp,
    const float* __restrict__ bvec, float* __restrict__ out, int m) {
  const int CTOT = CIN + CPRV;
  const int KT = CTOT / 32, NT = COUT / 16;
  __shared__ short sA[16][CTOT + 8];
  __shared__ float sWt[16][3];
  __shared__ int   sIt[16][3];
  int b = blockIdx.y, q0 = blockIdx.x * 16, t = threadIdx.x;
  int lane = t & 63, wv = t >> 6;
  if (t < 16) {
    size_t base = ((size_t)b * m + q0 + t) * 3;
    float d0 = d23[base + 0], d1 = d23[base + 1], d2v = d23[base + 2];
    float w0 = 1.f / (d0 + 1e-8f), w1 = 1.f / (d1 + 1e-8f), w2 = 1.f / (d2v + 1e-8f);
    float s = w0 + w1 + w2;
    sWt[t][0] = w0 / s; sWt[t][1] = w1 / s; sWt[t][2] = w2 / s;
    sIt[t][0] = idx3[base + 0]; sIt[t][1] = idx3[base + 1]; sIt[t][2] = idx3[base + 2];
  }
  __syncthreads();
  const float* xb = xc + (size_t)b * ncoarse * CIN;
  const float* pvb = prv + ((size_t)b * m + q0) * CPRV;
  for (int e = t; e < 16 * CIN; e += 64 * WPB) {
    int p = e / CIN, c = e % CIN;
    float v = sWt[p][0] * xb[(size_t)sIt[p][0] * CIN + c]
            + sWt[p][1] * xb[(size_t)sIt[p][1] * CIN + c]
            + sWt[p][2] * xb[(size_t)sIt[p][2] * CIN + c];
    sA[p][c] = f2bf(v);
  }
  for (int e = t; e < 16 * CPRV; e += 64 * WPB) {
    int p = e / CPRV, c = e % CPRV;
    sA[p][CIN + c] = f2bf(pvb[(size_t)p * CPRV + c]);
  }
  __syncthreads();
  int col = lane & 15, quad = lane >> 4;
  const bf8_t* Wt = (const bf8_t*)Wp;
  float* ob = out + ((size_t)b * m + q0) * COUT;
  for (int nt = 2 * wv; nt < NT; nt += 2 * WPB) {
    float bb0 = bvec[nt * 16 + col], bb1 = bvec[nt * 16 + 16 + col];
    f4_t acc0 = {bb0, bb0, bb0, bb0}, acc1 = {bb1, bb1, bb1, bb1};
#pragma unroll
    for (int kt = 0; kt < KT; ++kt) {
      bf8_t a = *(const bf8_t*)&sA[col][kt * 32 + quad * 8];
      bf8_t bf0 = Wt[(kt * NT + nt) * 64 + lane];
      bf8_t bf1 = Wt[(kt * NT + nt + 1) * 64 + lane];
      acc0 = __builtin_amdgcn_mfma_f32_16x16x32_bf16(a, bf0, acc0, 0, 0, 0);
      acc1 = __builtin_amdgcn_mfma_f32_16x16x32_bf16(a, bf1, acc1, 0, 0, 0);
    }
#pragma unroll
    for (int r = 0; r < 4; ++r) {
      ob[(size_t)(quad * 4 + r) * COUT + nt * 16 + col] = fmaxf(acc0[r], 0.f);
      ob[(size_t)(quad * 4 + r) * COUT + nt * 16 + 16 + col] = fmaxf(acc1[r], 0.f);
    }
  }
}

// ------------------------------------- fused up2 + final MLP (bf16 MFMA) ---
__global__ __launch_bounds__(128) void up2f_mfma_kernel(
    const float* __restrict__ xc,
    const int* __restrict__ idx3, const float* __restrict__ d23,
    const float* __restrict__ x0, const float* __restrict__ pos0,
    const short* __restrict__ u2Wp, const float* __restrict__ u2b,
    const short* __restrict__ fW1p, const float* __restrict__ fb1,
    const short* __restrict__ fW2p, const float* __restrict__ fb2,
    float* __restrict__ out) {
  __shared__ short sA[16][168];
  __shared__ short sB[16][136];
  __shared__ float sWt[16][3];
  __shared__ int   sIt[16][3];
  int b = blockIdx.y, q0 = blockIdx.x * 16, t = threadIdx.x;
  int lane = t & 63, wv = t >> 6;
  if (t < 16) {
    size_t base = ((size_t)b * NFULL + q0 + t) * 3;
    float d0 = d23[base + 0], d1 = d23[base + 1], d2v = d23[base + 2];
    float w0 = 1.f / (d0 + 1e-8f), w1 = 1.f / (d1 + 1e-8f), w2 = 1.f / (d2v + 1e-8f);
    float s = w0 + w1 + w2;
    sWt[t][0] = w0 / s; sWt[t][1] = w1 / s; sWt[t][2] = w2 / s;
    sIt[t][0] = idx3[base + 0]; sIt[t][1] = idx3[base + 1]; sIt[t][2] = idx3[base + 2];
  }
  __syncthreads();
  const float* xb = xc + (size_t)b * 2048 * 128;
#pragma unroll
  for (int p = 0; p < 16; ++p) {
    float v = sWt[p][0] * xb[(size_t)sIt[p][0] * 128 + t]
            + sWt[p][1] * xb[(size_t)sIt[p][1] * 128 + t]
            + sWt[p][2] * xb[(size_t)sIt[p][2] * 128 + t];
    sA[p][t] = f2bf(v);
  }
  for (int e = t; e < 16 * 32; e += 128) {
    int p = e / 32, c = 128 + (e % 32);
    float v = 0.f;
    if (c < 131) v = x0[((size_t)b * NFULL + q0 + p) * 3 + (c - 128)];
    else if (c < 134) v = pos0[((size_t)b * NFULL + q0 + p) * 3 + (c - 131)];
    sA[p][c] = f2bf(v);
  }
  __syncthreads();
  int col = lane & 15, quad = lane >> 4;

  bf8_t a1[5];
#pragma unroll
  for (int kt = 0; kt < 5; ++kt)
    a1[kt] = *(const bf8_t*)&sA[col][kt * 32 + quad * 8];
  const bf8_t* W1t = (const bf8_t*)u2Wp;
  for (int nt = 2 * wv; nt < 8; nt += 4) {
    float bb0 = u2b[nt * 16 + col], bb1 = u2b[nt * 16 + 16 + col];
    f4_t acc0 = {bb0, bb0, bb0, bb0}, acc1 = {bb1, bb1, bb1, bb1};
#pragma unroll
    for (int kt = 0; kt < 5; ++kt) {
      bf8_t bf0 = W1t[(kt * 8 + nt) * 64 + lane];
      bf8_t bf1 = W1t[(kt * 8 + nt + 1) * 64 + lane];
      acc0 = __builtin_amdgcn_mfma_f32_16x16x32_bf16(a1[kt], bf0, acc0, 0, 0, 0);
      acc1 = __builtin_amdgcn_mfma_f32_16x16x32_bf16(a1[kt], bf1, acc1, 0, 0, 0);
    }
#pragma unroll
    for (int r = 0; r < 4; ++r) {
      sB[quad * 4 + r][nt * 16 + col] = f2bf(fmaxf(acc0[r], 0.f));
      sB[quad * 4 + r][nt * 16 + 16 + col] = f2bf(fmaxf(acc1[r], 0.f));
    }
  }
  __syncthreads();

  bf8_t a2[4];
#pragma unroll
  for (int kt = 0; kt < 4; ++kt)
    a2[kt] = *(const bf8_t*)&sB[col][kt * 32 + quad * 8];
  const bf8_t* W2t = (const bf8_t*)fW1p;
  for (int nt = 2 * wv; nt < 8; nt += 4) {
    float bb0 = fb1[nt * 16 + col], bb1 = fb1[nt * 16 + 16 + col];
    f4_t acc0 = {bb0, bb0, bb0, bb0}, acc1 = {bb1, bb1, bb1, bb1};
#pragma unroll
    for (int kt = 0; kt < 4; ++kt) {
      bf8_t bf0 = W2t[(kt * 8 + nt) * 64 + lane];
      bf8_t bf1 = W2t[(kt * 8 + nt + 1) * 64 + lane];
      acc0 = __builtin_amdgcn_mfma_f32_16x16x32_bf16(a2[kt], bf0, acc0, 0, 0, 0);
      acc1 = __builtin_amdgcn_mfma_f32_16x16x32_bf16(a2[kt], bf1, acc1, 0, 0, 0);
    }
#pragma unroll
    for (int r = 0; r < 4; ++r) {
      sA[quad * 4 + r][nt * 16 + col] = f2bf(fmaxf(acc0[r], 0.f));
      sA[quad * 4 + r][nt * 16 + 16 + col] = f2bf(fmaxf(acc1[r], 0.f));
    }
  }
  __syncthreads();

  bf8_t a3[4];
#pragma unroll
  for (int kt = 0; kt < 4; ++kt)
    a3[kt] = *(const bf8_t*)&sA[col][kt * 32 + quad * 8];
  const bf8_t* W3t = (const bf8_t*)fW2p;
  float* ob = out + ((size_t)b * NFULL + q0) * 128;
  for (int nt = 2 * wv; nt < 8; nt += 4) {
    float bb0 = fb2[nt * 16 + col], bb1 = fb2[nt * 16 + 16 + col];
    f4_t acc0 = {bb0, bb0, bb0, bb0}, acc1 = {bb1, bb1, bb1, bb1};
#pragma unroll
    for (int kt = 0; kt < 4; ++kt) {
      bf8_t bf0 = W3t[(kt * 8 + nt) * 64 + lane];
      bf8_t bf1 = W3t[(kt * 8 + nt + 1) * 64 + lane];
      acc0 = __builtin_amdgcn_mfma_f32_16x16x32_bf16(a3[kt], bf0, acc0, 0, 0, 0);
      acc1 = __builtin_amdgcn_mfma_f32_16x16x32_bf16(a3[kt], bf1, acc1, 0, 0, 0);
    }
#pragma unroll
    for (int r = 0; r < 4; ++r) {
      ob[(size_t)(quad * 4 + r) * 128 + nt * 16 + col] = acc0[r];
      ob[(size_t)(quad * 4 + r) * 128 + nt * 16 + 16 + col] = acc1[r];
    }
  }
}

// ------------------------------------------------------------------ launch -
extern "C" void kernel_launch(void* const* d_in, const int* in_sizes, int n_in,
                              void* d_out, int out_size, void* d_ws, size_t ws_size,
                              hipStream_t stream) {
  const float* x    = (const float*)d_in[0];
  const float* pos  = (const float*)d_in[1];
  const float* d0W1 = (const float*)d_in[2];
  const float* d0b1 = (const float*)d_in[3];
  const float* d0W2 = (const float*)d_in[4];
  const float* d0b2 = (const float*)d_in[5];
  const float* d1W1 = (const float*)d_in[6];
  const float* d1b1 = (const float*)d_in[7];
  const float* d1W2 = (const float*)d_in[8];
  const float* d1b2 = (const float*)d_in[9];
  const float* d2W1 = (const float*)d_in[10];
  const float* d2b1 = (const float*)d_in[11];
  const float* d2W2 = (const float*)d_in[12];
  const float* d2b2 = (const float*)d_in[13];
  const float* u0W  = (const float*)d_in[14];
  const float* u0b  = (const float*)d_in[15];
  const float* u1W  = (const float*)d_in[16];
  const float* u1b  = (const float*)d_in[17];
  const float* u2W  = (const float*)d_in[18];
  const float* u2b  = (const float*)d_in[19];
  const float* fW1  = (const float*)d_in[20];
  const float* fb1  = (const float*)d_in[21];
  const float* fW2  = (const float*)d_in[22];
  const float* fb2  = (const float*)d_in[23];

  char* ws = (char*)d_ws;
  float* x1    = (float*)(ws + 0);
  float* x2    = (float*)(ws + 4194304);
  float* x3    = (float*)(ws + 6291456);
  float* up0o  = (float*)(ws + 7340032);
  float* up1o  = (float*)(ws + 9437184);
  int*   idx0  = (int*)  (ws + 13631488);
  int*   idx1  = (int*)  (ws + 14155776);
  int*   idx2  = (int*)  (ws + 14286848);
  float4* sortedC = (float4*)(ws + 14319616); // 4*512*16 = 32768
  int*    csC     = (int*)   (ws + 14352384); // 4*513*4  = 8208
  int*   idxu0 = (int*)  (ws + 14843904);
  float* d2u0  = (float*)(ws + 14868480);
  int*   idxu1 = (int*)  (ws + 14893056);
  float* d2u1  = (float*)(ws + 14991360);
  int*   idxu2 = (int*)  (ws + 15089664);
  float* d2u2  = (float*)(ws + 15482880);
  short* d1W1p = (short*)(ws + 15876096);
  short* d1W2p = (short*)(ws + 15958016);
  short* d2W1p = (short*)(ws + 16089088);
  short* d2W2p = (short*)(ws + 16384000);
  short* d0W1p = (short*)(ws + 16908288);
  short* d0W2p = (short*)(ws + 16916480);
  float4* sortedA = (float4*)(ws + 16949248);  // 4*8192*16 = 524288
  int*    csA     = (int*)   (ws + 17473536);  // 4*4097*4  = 65552
  float4* sortedB = (float4*)(ws + 17539136);  // 4*2048*16 = 131072
  int*    csB     = (int*)   (ws + 17670208);  // 4*513*4   = 8208
  short* u2Wp  = (short*)(ws + 17697920);
  short* fW1p  = (short*)(ws + 17738880);
  short* fW2p  = (short*)(ws + 17771648);

  float* out = (float*)d_out;
  // Packed u0W/u1W live in the d_out main region: it is dead until the final
  // up2f_mfma_kernel writes it, and both are fully consumed before that.
  short* u0Wp = (short*)out;                       // 768*256*2 = 393216 B
  short* u1Wp = (short*)(out + 98304);             // 384*128*2 =  98304 B

  // ---- fused packing + pos passthrough; fused grid builds (3 grids) ----
  pack_copy_all_kernel<<<dim3(2016), 64, 0, stream>>>(
      d0W1, d0W1p, d0W2, d0W2p, d1W1, d1W1p, d1W2, d1W2p,
      d2W1, d2W1p, d2W2, d2W2p, u2W, u2Wp, fW1, fW1p, fW2, fW2p,
      u0W, u0Wp, u1W, u1Wp,
      pos, out + (size_t)BATCH * NFULL * 128);
  build_grids_kernel<<<dim3(BATCH, 3), 256, 0, stream>>>(
      pos, sortedA, csA, sortedB, csB, sortedC, csC);

  // ---- ALL kNN queries in one dispatch (deps: pos + grids only) ----
  knn_all_kernel<<<dim3(840, BATCH), 256, 0, stream>>>(
      pos, sortedA, csA, sortedB, csB, sortedC, csC,
      idx0, idx1, idx2,
      idxu0, d2u0, idxu1, d2u1, idxu2, d2u2);

  // ---- down path ----
  down_mfma_kernel<6, 3, 128, 32, 4, 4><<<dim3(512, BATCH), 256, 0, stream>>>(
      pos, x, idx0, d0W1p, d0b1, d0W2p, d0b2, x1, 2048, 8192);
  down_mfma_kernel<131, 128, 256, 160, 4, 8><<<dim3(128, BATCH), 512, 0, stream>>>(
      pos, x1, idx1, d1W1p, d1b1, d1W2p, d1b2, x2, 512, 2048);
  down_mfma_kernel<259, 256, 512, 288, 2, 8><<<dim3(64, BATCH), 512, 0, stream>>>(
      pos, x2, idx2, d2W1p, d2b1, d2W2p, d2b2, x3, 128, 512);

  // ---- up path ----
  up_mfma_kernel<512, 256, 256, 4><<<dim3(32, BATCH), 256, 0, stream>>>(
      x3, 128, idxu0, d2u0, x2, u0Wp, u0b, up0o, 512);
  up_mfma_kernel<256, 128, 128, 2><<<dim3(128, BATCH), 128, 0, stream>>>(
      up0o, 512, idxu1, d2u1, x1, u1Wp, u1b, up1o, 2048);
  up2f_mfma_kernel<<<dim3(512, BATCH), 128, 0, stream>>>(
      up1o, idxu2, d2u2, x, pos, u2Wp, u2b, fW1p, fb1, fW2p, fb2, out);
}

// Round 6
// 306.142 us; speedup vs baseline: 1.6150x; 1.0202x over previous
//
#include <hip/hip_runtime.h>

#define NFULL 8192
#define BATCH 4

typedef unsigned long long u64;
typedef unsigned int u32;
typedef __attribute__((ext_vector_type(8))) short bf8_t;   // 8 bf16 (4 VGPRs)
typedef __attribute__((ext_vector_type(4))) float f4_t;    // MFMA C/D

__device__ __forceinline__ u32 fbias(float f) {
  u32 u = __float_as_uint(f);
  return (u & 0x80000000u) ? ~u : (u | 0x80000000u);
}
__device__ __forceinline__ float funbias(u32 b) {
  u32 u = (b & 0x80000000u) ? (b & 0x7fffffffu) : ~b;
  return __uint_as_float(u);
}
__device__ __forceinline__ short f2bf(float f) {
  u32 u = __float_as_uint(f);
  u32 r = u + 0x7FFFu + ((u >> 16) & 1u);
  return (short)(r >> 16);
}

// ------------------------------------------- fused grid build (all three) --
// y=0: GR=16 over pos[:8192]; y=1: GR=8 over pos[:2048]; y=2: GR=8 over
// pos[:512]. All h = 2^-k -> margin arithmetic exact in fp32.
__global__ __launch_bounds__(256) void build_grids_kernel(
    const float* __restrict__ pos, float4* __restrict__ sortedA,
    int* __restrict__ csA, float4* __restrict__ sortedB, int* __restrict__ csB,
    float4* __restrict__ sortedC, int* __restrict__ csC) {
  __shared__ int cnt[4096];
  __shared__ int partial[256];
  int which = blockIdx.y, b = blockIdx.x, t = threadIdx.x;
  int NREF = (which == 0) ? 8192 : (which == 1) ? 2048 : 512;
  int GR = (which == 0) ? 16 : 8;
  int NC = GR * GR * GR;
  float4* sorted = ((which == 0) ? sortedA : (which == 1) ? sortedB : sortedC)
                   + (size_t)b * NREF;
  int* cs = ((which == 0) ? csA + b * 4097 : (which == 1) ? csB + b * 513
                                           : csC + b * 513);
  const float* pb = pos + (size_t)b * NFULL * 3;
  for (int c = t; c < NC; c += 256) cnt[c] = 0;
  __syncthreads();
  for (int p = t; p < NREF; p += 256) {
    float x = pb[p * 3 + 0], y = pb[p * 3 + 1], z = pb[p * 3 + 2];
    int cx = min(max((int)(x * GR), 0), GR - 1);
    int cy = min(max((int)(y * GR), 0), GR - 1);
    int cz = min(max((int)(z * GR), 0), GR - 1);
    atomicAdd(&cnt[(cz * GR + cy) * GR + cx], 1);
  }
  __syncthreads();
  int chunk = (NC + 255) / 256;
  int s = 0;
  for (int i = 0; i < chunk; ++i) {
    int c = t * chunk + i;
    if (c < NC) s += cnt[c];
  }
  partial[t] = s;
  __syncthreads();
  if (t == 0) {
    int run = 0;
    for (int i = 0; i < 256; ++i) { int v = partial[i]; partial[i] = run; run += v; }
  }
  __syncthreads();
  int run = partial[t];
  for (int i = 0; i < chunk; ++i) {
    int c = t * chunk + i;
    if (c < NC) { int v = cnt[c]; cnt[c] = run; run += v; }
  }
  __syncthreads();
  for (int c = t; c < NC; c += 256) cs[c] = cnt[c];
  if (t == 0) cs[NC] = NREF;
  __syncthreads();
  for (int p = t; p < NREF; p += 256) {
    float x = pb[p * 3 + 0], y = pb[p * 3 + 1], z = pb[p * 3 + 2];
    int cx = min(max((int)(x * GR), 0), GR - 1);
    int cy = min(max((int)(y * GR), 0), GR - 1);
    int cz = min(max((int)(z * GR), 0), GR - 1);
    int slot = atomicAdd(&cnt[(cz * GR + cy) * GR + cx], 1);
    sorted[slot] = make_float4(x, y, z, __uint_as_float((u32)p));
  }
}

// --------------------------------------------------- grouped insert core ---
template<int SL>
__device__ __forceinline__ void group_insert(u32 m16, u64 ck, int slot,
                                             u64& val, u64& tau) {
  if (m16) {
    while (m16) {
      int src = __ffs(m16) - 1;
      m16 &= m16 - 1;
      u64 c = __shfl((unsigned long long)ck, src, 16);
      u64 prev = __shfl_up((unsigned long long)val, 1, SL);
      if (slot == 0) prev = 0ull;
      val = (val <= c) ? val : ((prev <= c) ? c : prev);
    }
    tau = __shfl((unsigned long long)val, SL - 1, SL);
  }
}

// -------------------- round-1 bulk build: bitonic sort of 16 candidates ----
// tau starts at infinity, so round 1 would serially insert ALL 16 candidates
// (16-deep shfl chain). Instead: 10-stage bitonic sort across the 16-lane
// group (ascending -> lane gl holds rank gl), then broadcast the SL-window.
// Padding candidates (~0ull) sort to the top; identical final state.
template<int SL>
__device__ __forceinline__ void first_round_sort(u64 ck, int gl,
                                                 u64& val, u64& tau) {
  u64 v = ck;
#pragma unroll
  for (int size = 2; size <= 16; size <<= 1) {
#pragma unroll
    for (int stride = size >> 1; stride > 0; stride >>= 1) {
      u64 other = __shfl_xor((unsigned long long)v, stride, 16);
      bool ddd = ((gl & size) == 0);
      bool takeMin = (((gl & stride) == 0) == ddd);
      u64 mn = (v <= other) ? v : other;
      u64 mx = (v <= other) ? other : v;
      v = takeMin ? mn : mx;
    }
  }
  if (SL < 16) v = __shfl((unsigned long long)v, gl & (SL - 1), 16);
  val = v;
  tau = __shfl((unsigned long long)v, SL - 1, SL);
}

// ------------------------- shared: scan a contiguous sorted[] range --------
template<int SL>
__device__ __forceinline__ void scan_range(const float4* __restrict__ sb,
    int s, int e, float qx, float qy, float qz, float qq,
    int g, int gl, int slot, u64& val, u64& tau) {
  for (int t0 = s; t0 < e; t0 += 16) {
    int j = t0 + gl;
    u64 ck = ~0ull;
    if (j < e) {
      float4 P = sb[j];
      float rr = P.x * P.x + P.y * P.y + P.z * P.z;
      float d2 = qq + rr - 2.0f * (qx * P.x + qy * P.y + qz * P.z);
      ck = ((u64)fbias(d2) << 32) | (u32)__float_as_uint(P.w);
    }
    u64 full = __ballot(ck < tau);
    u32 m16 = (u32)((full >> (g * 16)) & 0xFFFFull);
    group_insert<SL>(m16, ck, slot, val, tau);
  }
}

// Exactness: after scanning box B, if the KOUT-th smallest d2 is strictly
// less than the squared distance to the nearest NON-clipped face of B, no
// outside point can enter the top-KOUT. Ring expansion scans box(R+1)\box(R)
// exactly once per point via per-row segments; unique u64 keys keep the
// tie-breaking identical to the reference top_k.

// -------- shared tail: margin check + ring expansion + full fallback -------
template<int SL, int KOUT, int GR, int R, int NREF>
__device__ __forceinline__ void knn_tail(
    const float4* __restrict__ sb, const int* __restrict__ cs,
    float qx, float qy, float qz, float qq,
    int ix, int iy, int iz, int x0, int x1, int y0, int y1, int z0, int z1,
    int g, int gl, int slot, u64& val, u64& tau) {
  const float h = 1.0f / GR;
  float m = 1e30f;
  if (x0 > 0)      m = fminf(m, qx - x0 * h);
  if (x1 < GR - 1) m = fminf(m, (x1 + 1) * h - qx);
  if (y0 > 0)      m = fminf(m, qy - y0 * h);
  if (y1 < GR - 1) m = fminf(m, (y1 + 1) * h - qy);
  if (z0 > 0)      m = fminf(m, qz - z0 * h);
  if (z1 < GR - 1) m = fminf(m, (z1 + 1) * h - qz);
  float bound = m * m;
  u64 kv = __shfl((unsigned long long)val, KOUT - 1, SL);
  float kth_d2 = funbias((u32)(kv >> 32));
  if (!(kth_d2 < bound)) {  // group-uniform; rare (corner/edge queries)
    // ---- ring expansion: box(R+1) \ box(R) via cell structure ----
    int X0 = max(ix - (R + 1), 0), X1 = min(ix + (R + 1), GR - 1);
    int Y0 = max(iy - (R + 1), 0), Y1 = min(iy + (R + 1), GR - 1);
    int Z0 = max(iz - (R + 1), 0), Z1 = min(iz + (R + 1), GR - 1);
    int NY2 = Y1 - Y0 + 1;
    int nrow2 = (Z1 - Z0 + 1) * NY2;
    for (int rr2 = 0; rr2 < nrow2; ++rr2) {
      int zz = Z0 + rr2 / NY2, yy = Y0 + rr2 % NY2;
      int c0 = (zz * GR + yy) * GR;
      bool mid = (zz >= z0 && zz <= z1 && yy >= y0 && yy <= y1);
      int s1 = cs[c0 + X0];
      int e1 = mid ? cs[c0 + x0] : cs[c0 + X1 + 1];
      scan_range<SL>(sb, s1, e1, qx, qy, qz, qq, g, gl, slot, val, tau);
      if (mid) {
        int s2 = cs[c0 + x1 + 1];
        int e2 = cs[c0 + X1 + 1];
        scan_range<SL>(sb, s2, e2, qx, qy, qz, qq, g, gl, slot, val, tau);
      }
    }
    x0 = X0; x1 = X1; y0 = Y0; y1 = Y1; z0 = Z0; z1 = Z1;
    m = 1e30f;
    if (x0 > 0)      m = fminf(m, qx - x0 * h);
    if (x1 < GR - 1) m = fminf(m, (x1 + 1) * h - qx);
    if (y0 > 0)      m = fminf(m, qy - y0 * h);
    if (y1 < GR - 1) m = fminf(m, (y1 + 1) * h - qy);
    if (z0 > 0)      m = fminf(m, qz - z0 * h);
    if (z1 < GR - 1) m = fminf(m, (z1 + 1) * h - qz);
    bound = m * m;
    kv = __shfl((unsigned long long)val, KOUT - 1, SL);
    kth_d2 = funbias((u32)(kv >> 32));
    if (!(kth_d2 < bound)) {  // essentially unreachable
      for (int t0 = 0; t0 < NREF; t0 += 16) {
        int j = t0 + gl;
        u64 ck = ~0ull;
        if (j < NREF) {
          float4 P = sb[j];
          int cx = min(max((int)(P.x * GR), 0), GR - 1);
          int cy = min(max((int)(P.y * GR), 0), GR - 1);
          int cz = min(max((int)(P.z * GR), 0), GR - 1);
          bool inbox = (cx >= x0 && cx <= x1 && cy >= y0 && cy <= y1 &&
                        cz >= z0 && cz <= z1);
          if (!inbox) {
            float rr = P.x * P.x + P.y * P.y + P.z * P.z;
            float d2 = qq + rr - 2.0f * (qx * P.x + qy * P.y + qz * P.z);
            ck = ((u64)fbias(d2) << 32) | (u32)__float_as_uint(P.w);
          }
        }
        u64 full = __ballot(ck < tau);
        u32 m16 = (u32)((full >> (g * 16)) & 0xFFFFull);
        group_insert<SL>(m16, ck, slot, val, tau);
      }
    }
  }
}

// --------------------------------------- kNN grid, FLAT (NROW <= 16) -------
template<int SL, int KOUT, int GR, int R, int NREF>
__device__ void knn_grid_flat_dev(int vbx,
    const float* __restrict__ pos, const float4* __restrict__ sorted,
    const int* __restrict__ cellStart, int csStride, int Mq,
    int* __restrict__ oidx, float* __restrict__ od2) {
  int b = blockIdx.y;
  int wv = threadIdx.x >> 6, lane = threadIdx.x & 63;
  int g = lane >> 4, gl = lane & 15;
  int q = vbx * 16 + wv * 4 + g;
  const float* pb = pos + (size_t)b * NFULL * 3;
  const float4* sb = sorted + (size_t)b * NREF;
  const int* cs = cellStart + b * csStride;
  float qx = pb[q * 3 + 0], qy = pb[q * 3 + 1], qz = pb[q * 3 + 2];
  float qq = qx * qx + qy * qy + qz * qz;
  int ix = min(max((int)(qx * GR), 0), GR - 1);
  int iy = min(max((int)(qy * GR), 0), GR - 1);
  int iz = min(max((int)(qz * GR), 0), GR - 1);
  int x0 = max(ix - R, 0), x1 = min(ix + R, GR - 1);
  int y0 = max(iy - R, 0), y1 = min(iy + R, GR - 1);
  int z0 = max(iz - R, 0), z1 = min(iz + R, GR - 1);

  int ny = y1 - y0 + 1;
  int nrow = (z1 - z0 + 1) * ny;  // <= 9 for R=1
  int s_i = 0, len_i = 0;
  if (gl < nrow) {
    int zz = z0 + gl / ny, yy = y0 + gl % ny;
    int c0 = (zz * GR + yy) * GR + x0;
    s_i = cs[c0];
    len_i = cs[c0 + (x1 - x0) + 1] - s_i;
  }
  int p_i = len_i;
#pragma unroll
  for (int st = 1; st < 16; st <<= 1) {
    int o = __shfl_up(p_i, st, 16);
    if (gl >= st) p_i += o;
  }
  int T = __shfl(p_i, 15, 16);
  p_i -= len_i;              // exclusive prefix
  int d_i = s_i - p_i;       // sorted index = v + d_row
  if (gl >= nrow) p_i = 0x7fffffff;

  int slot = gl & (SL - 1);
  u64 val, tau;

  // ---- round 1: bulk-build via bitonic sort (replaces 16 serial inserts)
  {
    int v = gl;
    int r = 0;
#pragma unroll
    for (int st = 8; st >= 1; st >>= 1) {
      int pc = __shfl(p_i, r + st, 16);
      if (v >= pc) r += st;
    }
    int addr = v + __shfl(d_i, r, 16);
    u64 ck = ~0ull;
    if (v < T) {
      float4 P = sb[addr];
      float rr = P.x * P.x + P.y * P.y + P.z * P.z;
      float d2 = qq + rr - 2.0f * (qx * P.x + qy * P.y + qz * P.z);
      ck = ((u64)fbias(d2) << 32) | (u32)__float_as_uint(P.w);
    }
    first_round_sort<SL>(ck, gl, val, tau);
  }

  for (int v0 = 16; v0 < T; v0 += 16) {  // T group-uniform
    int v = v0 + gl;
    int r = 0;
#pragma unroll
    for (int st = 8; st >= 1; st >>= 1) {
      int pc = __shfl(p_i, r + st, 16);
      if (v >= pc) r += st;
    }
    int addr = v + __shfl(d_i, r, 16);
    u64 ck = ~0ull;
    if (v < T) {
      float4 P = sb[addr];
      float rr = P.x * P.x + P.y * P.y + P.z * P.z;
      float d2 = qq + rr - 2.0f * (qx * P.x + qy * P.y + qz * P.z);
      ck = ((u64)fbias(d2) << 32) | (u32)__float_as_uint(P.w);
    }
    u64 full = __ballot(ck < tau);
    u32 m16 = (u32)((full >> (g * 16)) & 0xFFFFull);
    group_insert<SL>(m16, ck, slot, val, tau);
  }

  knn_tail<SL, KOUT, GR, R, NREF>(sb, cs, qx, qy, qz, qq,
      ix, iy, iz, x0, x1, y0, y1, z0, z1, g, gl, slot, val, tau);

  if (gl < KOUT) {
    size_t base = ((size_t)b * Mq + q) * KOUT;
    oidx[base + gl] = (int)(u32)val;
    if (od2) od2[base + gl] = fmaxf(funbias((u32)(val >> 32)), 0.0f);
  }
}

// --------------------------------------- kNN grid, FLAT32 (NROW <= 32) -----
// Flattened virtual-candidate scan for boxes up to 32 rows: prefix over 32
// row lengths held in 2 regs/lane; 5-step lo/hi binary search per candidate.
template<int SL, int KOUT, int GR, int R, int NREF>
__device__ void knn_grid_flat32_dev(int vbx,
    const float* __restrict__ pos, const float4* __restrict__ sorted,
    const int* __restrict__ cellStart, int csStride, int Mq,
    int* __restrict__ oidx, float* __restrict__ od2) {
  int b = blockIdx.y;
  int wv = threadIdx.x >> 6, lane = threadIdx.x & 63;
  int g = lane >> 4, gl = lane & 15;
  int q = vbx * 16 + wv * 4 + g;
  const float* pb = pos + (size_t)b * NFULL * 3;
  const float4* sb = sorted + (size_t)b * NREF;
  const int* cs = cellStart + b * csStride;
  float qx = pb[q * 3 + 0], qy = pb[q * 3 + 1], qz = pb[q * 3 + 2];
  float qq = qx * qx + qy * qy + qz * qz;
  int ix = min(max((int)(qx * GR), 0), GR - 1);
  int iy = min(max((int)(qy * GR), 0), GR - 1);
  int iz = min(max((int)(qz * GR), 0), GR - 1);
  int x0 = max(ix - R, 0), x1 = min(ix + R, GR - 1);
  int y0 = max(iy - R, 0), y1 = min(iy + R, GR - 1);
  int z0 = max(iz - R, 0), z1 = min(iz + R, GR - 1);

  int ny = y1 - y0 + 1;
  int nrow = (z1 - z0 + 1) * ny;  // <= 25 for R=2
  int sLo = 0, lenLo = 0, sHi = 0, lenHi = 0;
  if (gl < nrow) {
    int zz = z0 + gl / ny, yy = y0 + gl % ny;
    int c0 = (zz * GR + yy) * GR + x0;
    sLo = cs[c0]; lenLo = cs[c0 + (x1 - x0) + 1] - sLo;
  }
  {
    int i2 = gl + 16;
    if (i2 < nrow) {
      int zz = z0 + i2 / ny, yy = y0 + i2 % ny;
      int c0 = (zz * GR + yy) * GR + x0;
      sHi = cs[c0]; lenHi = cs[c0 + (x1 - x0) + 1] - sHi;
    }
  }
  int pLo = lenLo, pHi = lenHi;
#pragma unroll
  for (int st = 1; st < 16; st <<= 1) {
    int o = __shfl_up(pLo, st, 16);
    if (gl >= st) pLo += o;
    int o2 = __shfl_up(pHi, st, 16);
    if (gl >= st) pHi += o2;
  }
  int tot16 = __shfl(pLo, 15, 16);
  pHi += tot16;
  int T = __shfl(pHi, 15, 16);
  pLo -= lenLo; pHi -= lenHi;      // exclusive prefixes
  int dLo = sLo - pLo, dHi = sHi - pHi;
  if (gl >= nrow) pLo = 0x7fffffff;
  if (gl + 16 >= nrow) pHi = 0x7fffffff;

  int slot = gl & (SL - 1);
  u64 val, tau;

  // ---- round 1: bulk-build via bitonic sort (replaces 16 serial inserts)
  {
    int v = gl;
    int r = 0;
#pragma unroll
    for (int st = 16; st >= 1; st >>= 1) {
      int j = r + st;                      // j <= 31
      int pcL = __shfl(pLo, j & 15, 16);
      int pcH = __shfl(pHi, j & 15, 16);
      int pc = (j < 16) ? pcL : pcH;
      if (v >= pc) r = j;
    }
    int dL = __shfl(dLo, r & 15, 16);
    int dH = __shfl(dHi, r & 15, 16);
    int addr = v + ((r < 16) ? dL : dH);
    u64 ck = ~0ull;
    if (v < T) {
      float4 P = sb[addr];
      float rr = P.x * P.x + P.y * P.y + P.z * P.z;
      float d2 = qq + rr - 2.0f * (qx * P.x + qy * P.y + qz * P.z);
      ck = ((u64)fbias(d2) << 32) | (u32)__float_as_uint(P.w);
    }
    first_round_sort<SL>(ck, gl, val, tau);
  }

  for (int v0 = 16; v0 < T; v0 += 16) {  // T group-uniform
    int v = v0 + gl;
    int r = 0;
#pragma unroll
    for (int st = 16; st >= 1; st >>= 1) {
      int j = r + st;                      // j <= 31
      int pcL = __shfl(pLo, j & 15, 16);
      int pcH = __shfl(pHi, j & 15, 16);
      int pc = (j < 16) ? pcL : pcH;
      if (v >= pc) r = j;
    }
    int dL = __shfl(dLo, r & 15, 16);
    int dH = __shfl(dHi, r & 15, 16);
    int addr = v + ((r < 16) ? dL : dH);
    u64 ck = ~0ull;
    if (v < T) {
      float4 P = sb[addr];
      float rr = P.x * P.x + P.y * P.y + P.z * P.z;
      float d2 = qq + rr - 2.0f * (qx * P.x + qy * P.y + qz * P.z);
      ck = ((u64)fbias(d2) << 32) | (u32)__float_as_uint(P.w);
    }
    u64 full = __ballot(ck < tau);
    u32 m16 = (u32)((full >> (g * 16)) & 0xFFFFull);
    group_insert<SL>(m16, ck, slot, val, tau);
  }

  knn_tail<SL, KOUT, GR, R, NREF>(sb, cs, qx, qy, qz, qq,
      ix, iy, iz, x0, x1, y0, y1, z0, z1, g, gl, slot, val, tau);

  if (gl < KOUT) {
    size_t base = ((size_t)b * Mq + q) * KOUT;
    oidx[base + gl] = (int)(u32)val;
    if (od2) od2[base + gl] = fmaxf(funbias((u32)(val >> 32)), 0.0f);
  }
}

// -------------------------------------------------------- kNN (brute) ------
template<int SL, int KOUT>
__device__ void knn_brute_dev(int vbx,
    const float* __restrict__ pos, int Nref, int Mq,
    int* __restrict__ oidx, float* __restrict__ od2) {
  int b = blockIdx.y;
  int wv = threadIdx.x >> 6, lane = threadIdx.x & 63;
  int g = lane >> 4, gl = lane & 15;
  int q = vbx * 16 + wv * 4 + g;
  const float* pb = pos + (size_t)b * NFULL * 3;
  float qx = pb[q * 3 + 0], qy = pb[q * 3 + 1], qz = pb[q * 3 + 2];
  float qq = qx * qx + qy * qy + qz * qz;

  int slot = gl & (SL - 1);
  u64 val, tau;

  // ---- round 1 (Nref >= 16 always): bitonic bulk build
  {
    int j = gl;
    float rx = pb[j * 3 + 0];
    float ry = pb[j * 3 + 1];
    float rz = pb[j * 3 + 2];
    float rr = rx * rx + ry * ry + rz * rz;
    float d2 = qq + rr - 2.0f * (qx * rx + qy * ry + qz * rz);
    u64 ck = ((u64)fbias(d2) << 32) | (u32)j;
    first_round_sort<SL>(ck, gl, val, tau);
  }

  for (int t0 = 16; t0 < Nref; t0 += 16) {
    int j = t0 + gl;
    float rx = pb[j * 3 + 0];
    float ry = pb[j * 3 + 1];
    float rz = pb[j * 3 + 2];
    float rr = rx * rx + ry * ry + rz * rz;
    float d2 = qq + rr - 2.0f * (qx * rx + qy * ry + qz * rz);
    u64 ck = ((u64)fbias(d2) << 32) | (u32)j;
    u64 full = __ballot(ck < tau);
    u32 m16 = (u32)((full >> (g * 16)) & 0xFFFFull);
    group_insert<SL>(m16, ck, slot, val, tau);
  }

  if (gl < KOUT) {
    size_t base = ((size_t)b * Mq + q) * KOUT;
    oidx[base + gl] = (int)(u32)val;
    if (od2) od2[base + gl] = fmaxf(funbias((u32)(val >> 32)), 0.0f);
  }
}

// ----------------------------- fused: ALL SIX kNN queries in one dispatch --
// Ranges ordered heaviest-per-block first to minimize the scheduling tail.
__global__ __launch_bounds__(256) void knn_all_kernel(
    const float* __restrict__ pos,
    const float4* __restrict__ sortedA, const int* __restrict__ csA,
    const float4* __restrict__ sortedB, const int* __restrict__ csB,
    const float4* __restrict__ sortedC, const int* __restrict__ csC,
    int* __restrict__ idx0, int* __restrict__ idx1, int* __restrict__ idx2,
    int* __restrict__ idxu0, float* __restrict__ d2u0,
    int* __restrict__ idxu1, float* __restrict__ d2u1,
    int* __restrict__ idxu2, float* __restrict__ d2u2) {
  int bx = blockIdx.x;
  if (bx < 8)          // idx2: 128 q over 512 pts (brute), K=16 — heaviest
    knn_brute_dev<16, 16>(bx, pos, 512, 128, idx2, nullptr);
  else if (bx < 40)    // idx1: 512 q over 2048 pts, K=16 (flat32, ~500 pts)
    knn_grid_flat32_dev<16, 16, 8, 2, 2048>(bx - 8, pos, sortedB, csB, 513, 512, idx1, nullptr);
  else if (bx < 168)   // idx0: 2048 q over 8192 pts, K=16 (flat32, ~250 pts)
    knn_grid_flat32_dev<16, 16, 16, 2, 8192>(bx - 40, pos, sortedA, csA, 4097, 2048, idx0, nullptr);
  else if (bx < 296)   // idxu1: 2048 q over 512 pts, K=3 (gridC, ~125 pts)
    knn_grid_flat32_dev<4, 3, 8, 2, 512>(bx - 168, pos, sortedC, csC, 513, 2048, idxu1, d2u1);
  else if (bx < 808)   // idxu2: 8192 q over 2048 pts, K=3 (flat, ~108 pts)
    knn_grid_flat_dev<4, 3, 8, 1, 2048>(bx - 296, pos, sortedB, csB, 513, 8192, idxu2, d2u2);
  else                 // idxu0: 512 q over 128 pts (brute), K=3
    knn_brute_dev<4, 3>(bx - 808, pos, 128, 512, idxu0, d2u0);
}

// ----------------------------------- fused weight packing + pos copy -------
__device__ __forceinline__ void pack_tile_rt(const float* __restrict__ W,
                                             short* __restrict__ outp,
                                             int KDIM, int N, int tile, int lane) {
  int NT = N >> 4;
  int kt = tile / NT, nt = tile - kt * NT;
  int n = nt * 16 + (lane & 15);
  int k0 = kt * 32 + (lane >> 4) * 8;
  bf8_t v;
#pragma unroll
  for (int j = 0; j < 8; ++j) {
    int k = k0 + j;
    v[j] = (k < KDIM) ? f2bf(W[(size_t)k * N + n]) : (short)0;
  }
  *(bf8_t*)(outp + ((size_t)tile * 64 + lane) * 8) = v;
}

__global__ __launch_bounds__(64) void pack_copy_all_kernel(
    const float* d0W1, short* d0W1p, const float* d0W2, short* d0W2p,
    const float* d1W1, short* d1W1p, const float* d1W2, short* d1W2p,
    const float* d2W1, short* d2W1p, const float* d2W2, short* d2W2p,
    const float* u2W, short* u2Wp, const float* fW1, short* fW1p,
    const float* fW2, short* fW2p,
    const float* u0W, short* u0Wp, const float* u1W, short* u1Wp,
    const float* pos, float* posOut) {
  int blk = blockIdx.x, lane = threadIdx.x;
  if      (blk < 8)    pack_tile_rt(d0W1, d0W1p, 6, 128, blk, lane);
  else if (blk < 40)   pack_tile_rt(d0W2, d0W2p, 128, 128, blk - 8, lane);
  else if (blk < 120)  pack_tile_rt(d1W1, d1W1p, 131, 256, blk - 40, lane);
  else if (blk < 248)  pack_tile_rt(d1W2, d1W2p, 256, 256, blk - 120, lane);
  else if (blk < 536)  pack_tile_rt(d2W1, d2W1p, 259, 512, blk - 248, lane);
  else if (blk < 1048) pack_tile_rt(d2W2, d2W2p, 512, 512, blk - 536, lane);
  else if (blk < 1088) pack_tile_rt(u2W, u2Wp, 134, 128, blk - 1048, lane);
  else if (blk < 1120) pack_tile_rt(fW1, fW1p, 128, 128, blk - 1088, lane);
  else if (blk < 1152) pack_tile_rt(fW2, fW2p, 128, 128, blk - 1120, lane);
  else if (blk < 1536) pack_tile_rt(u0W, u0Wp, 768, 256, blk - 1152, lane);
  else if (blk < 1632) pack_tile_rt(u1W, u1Wp, 384, 128, blk - 1536, lane);
  else {
    int base = (blk - 1632) * 256;  // 384 blocks x 256 = 98304 = BATCH*NFULL*3
#pragma unroll
    for (int j = 0; j < 4; ++j) {
      int i = base + lane + j * 64;
      posOut[i] = pos[i];
    }
  }
}

// ----------------------------------------------------- down MLP (MFMA) -----
// QB queries per block; weight tiles loaded ONCE per K-step and reused across
// all QB query A-fragments. LDS rows padded +8 shorts (bank-conflict fix).
template<int FEAT, int CIN, int CHID, int FPAD, int QB, int WAVES>
__global__ __launch_bounds__(64 * WAVES) void down_mfma_kernel(
    const float* __restrict__ pos, const float* __restrict__ xin,
    const int* __restrict__ idx,
    const short* __restrict__ W1p, const float* __restrict__ b1,
    const short* __restrict__ W2p, const float* __restrict__ b2,
    float* __restrict__ out, int n, int nprev) {
  const int KT1 = FPAD / 32, NT1 = CHID / 16;
  const int KT2 = CHID / 32, NT2 = CHID / 16;
  __shared__ short sFeat[QB][16][FPAD + 8];
  __shared__ short sH1[QB][16][CHID + 8];
  __shared__ int sIdx[QB][16];
  __shared__ float sCtr[QB][3];
  int b = blockIdx.y, q0 = blockIdx.x * QB;
  int t = threadIdx.x;
  int lane = t & 63, wv = t >> 6;
  const float* pb = pos + (size_t)b * NFULL * 3;
  const float* xb = xin + (size_t)b * nprev * CIN;
  if (t < QB * 16)
    sIdx[t >> 4][t & 15] = idx[((size_t)b * n + q0 + (t >> 4)) * 16 + (t & 15)];
  if (t < QB * 3) sCtr[t / 3][t % 3] = pb[(q0 + t / 3) * 3 + (t % 3)];
  __syncthreads();
  for (int e = t; e < QB * 16 * FPAD; e += 64 * WAVES) {
    int k = e / FPAD, c = e - k * FPAD;
    int qq = k >> 4, kk = k & 15;
    float v = 0.f;
    if (c < 3) v = pb[sIdx[qq][kk] * 3 + c] - sCtr[qq][c];
    else if (c < FEAT) v = xb[(size_t)sIdx[qq][kk] * CIN + (c - 3)];
    sFeat[qq][kk][c] = f2bf(v);
  }
  __syncthreads();

  int col = lane & 15, quad = lane >> 4;
  const bf8_t* W1t = (const bf8_t*)W1p;
  for (int nt = 2 * wv; nt < NT1; nt += 2 * WAVES) {
    f4_t acc[QB][2];
    float bb0 = b1[nt * 16 + col], bb1 = b1[nt * 16 + 16 + col];
#pragma unroll
    for (int q = 0; q < QB; ++q) {
      acc[q][0] = {bb0, bb0, bb0, bb0};
      acc[q][1] = {bb1, bb1, bb1, bb1};
    }
#pragma unroll
    for (int kt = 0; kt < KT1; ++kt) {
      bf8_t bf0 = W1t[(kt * NT1 + nt) * 64 + lane];
      bf8_t bf1 = W1t[(kt * NT1 + nt + 1) * 64 + lane];
#pragma unroll
      for (int q = 0; q < QB; ++q) {
        bf8_t a = *(const bf8_t*)&sFeat[q][col][kt * 32 + quad * 8];
        acc[q][0] = __builtin_amdgcn_mfma_f32_16x16x32_bf16(a, bf0, acc[q][0], 0, 0, 0);
        acc[q][1] = __builtin_amdgcn_mfma_f32_16x16x32_bf16(a, bf1, acc[q][1], 0, 0, 0);
      }
    }
#pragma unroll
    for (int q = 0; q < QB; ++q)
#pragma unroll
      for (int r = 0; r < 4; ++r) {
        sH1[q][quad * 4 + r][nt * 16 + col] = f2bf(fmaxf(acc[q][0][r], 0.f));
        sH1[q][quad * 4 + r][nt * 16 + 16 + col] = f2bf(fmaxf(acc[q][1][r], 0.f));
      }
  }
  __syncthreads();

  const bf8_t* W2t = (const bf8_t*)W2p;
  for (int nt = 2 * wv; nt < NT2; nt += 2 * WAVES) {
    f4_t acc[QB][2];
    float bb0 = b2[nt * 16 + col], bb1 = b2[nt * 16 + 16 + col];
#pragma unroll
    for (int q = 0; q < QB; ++q) {
      acc[q][0] = {bb0, bb0, bb0, bb0};
      acc[q][1] = {bb1, bb1, bb1, bb1};
    }
#pragma unroll
    for (int kt = 0; kt < KT2; ++kt) {
      bf8_t bf0 = W2t[(kt * NT2 + nt) * 64 + lane];
      bf8_t bf1 = W2t[(kt * NT2 + nt + 1) * 64 + lane];
#pragma unroll
      for (int q = 0; q < QB; ++q) {
        bf8_t a = *(const bf8_t*)&sH1[q][col][kt * 32 + quad * 8];
        acc[q][0] = __builtin_amdgcn_mfma_f32_16x16x32_bf16(a, bf0, acc[q][0], 0, 0, 0);
        acc[q][1] = __builtin_amdgcn_mfma_f32_16x16x32_bf16(a, bf1, acc[q][1], 0, 0, 0);
      }
    }
#pragma unroll
    for (int q = 0; q < QB; ++q) {
      float m0 = fmaxf(fmaxf(acc[q][0][0], acc[q][0][1]), fmaxf(acc[q][0][2], acc[q][0][3]));
      float m1 = fmaxf(fmaxf(acc[q][1][0], acc[q][1][1]), fmaxf(acc[q][1][2], acc[q][1][3]));
      m0 = fmaxf(m0, __shfl_xor(m0, 16, 64));
      m0 = fmaxf(m0, __shfl_xor(m0, 32, 64));
      m1 = fmaxf(m1, __shfl_xor(m1, 16, 64));
      m1 = fmaxf(m1, __shfl_xor(m1, 32, 64));
      if (lane < 16) {
        float* ob = out + ((size_t)b * n + q0 + q) * CHID;
        ob[nt * 16 + lane] = m0;
        ob[nt * 16 + 16 + lane] = m1;
      }
    }
  }
}

// -------------------------------------------- up MLP (bf16 MFMA version) ---
template<int CIN, int CPRV, int COUT, int WPB>
__global__ __launch_bounds__(64 * WPB) void up_mfma_kernel(
    const float* __restrict__ xc, int ncoarse,
    const int* __restrict__ idx3, const float* __restrict__ d23,
    const float* __restrict__ prv, const short* __restrict__ Wp,
    const float* __restrict__ bvec, float* __restrict__ out, int m) {
  const int CTOT = CIN + CPRV;
  const int KT = CTOT / 32, NT = COUT / 16;
  __shared__ short sA[16][CTOT + 8];
  __shared__ float sWt[16][3];
  __shared__ int   sIt[16][3];
  int b = blockIdx.y, q0 = blockIdx.x * 16, t = threadIdx.x;
  int lane = t & 63, wv = t >> 6;
  if (t < 16) {
    size_t base = ((size_t)b * m + q0 + t) * 3;
    float d0 = d23[base + 0], d1 = d23[base + 1], d2v = d23[base + 2];
    float w0 = 1.f / (d0 + 1e-8f), w1 = 1.f / (d1 + 1e-8f), w2 = 1.f / (d2v + 1e-8f);
    float s = w0 + w1 + w2;
    sWt[t][0] = w0 / s; sWt[t][1] = w1 / s; sWt[t][2] = w2 / s;
    sIt[t][0] = idx3[base + 0]; sIt[t][1] = idx3[base + 1]; sIt[t][2] = idx3[base + 2];
  }
  __syncthreads();
  const float* xb = xc + (size_t)b * ncoarse * CIN;
  const float* pvb = prv + ((size_t)b * m + q0) * CPRV;
  for (int e = t; e < 16 * CIN; e += 64 * WPB) {
    int p = e / CIN, c = e % CIN;
    float v = sWt[p][0] * xb[(size_t)sIt[p][0] * CIN + c]
            + sWt[p][1] * xb[(size_t)sIt[p][1] * CIN + c]
            + sWt[p][2] * xb[(size_t)sIt[p][2] * CIN + c];
    sA[p][c] = f2bf(v);
  }
  for (int e = t; e < 16 * CPRV; e += 64 * WPB) {
    int p = e / CPRV, c = e % CPRV;
    sA[p][CIN + c] = f2bf(pvb[(size_t)p * CPRV + c]);
  }
  __syncthreads();
  int col = lane & 15, quad = lane >> 4;
  const bf8_t* Wt = (const bf8_t*)Wp;
  float* ob = out + ((size_t)b * m + q0) * COUT;
  for (int nt = 2 * wv; nt < NT; nt += 2 * WPB) {
    float bb0 = bvec[nt * 16 + col], bb1 = bvec[nt * 16 + 16 + col];
    f4_t acc0 = {bb0, bb0, bb0, bb0}, acc1 = {bb1, bb1, bb1, bb1};
#pragma unroll
    for (int kt = 0; kt < KT; ++kt) {
      bf8_t a = *(const bf8_t*)&sA[col][kt * 32 + quad * 8];
      bf8_t bf0 = Wt[(kt * NT + nt) * 64 + lane];
      bf8_t bf1 = Wt[(kt * NT + nt + 1) * 64 + lane];
      acc0 = __builtin_amdgcn_mfma_f32_16x16x32_bf16(a, bf0, acc0, 0, 0, 0);
      acc1 = __builtin_amdgcn_mfma_f32_16x16x32_bf16(a, bf1, acc1, 0, 0, 0);
    }
#pragma unroll
    for (int r = 0; r < 4; ++r) {
      ob[(size_t)(quad * 4 + r) * COUT + nt * 16 + col] = fmaxf(acc0[r], 0.f);
      ob[(size_t)(quad * 4 + r) * COUT + nt * 16 + 16 + col] = fmaxf(acc1[r], 0.f);
    }
  }
}

// ------------------------------------- fused up2 + final MLP (bf16 MFMA) ---
__global__ __launch_bounds__(128) void up2f_mfma_kernel(
    const float* __restrict__ xc,
    const int* __restrict__ idx3, const float* __restrict__ d23,
    const float* __restrict__ x0, const float* __restrict__ pos0,
    const short* __restrict__ u2Wp, const float* __restrict__ u2b,
    const short* __restrict__ fW1p, const float* __restrict__ fb1,
    const short* __restrict__ fW2p, const float* __restrict__ fb2,
    float* __restrict__ out) {
  __shared__ short sA[16][168];
  __shared__ short sB[16][136];
  __shared__ float sWt[16][3];
  __shared__ int   sIt[16][3];
  int b = blockIdx.y, q0 = blockIdx.x * 16, t = threadIdx.x;
  int lane = t & 63, wv = t >> 6;
  if (t < 16) {
    size_t base = ((size_t)b * NFULL + q0 + t) * 3;
    float d0 = d23[base + 0], d1 = d23[base + 1], d2v = d23[base + 2];
    float w0 = 1.f / (d0 + 1e-8f), w1 = 1.f / (d1 + 1e-8f), w2 = 1.f / (d2v + 1e-8f);
    float s = w0 + w1 + w2;
    sWt[t][0] = w0 / s; sWt[t][1] = w1 / s; sWt[t][2] = w2 / s;
    sIt[t][0] = idx3[base + 0]; sIt[t][1] = idx3[base + 1]; sIt[t][2] = idx3[base + 2];
  }
  __syncthreads();
  const float* xb = xc + (size_t)b * 2048 * 128;
#pragma unroll
  for (int p = 0; p < 16; ++p) {
    float v = sWt[p][0] * xb[(size_t)sIt[p][0] * 128 + t]
            + sWt[p][1] * xb[(size_t)sIt[p][1] * 128 + t]
            + sWt[p][2] * xb[(size_t)sIt[p][2] * 128 + t];
    sA[p][t] = f2bf(v);
  }
  for (int e = t; e < 16 * 32; e += 128) {
    int p = e / 32, c = 128 + (e % 32);
    float v = 0.f;
    if (c < 131) v = x0[((size_t)b * NFULL + q0 + p) * 3 + (c - 128)];
    else if (c < 134) v = pos0[((size_t)b * NFULL + q0 + p) * 3 + (c - 131)];
    sA[p][c] = f2bf(v);
  }
  __syncthreads();
  int col = lane & 15, quad = lane >> 4;

  bf8_t a1[5];
#pragma unroll
  for (int kt = 0; kt < 5; ++kt)
    a1[kt] = *(const bf8_t*)&sA[col][kt * 32 + quad * 8];
  const bf8_t* W1t = (const bf8_t*)u2Wp;
  for (int nt = 2 * wv; nt < 8; nt += 4) {
    float bb0 = u2b[nt * 16 + col], bb1 = u2b[nt * 16 + 16 + col];
    f4_t acc0 = {bb0, bb0, bb0, bb0}, acc1 = {bb1, bb1, bb1, bb1};
#pragma unroll
    for (int kt = 0; kt < 5; ++kt) {
      bf8_t bf0 = W1t[(kt * 8 + nt) * 64 + lane];
      bf8_t bf1 = W1t[(kt * 8 + nt + 1) * 64 + lane];
      acc0 = __builtin_amdgcn_mfma_f32_16x16x32_bf16(a1[kt], bf0, acc0, 0, 0, 0);
      acc1 = __builtin_amdgcn_mfma_f32_16x16x32_bf16(a1[kt], bf1, acc1, 0, 0, 0);
    }
#pragma unroll
    for (int r = 0; r < 4; ++r) {
      sB[quad * 4 + r][nt * 16 + col] = f2bf(fmaxf(acc0[r], 0.f));
      sB[quad * 4 + r][nt * 16 + 16 + col] = f2bf(fmaxf(acc1[r], 0.f));
    }
  }
  __syncthreads();

  bf8_t a2[4];
#pragma unroll
  for (int kt = 0; kt < 4; ++kt)
    a2[kt] = *(const bf8_t*)&sB[col][kt * 32 + quad * 8];
  const bf8_t* W2t = (const bf8_t*)fW1p;
  for (int nt = 2 * wv; nt < 8; nt += 4) {
    float bb0 = fb1[nt * 16 + col], bb1 = fb1[nt * 16 + 16 + col];
    f4_t acc0 = {bb0, bb0, bb0, bb0}, acc1 = {bb1, bb1, bb1, bb1};
#pragma unroll
    for (int kt = 0; kt < 4; ++kt) {
      bf8_t bf0 = W2t[(kt * 8 + nt) * 64 + lane];
      bf8_t bf1 = W2t[(kt * 8 + nt + 1) * 64 + lane];
      acc0 = __builtin_amdgcn_mfma_f32_16x16x32_bf16(a2[kt], bf0, acc0, 0, 0, 0);
      acc1 = __builtin_amdgcn_mfma_f32_16x16x32_bf16(a2[kt], bf1, acc1, 0, 0, 0);
    }
#pragma unroll
    for (int r = 0; r < 4; ++r) {
      sA[quad * 4 + r][nt * 16 + col] = f2bf(fmaxf(acc0[r], 0.f));
      sA[quad * 4 + r][nt * 16 + 16 + col] = f2bf(fmaxf(acc1[r], 0.f));
    }
  }
  __syncthreads();

  bf8_t a3[4];
#pragma unroll
  for (int kt = 0; kt < 4; ++kt)
    a3[kt] = *(const bf8_t*)&sA[col][kt * 32 + quad * 8];
  const bf8_t* W3t = (const bf8_t*)fW2p;
  float* ob = out + ((size_t)b * NFULL + q0) * 128;
  for (int nt = 2 * wv; nt < 8; nt += 4) {
    float bb0 = fb2[nt * 16 + col], bb1 = fb2[nt * 16 + 16 + col];
    f4_t acc0 = {bb0, bb0, bb0, bb0}, acc1 = {bb1, bb1, bb1, bb1};
#pragma unroll
    for (int kt = 0; kt < 4; ++kt) {
      bf8_t bf0 = W3t[(kt * 8 + nt) * 64 + lane];
      bf8_t bf1 = W3t[(kt * 8 + nt + 1) * 64 + lane];
      acc0 = __builtin_amdgcn_mfma_f32_16x16x32_bf16(a3[kt], bf0, acc0, 0, 0, 0);
      acc1 = __builtin_amdgcn_mfma_f32_16x16x32_bf16(a3[kt], bf1, acc1, 0, 0, 0);
    }
#pragma unroll
    for (int r = 0; r < 4; ++r) {
      ob[(size_t)(quad * 4 + r) * 128 + nt * 16 + col] = acc0[r];
      ob[(size_t)(quad * 4 + r) * 128 + nt * 16 + 16 + col] = acc1[r];
    }
  }
}

// ------------------------------------------------------------------ launch -
extern "C" void kernel_launch(void* const* d_in, const int* in_sizes, int n_in,
                              void* d_out, int out_size, void* d_ws, size_t ws_size,
                              hipStream_t stream) {
  const float* x    = (const float*)d_in[0];
  const float* pos  = (const float*)d_in[1];
  const float* d0W1 = (const float*)d_in[2];
  const float* d0b1 = (const float*)d_in[3];
  const float* d0W2 = (const float*)d_in[4];
  const float* d0b2 = (const float*)d_in[5];
  const float* d1W1 = (const float*)d_in[6];
  const float* d1b1 = (const float*)d_in[7];
  const float* d1W2 = (const float*)d_in[8];
  const float* d1b2 = (const float*)d_in[9];
  const float* d2W1 = (const float*)d_in[10];
  const float* d2b1 = (const float*)d_in[11];
  const float* d2W2 = (const float*)d_in[12];
  const float* d2b2 = (const float*)d_in[13];
  const float* u0W  = (const float*)d_in[14];
  const float* u0b  = (const float*)d_in[15];
  const float* u1W  = (const float*)d_in[16];
  const float* u1b  = (const float*)d_in[17];
  const float* u2W  = (const float*)d_in[18];
  const float* u2b  = (const float*)d_in[19];
  const float* fW1  = (const float*)d_in[20];
  const float* fb1  = (const float*)d_in[21];
  const float* fW2  = (const float*)d_in[22];
  const float* fb2  = (const float*)d_in[23];

  char* ws = (char*)d_ws;
  float* x1    = (float*)(ws + 0);
  float* x2    = (float*)(ws + 4194304);
  float* x3    = (float*)(ws + 6291456);
  float* up0o  = (float*)(ws + 7340032);
  float* up1o  = (float*)(ws + 9437184);
  int*   idx0  = (int*)  (ws + 13631488);
  int*   idx1  = (int*)  (ws + 14155776);
  int*   idx2  = (int*)  (ws + 14286848);
  float4* sortedC = (float4*)(ws + 14319616); // 4*512*16 = 32768
  int*    csC     = (int*)   (ws + 14352384); // 4*513*4  = 8208
  int*   idxu0 = (int*)  (ws + 14843904);
  float* d2u0  = (float*)(ws + 14868480);
  int*   idxu1 = (int*)  (ws + 14893056);
  float* d2u1  = (float*)(ws + 14991360);
  int*   idxu2 = (int*)  (ws + 15089664);
  float* d2u2  = (float*)(ws + 15482880);
  short* d1W1p = (short*)(ws + 15876096);
  short* d1W2p = (short*)(ws + 15958016);
  short* d2W1p = (short*)(ws + 16089088);
  short* d2W2p = (short*)(ws + 16384000);
  short* d0W1p = (short*)(ws + 16908288);
  short* d0W2p = (short*)(ws + 16916480);
  float4* sortedA = (float4*)(ws + 16949248);  // 4*8192*16 = 524288
  int*    csA     = (int*)   (ws + 17473536);  // 4*4097*4  = 65552
  float4* sortedB = (float4*)(ws + 17539136);  // 4*2048*16 = 131072
  int*    csB     = (int*)   (ws + 17670208);  // 4*513*4   = 8208
  short* u2Wp  = (short*)(ws + 17697920);
  short* fW1p  = (short*)(ws + 17738880);
  short* fW2p  = (short*)(ws + 17771648);

  float* out = (float*)d_out;
  // Packed u0W/u1W live in the d_out main region: it is dead until the final
  // up2f_mfma_kernel writes it, and both are fully consumed before that.
  short* u0Wp = (short*)out;                       // 768*256*2 = 393216 B
  short* u1Wp = (short*)(out + 98304);             // 384*128*2 =  98304 B

  // ---- fused packing + pos passthrough; fused grid builds (3 grids) ----
  pack_copy_all_kernel<<<dim3(2016), 64, 0, stream>>>(
      d0W1, d0W1p, d0W2, d0W2p, d1W1, d1W1p, d1W2, d1W2p,
      d2W1, d2W1p, d2W2, d2W2p, u2W, u2Wp, fW1, fW1p, fW2, fW2p,
      u0W, u0Wp, u1W, u1Wp,
      pos, out + (size_t)BATCH * NFULL * 128);
  build_grids_kernel<<<dim3(BATCH, 3), 256, 0, stream>>>(
      pos, sortedA, csA, sortedB, csB, sortedC, csC);

  // ---- ALL kNN queries in one dispatch (deps: pos + grids only) ----
  knn_all_kernel<<<dim3(840, BATCH), 256, 0, stream>>>(
      pos, sortedA, csA, sortedB, csB, sortedC, csC,
      idx0, idx1, idx2,
      idxu0, d2u0, idxu1, d2u1, idxu2, d2u2);

  // ---- down path ----
  down_mfma_kernel<6, 3, 128, 32, 4, 4><<<dim3(512, BATCH), 256, 0, stream>>>(
      pos, x, idx0, d0W1p, d0b1, d0W2p, d0b2, x1, 2048, 8192);
  down_mfma_kernel<131, 128, 256, 160, 4, 8><<<dim3(128, BATCH), 512, 0, stream>>>(
      pos, x1, idx1, d1W1p, d1b1, d1W2p, d1b2, x2, 512, 2048);
  down_mfma_kernel<259, 256, 512, 288, 2, 8><<<dim3(64, BATCH), 512, 0, stream>>>(
      pos, x2, idx2, d2W1p, d2b1, d2W2p, d2b2, x3, 128, 512);

  // ---- up path ----
  up_mfma_kernel<512, 256, 256, 4><<<dim3(32, BATCH), 256, 0, stream>>>(
      x3, 128, idxu0, d2u0, x2, u0Wp, u0b, up0o, 512);
  up_mfma_kernel<256, 128, 128, 2><<<dim3(128, BATCH), 128, 0, stream>>>(
      up0o, 512, idxu1, d2u1, x1, u1Wp, u1b, up1o, 2048);
  up2f_mfma_kernel<<<dim3(512, BATCH), 128, 0, stream>>>(
      up1o, idxu2, d2u2, x, pos, u2Wp, u2b, fW1p, fb1, fW2p, fb2, out);
}

// Round 7
// 299.857 us; speedup vs baseline: 1.6489x; 1.0210x over previous
//
#include <hip/hip_runtime.h>

#define NFULL 8192
#define BATCH 4

typedef unsigned long long u64;
typedef unsigned int u32;
typedef __attribute__((ext_vector_type(8))) short bf8_t;   // 8 bf16 (4 VGPRs)
typedef __attribute__((ext_vector_type(4))) float f4_t;    // MFMA C/D

__device__ __forceinline__ u32 fbias(float f) {
  u32 u = __float_as_uint(f);
  return (u & 0x80000000u) ? ~u : (u | 0x80000000u);
}
__device__ __forceinline__ float funbias(u32 b) {
  u32 u = (b & 0x80000000u) ? (b & 0x7fffffffu) : ~b;
  return __uint_as_float(u);
}
__device__ __forceinline__ short f2bf(float f) {
  u32 u = __float_as_uint(f);
  u32 r = u + 0x7FFFu + ((u >> 16) & 1u);
  return (short)(r >> 16);
}

// ------------------------------------------- fused grid build (all three) --
__global__ __launch_bounds__(256) void build_grids_kernel(
    const float* __restrict__ pos, float4* __restrict__ sortedA,
    int* __restrict__ csA, float4* __restrict__ sortedB, int* __restrict__ csB,
    float4* __restrict__ sortedC, int* __restrict__ csC) {
  __shared__ int cnt[4096];
  __shared__ int partial[256];
  int which = blockIdx.y, b = blockIdx.x, t = threadIdx.x;
  int NREF = (which == 0) ? 8192 : (which == 1) ? 2048 : 512;
  int GR = (which == 0) ? 16 : 8;
  int NC = GR * GR * GR;
  float4* sorted = ((which == 0) ? sortedA : (which == 1) ? sortedB : sortedC)
                   + (size_t)b * NREF;
  int* cs = ((which == 0) ? csA + b * 4097 : (which == 1) ? csB + b * 513
                                           : csC + b * 513);
  const float* pb = pos + (size_t)b * NFULL * 3;
  for (int c = t; c < NC; c += 256) cnt[c] = 0;
  __syncthreads();
  for (int p = t; p < NREF; p += 256) {
    float x = pb[p * 3 + 0], y = pb[p * 3 + 1], z = pb[p * 3 + 2];
    int cx = min(max((int)(x * GR), 0), GR - 1);
    int cy = min(max((int)(y * GR), 0), GR - 1);
    int cz = min(max((int)(z * GR), 0), GR - 1);
    atomicAdd(&cnt[(cz * GR + cy) * GR + cx], 1);
  }
  __syncthreads();
  int chunk = (NC + 255) / 256;
  int s = 0;
  for (int i = 0; i < chunk; ++i) {
    int c = t * chunk + i;
    if (c < NC) s += cnt[c];
  }
  partial[t] = s;
  __syncthreads();
  if (t == 0) {
    int run = 0;
    for (int i = 0; i < 256; ++i) { int v = partial[i]; partial[i] = run; run += v; }
  }
  __syncthreads();
  int run = partial[t];
  for (int i = 0; i < chunk; ++i) {
    int c = t * chunk + i;
    if (c < NC) { int v = cnt[c]; cnt[c] = run; run += v; }
  }
  __syncthreads();
  for (int c = t; c < NC; c += 256) cs[c] = cnt[c];
  if (t == 0) cs[NC] = NREF;
  __syncthreads();
  for (int p = t; p < NREF; p += 256) {
    float x = pb[p * 3 + 0], y = pb[p * 3 + 1], z = pb[p * 3 + 2];
    int cx = min(max((int)(x * GR), 0), GR - 1);
    int cy = min(max((int)(y * GR), 0), GR - 1);
    int cz = min(max((int)(z * GR), 0), GR - 1);
    int slot = atomicAdd(&cnt[(cz * GR + cy) * GR + cx], 1);
    sorted[slot] = make_float4(x, y, z, __uint_as_float((u32)p));
  }
}

// --------------------------------------------------- grouped insert core ---
template<int SL>
__device__ __forceinline__ void group_insert(u32 m16, u64 ck, int slot,
                                             u64& val, u64& tau) {
  if (m16) {
    while (m16) {
      int src = __ffs(m16) - 1;
      m16 &= m16 - 1;
      u64 c = __shfl((unsigned long long)ck, src, 16);
      u64 prev = __shfl_up((unsigned long long)val, 1, SL);
      if (slot == 0) prev = 0ull;
      val = (val <= c) ? val : ((prev <= c) ? c : prev);
    }
    tau = __shfl((unsigned long long)val, SL - 1, SL);
  }
}

// -------------------- round-1 bulk build: bitonic sort of 16 candidates ----
template<int SL>
__device__ __forceinline__ void first_round_sort(u64 ck, int gl,
                                                 u64& val, u64& tau) {
  u64 v = ck;
#pragma unroll
  for (int size = 2; size <= 16; size <<= 1) {
#pragma unroll
    for (int stride = size >> 1; stride > 0; stride >>= 1) {
      u64 other = __shfl_xor((unsigned long long)v, stride, 16);
      bool ddd = ((gl & size) == 0);
      bool takeMin = (((gl & stride) == 0) == ddd);
      u64 mn = (v <= other) ? v : other;
      u64 mx = (v <= other) ? other : v;
      v = takeMin ? mn : mx;
    }
  }
  if (SL < 16) v = __shfl((unsigned long long)v, gl & (SL - 1), 16);
  val = v;
  tau = __shfl((unsigned long long)v, SL - 1, SL);
}

// ----------------------------- per-lane top-3 machinery (K=3 paths) --------
// No cross-lane ops in the scan loop: each lane keeps its local sorted top-3
// (v0<=v1<=v2) of its strided candidate subset; a single 16-way shfl merge
// at the end extracts the exact global top-3 (unique u64 keys -> identical
// tie-breaking).
__device__ __forceinline__ void lane_insert3(u64 ck, u64& v0, u64& v1, u64& v2) {
  u64 a = (v0 <= ck) ? v0 : ck;
  u64 bb = (v0 <= ck) ? ck : v0;
  v0 = a;
  u64 c = (v1 <= bb) ? v1 : bb;
  u64 d = (v1 <= bb) ? bb : v1;
  v1 = c;
  v2 = (v2 <= d) ? v2 : d;
}

__device__ __forceinline__ void merge3(u64 v0, u64 v1, u64 v2,
                                       u64& o0, u64& o1, u64& o2) {
  u64 h = v0;
  int hc = 0;
  u64 outs[3];
#pragma unroll
  for (int k = 0; k < 3; ++k) {
    u64 m = h;
#pragma unroll
    for (int st = 1; st < 16; st <<= 1) {
      u64 o = __shfl_xor((unsigned long long)m, st, 16);
      m = (m <= o) ? m : o;
    }
    outs[k] = m;
    if (h == m) { ++hc; h = (hc == 1) ? v1 : ((hc == 2) ? v2 : ~0ull); }
  }
  o0 = outs[0]; o1 = outs[1]; o2 = outs[2];
}

__device__ __forceinline__ void scan_range3(const float4* __restrict__ sb,
    int s, int e, float qx, float qy, float qz, float qq,
    int gl, u64& v0, u64& v1, u64& v2) {
  for (int t0 = s; t0 < e; t0 += 16) {
    int j = t0 + gl;
    if (j < e) {
      float4 P = sb[j];
      float rr = P.x * P.x + P.y * P.y + P.z * P.z;
      float d2 = qq + rr - 2.0f * (qx * P.x + qy * P.y + qz * P.z);
      u64 ck = ((u64)fbias(d2) << 32) | (u32)__float_as_uint(P.w);
      lane_insert3(ck, v0, v1, v2);
    }
  }
}

// ------------------------- shared: scan a contiguous sorted[] range (K=16) -
template<int SL>
__device__ __forceinline__ void scan_range(const float4* __restrict__ sb,
    int s, int e, float qx, float qy, float qz, float qq,
    int g, int gl, int slot, u64& val, u64& tau) {
  for (int t0 = s; t0 < e; t0 += 16) {
    int j = t0 + gl;
    u64 ck = ~0ull;
    if (j < e) {
      float4 P = sb[j];
      float rr = P.x * P.x + P.y * P.y + P.z * P.z;
      float d2 = qq + rr - 2.0f * (qx * P.x + qy * P.y + qz * P.z);
      ck = ((u64)fbias(d2) << 32) | (u32)__float_as_uint(P.w);
    }
    u64 full = __ballot(ck < tau);
    u32 m16 = (u32)((full >> (g * 16)) & 0xFFFFull);
    group_insert<SL>(m16, ck, slot, val, tau);
  }
}

// Exactness: after scanning box B, if the KOUT-th smallest d2 is strictly
// less than the squared distance to the nearest NON-clipped face of B, no
// outside point can enter the top-KOUT. Ring expansion scans box(R+1)\box(R)
// exactly once per point via per-row segments; unique u64 keys keep the
// tie-breaking identical to the reference top_k.

// -------- K=16 tail: margin check + ring expansion + full fallback ---------
template<int SL, int KOUT, int GR, int R, int NREF>
__device__ __forceinline__ void knn_tail(
    const float4* __restrict__ sb, const int* __restrict__ cs,
    float qx, float qy, float qz, float qq,
    int ix, int iy, int iz, int x0, int x1, int y0, int y1, int z0, int z1,
    int g, int gl, int slot, u64& val, u64& tau) {
  const float h = 1.0f / GR;
  float m = 1e30f;
  if (x0 > 0)      m = fminf(m, qx - x0 * h);
  if (x1 < GR - 1) m = fminf(m, (x1 + 1) * h - qx);
  if (y0 > 0)      m = fminf(m, qy - y0 * h);
  if (y1 < GR - 1) m = fminf(m, (y1 + 1) * h - qy);
  if (z0 > 0)      m = fminf(m, qz - z0 * h);
  if (z1 < GR - 1) m = fminf(m, (z1 + 1) * h - qz);
  float bound = m * m;
  u64 kv = __shfl((unsigned long long)val, KOUT - 1, SL);
  float kth_d2 = funbias((u32)(kv >> 32));
  if (!(kth_d2 < bound)) {  // group-uniform; rare (corner/edge queries)
    int X0 = max(ix - (R + 1), 0), X1 = min(ix + (R + 1), GR - 1);
    int Y0 = max(iy - (R + 1), 0), Y1 = min(iy + (R + 1), GR - 1);
    int Z0 = max(iz - (R + 1), 0), Z1 = min(iz + (R + 1), GR - 1);
    int NY2 = Y1 - Y0 + 1;
    int nrow2 = (Z1 - Z0 + 1) * NY2;
    for (int rr2 = 0; rr2 < nrow2; ++rr2) {
      int zz = Z0 + rr2 / NY2, yy = Y0 + rr2 % NY2;
      int c0 = (zz * GR + yy) * GR;
      bool mid = (zz >= z0 && zz <= z1 && yy >= y0 && yy <= y1);
      int s1 = cs[c0 + X0];
      int e1 = mid ? cs[c0 + x0] : cs[c0 + X1 + 1];
      scan_range<SL>(sb, s1, e1, qx, qy, qz, qq, g, gl, slot, val, tau);
      if (mid) {
        int s2 = cs[c0 + x1 + 1];
        int e2 = cs[c0 + X1 + 1];
        scan_range<SL>(sb, s2, e2, qx, qy, qz, qq, g, gl, slot, val, tau);
      }
    }
    x0 = X0; x1 = X1; y0 = Y0; y1 = Y1; z0 = Z0; z1 = Z1;
    m = 1e30f;
    if (x0 > 0)      m = fminf(m, qx - x0 * h);
    if (x1 < GR - 1) m = fminf(m, (x1 + 1) * h - qx);
    if (y0 > 0)      m = fminf(m, qy - y0 * h);
    if (y1 < GR - 1) m = fminf(m, (y1 + 1) * h - qy);
    if (z0 > 0)      m = fminf(m, qz - z0 * h);
    if (z1 < GR - 1) m = fminf(m, (z1 + 1) * h - qz);
    bound = m * m;
    kv = __shfl((unsigned long long)val, KOUT - 1, SL);
    kth_d2 = funbias((u32)(kv >> 32));
    if (!(kth_d2 < bound)) {  // essentially unreachable
      for (int t0 = 0; t0 < NREF; t0 += 16) {
        int j = t0 + gl;
        u64 ck = ~0ull;
        if (j < NREF) {
          float4 P = sb[j];
          int cx = min(max((int)(P.x * GR), 0), GR - 1);
          int cy = min(max((int)(P.y * GR), 0), GR - 1);
          int cz = min(max((int)(P.z * GR), 0), GR - 1);
          bool inbox = (cx >= x0 && cx <= x1 && cy >= y0 && cy <= y1 &&
                        cz >= z0 && cz <= z1);
          if (!inbox) {
            float rr = P.x * P.x + P.y * P.y + P.z * P.z;
            float d2 = qq + rr - 2.0f * (qx * P.x + qy * P.y + qz * P.z);
            ck = ((u64)fbias(d2) << 32) | (u32)__float_as_uint(P.w);
          }
        }
        u64 full = __ballot(ck < tau);
        u32 m16 = (u32)((full >> (g * 16)) & 0xFFFFull);
        group_insert<SL>(m16, ck, slot, val, tau);
      }
    }
  }
}

// -------- K=3 tail: margin check + ring expansion + full fallback ----------
template<int GR, int R, int NREF>
__device__ __forceinline__ void knn_tail3(
    const float4* __restrict__ sb, const int* __restrict__ cs,
    float qx, float qy, float qz, float qq,
    int ix, int iy, int iz, int x0, int x1, int y0, int y1, int z0, int z1,
    int gl, u64& v0, u64& v1, u64& v2, u64& o0, u64& o1, u64& o2) {
  const float h = 1.0f / GR;
  float m = 1e30f;
  if (x0 > 0)      m = fminf(m, qx - x0 * h);
  if (x1 < GR - 1) m = fminf(m, (x1 + 1) * h - qx);
  if (y0 > 0)      m = fminf(m, qy - y0 * h);
  if (y1 < GR - 1) m = fminf(m, (y1 + 1) * h - qy);
  if (z0 > 0)      m = fminf(m, qz - z0 * h);
  if (z1 < GR - 1) m = fminf(m, (z1 + 1) * h - qz);
  float bound = m * m;
  merge3(v0, v1, v2, o0, o1, o2);
  float kth_d2 = funbias((u32)(o2 >> 32));
  if (!(kth_d2 < bound)) {  // group-uniform; rare (corner/edge queries)
    int X0 = max(ix - (R + 1), 0), X1 = min(ix + (R + 1), GR - 1);
    int Y0 = max(iy - (R + 1), 0), Y1 = min(iy + (R + 1), GR - 1);
    int Z0 = max(iz - (R + 1), 0), Z1 = min(iz + (R + 1), GR - 1);
    int NY2 = Y1 - Y0 + 1;
    int nrow2 = (Z1 - Z0 + 1) * NY2;
    for (int rr2 = 0; rr2 < nrow2; ++rr2) {
      int zz = Z0 + rr2 / NY2, yy = Y0 + rr2 % NY2;
      int c0 = (zz * GR + yy) * GR;
      bool mid = (zz >= z0 && zz <= z1 && yy >= y0 && yy <= y1);
      int s1 = cs[c0 + X0];
      int e1 = mid ? cs[c0 + x0] : cs[c0 + X1 + 1];
      scan_range3(sb, s1, e1, qx, qy, qz, qq, gl, v0, v1, v2);
      if (mid) {
        int s2 = cs[c0 + x1 + 1];
        int e2 = cs[c0 + X1 + 1];
        scan_range3(sb, s2, e2, qx, qy, qz, qq, gl, v0, v1, v2);
      }
    }
    x0 = X0; x1 = X1; y0 = Y0; y1 = Y1; z0 = Z0; z1 = Z1;
    m = 1e30f;
    if (x0 > 0)      m = fminf(m, qx - x0 * h);
    if (x1 < GR - 1) m = fminf(m, (x1 + 1) * h - qx);
    if (y0 > 0)      m = fminf(m, qy - y0 * h);
    if (y1 < GR - 1) m = fminf(m, (y1 + 1) * h - qy);
    if (z0 > 0)      m = fminf(m, qz - z0 * h);
    if (z1 < GR - 1) m = fminf(m, (z1 + 1) * h - qz);
    bound = m * m;
    merge3(v0, v1, v2, o0, o1, o2);
    kth_d2 = funbias((u32)(o2 >> 32));
    if (!(kth_d2 < bound)) {  // essentially unreachable
      for (int t0 = 0; t0 < NREF; t0 += 16) {
        int j = t0 + gl;
        if (j < NREF) {
          float4 P = sb[j];
          int cx = min(max((int)(P.x * GR), 0), GR - 1);
          int cy = min(max((int)(P.y * GR), 0), GR - 1);
          int cz = min(max((int)(P.z * GR), 0), GR - 1);
          bool inbox = (cx >= x0 && cx <= x1 && cy >= y0 && cy <= y1 &&
                        cz >= z0 && cz <= z1);
          if (!inbox) {
            float rr = P.x * P.x + P.y * P.y + P.z * P.z;
            float d2 = qq + rr - 2.0f * (qx * P.x + qy * P.y + qz * P.z);
            u64 ck = ((u64)fbias(d2) << 32) | (u32)__float_as_uint(P.w);
            lane_insert3(ck, v0, v1, v2);
          }
        }
      }
      merge3(v0, v1, v2, o0, o1, o2);
    }
  }
}

// ------------------------------- kNN K=3, grid FLAT (NROW <= 16) -----------
template<int GR, int R, int NREF>
__device__ void knn_grid_flat3_dev(int vbx,
    const float* __restrict__ pos, const float4* __restrict__ sorted,
    const int* __restrict__ cellStart, int csStride, int Mq,
    int* __restrict__ oidx, float* __restrict__ od2) {
  int b = blockIdx.y;
  int wv = threadIdx.x >> 6, lane = threadIdx.x & 63;
  int g = lane >> 4, gl = lane & 15;
  int q = vbx * 16 + wv * 4 + g;
  const float* pb = pos + (size_t)b * NFULL * 3;
  const float4* sb = sorted + (size_t)b * NREF;
  const int* cs = cellStart + b * csStride;
  float qx = pb[q * 3 + 0], qy = pb[q * 3 + 1], qz = pb[q * 3 + 2];
  float qq = qx * qx + qy * qy + qz * qz;
  int ix = min(max((int)(qx * GR), 0), GR - 1);
  int iy = min(max((int)(qy * GR), 0), GR - 1);
  int iz = min(max((int)(qz * GR), 0), GR - 1);
  int x0 = max(ix - R, 0), x1 = min(ix + R, GR - 1);
  int y0 = max(iy - R, 0), y1 = min(iy + R, GR - 1);
  int z0 = max(iz - R, 0), z1 = min(iz + R, GR - 1);

  int ny = y1 - y0 + 1;
  int nrow = (z1 - z0 + 1) * ny;  // <= 9 for R=1
  int s_i = 0, len_i = 0;
  if (gl < nrow) {
    int zz = z0 + gl / ny, yy = y0 + gl % ny;
    int c0 = (zz * GR + yy) * GR + x0;
    s_i = cs[c0];
    len_i = cs[c0 + (x1 - x0) + 1] - s_i;
  }
  int p_i = len_i;
#pragma unroll
  for (int st = 1; st < 16; st <<= 1) {
    int o = __shfl_up(p_i, st, 16);
    if (gl >= st) p_i += o;
  }
  int T = __shfl(p_i, 15, 16);
  p_i -= len_i;              // exclusive prefix
  int d_i = s_i - p_i;       // sorted index = v + d_row
  if (gl >= nrow) p_i = 0x7fffffff;

  u64 v0 = ~0ull, v1 = ~0ull, v2 = ~0ull;

  for (int vb = 0; vb < T; vb += 16) {  // T group-uniform
    int v = vb + gl;
    int r = 0;
#pragma unroll
    for (int st = 8; st >= 1; st >>= 1) {
      int pc = __shfl(p_i, r + st, 16);
      if (v >= pc) r += st;
    }
    int addr = v + __shfl(d_i, r, 16);
    if (v < T) {
      float4 P = sb[addr];
      float rr = P.x * P.x + P.y * P.y + P.z * P.z;
      float d2 = qq + rr - 2.0f * (qx * P.x + qy * P.y + qz * P.z);
      u64 ck = ((u64)fbias(d2) << 32) | (u32)__float_as_uint(P.w);
      lane_insert3(ck, v0, v1, v2);
    }
  }

  u64 o0, o1, o2;
  knn_tail3<GR, R, NREF>(sb, cs, qx, qy, qz, qq,
      ix, iy, iz, x0, x1, y0, y1, z0, z1, gl, v0, v1, v2, o0, o1, o2);

  if (gl < 3) {
    u64 val = (gl == 0) ? o0 : ((gl == 1) ? o1 : o2);
    size_t base = ((size_t)b * Mq + q) * 3;
    oidx[base + gl] = (int)(u32)val;
    od2[base + gl] = fmaxf(funbias((u32)(val >> 32)), 0.0f);
  }
}

// ------------------------------- kNN K=3, grid FLAT32 (NROW <= 32) ---------
template<int GR, int R, int NREF>
__device__ void knn_grid_flat32_3_dev(int vbx,
    const float* __restrict__ pos, const float4* __restrict__ sorted,
    const int* __restrict__ cellStart, int csStride, int Mq,
    int* __restrict__ oidx, float* __restrict__ od2) {
  int b = blockIdx.y;
  int wv = threadIdx.x >> 6, lane = threadIdx.x & 63;
  int g = lane >> 4, gl = lane & 15;
  int q = vbx * 16 + wv * 4 + g;
  const float* pb = pos + (size_t)b * NFULL * 3;
  const float4* sb = sorted + (size_t)b * NREF;
  const int* cs = cellStart + b * csStride;
  float qx = pb[q * 3 + 0], qy = pb[q * 3 + 1], qz = pb[q * 3 + 2];
  float qq = qx * qx + qy * qy + qz * qz;
  int ix = min(max((int)(qx * GR), 0), GR - 1);
  int iy = min(max((int)(qy * GR), 0), GR - 1);
  int iz = min(max((int)(qz * GR), 0), GR - 1);
  int x0 = max(ix - R, 0), x1 = min(ix + R, GR - 1);
  int y0 = max(iy - R, 0), y1 = min(iy + R, GR - 1);
  int z0 = max(iz - R, 0), z1 = min(iz + R, GR - 1);

  int ny = y1 - y0 + 1;
  int nrow = (z1 - z0 + 1) * ny;  // <= 25 for R=2
  int sLo = 0, lenLo = 0, sHi = 0, lenHi = 0;
  if (gl < nrow) {
    int zz = z0 + gl / ny, yy = y0 + gl % ny;
    int c0 = (zz * GR + yy) * GR + x0;
    sLo = cs[c0]; lenLo = cs[c0 + (x1 - x0) + 1] - sLo;
  }
  {
    int i2 = gl + 16;
    if (i2 < nrow) {
      int zz = z0 + i2 / ny, yy = y0 + i2 % ny;
      int c0 = (zz * GR + yy) * GR + x0;
      sHi = cs[c0]; lenHi = cs[c0 + (x1 - x0) + 1] - sHi;
    }
  }
  int pLo = lenLo, pHi = lenHi;
#pragma unroll
  for (int st = 1; st < 16; st <<= 1) {
    int o = __shfl_up(pLo, st, 16);
    if (gl >= st) pLo += o;
    int o2_ = __shfl_up(pHi, st, 16);
    if (gl >= st) pHi += o2_;
  }
  int tot16 = __shfl(pLo, 15, 16);
  pHi += tot16;
  int T = __shfl(pHi, 15, 16);
  pLo -= lenLo; pHi -= lenHi;      // exclusive prefixes
  int dLo = sLo - pLo, dHi = sHi - pHi;
  if (gl >= nrow) pLo = 0x7fffffff;
  if (gl + 16 >= nrow) pHi = 0x7fffffff;

  u64 v0 = ~0ull, v1 = ~0ull, v2 = ~0ull;

  for (int vb = 0; vb < T; vb += 16) {  // T group-uniform
    int v = vb + gl;
    int r = 0;
#pragma unroll
    for (int st = 16; st >= 1; st >>= 1) {
      int j = r + st;                      // j <= 31
      int pcL = __shfl(pLo, j & 15, 16);
      int pcH = __shfl(pHi, j & 15, 16);
      int pc = (j < 16) ? pcL : pcH;
      if (v >= pc) r = j;
    }
    int dL = __shfl(dLo, r & 15, 16);
    int dH = __shfl(dHi, r & 15, 16);
    int addr = v + ((r < 16) ? dL : dH);
    if (v < T) {
      float4 P = sb[addr];
      float rr = P.x * P.x + P.y * P.y + P.z * P.z;
      float d2 = qq + rr - 2.0f * (qx * P.x + qy * P.y + qz * P.z);
      u64 ck = ((u64)fbias(d2) << 32) | (u32)__float_as_uint(P.w);
      lane_insert3(ck, v0, v1, v2);
    }
  }

  u64 o0, o1, o2;
  knn_tail3<GR, R, NREF>(sb, cs, qx, qy, qz, qq,
      ix, iy, iz, x0, x1, y0, y1, z0, z1, gl, v0, v1, v2, o0, o1, o2);

  if (gl < 3) {
    u64 val = (gl == 0) ? o0 : ((gl == 1) ? o1 : o2);
    size_t base = ((size_t)b * Mq + q) * 3;
    oidx[base + gl] = (int)(u32)val;
    od2[base + gl] = fmaxf(funbias((u32)(val >> 32)), 0.0f);
  }
}

// ----------------------------------------------- kNN K=3 (brute, per-lane) -
__device__ void knn_brute3_dev(int vbx,
    const float* __restrict__ pos, int Nref, int Mq,
    int* __restrict__ oidx, float* __restrict__ od2) {
  int b = blockIdx.y;
  int wv = threadIdx.x >> 6, lane = threadIdx.x & 63;
  int g = lane >> 4, gl = lane & 15;
  int q = vbx * 16 + wv * 4 + g;
  const float* pb = pos + (size_t)b * NFULL * 3;
  float qx = pb[q * 3 + 0], qy = pb[q * 3 + 1], qz = pb[q * 3 + 2];
  float qq = qx * qx + qy * qy + qz * qz;

  u64 v0 = ~0ull, v1 = ~0ull, v2 = ~0ull;
  for (int j = gl; j < Nref; j += 16) {
    float rx = pb[j * 3 + 0];
    float ry = pb[j * 3 + 1];
    float rz = pb[j * 3 + 2];
    float rr = rx * rx + ry * ry + rz * rz;
    float d2 = qq + rr - 2.0f * (qx * rx + qy * ry + qz * rz);
    u64 ck = ((u64)fbias(d2) << 32) | (u32)j;
    lane_insert3(ck, v0, v1, v2);
  }
  u64 o0, o1, o2;
  merge3(v0, v1, v2, o0, o1, o2);

  if (gl < 3) {
    u64 val = (gl == 0) ? o0 : ((gl == 1) ? o1 : o2);
    size_t base = ((size_t)b * Mq + q) * 3;
    oidx[base + gl] = (int)(u32)val;
    od2[base + gl] = fmaxf(funbias((u32)(val >> 32)), 0.0f);
  }
}

// --------------------------------------- kNN grid, FLAT32, K=16 (ballot) ---
template<int SL, int KOUT, int GR, int R, int NREF>
__device__ void knn_grid_flat32_dev(int vbx,
    const float* __restrict__ pos, const float4* __restrict__ sorted,
    const int* __restrict__ cellStart, int csStride, int Mq,
    int* __restrict__ oidx, float* __restrict__ od2) {
  int b = blockIdx.y;
  int wv = threadIdx.x >> 6, lane = threadIdx.x & 63;
  int g = lane >> 4, gl = lane & 15;
  int q = vbx * 16 + wv * 4 + g;
  const float* pb = pos + (size_t)b * NFULL * 3;
  const float4* sb = sorted + (size_t)b * NREF;
  const int* cs = cellStart + b * csStride;
  float qx = pb[q * 3 + 0], qy = pb[q * 3 + 1], qz = pb[q * 3 + 2];
  float qq = qx * qx + qy * qy + qz * qz;
  int ix = min(max((int)(qx * GR), 0), GR - 1);
  int iy = min(max((int)(qy * GR), 0), GR - 1);
  int iz = min(max((int)(qz * GR), 0), GR - 1);
  int x0 = max(ix - R, 0), x1 = min(ix + R, GR - 1);
  int y0 = max(iy - R, 0), y1 = min(iy + R, GR - 1);
  int z0 = max(iz - R, 0), z1 = min(iz + R, GR - 1);

  int ny = y1 - y0 + 1;
  int nrow = (z1 - z0 + 1) * ny;  // <= 25 for R=2
  int sLo = 0, lenLo = 0, sHi = 0, lenHi = 0;
  if (gl < nrow) {
    int zz = z0 + gl / ny, yy = y0 + gl % ny;
    int c0 = (zz * GR + yy) * GR + x0;
    sLo = cs[c0]; lenLo = cs[c0 + (x1 - x0) + 1] - sLo;
  }
  {
    int i2 = gl + 16;
    if (i2 < nrow) {
      int zz = z0 + i2 / ny, yy = y0 + i2 % ny;
      int c0 = (zz * GR + yy) * GR + x0;
      sHi = cs[c0]; lenHi = cs[c0 + (x1 - x0) + 1] - sHi;
    }
  }
  int pLo = lenLo, pHi = lenHi;
#pragma unroll
  for (int st = 1; st < 16; st <<= 1) {
    int o = __shfl_up(pLo, st, 16);
    if (gl >= st) pLo += o;
    int o2 = __shfl_up(pHi, st, 16);
    if (gl >= st) pHi += o2;
  }
  int tot16 = __shfl(pLo, 15, 16);
  pHi += tot16;
  int T = __shfl(pHi, 15, 16);
  pLo -= lenLo; pHi -= lenHi;      // exclusive prefixes
  int dLo = sLo - pLo, dHi = sHi - pHi;
  if (gl >= nrow) pLo = 0x7fffffff;
  if (gl + 16 >= nrow) pHi = 0x7fffffff;

  int slot = gl & (SL - 1);
  u64 val, tau;

  // ---- round 1: bulk-build via bitonic sort (replaces 16 serial inserts)
  {
    int v = gl;
    int r = 0;
#pragma unroll
    for (int st = 16; st >= 1; st >>= 1) {
      int j = r + st;                      // j <= 31
      int pcL = __shfl(pLo, j & 15, 16);
      int pcH = __shfl(pHi, j & 15, 16);
      int pc = (j < 16) ? pcL : pcH;
      if (v >= pc) r = j;
    }
    int dL = __shfl(dLo, r & 15, 16);
    int dH = __shfl(dHi, r & 15, 16);
    int addr = v + ((r < 16) ? dL : dH);
    u64 ck = ~0ull;
    if (v < T) {
      float4 P = sb[addr];
      float rr = P.x * P.x + P.y * P.y + P.z * P.z;
      float d2 = qq + rr - 2.0f * (qx * P.x + qy * P.y + qz * P.z);
      ck = ((u64)fbias(d2) << 32) | (u32)__float_as_uint(P.w);
    }
    first_round_sort<SL>(ck, gl, val, tau);
  }

  for (int v0 = 16; v0 < T; v0 += 16) {  // T group-uniform
    int v = v0 + gl;
    int r = 0;
#pragma unroll
    for (int st = 16; st >= 1; st >>= 1) {
      int j = r + st;                      // j <= 31
      int pcL = __shfl(pLo, j & 15, 16);
      int pcH = __shfl(pHi, j & 15, 16);
      int pc = (j < 16) ? pcL : pcH;
      if (v >= pc) r = j;
    }
    int dL = __shfl(dLo, r & 15, 16);
    int dH = __shfl(dHi, r & 15, 16);
    int addr = v + ((r < 16) ? dL : dH);
    u64 ck = ~0ull;
    if (v < T) {
      float4 P = sb[addr];
      float rr = P.x * P.x + P.y * P.y + P.z * P.z;
      float d2 = qq + rr - 2.0f * (qx * P.x + qy * P.y + qz * P.z);
      ck = ((u64)fbias(d2) << 32) | (u32)__float_as_uint(P.w);
    }
    u64 full = __ballot(ck < tau);
    u32 m16 = (u32)((full >> (g * 16)) & 0xFFFFull);
    group_insert<SL>(m16, ck, slot, val, tau);
  }

  knn_tail<SL, KOUT, GR, R, NREF>(sb, cs, qx, qy, qz, qq,
      ix, iy, iz, x0, x1, y0, y1, z0, z1, g, gl, slot, val, tau);

  if (gl < KOUT) {
    size_t base = ((size_t)b * Mq + q) * KOUT;
    oidx[base + gl] = (int)(u32)val;
    if (od2) od2[base + gl] = fmaxf(funbias((u32)(val >> 32)), 0.0f);
  }
}

// -------------------------------------------------- kNN K=16 (brute) -------
template<int SL, int KOUT>
__device__ void knn_brute_dev(int vbx,
    const float* __restrict__ pos, int Nref, int Mq,
    int* __restrict__ oidx, float* __restrict__ od2) {
  int b = blockIdx.y;
  int wv = threadIdx.x >> 6, lane = threadIdx.x & 63;
  int g = lane >> 4, gl = lane & 15;
  int q = vbx * 16 + wv * 4 + g;
  const float* pb = pos + (size_t)b * NFULL * 3;
  float qx = pb[q * 3 + 0], qy = pb[q * 3 + 1], qz = pb[q * 3 + 2];
  float qq = qx * qx + qy * qy + qz * qz;

  int slot = gl & (SL - 1);
  u64 val, tau;

  // ---- round 1 (Nref >= 16 always): bitonic bulk build
  {
    int j = gl;
    float rx = pb[j * 3 + 0];
    float ry = pb[j * 3 + 1];
    float rz = pb[j * 3 + 2];
    float rr = rx * rx + ry * ry + rz * rz;
    float d2 = qq + rr - 2.0f * (qx * rx + qy * ry + qz * rz);
    u64 ck = ((u64)fbias(d2) << 32) | (u32)j;
    first_round_sort<SL>(ck, gl, val, tau);
  }

  for (int t0 = 16; t0 < Nref; t0 += 16) {
    int j = t0 + gl;
    float rx = pb[j * 3 + 0];
    float ry = pb[j * 3 + 1];
    float rz = pb[j * 3 + 2];
    float rr = rx * rx + ry * ry + rz * rz;
    float d2 = qq + rr - 2.0f * (qx * rx + qy * ry + qz * rz);
    u64 ck = ((u64)fbias(d2) << 32) | (u32)j;
    u64 full = __ballot(ck < tau);
    u32 m16 = (u32)((full >> (g * 16)) & 0xFFFFull);
    group_insert<SL>(m16, ck, slot, val, tau);
  }

  if (gl < KOUT) {
    size_t base = ((size_t)b * Mq + q) * KOUT;
    oidx[base + gl] = (int)(u32)val;
    if (od2) od2[base + gl] = fmaxf(funbias((u32)(val >> 32)), 0.0f);
  }
}

// ----------------------------- fused: ALL SIX kNN queries in one dispatch --
// Ranges ordered heaviest-per-block first to minimize the scheduling tail.
__global__ __launch_bounds__(256) void knn_all_kernel(
    const float* __restrict__ pos,
    const float4* __restrict__ sortedA, const int* __restrict__ csA,
    const float4* __restrict__ sortedB, const int* __restrict__ csB,
    const float4* __restrict__ sortedC, const int* __restrict__ csC,
    int* __restrict__ idx0, int* __restrict__ idx1, int* __restrict__ idx2,
    int* __restrict__ idxu0, float* __restrict__ d2u0,
    int* __restrict__ idxu1, float* __restrict__ d2u1,
    int* __restrict__ idxu2, float* __restrict__ d2u2) {
  int bx = blockIdx.x;
  if (bx < 8)          // idx2: 128 q over 512 pts (brute), K=16 — heaviest
    knn_brute_dev<16, 16>(bx, pos, 512, 128, idx2, nullptr);
  else if (bx < 40)    // idx1: 512 q over 2048 pts, K=16 (flat32, ~500 pts)
    knn_grid_flat32_dev<16, 16, 8, 2, 2048>(bx - 8, pos, sortedB, csB, 513, 512, idx1, nullptr);
  else if (bx < 168)   // idx0: 2048 q over 8192 pts, K=16 (flat32, ~250 pts)
    knn_grid_flat32_dev<16, 16, 16, 2, 8192>(bx - 40, pos, sortedA, csA, 4097, 2048, idx0, nullptr);
  else if (bx < 296)   // idxu1: 2048 q over 512 pts, K=3 (gridC, per-lane)
    knn_grid_flat32_3_dev<8, 2, 512>(bx - 168, pos, sortedC, csC, 513, 2048, idxu1, d2u1);
  else if (bx < 808)   // idxu2: 8192 q over 2048 pts, K=3 (flat, per-lane)
    knn_grid_flat3_dev<8, 1, 2048>(bx - 296, pos, sortedB, csB, 513, 8192, idxu2, d2u2);
  else                 // idxu0: 512 q over 128 pts (brute, per-lane), K=3
    knn_brute3_dev(bx - 808, pos, 128, 512, idxu0, d2u0);
}

// ----------------------------------- fused weight packing + pos copy -------
__device__ __forceinline__ void pack_tile_rt(const float* __restrict__ W,
                                             short* __restrict__ outp,
                                             int KDIM, int N, int tile, int lane) {
  int NT = N >> 4;
  int kt = tile / NT, nt = tile - kt * NT;
  int n = nt * 16 + (lane & 15);
  int k0 = kt * 32 + (lane >> 4) * 8;
  bf8_t v;
#pragma unroll
  for (int j = 0; j < 8; ++j) {
    int k = k0 + j;
    v[j] = (k < KDIM) ? f2bf(W[(size_t)k * N + n]) : (short)0;
  }
  *(bf8_t*)(outp + ((size_t)tile * 64 + lane) * 8) = v;
}

__global__ __launch_bounds__(64) void pack_copy_all_kernel(
    const float* d0W1, short* d0W1p, const float* d0W2, short* d0W2p,
    const float* d1W1, short* d1W1p, const float* d1W2, short* d1W2p,
    const float* d2W1, short* d2W1p, const float* d2W2, short* d2W2p,
    const float* u2W, short* u2Wp, const float* fW1, short* fW1p,
    const float* fW2, short* fW2p,
    const float* u0W, short* u0Wp, const float* u1W, short* u1Wp,
    const float* pos, float* posOut) {
  int blk = blockIdx.x, lane = threadIdx.x;
  if      (blk < 8)    pack_tile_rt(d0W1, d0W1p, 6, 128, blk, lane);
  else if (blk < 40)   pack_tile_rt(d0W2, d0W2p, 128, 128, blk - 8, lane);
  else if (blk < 120)  pack_tile_rt(d1W1, d1W1p, 131, 256, blk - 40, lane);
  else if (blk < 248)  pack_tile_rt(d1W2, d1W2p, 256, 256, blk - 120, lane);
  else if (blk < 536)  pack_tile_rt(d2W1, d2W1p, 259, 512, blk - 248, lane);
  else if (blk < 1048) pack_tile_rt(d2W2, d2W2p, 512, 512, blk - 536, lane);
  else if (blk < 1088) pack_tile_rt(u2W, u2Wp, 134, 128, blk - 1048, lane);
  else if (blk < 1120) pack_tile_rt(fW1, fW1p, 128, 128, blk - 1088, lane);
  else if (blk < 1152) pack_tile_rt(fW2, fW2p, 128, 128, blk - 1120, lane);
  else if (blk < 1536) pack_tile_rt(u0W, u0Wp, 768, 256, blk - 1152, lane);
  else if (blk < 1632) pack_tile_rt(u1W, u1Wp, 384, 128, blk - 1536, lane);
  else {
    int base = (blk - 1632) * 256;  // 384 blocks x 256 = 98304 = BATCH*NFULL*3
#pragma unroll
    for (int j = 0; j < 4; ++j) {
      int i = base + lane + j * 64;
      posOut[i] = pos[i];
    }
  }
}

// ----------------------------------------------------- down MLP (MFMA) -----
// QB queries per block; weight tiles loaded ONCE per K-step and reused across
// all QB query A-fragments. LDS rows padded +8 shorts (bank-conflict fix).
template<int FEAT, int CIN, int CHID, int FPAD, int QB, int WAVES>
__global__ __launch_bounds__(64 * WAVES) void down_mfma_kernel(
    const float* __restrict__ pos, const float* __restrict__ xin,
    const int* __restrict__ idx,
    const short* __restrict__ W1p, const float* __restrict__ b1,
    const short* __restrict__ W2p, const float* __restrict__ b2,
    float* __restrict__ out, int n, int nprev) {
  const int KT1 = FPAD / 32, NT1 = CHID / 16;
  const int KT2 = CHID / 32, NT2 = CHID / 16;
  __shared__ short sFeat[QB][16][FPAD + 8];
  __shared__ short sH1[QB][16][CHID + 8];
  __shared__ int sIdx[QB][16];
  __shared__ float sCtr[QB][3];
  int b = blockIdx.y, q0 = blockIdx.x * QB;
  int t = threadIdx.x;
  int lane = t & 63, wv = t >> 6;
  const float* pb = pos + (size_t)b * NFULL * 3;
  const float* xb = xin + (size_t)b * nprev * CIN;
  if (t < QB * 16)
    sIdx[t >> 4][t & 15] = idx[((size_t)b * n + q0 + (t >> 4)) * 16 + (t & 15)];
  if (t < QB * 3) sCtr[t / 3][t % 3] = pb[(q0 + t / 3) * 3 + (t % 3)];
  __syncthreads();
  for (int e = t; e < QB * 16 * FPAD; e += 64 * WAVES) {
    int k = e / FPAD, c = e - k * FPAD;
    int qq = k >> 4, kk = k & 15;
    float v = 0.f;
    if (c < 3) v = pb[sIdx[qq][kk] * 3 + c] - sCtr[qq][c];
    else if (c < FEAT) v = xb[(size_t)sIdx[qq][kk] * CIN + (c - 3)];
    sFeat[qq][kk][c] = f2bf(v);
  }
  __syncthreads();

  int col = lane & 15, quad = lane >> 4;
  const bf8_t* W1t = (const bf8_t*)W1p;
  for (int nt = 2 * wv; nt < NT1; nt += 2 * WAVES) {
    f4_t acc[QB][2];
    float bb0 = b1[nt * 16 + col], bb1 = b1[nt * 16 + 16 + col];
#pragma unroll
    for (int q = 0; q < QB; ++q) {
      acc[q][0] = {bb0, bb0, bb0, bb0};
      acc[q][1] = {bb1, bb1, bb1, bb1};
    }
#pragma unroll
    for (int kt = 0; kt < KT1; ++kt) {
      bf8_t bf0 = W1t[(kt * NT1 + nt) * 64 + lane];
      bf8_t bf1 = W1t[(kt * NT1 + nt + 1) * 64 + lane];
#pragma unroll
      for (int q = 0; q < QB; ++q) {
        bf8_t a = *(const bf8_t*)&sFeat[q][col][kt * 32 + quad * 8];
        acc[q][0] = __builtin_amdgcn_mfma_f32_16x16x32_bf16(a, bf0, acc[q][0], 0, 0, 0);
        acc[q][1] = __builtin_amdgcn_mfma_f32_16x16x32_bf16(a, bf1, acc[q][1], 0, 0, 0);
      }
    }
#pragma unroll
    for (int q = 0; q < QB; ++q)
#pragma unroll
      for (int r = 0; r < 4; ++r) {
        sH1[q][quad * 4 + r][nt * 16 + col] = f2bf(fmaxf(acc[q][0][r], 0.f));
        sH1[q][quad * 4 + r][nt * 16 + 16 + col] = f2bf(fmaxf(acc[q][1][r], 0.f));
      }
  }
  __syncthreads();

  const bf8_t* W2t = (const bf8_t*)W2p;
  for (int nt = 2 * wv; nt < NT2; nt += 2 * WAVES) {
    f4_t acc[QB][2];
    float bb0 = b2[nt * 16 + col], bb1 = b2[nt * 16 + 16 + col];
#pragma unroll
    for (int q = 0; q < QB; ++q) {
      acc[q][0] = {bb0, bb0, bb0, bb0};
      acc[q][1] = {bb1, bb1, bb1, bb1};
    }
#pragma unroll
    for (int kt = 0; kt < KT2; ++kt) {
      bf8_t bf0 = W2t[(kt * NT2 + nt) * 64 + lane];
      bf8_t bf1 = W2t[(kt * NT2 + nt + 1) * 64 + lane];
#pragma unroll
      for (int q = 0; q < QB; ++q) {
        bf8_t a = *(const bf8_t*)&sH1[q][col][kt * 32 + quad * 8];
        acc[q][0] = __builtin_amdgcn_mfma_f32_16x16x32_bf16(a, bf0, acc[q][0], 0, 0, 0);
        acc[q][1] = __builtin_amdgcn_mfma_f32_16x16x32_bf16(a, bf1, acc[q][1], 0, 0, 0);
      }
    }
#pragma unroll
    for (int q = 0; q < QB; ++q) {
      float m0 = fmaxf(fmaxf(acc[q][0][0], acc[q][0][1]), fmaxf(acc[q][0][2], acc[q][0][3]));
      float m1 = fmaxf(fmaxf(acc[q][1][0], acc[q][1][1]), fmaxf(acc[q][1][2], acc[q][1][3]));
      m0 = fmaxf(m0, __shfl_xor(m0, 16, 64));
      m0 = fmaxf(m0, __shfl_xor(m0, 32, 64));
      m1 = fmaxf(m1, __shfl_xor(m1, 16, 64));
      m1 = fmaxf(m1, __shfl_xor(m1, 32, 64));
      if (lane < 16) {
        float* ob = out + ((size_t)b * n + q0 + q) * CHID;
        ob[nt * 16 + lane] = m0;
        ob[nt * 16 + 16 + lane] = m1;
      }
    }
  }
}

// -------------------------------------------- up MLP (bf16 MFMA version) ---
template<int CIN, int CPRV, int COUT, int WPB>
__global__ __launch_bounds__(64 * WPB) void up_mfma_kernel(
    const float* __restrict__ xc, int ncoarse,
    const int* __restrict__ idx3, const float* __restrict__ d23,
    const float* __restrict__ prv, const short* __restrict__ Wp,
    const float* __restrict__ bvec, float* __restrict__ out, int m) {
  const int CTOT = CIN + CPRV;
  const int KT = CTOT / 32, NT = COUT / 16;
  __shared__ short sA[16][CTOT + 8];
  __shared__ float sWt[16][3];
  __shared__ int   sIt[16][3];
  int b = blockIdx.y, q0 = blockIdx.x * 16, t = threadIdx.x;
  int lane = t & 63, wv = t >> 6;
  if (t < 16) {
    size_t base = ((size_t)b * m + q0 + t) * 3;
    float d0 = d23[base + 0], d1 = d23[base + 1], d2v = d23[base + 2];
    float w0 = 1.f / (d0 + 1e-8f), w1 = 1.f / (d1 + 1e-8f), w2 = 1.f / (d2v + 1e-8f);
    float s = w0 + w1 + w2;
    sWt[t][0] = w0 / s; sWt[t][1] = w1 / s; sWt[t][2] = w2 / s;
    sIt[t][0] = idx3[base + 0]; sIt[t][1] = idx3[base + 1]; sIt[t][2] = idx3[base + 2];
  }
  __syncthreads();
  const float* xb = xc + (size_t)b * ncoarse * CIN;
  const float* pvb = prv + ((size_t)b * m + q0) * CPRV;
  for (int e = t; e < 16 * CIN; e += 64 * WPB) {
    int p = e / CIN, c = e % CIN;
    float v = sWt[p][0] * xb[(size_t)sIt[p][0] * CIN + c]
            + sWt[p][1] * xb[(size_t)sIt[p][1] * CIN + c]
            + sWt[p][2] * xb[(size_t)sIt[p][2] * CIN + c];
    sA[p][c] = f2bf(v);
  }
  for (int e = t; e < 16 * CPRV; e += 64 * WPB) {
    int p = e / CPRV, c = e % CPRV;
    sA[p][CIN + c] = f2bf(pvb[(size_t)p * CPRV + c]);
  }
  __syncthreads();
  int col = lane & 15, quad = lane >> 4;
  const bf8_t* Wt = (const bf8_t*)Wp;
  float* ob = out + ((size_t)b * m + q0) * COUT;
  for (int nt = 2 * wv; nt < NT; nt += 2 * WPB) {
    float bb0 = bvec[nt * 16 + col], bb1 = bvec[nt * 16 + 16 + col];
    f4_t acc0 = {bb0, bb0, bb0, bb0}, acc1 = {bb1, bb1, bb1, bb1};
#pragma unroll
    for (int kt = 0; kt < KT; ++kt) {
      bf8_t a = *(const bf8_t*)&sA[col][kt * 32 + quad * 8];
      bf8_t bf0 = Wt[(kt * NT + nt) * 64 + lane];
      bf8_t bf1 = Wt[(kt * NT + nt + 1) * 64 + lane];
      acc0 = __builtin_amdgcn_mfma_f32_16x16x32_bf16(a, bf0, acc0, 0, 0, 0);
      acc1 = __builtin_amdgcn_mfma_f32_16x16x32_bf16(a, bf1, acc1, 0, 0, 0);
    }
#pragma unroll
    for (int r = 0; r < 4; ++r) {
      ob[(size_t)(quad * 4 + r) * COUT + nt * 16 + col] = fmaxf(acc0[r], 0.f);
      ob[(size_t)(quad * 4 + r) * COUT + nt * 16 + 16 + col] = fmaxf(acc1[r], 0.f);
    }
  }
}

// ------------------------------------- fused up2 + final MLP (bf16 MFMA) ---
__global__ __launch_bounds__(128) void up2f_mfma_kernel(
    const float* __restrict__ xc,
    const int* __restrict__ idx3, const float* __restrict__ d23,
    const float* __restrict__ x0, const float* __restrict__ pos0,
    const short* __restrict__ u2Wp, const float* __restrict__ u2b,
    const short* __restrict__ fW1p, const float* __restrict__ fb1,
    const short* __restrict__ fW2p, const float* __restrict__ fb2,
    float* __restrict__ out) {
  __shared__ short sA[16][168];
  __shared__ short sB[16][136];
  __shared__ float sWt[16][3];
  __shared__ int   sIt[16][3];
  int b = blockIdx.y, q0 = blockIdx.x * 16, t = threadIdx.x;
  int lane = t & 63, wv = t >> 6;
  if (t < 16) {
    size_t base = ((size_t)b * NFULL + q0 + t) * 3;
    float d0 = d23[base + 0], d1 = d23[base + 1], d2v = d23[base + 2];
    float w0 = 1.f / (d0 + 1e-8f), w1 = 1.f / (d1 + 1e-8f), w2 = 1.f / (d2v + 1e-8f);
    float s = w0 + w1 + w2;
    sWt[t][0] = w0 / s; sWt[t][1] = w1 / s; sWt[t][2] = w2 / s;
    sIt[t][0] = idx3[base + 0]; sIt[t][1] = idx3[base + 1]; sIt[t][2] = idx3[base + 2];
  }
  __syncthreads();
  const float* xb = xc + (size_t)b * 2048 * 128;
#pragma unroll
  for (int p = 0; p < 16; ++p) {
    float v = sWt[p][0] * xb[(size_t)sIt[p][0] * 128 + t]
            + sWt[p][1] * xb[(size_t)sIt[p][1] * 128 + t]
            + sWt[p][2] * xb[(size_t)sIt[p][2] * 128 + t];
    sA[p][t] = f2bf(v);
  }
  for (int e = t; e < 16 * 32; e += 128) {
    int p = e / 32, c = 128 + (e % 32);
    float v = 0.f;
    if (c < 131) v = x0[((size_t)b * NFULL + q0 + p) * 3 + (c - 128)];
    else if (c < 134) v = pos0[((size_t)b * NFULL + q0 + p) * 3 + (c - 131)];
    sA[p][c] = f2bf(v);
  }
  __syncthreads();
  int col = lane & 15, quad = lane >> 4;

  bf8_t a1[5];
#pragma unroll
  for (int kt = 0; kt < 5; ++kt)
    a1[kt] = *(const bf8_t*)&sA[col][kt * 32 + quad * 8];
  const bf8_t* W1t = (const bf8_t*)u2Wp;
  for (int nt = 2 * wv; nt < 8; nt += 4) {
    float bb0 = u2b[nt * 16 + col], bb1 = u2b[nt * 16 + 16 + col];
    f4_t acc0 = {bb0, bb0, bb0, bb0}, acc1 = {bb1, bb1, bb1, bb1};
#pragma unroll
    for (int kt = 0; kt < 5; ++kt) {
      bf8_t bf0 = W1t[(kt * 8 + nt) * 64 + lane];
      bf8_t bf1 = W1t[(kt * 8 + nt + 1) * 64 + lane];
      acc0 = __builtin_amdgcn_mfma_f32_16x16x32_bf16(a1[kt], bf0, acc0, 0, 0, 0);
      acc1 = __builtin_amdgcn_mfma_f32_16x16x32_bf16(a1[kt], bf1, acc1, 0, 0, 0);
    }
#pragma unroll
    for (int r = 0; r < 4; ++r) {
      sB[quad * 4 + r][nt * 16 + col] = f2bf(fmaxf(acc0[r], 0.f));
      sB[quad * 4 + r][nt * 16 + 16 + col] = f2bf(fmaxf(acc1[r], 0.f));
    }
  }
  __syncthreads();

  bf8_t a2[4];
#pragma unroll
  for (int kt = 0; kt < 4; ++kt)
    a2[kt] = *(const bf8_t*)&sB[col][kt * 32 + quad * 8];
  const bf8_t* W2t = (const bf8_t*)fW1p;
  for (int nt = 2 * wv; nt < 8; nt += 4) {
    float bb0 = fb1[nt * 16 + col], bb1 = fb1[nt * 16 + 16 + col];
    f4_t acc0 = {bb0, bb0, bb0, bb0}, acc1 = {bb1, bb1, bb1, bb1};
#pragma unroll
    for (int kt = 0; kt < 4; ++kt) {
      bf8_t bf0 = W2t[(kt * 8 + nt) * 64 + lane];
      bf8_t bf1 = W2t[(kt * 8 + nt + 1) * 64 + lane];
      acc0 = __builtin_amdgcn_mfma_f32_16x16x32_bf16(a2[kt], bf0, acc0, 0, 0, 0);
      acc1 = __builtin_amdgcn_mfma_f32_16x16x32_bf16(a2[kt], bf1, acc1, 0, 0, 0);
    }
#pragma unroll
    for (int r = 0; r < 4; ++r) {
      sA[quad * 4 + r][nt * 16 + col] = f2bf(fmaxf(acc0[r], 0.f));
      sA[quad * 4 + r][nt * 16 + 16 + col] = f2bf(fmaxf(acc1[r], 0.f));
    }
  }
  __syncthreads();

  bf8_t a3[4];
#pragma unroll
  for (int kt = 0; kt < 4; ++kt)
    a3[kt] = *(const bf8_t*)&sA[col][kt * 32 + quad * 8];
  const bf8_t* W3t = (const bf8_t*)fW2p;
  float* ob = out + ((size_t)b * NFULL + q0) * 128;
  for (int nt = 2 * wv; nt < 8; nt += 4) {
    float bb0 = fb2[nt * 16 + col], bb1 = fb2[nt * 16 + 16 + col];
    f4_t acc0 = {bb0, bb0, bb0, bb0}, acc1 = {bb1, bb1, bb1, bb1};
#pragma unroll
    for (int kt = 0; kt < 4; ++kt) {
      bf8_t bf0 = W3t[(kt * 8 + nt) * 64 + lane];
      bf8_t bf1 = W3t[(kt * 8 + nt + 1) * 64 + lane];
      acc0 = __builtin_amdgcn_mfma_f32_16x16x32_bf16(a3[kt], bf0, acc0, 0, 0, 0);
      acc1 = __builtin_amdgcn_mfma_f32_16x16x32_bf16(a3[kt], bf1, acc1, 0, 0, 0);
    }
#pragma unroll
    for (int r = 0; r < 4; ++r) {
      ob[(size_t)(quad * 4 + r) * 128 + nt * 16 + col] = acc0[r];
      ob[(size_t)(quad * 4 + r) * 128 + nt * 16 + 16 + col] = acc1[r];
    }
  }
}

// ------------------------------------------------------------------ launch -
extern "C" void kernel_launch(void* const* d_in, const int* in_sizes, int n_in,
                              void* d_out, int out_size, void* d_ws, size_t ws_size,
                              hipStream_t stream) {
  const float* x    = (const float*)d_in[0];
  const float* pos  = (const float*)d_in[1];
  const float* d0W1 = (const float*)d_in[2];
  const float* d0b1 = (const float*)d_in[3];
  const float* d0W2 = (const float*)d_in[4];
  const float* d0b2 = (const float*)d_in[5];
  const float* d1W1 = (const float*)d_in[6];
  const float* d1b1 = (const float*)d_in[7];
  const float* d1W2 = (const float*)d_in[8];
  const float* d1b2 = (const float*)d_in[9];
  const float* d2W1 = (const float*)d_in[10];
  const float* d2b1 = (const float*)d_in[11];
  const float* d2W2 = (const float*)d_in[12];
  const float* d2b2 = (const float*)d_in[13];
  const float* u0W  = (const float*)d_in[14];
  const float* u0b  = (const float*)d_in[15];
  const float* u1W  = (const float*)d_in[16];
  const float* u1b  = (const float*)d_in[17];
  const float* u2W  = (const float*)d_in[18];
  const float* u2b  = (const float*)d_in[19];
  const float* fW1  = (const float*)d_in[20];
  const float* fb1  = (const float*)d_in[21];
  const float* fW2  = (const float*)d_in[22];
  const float* fb2  = (const float*)d_in[23];

  char* ws = (char*)d_ws;
  float* x1    = (float*)(ws + 0);
  float* x2    = (float*)(ws + 4194304);
  float* x3    = (float*)(ws + 6291456);
  float* up0o  = (float*)(ws + 7340032);
  float* up1o  = (float*)(ws + 9437184);
  int*   idx0  = (int*)  (ws + 13631488);
  int*   idx1  = (int*)  (ws + 14155776);
  int*   idx2  = (int*)  (ws + 14286848);
  float4* sortedC = (float4*)(ws + 14319616); // 4*512*16 = 32768
  int*    csC     = (int*)   (ws + 14352384); // 4*513*4  = 8208
  int*   idxu0 = (int*)  (ws + 14843904);
  float* d2u0  = (float*)(ws + 14868480);
  int*   idxu1 = (int*)  (ws + 14893056);
  float* d2u1  = (float*)(ws + 14991360);
  int*   idxu2 = (int*)  (ws + 15089664);
  float* d2u2  = (float*)(ws + 15482880);
  short* d1W1p = (short*)(ws + 15876096);
  short* d1W2p = (short*)(ws + 15958016);
  short* d2W1p = (short*)(ws + 16089088);
  short* d2W2p = (short*)(ws + 16384000);
  short* d0W1p = (short*)(ws + 16908288);
  short* d0W2p = (short*)(ws + 16916480);
  float4* sortedA = (float4*)(ws + 16949248);  // 4*8192*16 = 524288
  int*    csA     = (int*)   (ws + 17473536);  // 4*4097*4  = 65552
  float4* sortedB = (float4*)(ws + 17539136);  // 4*2048*16 = 131072
  int*    csB     = (int*)   (ws + 17670208);  // 4*513*4   = 8208
  short* u2Wp  = (short*)(ws + 17697920);
  short* fW1p  = (short*)(ws + 17738880);
  short* fW2p  = (short*)(ws + 17771648);

  float* out = (float*)d_out;
  // Packed u0W/u1W live in the d_out main region: it is dead until the final
  // up2f_mfma_kernel writes it, and both are fully consumed before that.
  short* u0Wp = (short*)out;                       // 768*256*2 = 393216 B
  short* u1Wp = (short*)(out + 98304);             // 384*128*2 =  98304 B

  // ---- fused packing + pos passthrough; fused grid builds (3 grids) ----
  pack_copy_all_kernel<<<dim3(2016), 64, 0, stream>>>(
      d0W1, d0W1p, d0W2, d0W2p, d1W1, d1W1p, d1W2, d1W2p,
      d2W1, d2W1p, d2W2, d2W2p, u2W, u2Wp, fW1, fW1p, fW2, fW2p,
      u0W, u0Wp, u1W, u1Wp,
      pos, out + (size_t)BATCH * NFULL * 128);
  build_grids_kernel<<<dim3(BATCH, 3), 256, 0, stream>>>(
      pos, sortedA, csA, sortedB, csB, sortedC, csC);

  // ---- ALL kNN queries in one dispatch (deps: pos + grids only) ----
  knn_all_kernel<<<dim3(840, BATCH), 256, 0, stream>>>(
      pos, sortedA, csA, sortedB, csB, sortedC, csC,
      idx0, idx1, idx2,
      idxu0, d2u0, idxu1, d2u1, idxu2, d2u2);

  // ---- down path ----
  down_mfma_kernel<6, 3, 128, 32, 4, 4><<<dim3(512, BATCH), 256, 0, stream>>>(
      pos, x, idx0, d0W1p, d0b1, d0W2p, d0b2, x1, 2048, 8192);
  down_mfma_kernel<131, 128, 256, 160, 4, 8><<<dim3(128, BATCH), 512, 0, stream>>>(
      pos, x1, idx1, d1W1p, d1b1, d1W2p, d1b2, x2, 512, 2048);
  down_mfma_kernel<259, 256, 512, 288, 2, 8><<<dim3(64, BATCH), 512, 0, stream>>>(
      pos, x2, idx2, d2W1p, d2b1, d2W2p, d2b2, x3, 128, 512);

  // ---- up path ----
  up_mfma_kernel<512, 256, 256, 4><<<dim3(32, BATCH), 256, 0, stream>>>(
      x3, 128, idxu0, d2u0, x2, u0Wp, u0b, up0o, 512);
  up_mfma_kernel<256, 128, 128, 2><<<dim3(128, BATCH), 128, 0, stream>>>(
      up0o, 512, idxu1, d2u1, x1, u1Wp, u1b, up1o, 2048);
  up2f_mfma_kernel<<<dim3(512, BATCH), 128, 0, stream>>>(
      up1o, idxu2, d2u2, x, pos, u2Wp, u2b, fW1p, fb1, fW2p, fb2, out);
}

// Round 8
// 290.131 us; speedup vs baseline: 1.7042x; 1.0335x over previous
//
#include <hip/hip_runtime.h>

#define NFULL 8192
#define BATCH 4

typedef unsigned long long u64;
typedef unsigned int u32;
typedef __attribute__((ext_vector_type(8))) short bf8_t;   // 8 bf16 (4 VGPRs)
typedef __attribute__((ext_vector_type(4))) float f4_t;    // MFMA C/D

__device__ __forceinline__ u32 fbias(float f) {
  u32 u = __float_as_uint(f);
  return (u & 0x80000000u) ? ~u : (u | 0x80000000u);
}
__device__ __forceinline__ float funbias(u32 b) {
  u32 u = (b & 0x80000000u) ? (b & 0x7fffffffu) : ~b;
  return __uint_as_float(u);
}
__device__ __forceinline__ short f2bf(float f) {
  u32 u = __float_as_uint(f);
  u32 r = u + 0x7FFFu + ((u >> 16) & 1u);
  return (short)(r >> 16);
}

// ----------------------------------- fused weight packing helpers ---------
__device__ __forceinline__ void pack_tile_rt(const float* __restrict__ W,
                                             short* __restrict__ outp,
                                             int KDIM, int N, int tile, int lane) {
  int NT = N >> 4;
  int kt = tile / NT, nt = tile - kt * NT;
  int n = nt * 16 + (lane & 15);
  int k0 = kt * 32 + (lane >> 4) * 8;
  bf8_t v;
#pragma unroll
  for (int j = 0; j < 8; ++j) {
    int k = k0 + j;
    v[j] = (k < KDIM) ? f2bf(W[(size_t)k * N + n]) : (short)0;
  }
  *(bf8_t*)(outp + ((size_t)tile * 64 + lane) * 8) = v;
}

__device__ void pack_dispatch(int blk, int lane,
    const float* d0W1, short* d0W1p, const float* d0W2, short* d0W2p,
    const float* d1W1, short* d1W1p, const float* d1W2, short* d1W2p,
    const float* d2W1, short* d2W1p, const float* d2W2, short* d2W2p,
    const float* u2W, short* u2Wp, const float* fW1, short* fW1p,
    const float* fW2, short* fW2p,
    const float* u0W, short* u0Wp, const float* u1W, short* u1Wp,
    const float* pos, float* posOut) {
  if      (blk < 8)    pack_tile_rt(d0W1, d0W1p, 6, 128, blk, lane);
  else if (blk < 40)   pack_tile_rt(d0W2, d0W2p, 128, 128, blk - 8, lane);
  else if (blk < 120)  pack_tile_rt(d1W1, d1W1p, 131, 256, blk - 40, lane);
  else if (blk < 248)  pack_tile_rt(d1W2, d1W2p, 256, 256, blk - 120, lane);
  else if (blk < 536)  pack_tile_rt(d2W1, d2W1p, 259, 512, blk - 248, lane);
  else if (blk < 1048) pack_tile_rt(d2W2, d2W2p, 512, 512, blk - 536, lane);
  else if (blk < 1088) pack_tile_rt(u2W, u2Wp, 134, 128, blk - 1048, lane);
  else if (blk < 1120) pack_tile_rt(fW1, fW1p, 128, 128, blk - 1088, lane);
  else if (blk < 1152) pack_tile_rt(fW2, fW2p, 128, 128, blk - 1120, lane);
  else if (blk < 1536) pack_tile_rt(u0W, u0Wp, 768, 256, blk - 1152, lane);
  else if (blk < 1632) pack_tile_rt(u1W, u1Wp, 384, 128, blk - 1536, lane);
  else {
    int base = (blk - 1632) * 256;  // 384 x 256 = 98304 = BATCH*NFULL*3
#pragma unroll
    for (int j = 0; j < 4; ++j) {
      int i = base + lane + j * 64;
      posOut[i] = pos[i];
    }
  }
}

// ------------------- fused pre-kernel: 3 grid builds + all weight packing --
// bx < 12: grid build (which = bx>>2, b = bx&3). bx >= 12: 4 pack tiles/blk.
__global__ __launch_bounds__(256) void pre_kernel(
    const float* __restrict__ pos, float4* __restrict__ sortedA,
    int* __restrict__ csA, float4* __restrict__ sortedB, int* __restrict__ csB,
    float4* __restrict__ sortedC, int* __restrict__ csC,
    const float* d0W1, short* d0W1p, const float* d0W2, short* d0W2p,
    const float* d1W1, short* d1W1p, const float* d1W2, short* d1W2p,
    const float* d2W1, short* d2W1p, const float* d2W2, short* d2W2p,
    const float* u2W, short* u2Wp, const float* fW1, short* fW1p,
    const float* fW2, short* fW2p,
    const float* u0W, short* u0Wp, const float* u1W, short* u1Wp,
    float* posOut) {
  __shared__ int cnt[4096];
  __shared__ int partial[256];
  int bx = blockIdx.x, t = threadIdx.x;
  if (bx >= 12) {
    int tt = (bx - 12) * 4 + (t >> 6);
    pack_dispatch(tt, t & 63,
        d0W1, d0W1p, d0W2, d0W2p, d1W1, d1W1p, d1W2, d1W2p,
        d2W1, d2W1p, d2W2, d2W2p, u2W, u2Wp, fW1, fW1p, fW2, fW2p,
        u0W, u0Wp, u1W, u1Wp, pos, posOut);
    return;
  }
  int which = bx >> 2, b = bx & 3;
  int NREF = (which == 0) ? 8192 : (which == 1) ? 2048 : 512;
  int GR = (which == 0) ? 16 : 8;
  int NC = GR * GR * GR;
  float4* sorted = ((which == 0) ? sortedA : (which == 1) ? sortedB : sortedC)
                   + (size_t)b * NREF;
  int* cs = ((which == 0) ? csA + b * 4097 : (which == 1) ? csB + b * 513
                                           : csC + b * 513);
  const float* pb = pos + (size_t)b * NFULL * 3;
  for (int c = t; c < NC; c += 256) cnt[c] = 0;
  __syncthreads();
  for (int p = t; p < NREF; p += 256) {
    float x = pb[p * 3 + 0], y = pb[p * 3 + 1], z = pb[p * 3 + 2];
    int cx = min(max((int)(x * GR), 0), GR - 1);
    int cy = min(max((int)(y * GR), 0), GR - 1);
    int cz = min(max((int)(z * GR), 0), GR - 1);
    atomicAdd(&cnt[(cz * GR + cy) * GR + cx], 1);
  }
  __syncthreads();
  int chunk = (NC + 255) / 256;
  int s = 0;
  for (int i = 0; i < chunk; ++i) {
    int c = t * chunk + i;
    if (c < NC) s += cnt[c];
  }
  partial[t] = s;
  __syncthreads();
  if (t == 0) {
    int run = 0;
    for (int i = 0; i < 256; ++i) { int v = partial[i]; partial[i] = run; run += v; }
  }
  __syncthreads();
  int run = partial[t];
  for (int i = 0; i < chunk; ++i) {
    int c = t * chunk + i;
    if (c < NC) { int v = cnt[c]; cnt[c] = run; run += v; }
  }
  __syncthreads();
  for (int c = t; c < NC; c += 256) cs[c] = cnt[c];
  if (t == 0) cs[NC] = NREF;
  __syncthreads();
  for (int p = t; p < NREF; p += 256) {
    float x = pb[p * 3 + 0], y = pb[p * 3 + 1], z = pb[p * 3 + 2];
    int cx = min(max((int)(x * GR), 0), GR - 1);
    int cy = min(max((int)(y * GR), 0), GR - 1);
    int cz = min(max((int)(z * GR), 0), GR - 1);
    int slot = atomicAdd(&cnt[(cz * GR + cy) * GR + cx], 1);
    sorted[slot] = make_float4(x, y, z, __uint_as_float((u32)p));
  }
}

// ================= K=16 machinery, 32 lanes per query ======================
// The sorted top-16 window lives replicated in BOTH 16-lane halves of the
// 32-lane group; candidates are gathered from all 32 lanes (shfl width 32),
// the insertion shift stays within each 16-half (identical updates in both).
__device__ __forceinline__ void group_insert_g32(u32 m32, u64 ck, int slot16,
                                                 u64& val, u64& tau) {
  if (m32) {
    while (m32) {
      int src = __ffs(m32) - 1;
      m32 &= m32 - 1;
      u64 c = __shfl((unsigned long long)ck, src, 32);
      u64 prev = __shfl_up((unsigned long long)val, 1, 16);
      if (slot16 == 0) prev = 0ull;
      val = (val <= c) ? val : ((prev <= c) ? c : prev);
    }
    tau = __shfl((unsigned long long)val, 15, 16);
  }
}

// Round-1 bulk build: 15-stage bitonic sort of the first 32 candidates
// across the 32-lane group; lower 16 ranks replicated into both halves.
__device__ __forceinline__ void first_round_sort32(u64 ck, int gl,
                                                   u64& val, u64& tau) {
  u64 v = ck;
#pragma unroll
  for (int size = 2; size <= 32; size <<= 1) {
#pragma unroll
    for (int stride = size >> 1; stride > 0; stride >>= 1) {
      u64 other = __shfl_xor((unsigned long long)v, stride, 32);
      bool ddd = ((gl & size) == 0);
      bool takeMin = (((gl & stride) == 0) == ddd);
      u64 mn = (v <= other) ? v : other;
      u64 mx = (v <= other) ? other : v;
      v = takeMin ? mn : mx;
    }
  }
  val = __shfl((unsigned long long)v, gl & 15, 32);
  tau = __shfl((unsigned long long)val, 15, 16);
}

__device__ __forceinline__ void scan_range_g32(const float4* __restrict__ sb,
    int s, int e, float qx, float qy, float qz, float qq,
    int g32, int gl, int slot16, u64& val, u64& tau) {
  for (int t0 = s; t0 < e; t0 += 32) {
    int j = t0 + gl;
    u64 ck = ~0ull;
    if (j < e) {
      float4 P = sb[j];
      float rr = P.x * P.x + P.y * P.y + P.z * P.z;
      float d2 = qq + rr - 2.0f * (qx * P.x + qy * P.y + qz * P.z);
      ck = ((u64)fbias(d2) << 32) | (u32)__float_as_uint(P.w);
    }
    u64 full = __ballot(ck < tau);
    u32 m32 = (u32)(full >> (g32 * 32));
    group_insert_g32(m32, ck, slot16, val, tau);
  }
}

// Exactness: after scanning box B, if the 16th smallest d2 is strictly less
// than the squared distance to the nearest NON-clipped face of B, no outside
// point can enter the top-16. Ring expansion scans box(R+1)\box(R) exactly
// once per point; unique u64 keys keep tie-breaking identical to reference.
template<int GR, int R, int NREF>
__device__ __forceinline__ void knn_tail16_g32(
    const float4* __restrict__ sb, const int* __restrict__ cs,
    float qx, float qy, float qz, float qq,
    int ix, int iy, int iz, int x0, int x1, int y0, int y1, int z0, int z1,
    int g32, int gl, int slot16, u64& val, u64& tau) {
  const float h = 1.0f / GR;
  float m = 1e30f;
  if (x0 > 0)      m = fminf(m, qx - x0 * h);
  if (x1 < GR - 1) m = fminf(m, (x1 + 1) * h - qx);
  if (y0 > 0)      m = fminf(m, qy - y0 * h);
  if (y1 < GR - 1) m = fminf(m, (y1 + 1) * h - qy);
  if (z0 > 0)      m = fminf(m, qz - z0 * h);
  if (z1 < GR - 1) m = fminf(m, (z1 + 1) * h - qz);
  float bound = m * m;
  float kth_d2 = funbias((u32)(tau >> 32));
  if (!(kth_d2 < bound)) {  // group-uniform; rare
    int X0 = max(ix - (R + 1), 0), X1 = min(ix + (R + 1), GR - 1);
    int Y0 = max(iy - (R + 1), 0), Y1 = min(iy + (R + 1), GR - 1);
    int Z0 = max(iz - (R + 1), 0), Z1 = min(iz + (R + 1), GR - 1);
    int NY2 = Y1 - Y0 + 1;
    int nrow2 = (Z1 - Z0 + 1) * NY2;
    for (int rr2 = 0; rr2 < nrow2; ++rr2) {
      int zz = Z0 + rr2 / NY2, yy = Y0 + rr2 % NY2;
      int c0 = (zz * GR + yy) * GR;
      bool mid = (zz >= z0 && zz <= z1 && yy >= y0 && yy <= y1);
      int s1 = cs[c0 + X0];
      int e1 = mid ? cs[c0 + x0] : cs[c0 + X1 + 1];
      scan_range_g32(sb, s1, e1, qx, qy, qz, qq, g32, gl, slot16, val, tau);
      if (mid) {
        int s2 = cs[c0 + x1 + 1];
        int e2 = cs[c0 + X1 + 1];
        scan_range_g32(sb, s2, e2, qx, qy, qz, qq, g32, gl, slot16, val, tau);
      }
    }
    x0 = X0; x1 = X1; y0 = Y0; y1 = Y1; z0 = Z0; z1 = Z1;
    m = 1e30f;
    if (x0 > 0)      m = fminf(m, qx - x0 * h);
    if (x1 < GR - 1) m = fminf(m, (x1 + 1) * h - qx);
    if (y0 > 0)      m = fminf(m, qy - y0 * h);
    if (y1 < GR - 1) m = fminf(m, (y1 + 1) * h - qy);
    if (z0 > 0)      m = fminf(m, qz - z0 * h);
    if (z1 < GR - 1) m = fminf(m, (z1 + 1) * h - qz);
    bound = m * m;
    kth_d2 = funbias((u32)(tau >> 32));
    if (!(kth_d2 < bound)) {  // essentially unreachable
      for (int t0 = 0; t0 < NREF; t0 += 32) {
        int j = t0 + gl;
        u64 ck = ~0ull;
        if (j < NREF) {
          float4 P = sb[j];
          int cx = min(max((int)(P.x * GR), 0), GR - 1);
          int cy = min(max((int)(P.y * GR), 0), GR - 1);
          int cz = min(max((int)(P.z * GR), 0), GR - 1);
          bool inbox = (cx >= x0 && cx <= x1 && cy >= y0 && cy <= y1 &&
                        cz >= z0 && cz <= z1);
          if (!inbox) {
            float rr = P.x * P.x + P.y * P.y + P.z * P.z;
            float d2 = qq + rr - 2.0f * (qx * P.x + qy * P.y + qz * P.z);
            ck = ((u64)fbias(d2) << 32) | (u32)__float_as_uint(P.w);
          }
        }
        u64 full = __ballot(ck < tau);
        u32 m32 = (u32)(full >> (g32 * 32));
        group_insert_g32(m32, ck, slot16, val, tau);
      }
    }
  }
}

// ---------------- K=16 grid (nrow <= 32 fits directly in 32 lanes) ---------
template<int GR, int R, int NREF>
__device__ void knn_grid16_g32_dev(int vbx,
    const float* __restrict__ pos, const float4* __restrict__ sorted,
    const int* __restrict__ cellStart, int csStride, int Mq,
    int* __restrict__ oidx) {
  int b = blockIdx.y;
  int wv = threadIdx.x >> 6, lane = threadIdx.x & 63;
  int g32 = lane >> 5, gl = lane & 31;
  int q = vbx * 8 + wv * 2 + g32;
  const float* pb = pos + (size_t)b * NFULL * 3;
  const float4* sb = sorted + (size_t)b * NREF;
  const int* cs = cellStart + b * csStride;
  float qx = pb[q * 3 + 0], qy = pb[q * 3 + 1], qz = pb[q * 3 + 2];
  float qq = qx * qx + qy * qy + qz * qz;
  int ix = min(max((int)(qx * GR), 0), GR - 1);
  int iy = min(max((int)(qy * GR), 0), GR - 1);
  int iz = min(max((int)(qz * GR), 0), GR - 1);
  int x0 = max(ix - R, 0), x1 = min(ix + R, GR - 1);
  int y0 = max(iy - R, 0), y1 = min(iy + R, GR - 1);
  int z0 = max(iz - R, 0), z1 = min(iz + R, GR - 1);

  int ny = y1 - y0 + 1;
  int nrow = (z1 - z0 + 1) * ny;  // <= 25 for R=2
  int s_i = 0, len_i = 0;
  if (gl < nrow) {
    int zz = z0 + gl / ny, yy = y0 + gl % ny;
    int c0 = (zz * GR + yy) * GR + x0;
    s_i = cs[c0];
    len_i = cs[c0 + (x1 - x0) + 1] - s_i;
  }
  int p_i = len_i;
#pragma unroll
  for (int st = 1; st < 32; st <<= 1) {
    int o = __shfl_up(p_i, st, 32);
    if (gl >= st) p_i += o;
  }
  int T = __shfl(p_i, 31, 32);
  p_i -= len_i;              // exclusive prefix
  int d_i = s_i - p_i;       // sorted index = v + d_row
  if (gl >= nrow) p_i = 0x7fffffff;

  int slot16 = lane & 15;
  u64 val, tau;

  // ---- round 1: 32-candidate bitonic bulk build
  {
    int v = gl;
    int r = 0;
#pragma unroll
    for (int st = 16; st >= 1; st >>= 1) {
      int pc = __shfl(p_i, r + st, 32);
      if (v >= pc) r += st;
    }
    int addr = v + __shfl(d_i, r, 32);
    u64 ck = ~0ull;
    if (v < T) {
      float4 P = sb[addr];
      float rr = P.x * P.x + P.y * P.y + P.z * P.z;
      float d2 = qq + rr - 2.0f * (qx * P.x + qy * P.y + qz * P.z);
      ck = ((u64)fbias(d2) << 32) | (u32)__float_as_uint(P.w);
    }
    first_round_sort32(ck, gl, val, tau);
  }

  for (int v0 = 32; v0 < T; v0 += 32) {  // T group-uniform
    int v = v0 + gl;
    int r = 0;
#pragma unroll
    for (int st = 16; st >= 1; st >>= 1) {
      int pc = __shfl(p_i, r + st, 32);
      if (v >= pc) r += st;
    }
    int addr = v + __shfl(d_i, r, 32);
    u64 ck = ~0ull;
    if (v < T) {
      float4 P = sb[addr];
      float rr = P.x * P.x + P.y * P.y + P.z * P.z;
      float d2 = qq + rr - 2.0f * (qx * P.x + qy * P.y + qz * P.z);
      ck = ((u64)fbias(d2) << 32) | (u32)__float_as_uint(P.w);
    }
    u64 full = __ballot(ck < tau);
    u32 m32 = (u32)(full >> (g32 * 32));
    group_insert_g32(m32, ck, slot16, val, tau);
  }

  knn_tail16_g32<GR, R, NREF>(sb, cs, qx, qy, qz, qq,
      ix, iy, iz, x0, x1, y0, y1, z0, z1, g32, gl, slot16, val, tau);

  if (gl < 16) {
    size_t base = ((size_t)b * Mq + q) * 16;
    oidx[base + gl] = (int)(u32)val;
  }
}

// ----------------------------------------------- K=16 brute (32-lane) ------
__device__ void knn_brute16_g32_dev(int vbx,
    const float* __restrict__ pos, int Nref, int Mq, int* __restrict__ oidx) {
  int b = blockIdx.y;
  int wv = threadIdx.x >> 6, lane = threadIdx.x & 63;
  int g32 = lane >> 5, gl = lane & 31;
  int q = vbx * 8 + wv * 2 + g32;
  const float* pb = pos + (size_t)b * NFULL * 3;
  float qx = pb[q * 3 + 0], qy = pb[q * 3 + 1], qz = pb[q * 3 + 2];
  float qq = qx * qx + qy * qy + qz * qz;

  int slot16 = lane & 15;
  u64 val, tau;

  {
    int j = gl;
    float rx = pb[j * 3 + 0];
    float ry = pb[j * 3 + 1];
    float rz = pb[j * 3 + 2];
    float rr = rx * rx + ry * ry + rz * rz;
    float d2 = qq + rr - 2.0f * (qx * rx + qy * ry + qz * rz);
    u64 ck = ((u64)fbias(d2) << 32) | (u32)j;
    first_round_sort32(ck, gl, val, tau);
  }

  for (int t0 = 32; t0 < Nref; t0 += 32) {
    int j = t0 + gl;
    float rx = pb[j * 3 + 0];
    float ry = pb[j * 3 + 1];
    float rz = pb[j * 3 + 2];
    float rr = rx * rx + ry * ry + rz * rz;
    float d2 = qq + rr - 2.0f * (qx * rx + qy * ry + qz * rz);
    u64 ck = ((u64)fbias(d2) << 32) | (u32)j;
    u64 full = __ballot(ck < tau);
    u32 m32 = (u32)(full >> (g32 * 32));
    group_insert_g32(m32, ck, slot16, val, tau);
  }

  if (gl < 16) {
    size_t base = ((size_t)b * Mq + q) * 16;
    oidx[base + gl] = (int)(u32)val;
  }
}

// ================= K=3 machinery (16 lanes/query, per-lane top-3) ==========
__device__ __forceinline__ void lane_insert3(u64 ck, u64& v0, u64& v1, u64& v2) {
  u64 a = (v0 <= ck) ? v0 : ck;
  u64 bb = (v0 <= ck) ? ck : v0;
  v0 = a;
  u64 c = (v1 <= bb) ? v1 : bb;
  u64 d = (v1 <= bb) ? bb : v1;
  v1 = c;
  v2 = (v2 <= d) ? v2 : d;
}

__device__ __forceinline__ void merge3(u64 v0, u64 v1, u64 v2,
                                       u64& o0, u64& o1, u64& o2) {
  u64 h = v0;
  int hc = 0;
  u64 outs[3];
#pragma unroll
  for (int k = 0; k < 3; ++k) {
    u64 m = h;
#pragma unroll
    for (int st = 1; st < 16; st <<= 1) {
      u64 o = __shfl_xor((unsigned long long)m, st, 16);
      m = (m <= o) ? m : o;
    }
    outs[k] = m;
    if (h == m) { ++hc; h = (hc == 1) ? v1 : ((hc == 2) ? v2 : ~0ull); }
  }
  o0 = outs[0]; o1 = outs[1]; o2 = outs[2];
}

__device__ __forceinline__ void scan_range3(const float4* __restrict__ sb,
    int s, int e, float qx, float qy, float qz, float qq,
    int gl, u64& v0, u64& v1, u64& v2) {
  for (int t0 = s; t0 < e; t0 += 16) {
    int j = t0 + gl;
    if (j < e) {
      float4 P = sb[j];
      float rr = P.x * P.x + P.y * P.y + P.z * P.z;
      float d2 = qq + rr - 2.0f * (qx * P.x + qy * P.y + qz * P.z);
      u64 ck = ((u64)fbias(d2) << 32) | (u32)__float_as_uint(P.w);
      lane_insert3(ck, v0, v1, v2);
    }
  }
}

template<int GR, int R, int NREF>
__device__ __forceinline__ void knn_tail3(
    const float4* __restrict__ sb, const int* __restrict__ cs,
    float qx, float qy, float qz, float qq,
    int ix, int iy, int iz, int x0, int x1, int y0, int y1, int z0, int z1,
    int gl, u64& v0, u64& v1, u64& v2, u64& o0, u64& o1, u64& o2) {
  const float h = 1.0f / GR;
  float m = 1e30f;
  if (x0 > 0)      m = fminf(m, qx - x0 * h);
  if (x1 < GR - 1) m = fminf(m, (x1 + 1) * h - qx);
  if (y0 > 0)      m = fminf(m, qy - y0 * h);
  if (y1 < GR - 1) m = fminf(m, (y1 + 1) * h - qy);
  if (z0 > 0)      m = fminf(m, qz - z0 * h);
  if (z1 < GR - 1) m = fminf(m, (z1 + 1) * h - qz);
  float bound = m * m;
  merge3(v0, v1, v2, o0, o1, o2);
  float kth_d2 = funbias((u32)(o2 >> 32));
  if (!(kth_d2 < bound)) {  // group-uniform; rare
    int X0 = max(ix - (R + 1), 0), X1 = min(ix + (R + 1), GR - 1);
    int Y0 = max(iy - (R + 1), 0), Y1 = min(iy + (R + 1), GR - 1);
    int Z0 = max(iz - (R + 1), 0), Z1 = min(iz + (R + 1), GR - 1);
    int NY2 = Y1 - Y0 + 1;
    int nrow2 = (Z1 - Z0 + 1) * NY2;
    for (int rr2 = 0; rr2 < nrow2; ++rr2) {
      int zz = Z0 + rr2 / NY2, yy = Y0 + rr2 % NY2;
      int c0 = (zz * GR + yy) * GR;
      bool mid = (zz >= z0 && zz <= z1 && yy >= y0 && yy <= y1);
      int s1 = cs[c0 + X0];
      int e1 = mid ? cs[c0 + x0] : cs[c0 + X1 + 1];
      scan_range3(sb, s1, e1, qx, qy, qz, qq, gl, v0, v1, v2);
      if (mid) {
        int s2 = cs[c0 + x1 + 1];
        int e2 = cs[c0 + X1 + 1];
        scan_range3(sb, s2, e2, qx, qy, qz, qq, gl, v0, v1, v2);
      }
    }
    x0 = X0; x1 = X1; y0 = Y0; y1 = Y1; z0 = Z0; z1 = Z1;
    m = 1e30f;
    if (x0 > 0)      m = fminf(m, qx - x0 * h);
    if (x1 < GR - 1) m = fminf(m, (x1 + 1) * h - qx);
    if (y0 > 0)      m = fminf(m, qy - y0 * h);
    if (y1 < GR - 1) m = fminf(m, (y1 + 1) * h - qy);
    if (z0 > 0)      m = fminf(m, qz - z0 * h);
    if (z1 < GR - 1) m = fminf(m, (z1 + 1) * h - qz);
    bound = m * m;
    merge3(v0, v1, v2, o0, o1, o2);
    kth_d2 = funbias((u32)(o2 >> 32));
    if (!(kth_d2 < bound)) {  // essentially unreachable
      for (int t0 = 0; t0 < NREF; t0 += 16) {
        int j = t0 + gl;
        if (j < NREF) {
          float4 P = sb[j];
          int cx = min(max((int)(P.x * GR), 0), GR - 1);
          int cy = min(max((int)(P.y * GR), 0), GR - 1);
          int cz = min(max((int)(P.z * GR), 0), GR - 1);
          bool inbox = (cx >= x0 && cx <= x1 && cy >= y0 && cy <= y1 &&
                        cz >= z0 && cz <= z1);
          if (!inbox) {
            float rr = P.x * P.x + P.y * P.y + P.z * P.z;
            float d2 = qq + rr - 2.0f * (qx * P.x + qy * P.y + qz * P.z);
            u64 ck = ((u64)fbias(d2) << 32) | (u32)__float_as_uint(P.w);
            lane_insert3(ck, v0, v1, v2);
          }
        }
      }
      merge3(v0, v1, v2, o0, o1, o2);
    }
  }
}

template<int GR, int R, int NREF>
__device__ void knn_grid_flat3_dev(int vbx,
    const float* __restrict__ pos, const float4* __restrict__ sorted,
    const int* __restrict__ cellStart, int csStride, int Mq,
    int* __restrict__ oidx, float* __restrict__ od2) {
  int b = blockIdx.y;
  int wv = threadIdx.x >> 6, lane = threadIdx.x & 63;
  int g = lane >> 4, gl = lane & 15;
  int q = vbx * 16 + wv * 4 + g;
  const float* pb = pos + (size_t)b * NFULL * 3;
  const float4* sb = sorted + (size_t)b * NREF;
  const int* cs = cellStart + b * csStride;
  float qx = pb[q * 3 + 0], qy = pb[q * 3 + 1], qz = pb[q * 3 + 2];
  float qq = qx * qx + qy * qy + qz * qz;
  int ix = min(max((int)(qx * GR), 0), GR - 1);
  int iy = min(max((int)(qy * GR), 0), GR - 1);
  int iz = min(max((int)(qz * GR), 0), GR - 1);
  int x0 = max(ix - R, 0), x1 = min(ix + R, GR - 1);
  int y0 = max(iy - R, 0), y1 = min(iy + R, GR - 1);
  int z0 = max(iz - R, 0), z1 = min(iz + R, GR - 1);

  int ny = y1 - y0 + 1;
  int nrow = (z1 - z0 + 1) * ny;  // <= 9 for R=1
  int s_i = 0, len_i = 0;
  if (gl < nrow) {
    int zz = z0 + gl / ny, yy = y0 + gl % ny;
    int c0 = (zz * GR + yy) * GR + x0;
    s_i = cs[c0];
    len_i = cs[c0 + (x1 - x0) + 1] - s_i;
  }
  int p_i = len_i;
#pragma unroll
  for (int st = 1; st < 16; st <<= 1) {
    int o = __shfl_up(p_i, st, 16);
    if (gl >= st) p_i += o;
  }
  int T = __shfl(p_i, 15, 16);
  p_i -= len_i;              // exclusive prefix
  int d_i = s_i - p_i;       // sorted index = v + d_row
  if (gl >= nrow) p_i = 0x7fffffff;

  u64 v0 = ~0ull, v1 = ~0ull, v2 = ~0ull;

  for (int vb = 0; vb < T; vb += 16) {  // T group-uniform
    int v = vb + gl;
    int r = 0;
#pragma unroll
    for (int st = 8; st >= 1; st >>= 1) {
      int pc = __shfl(p_i, r + st, 16);
      if (v >= pc) r += st;
    }
    int addr = v + __shfl(d_i, r, 16);
    if (v < T) {
      float4 P = sb[addr];
      float rr = P.x * P.x + P.y * P.y + P.z * P.z;
      float d2 = qq + rr - 2.0f * (qx * P.x + qy * P.y + qz * P.z);
      u64 ck = ((u64)fbias(d2) << 32) | (u32)__float_as_uint(P.w);
      lane_insert3(ck, v0, v1, v2);
    }
  }

  u64 o0, o1, o2;
  knn_tail3<GR, R, NREF>(sb, cs, qx, qy, qz, qq,
      ix, iy, iz, x0, x1, y0, y1, z0, z1, gl, v0, v1, v2, o0, o1, o2);

  if (gl < 3) {
    u64 val = (gl == 0) ? o0 : ((gl == 1) ? o1 : o2);
    size_t base = ((size_t)b * Mq + q) * 3;
    oidx[base + gl] = (int)(u32)val;
    od2[base + gl] = fmaxf(funbias((u32)(val >> 32)), 0.0f);
  }
}

template<int GR, int R, int NREF>
__device__ void knn_grid_flat32_3_dev(int vbx,
    const float* __restrict__ pos, const float4* __restrict__ sorted,
    const int* __restrict__ cellStart, int csStride, int Mq,
    int* __restrict__ oidx, float* __restrict__ od2) {
  int b = blockIdx.y;
  int wv = threadIdx.x >> 6, lane = threadIdx.x & 63;
  int g = lane >> 4, gl = lane & 15;
  int q = vbx * 16 + wv * 4 + g;
  const float* pb = pos + (size_t)b * NFULL * 3;
  const float4* sb = sorted + (size_t)b * NREF;
  const int* cs = cellStart + b * csStride;
  float qx = pb[q * 3 + 0], qy = pb[q * 3 + 1], qz = pb[q * 3 + 2];
  float qq = qx * qx + qy * qy + qz * qz;
  int ix = min(max((int)(qx * GR), 0), GR - 1);
  int iy = min(max((int)(qy * GR), 0), GR - 1);
  int iz = min(max((int)(qz * GR), 0), GR - 1);
  int x0 = max(ix - R, 0), x1 = min(ix + R, GR - 1);
  int y0 = max(iy - R, 0), y1 = min(iy + R, GR - 1);
  int z0 = max(iz - R, 0), z1 = min(iz + R, GR - 1);

  int ny = y1 - y0 + 1;
  int nrow = (z1 - z0 + 1) * ny;  // <= 25 for R=2
  int sLo = 0, lenLo = 0, sHi = 0, lenHi = 0;
  if (gl < nrow) {
    int zz = z0 + gl / ny, yy = y0 + gl % ny;
    int c0 = (zz * GR + yy) * GR + x0;
    sLo = cs[c0]; lenLo = cs[c0 + (x1 - x0) + 1] - sLo;
  }
  {
    int i2 = gl + 16;
    if (i2 < nrow) {
      int zz = z0 + i2 / ny, yy = y0 + i2 % ny;
      int c0 = (zz * GR + yy) * GR + x0;
      sHi = cs[c0]; lenHi = cs[c0 + (x1 - x0) + 1] - sHi;
    }
  }
  int pLo = lenLo, pHi = lenHi;
#pragma unroll
  for (int st = 1; st < 16; st <<= 1) {
    int o = __shfl_up(pLo, st, 16);
    if (gl >= st) pLo += o;
    int o2_ = __shfl_up(pHi, st, 16);
    if (gl >= st) pHi += o2_;
  }
  int tot16 = __shfl(pLo, 15, 16);
  pHi += tot16;
  int T = __shfl(pHi, 15, 16);
  pLo -= lenLo; pHi -= lenHi;      // exclusive prefixes
  int dLo = sLo - pLo, dHi = sHi - pHi;
  if (gl >= nrow) pLo = 0x7fffffff;
  if (gl + 16 >= nrow) pHi = 0x7fffffff;

  u64 v0 = ~0ull, v1 = ~0ull, v2 = ~0ull;

  for (int vb = 0; vb < T; vb += 16) {  // T group-uniform
    int v = vb + gl;
    int r = 0;
#pragma unroll
    for (int st = 16; st >= 1; st >>= 1) {
      int j = r + st;                      // j <= 31
      int pcL = __shfl(pLo, j & 15, 16);
      int pcH = __shfl(pHi, j & 15, 16);
      int pc = (j < 16) ? pcL : pcH;
      if (v >= pc) r = j;
    }
    int dL = __shfl(dLo, r & 15, 16);
    int dH = __shfl(dHi, r & 15, 16);
    int addr = v + ((r < 16) ? dL : dH);
    if (v < T) {
      float4 P = sb[addr];
      float rr = P.x * P.x + P.y * P.y + P.z * P.z;
      float d2 = qq + rr - 2.0f * (qx * P.x + qy * P.y + qz * P.z);
      u64 ck = ((u64)fbias(d2) << 32) | (u32)__float_as_uint(P.w);
      lane_insert3(ck, v0, v1, v2);
    }
  }

  u64 o0, o1, o2;
  knn_tail3<GR, R, NREF>(sb, cs, qx, qy, qz, qq,
      ix, iy, iz, x0, x1, y0, y1, z0, z1, gl, v0, v1, v2, o0, o1, o2);

  if (gl < 3) {
    u64 val = (gl == 0) ? o0 : ((gl == 1) ? o1 : o2);
    size_t base = ((size_t)b * Mq + q) * 3;
    oidx[base + gl] = (int)(u32)val;
    od2[base + gl] = fmaxf(funbias((u32)(val >> 32)), 0.0f);
  }
}

__device__ void knn_brute3_dev(int vbx,
    const float* __restrict__ pos, int Nref, int Mq,
    int* __restrict__ oidx, float* __restrict__ od2) {
  int b = blockIdx.y;
  int wv = threadIdx.x >> 6, lane = threadIdx.x & 63;
  int g = lane >> 4, gl = lane & 15;
  int q = vbx * 16 + wv * 4 + g;
  const float* pb = pos + (size_t)b * NFULL * 3;
  float qx = pb[q * 3 + 0], qy = pb[q * 3 + 1], qz = pb[q * 3 + 2];
  float qq = qx * qx + qy * qy + qz * qz;

  u64 v0 = ~0ull, v1 = ~0ull, v2 = ~0ull;
  for (int j = gl; j < Nref; j += 16) {
    float rx = pb[j * 3 + 0];
    float ry = pb[j * 3 + 1];
    float rz = pb[j * 3 + 2];
    float rr = rx * rx + ry * ry + rz * rz;
    float d2 = qq + rr - 2.0f * (qx * rx + qy * ry + qz * rz);
    u64 ck = ((u64)fbias(d2) << 32) | (u32)j;
    lane_insert3(ck, v0, v1, v2);
  }
  u64 o0, o1, o2;
  merge3(v0, v1, v2, o0, o1, o2);

  if (gl < 3) {
    u64 val = (gl == 0) ? o0 : ((gl == 1) ? o1 : o2);
    size_t base = ((size_t)b * Mq + q) * 3;
    oidx[base + gl] = (int)(u32)val;
    od2[base + gl] = fmaxf(funbias((u32)(val >> 32)), 0.0f);
  }
}

// ----------------------------- fused: ALL SIX kNN queries in one dispatch --
// K=16 paths use 32 lanes/query (8 q/block); K=3 use 16 lanes (16 q/block).
__global__ __launch_bounds__(256) void knn_all_kernel(
    const float* __restrict__ pos,
    const float4* __restrict__ sortedA, const int* __restrict__ csA,
    const float4* __restrict__ sortedB, const int* __restrict__ csB,
    const float4* __restrict__ sortedC, const int* __restrict__ csC,
    int* __restrict__ idx0, int* __restrict__ idx1, int* __restrict__ idx2,
    int* __restrict__ idxu0, float* __restrict__ d2u0,
    int* __restrict__ idxu1, float* __restrict__ d2u1,
    int* __restrict__ idxu2, float* __restrict__ d2u2) {
  int bx = blockIdx.x;
  if (bx < 16)         // idx2: 128 q over 512 pts (brute g32), K=16
    knn_brute16_g32_dev(bx, pos, 512, 128, idx2);
  else if (bx < 80)    // idx1: 512 q over 2048 pts, K=16 (g32)
    knn_grid16_g32_dev<8, 2, 2048>(bx - 16, pos, sortedB, csB, 513, 512, idx1);
  else if (bx < 336)   // idx0: 2048 q over 8192 pts, K=16 (g32)
    knn_grid16_g32_dev<16, 2, 8192>(bx - 80, pos, sortedA, csA, 4097, 2048, idx0);
  else if (bx < 464)   // idxu1: 2048 q over 512 pts, K=3 (gridC, per-lane)
    knn_grid_flat32_3_dev<8, 2, 512>(bx - 336, pos, sortedC, csC, 513, 2048, idxu1, d2u1);
  else if (bx < 976)   // idxu2: 8192 q over 2048 pts, K=3 (flat, per-lane)
    knn_grid_flat3_dev<8, 1, 2048>(bx - 464, pos, sortedB, csB, 513, 8192, idxu2, d2u2);
  else                 // idxu0: 512 q over 128 pts (brute, per-lane), K=3
    knn_brute3_dev(bx - 976, pos, 128, 512, idxu0, d2u0);
}

// ----------------------------------------------------- down MLP (MFMA) -----
template<int FEAT, int CIN, int CHID, int FPAD, int QB, int WAVES>
__global__ __launch_bounds__(64 * WAVES) void down_mfma_kernel(
    const float* __restrict__ pos, const float* __restrict__ xin,
    const int* __restrict__ idx,
    const short* __restrict__ W1p, const float* __restrict__ b1,
    const short* __restrict__ W2p, const float* __restrict__ b2,
    float* __restrict__ out, int n, int nprev) {
  const int KT1 = FPAD / 32, NT1 = CHID / 16;
  const int KT2 = CHID / 32, NT2 = CHID / 16;
  __shared__ short sFeat[QB][16][FPAD + 8];
  __shared__ short sH1[QB][16][CHID + 8];
  __shared__ int sIdx[QB][16];
  __shared__ float sCtr[QB][3];
  int b = blockIdx.y, q0 = blockIdx.x * QB;
  int t = threadIdx.x;
  int lane = t & 63, wv = t >> 6;
  const float* pb = pos + (size_t)b * NFULL * 3;
  const float* xb = xin + (size_t)b * nprev * CIN;
  if (t < QB * 16)
    sIdx[t >> 4][t & 15] = idx[((size_t)b * n + q0 + (t >> 4)) * 16 + (t & 15)];
  if (t < QB * 3) sCtr[t / 3][t % 3] = pb[(q0 + t / 3) * 3 + (t % 3)];
  __syncthreads();
  for (int e = t; e < QB * 16 * FPAD; e += 64 * WAVES) {
    int k = e / FPAD, c = e - k * FPAD;
    int qq = k >> 4, kk = k & 15;
    float v = 0.f;
    if (c < 3) v = pb[sIdx[qq][kk] * 3 + c] - sCtr[qq][c];
    else if (c < FEAT) v = xb[(size_t)sIdx[qq][kk] * CIN + (c - 3)];
    sFeat[qq][kk][c] = f2bf(v);
  }
  __syncthreads();

  int col = lane & 15, quad = lane >> 4;
  const bf8_t* W1t = (const bf8_t*)W1p;
  for (int nt = 2 * wv; nt < NT1; nt += 2 * WAVES) {
    f4_t acc[QB][2];
    float bb0 = b1[nt * 16 + col], bb1 = b1[nt * 16 + 16 + col];
#pragma unroll
    for (int q = 0; q < QB; ++q) {
      acc[q][0] = {bb0, bb0, bb0, bb0};
      acc[q][1] = {bb1, bb1, bb1, bb1};
    }
#pragma unroll
    for (int kt = 0; kt < KT1; ++kt) {
      bf8_t bf0 = W1t[(kt * NT1 + nt) * 64 + lane];
      bf8_t bf1 = W1t[(kt * NT1 + nt + 1) * 64 + lane];
#pragma unroll
      for (int q = 0; q < QB; ++q) {
        bf8_t a = *(const bf8_t*)&sFeat[q][col][kt * 32 + quad * 8];
        acc[q][0] = __builtin_amdgcn_mfma_f32_16x16x32_bf16(a, bf0, acc[q][0], 0, 0, 0);
        acc[q][1] = __builtin_amdgcn_mfma_f32_16x16x32_bf16(a, bf1, acc[q][1], 0, 0, 0);
      }
    }
#pragma unroll
    for (int q = 0; q < QB; ++q)
#pragma unroll
      for (int r = 0; r < 4; ++r) {
        sH1[q][quad * 4 + r][nt * 16 + col] = f2bf(fmaxf(acc[q][0][r], 0.f));
        sH1[q][quad * 4 + r][nt * 16 + 16 + col] = f2bf(fmaxf(acc[q][1][r], 0.f));
      }
  }
  __syncthreads();

  const bf8_t* W2t = (const bf8_t*)W2p;
  for (int nt = 2 * wv; nt < NT2; nt += 2 * WAVES) {
    f4_t acc[QB][2];
    float bb0 = b2[nt * 16 + col], bb1 = b2[nt * 16 + 16 + col];
#pragma unroll
    for (int q = 0; q < QB; ++q) {
      acc[q][0] = {bb0, bb0, bb0, bb0};
      acc[q][1] = {bb1, bb1, bb1, bb1};
    }
#pragma unroll
    for (int kt = 0; kt < KT2; ++kt) {
      bf8_t bf0 = W2t[(kt * NT2 + nt) * 64 + lane];
      bf8_t bf1 = W2t[(kt * NT2 + nt + 1) * 64 + lane];
#pragma unroll
      for (int q = 0; q < QB; ++q) {
        bf8_t a = *(const bf8_t*)&sH1[q][col][kt * 32 + quad * 8];
        acc[q][0] = __builtin_amdgcn_mfma_f32_16x16x32_bf16(a, bf0, acc[q][0], 0, 0, 0);
        acc[q][1] = __builtin_amdgcn_mfma_f32_16x16x32_bf16(a, bf1, acc[q][1], 0, 0, 0);
      }
    }
#pragma unroll
    for (int q = 0; q < QB; ++q) {
      float m0 = fmaxf(fmaxf(acc[q][0][0], acc[q][0][1]), fmaxf(acc[q][0][2], acc[q][0][3]));
      float m1 = fmaxf(fmaxf(acc[q][1][0], acc[q][1][1]), fmaxf(acc[q][1][2], acc[q][1][3]));
      m0 = fmaxf(m0, __shfl_xor(m0, 16, 64));
      m0 = fmaxf(m0, __shfl_xor(m0, 32, 64));
      m1 = fmaxf(m1, __shfl_xor(m1, 16, 64));
      m1 = fmaxf(m1, __shfl_xor(m1, 32, 64));
      if (lane < 16) {
        float* ob = out + ((size_t)b * n + q0 + q) * CHID;
        ob[nt * 16 + lane] = m0;
        ob[nt * 16 + 16 + lane] = m1;
      }
    }
  }
}

// -------------------------------------------- up MLP (bf16 MFMA version) ---
template<int CIN, int CPRV, int COUT, int WPB>
__global__ __launch_bounds__(64 * WPB) void up_mfma_kernel(
    const float* __restrict__ xc, int ncoarse,
    const int* __restrict__ idx3, const float* __restrict__ d23,
    const float* __restrict__ prv, const short* __restrict__ Wp,
    const float* __restrict__ bvec, float* __restrict__ out, int m) {
  const int CTOT = CIN + CPRV;
  const int KT = CTOT / 32, NT = COUT / 16;
  __shared__ short sA[16][CTOT + 8];
  __shared__ float sWt[16][3];
  __shared__ int   sIt[16][3];
  int b = blockIdx.y, q0 = blockIdx.x * 16, t = threadIdx.x;
  int lane = t & 63, wv = t >> 6;
  if (t < 16) {
    size_t base = ((size_t)b * m + q0 + t) * 3;
    float d0 = d23[base + 0], d1 = d23[base + 1], d2v = d23[base + 2];
    float w0 = 1.f / (d0 + 1e-8f), w1 = 1.f / (d1 + 1e-8f), w2 = 1.f / (d2v + 1e-8f);
    float s = w0 + w1 + w2;
    sWt[t][0] = w0 / s; sWt[t][1] = w1 / s; sWt[t][2] = w2 / s;
    sIt[t][0] = idx3[base + 0]; sIt[t][1] = idx3[base + 1]; sIt[t][2] = idx3[base + 2];
  }
  __syncthreads();
  const float* xb = xc + (size_t)b * ncoarse * CIN;
  const float* pvb = prv + ((size_t)b * m + q0) * CPRV;
  for (int e = t; e < 16 * CIN; e += 64 * WPB) {
    int p = e / CIN, c = e % CIN;
    float v = sWt[p][0] * xb[(size_t)sIt[p][0] * CIN + c]
            + sWt[p][1] * xb[(size_t)sIt[p][1] * CIN + c]
            + sWt[p][2] * xb[(size_t)sIt[p][2] * CIN + c];
    sA[p][c] = f2bf(v);
  }
  for (int e = t; e < 16 * CPRV; e += 64 * WPB) {
    int p = e / CPRV, c = e % CPRV;
    sA[p][CIN + c] = f2bf(pvb[(size_t)p * CPRV + c]);
  }
  __syncthreads();
  int col = lane & 15, quad = lane >> 4;
  const bf8_t* Wt = (const bf8_t*)Wp;
  float* ob = out + ((size_t)b * m + q0) * COUT;
  for (int nt = 2 * wv; nt < NT; nt += 2 * WPB) {
    float bb0 = bvec[nt * 16 + col], bb1 = bvec[nt * 16 + 16 + col];
    f4_t acc0 = {bb0, bb0, bb0, bb0}, acc1 = {bb1, bb1, bb1, bb1};
#pragma unroll
    for (int kt = 0; kt < KT; ++kt) {
      bf8_t a = *(const bf8_t*)&sA[col][kt * 32 + quad * 8];
      bf8_t bf0 = Wt[(kt * NT + nt) * 64 + lane];
      bf8_t bf1 = Wt[(kt * NT + nt + 1) * 64 + lane];
      acc0 = __builtin_amdgcn_mfma_f32_16x16x32_bf16(a, bf0, acc0, 0, 0, 0);
      acc1 = __builtin_amdgcn_mfma_f32_16x16x32_bf16(a, bf1, acc1, 0, 0, 0);
    }
#pragma unroll
    for (int r = 0; r < 4; ++r) {
      ob[(size_t)(quad * 4 + r) * COUT + nt * 16 + col] = fmaxf(acc0[r], 0.f);
      ob[(size_t)(quad * 4 + r) * COUT + nt * 16 + 16 + col] = fmaxf(acc1[r], 0.f);
    }
  }
}

// ------------------------------------- fused up2 + final MLP (bf16 MFMA) ---
__global__ __launch_bounds__(128) void up2f_mfma_kernel(
    const float* __restrict__ xc,
    const int* __restrict__ idx3, const float* __restrict__ d23,
    const float* __restrict__ x0, const float* __restrict__ pos0,
    const short* __restrict__ u2Wp, const float* __restrict__ u2b,
    const short* __restrict__ fW1p, const float* __restrict__ fb1,
    const short* __restrict__ fW2p, const float* __restrict__ fb2,
    float* __restrict__ out) {
  __shared__ short sA[16][168];
  __shared__ short sB[16][136];
  __shared__ float sWt[16][3];
  __shared__ int   sIt[16][3];
  int b = blockIdx.y, q0 = blockIdx.x * 16, t = threadIdx.x;
  int lane = t & 63, wv = t >> 6;
  if (t < 16) {
    size_t base = ((size_t)b * NFULL + q0 + t) * 3;
    float d0 = d23[base + 0], d1 = d23[base + 1], d2v = d23[base + 2];
    float w0 = 1.f / (d0 + 1e-8f), w1 = 1.f / (d1 + 1e-8f), w2 = 1.f / (d2v + 1e-8f);
    float s = w0 + w1 + w2;
    sWt[t][0] = w0 / s; sWt[t][1] = w1 / s; sWt[t][2] = w2 / s;
    sIt[t][0] = idx3[base + 0]; sIt[t][1] = idx3[base + 1]; sIt[t][2] = idx3[base + 2];
  }
  __syncthreads();
  const float* xb = xc + (size_t)b * 2048 * 128;
#pragma unroll
  for (int p = 0; p < 16; ++p) {
    float v = sWt[p][0] * xb[(size_t)sIt[p][0] * 128 + t]
            + sWt[p][1] * xb[(size_t)sIt[p][1] * 128 + t]
            + sWt[p][2] * xb[(size_t)sIt[p][2] * 128 + t];
    sA[p][t] = f2bf(v);
  }
  for (int e = t; e < 16 * 32; e += 128) {
    int p = e / 32, c = 128 + (e % 32);
    float v = 0.f;
    if (c < 131) v = x0[((size_t)b * NFULL + q0 + p) * 3 + (c - 128)];
    else if (c < 134) v = pos0[((size_t)b * NFULL + q0 + p) * 3 + (c - 131)];
    sA[p][c] = f2bf(v);
  }
  __syncthreads();
  int col = lane & 15, quad = lane >> 4;

  bf8_t a1[5];
#pragma unroll
  for (int kt = 0; kt < 5; ++kt)
    a1[kt] = *(const bf8_t*)&sA[col][kt * 32 + quad * 8];
  const bf8_t* W1t = (const bf8_t*)u2Wp;
  for (int nt = 2 * wv; nt < 8; nt += 4) {
    float bb0 = u2b[nt * 16 + col], bb1 = u2b[nt * 16 + 16 + col];
    f4_t acc0 = {bb0, bb0, bb0, bb0}, acc1 = {bb1, bb1, bb1, bb1};
#pragma unroll
    for (int kt = 0; kt < 5; ++kt) {
      bf8_t bf0 = W1t[(kt * 8 + nt) * 64 + lane];
      bf8_t bf1 = W1t[(kt * 8 + nt + 1) * 64 + lane];
      acc0 = __builtin_amdgcn_mfma_f32_16x16x32_bf16(a1[kt], bf0, acc0, 0, 0, 0);
      acc1 = __builtin_amdgcn_mfma_f32_16x16x32_bf16(a1[kt], bf1, acc1, 0, 0, 0);
    }
#pragma unroll
    for (int r = 0; r < 4; ++r) {
      sB[quad * 4 + r][nt * 16 + col] = f2bf(fmaxf(acc0[r], 0.f));
      sB[quad * 4 + r][nt * 16 + 16 + col] = f2bf(fmaxf(acc1[r], 0.f));
    }
  }
  __syncthreads();

  bf8_t a2[4];
#pragma unroll
  for (int kt = 0; kt < 4; ++kt)
    a2[kt] = *(const bf8_t*)&sB[col][kt * 32 + quad * 8];
  const bf8_t* W2t = (const bf8_t*)fW1p;
  for (int nt = 2 * wv; nt < 8; nt += 4) {
    float bb0 = fb1[nt * 16 + col], bb1 = fb1[nt * 16 + 16 + col];
    f4_t acc0 = {bb0, bb0, bb0, bb0}, acc1 = {bb1, bb1, bb1, bb1};
#pragma unroll
    for (int kt = 0; kt < 4; ++kt) {
      bf8_t bf0 = W2t[(kt * 8 + nt) * 64 + lane];
      bf8_t bf1 = W2t[(kt * 8 + nt + 1) * 64 + lane];
      acc0 = __builtin_amdgcn_mfma_f32_16x16x32_bf16(a2[kt], bf0, acc0, 0, 0, 0);
      acc1 = __builtin_amdgcn_mfma_f32_16x16x32_bf16(a2[kt], bf1, acc1, 0, 0, 0);
    }
#pragma unroll
    for (int r = 0; r < 4; ++r) {
      sA[quad * 4 + r][nt * 16 + col] = f2bf(fmaxf(acc0[r], 0.f));
      sA[quad * 4 + r][nt * 16 + 16 + col] = f2bf(fmaxf(acc1[r], 0.f));
    }
  }
  __syncthreads();

  bf8_t a3[4];
#pragma unroll
  for (int kt = 0; kt < 4; ++kt)
    a3[kt] = *(const bf8_t*)&sA[col][kt * 32 + quad * 8];
  const bf8_t* W3t = (const bf8_t*)fW2p;
  float* ob = out + ((size_t)b * NFULL + q0) * 128;
  for (int nt = 2 * wv; nt < 8; nt += 4) {
    float bb0 = fb2[nt * 16 + col], bb1 = fb2[nt * 16 + 16 + col];
    f4_t acc0 = {bb0, bb0, bb0, bb0}, acc1 = {bb1, bb1, bb1, bb1};
#pragma unroll
    for (int kt = 0; kt < 4; ++kt) {
      bf8_t bf0 = W3t[(kt * 8 + nt) * 64 + lane];
      bf8_t bf1 = W3t[(kt * 8 + nt + 1) * 64 + lane];
      acc0 = __builtin_amdgcn_mfma_f32_16x16x32_bf16(a3[kt], bf0, acc0, 0, 0, 0);
      acc1 = __builtin_amdgcn_mfma_f32_16x16x32_bf16(a3[kt], bf1, acc1, 0, 0, 0);
    }
#pragma unroll
    for (int r = 0; r < 4; ++r) {
      ob[(size_t)(quad * 4 + r) * 128 + nt * 16 + col] = acc0[r];
      ob[(size_t)(quad * 4 + r) * 128 + nt * 16 + 16 + col] = acc1[r];
    }
  }
}

// ------------------------------------------------------------------ launch -
extern "C" void kernel_launch(void* const* d_in, const int* in_sizes, int n_in,
                              void* d_out, int out_size, void* d_ws, size_t ws_size,
                              hipStream_t stream) {
  const float* x    = (const float*)d_in[0];
  const float* pos  = (const float*)d_in[1];
  const float* d0W1 = (const float*)d_in[2];
  const float* d0b1 = (const float*)d_in[3];
  const float* d0W2 = (const float*)d_in[4];
  const float* d0b2 = (const float*)d_in[5];
  const float* d1W1 = (const float*)d_in[6];
  const float* d1b1 = (const float*)d_in[7];
  const float* d1W2 = (const float*)d_in[8];
  const float* d1b2 = (const float*)d_in[9];
  const float* d2W1 = (const float*)d_in[10];
  const float* d2b1 = (const float*)d_in[11];
  const float* d2W2 = (const float*)d_in[12];
  const float* d2b2 = (const float*)d_in[13];
  const float* u0W  = (const float*)d_in[14];
  const float* u0b  = (const float*)d_in[15];
  const float* u1W  = (const float*)d_in[16];
  const float* u1b  = (const float*)d_in[17];
  const float* u2W  = (const float*)d_in[18];
  const float* u2b  = (const float*)d_in[19];
  const float* fW1  = (const float*)d_in[20];
  const float* fb1  = (const float*)d_in[21];
  const float* fW2  = (const float*)d_in[22];
  const float* fb2  = (const float*)d_in[23];

  char* ws = (char*)d_ws;
  float* x1    = (float*)(ws + 0);
  float* x2    = (float*)(ws + 4194304);
  float* x3    = (float*)(ws + 6291456);
  float* up0o  = (float*)(ws + 7340032);
  float* up1o  = (float*)(ws + 9437184);
  int*   idx0  = (int*)  (ws + 13631488);
  int*   idx1  = (int*)  (ws + 14155776);
  int*   idx2  = (int*)  (ws + 14286848);
  float4* sortedC = (float4*)(ws + 14319616); // 4*512*16 = 32768
  int*    csC     = (int*)   (ws + 14352384); // 4*513*4  = 8208
  int*   idxu0 = (int*)  (ws + 14843904);
  float* d2u0  = (float*)(ws + 14868480);
  int*   idxu1 = (int*)  (ws + 14893056);
  float* d2u1  = (float*)(ws + 14991360);
  int*   idxu2 = (int*)  (ws + 15089664);
  float* d2u2  = (float*)(ws + 15482880);
  short* d1W1p = (short*)(ws + 15876096);
  short* d1W2p = (short*)(ws + 15958016);
  short* d2W1p = (short*)(ws + 16089088);
  short* d2W2p = (short*)(ws + 16384000);
  short* d0W1p = (short*)(ws + 16908288);
  short* d0W2p = (short*)(ws + 16916480);
  float4* sortedA = (float4*)(ws + 16949248);  // 4*8192*16 = 524288
  int*    csA     = (int*)   (ws + 17473536);  // 4*4097*4  = 65552
  float4* sortedB = (float4*)(ws + 17539136);  // 4*2048*16 = 131072
  int*    csB     = (int*)   (ws + 17670208);  // 4*513*4   = 8208
  short* u2Wp  = (short*)(ws + 17697920);
  short* fW1p  = (short*)(ws + 17738880);
  short* fW2p  = (short*)(ws + 17771648);

  float* out = (float*)d_out;
  // Packed u0W/u1W live in the d_out main region: it is dead until the final
  // up2f_mfma_kernel writes it, and both are fully consumed before that.
  short* u0Wp = (short*)out;                       // 768*256*2 = 393216 B
  short* u1Wp = (short*)(out + 98304);             // 384*128*2 =  98304 B

  // ---- fused pre-kernel: 3 grid builds + weight packing + pos copy ----
  pre_kernel<<<dim3(516), 256, 0, stream>>>(
      pos, sortedA, csA, sortedB, csB, sortedC, csC,
      d0W1, d0W1p, d0W2, d0W2p, d1W1, d1W1p, d1W2, d1W2p,
      d2W1, d2W1p, d2W2, d2W2p, u2W, u2Wp, fW1, fW1p, fW2, fW2p,
      u0W, u0Wp, u1W, u1Wp,
      out + (size_t)BATCH * NFULL * 128);

  // ---- ALL kNN queries in one dispatch (deps: pos + grids only) ----
  knn_all_kernel<<<dim3(1008, BATCH), 256, 0, stream>>>(
      pos, sortedA, csA, sortedB, csB, sortedC, csC,
      idx0, idx1, idx2,
      idxu0, d2u0, idxu1, d2u1, idxu2, d2u2);

  // ---- down path ----
  down_mfma_kernel<6, 3, 128, 32, 4, 4><<<dim3(512, BATCH), 256, 0, stream>>>(
      pos, x, idx0, d0W1p, d0b1, d0W2p, d0b2, x1, 2048, 8192);
  down_mfma_kernel<131, 128, 256, 160, 4, 8><<<dim3(128, BATCH), 512, 0, stream>>>(
      pos, x1, idx1, d1W1p, d1b1, d1W2p, d1b2, x2, 512, 2048);
  down_mfma_kernel<259, 256, 512, 288, 2, 8><<<dim3(64, BATCH), 512, 0, stream>>>(
      pos, x2, idx2, d2W1p, d2b1, d2W2p, d2b2, x3, 128, 512);

  // ---- up path ----
  up_mfma_kernel<512, 256, 256, 4><<<dim3(32, BATCH), 256, 0, stream>>>(
      x3, 128, idxu0, d2u0, x2, u0Wp, u0b, up0o, 512);
  up_mfma_kernel<256, 128, 128, 2><<<dim3(128, BATCH), 128, 0, stream>>>(
      up0o, 512, idxu1, d2u1, x1, u1Wp, u1b, up1o, 2048);
  up2f_mfma_kernel<<<dim3(512, BATCH), 128, 0, stream>>>(
      up1o, idxu2, d2u2, x, pos, u2Wp, u2b, fW1p, fb1, fW2p, fb2, out);
}